// Round 7
// baseline (1395.622 us; speedup 1.0000x reference)
//
#include <hip/hip_runtime.h>
#include <math.h>

#define BB 32
#define NN 4096
#define NPp 256
#define NSs 64
#define KC 20

typedef unsigned long long ull;
typedef unsigned short u16;
typedef short bf16x8 __attribute__((ext_vector_type(8)));
typedef float f32x4 __attribute__((ext_vector_type(4)));
typedef int i32x4 __attribute__((ext_vector_type(4)));

__device__ __forceinline__ float fma4(const float4 w, const float4 v, float a){
  a = fmaf(w.x, v.x, a); a = fmaf(w.y, v.y, a);
  a = fmaf(w.z, v.z, a); a = fmaf(w.w, v.w, a); return a;
}
__device__ __forceinline__ float4 fma4s(const float4 w, float s, float4 a){
  a.x = fmaf(w.x, s, a.x); a.y = fmaf(w.y, s, a.y);
  a.z = fmaf(w.z, s, a.z); a.w = fmaf(w.w, s, a.w); return a;
}
__device__ __forceinline__ float4 max4(float4 a, float4 b){
  a.x = fmaxf(a.x, b.x); a.y = fmaxf(a.y, b.y);
  a.z = fmaxf(a.z, b.z); a.w = fmaxf(a.w, b.w); return a;
}
__device__ __forceinline__ float4 add4(float4 a, float4 b){
  a.x += b.x; a.y += b.y; a.z += b.z; a.w += b.w; return a;
}

template<int C>
__device__ __forceinline__ int dpp_i(int x){
  return __builtin_amdgcn_update_dpp(x, x, C, 0xf, 0xf, false);
}

// split fp32 -> bf16 hi + bf16 lo (truncating; v - hi is exact in fp32)
__device__ __host__ __forceinline__ void bf16_split(float v, unsigned& h16, unsigned& l16){
  unsigned bits = __float_as_uint(v);
  h16 = bits >> 16;
  float hf = __uint_as_float(h16 << 16);
  l16 = __float_as_uint(v - hf) >> 16;
}

// ---------------- unified weight prep (all transposes/splits in one kernel) ----------------
__global__ void k_wprep(const float* __restrict__ t0, const float* __restrict__ t1,
                        const float* __restrict__ d0, const float* __restrict__ d1,
                        const float* __restrict__ d2, const float* __restrict__ saw1,
                        float* __restrict__ waT0, float* __restrict__ wbT0,
                        float* __restrict__ wt_t1,
                        float* __restrict__ waD0, float* __restrict__ wbD0,
                        float* __restrict__ waD1, float* __restrict__ wbD1,
                        float* __restrict__ waD2, float* __restrict__ wbD2,
                        float* __restrict__ w1T){
  int i = blockIdx.x*256 + threadIdx.x;
  if (i < 8384){                       // t_ec_w0: [64][262] -> A/B [131][64]
    int m = i >> 6;
    int c = i & 63;
    float bb = t0[(size_t)c*262 + m];
    float dd = t0[(size_t)c*262 + 131 + m];
    waT0[i] = __fsub_rn(bb, dd); wbT0[i] = dd;
    return;
  }
  i -= 8384;
  if (i < 8192){                       // t_ec_w1: [128][64] -> [64][128]
    int m = i >> 7, c = i & 127;
    wt_t1[i] = t1[(size_t)c*64 + m];
    return;
  }
  i -= 8192;
  if (i < 16768){                      // dg_ec_w0: [128][262] -> A/B [131][128]
    int m = i >> 7, c = i & 127;
    float bb = d0[(size_t)c*262 + m];
    float dd = d0[(size_t)c*262 + 131 + m];
    waD0[i] = __fsub_rn(bb, dd); wbD0[i] = dd;
    return;
  }
  i -= 16768;
  if (i < 32768){                      // dg_ec_w1: [256][256] -> A/B [128][256]
    int m = i >> 8, c = i & 255;
    float bb = d1[(size_t)c*256 + m];
    float dd = d1[(size_t)c*256 + 128 + m];
    waD1[i] = __fsub_rn(bb, dd); wbD1[i] = dd;
    return;
  }
  i -= 32768;
  if (i < 131072){                     // dg_ec_w2: [512][512] -> A/B [256][512]
    int m = i >> 9, c = i & 511;
    float bb = d2[(size_t)c*512 + m];
    float dd = d2[(size_t)c*512 + 256 + m];
    waD2[i] = __fsub_rn(bb, dd); wbD2[i] = dd;
    return;
  }
  i -= 131072;
  if (i < 4096){                       // sa_w1: [64][64] -> w1T[m][c] (legacy, unused)
    int m = i >> 6, c = i & 63;
    w1T[i] = saw1[(size_t)c*64 + m];
  }
}

// ---------------- SA MFMA weight prep: split-bf16 fragments in lane order ----------------
__global__ void k_wprep2(const float* __restrict__ w0, const float* __restrict__ w1,
                         const float* __restrict__ w2,
                         float* __restrict__ w0f, u16* __restrict__ w1fh, u16* __restrict__ w1fl,
                         u16* __restrict__ w2fh, u16* __restrict__ w2fl){
  int i = blockIdx.x*256 + threadIdx.x;
  if (i < 4096){                       // w0f: [kt][lane][e][4] (xyz + pad)
    int kt = i >> 11, r = i & 2047;
    int ln = r >> 5, ee = r & 31;
    int e = ee >> 2, j = ee & 3;
    int k = kt*32 + 8*(ln>>4) + e;
    w0f[i] = (j < 3) ? w0[k*3 + j] : 0.0f;
    return;
  }
  i -= 4096;
  if (i < 4096){                       // w1 frags: [ct*2+kt][lane][e], B[k][c]=w1[c][k]
    int e = i & 7, ln = (i >> 3) & 63, q = i >> 9;
    int kt = q & 1, ct = q >> 1;
    int k = kt*32 + 8*(ln>>4) + e;
    int c = ct*16 + (ln & 15);
    unsigned h16, l16; bf16_split(w1[(size_t)c*64 + k], h16, l16);
    w1fh[i] = (u16)h16; w1fl[i] = (u16)l16;
    return;
  }
  i -= 4096;
  if (i < 8192){                       // w2 frags: [c2t*2+kt][lane][e], B[k][c2]=w2[c2][k]
    int e = i & 7, ln = (i >> 3) & 63, q = i >> 9;
    int kt = q & 1, c2t = q >> 1;
    int k = kt*32 + 8*(ln>>4) + e;
    int c2 = c2t*16 + (ln & 15);
    unsigned h16, l16; bf16_split(w2[(size_t)c2*64 + k], h16, l16);
    w2fh[i] = (u16)h16; w2fl[i] = (u16)l16;
  }
}

// ---------------- transpose + point norms ----------------
__global__ void k_prep(const float* __restrict__ pts, float* __restrict__ xyz, float* __restrict__ xnrm){
  int i = blockIdx.x*256 + threadIdx.x;
  if (i >= BB*NN) return;
  int b = i >> 12, n = i & (NN-1);
  float X = pts[(b*3+0)*NN + n];
  float Y = pts[(b*3+1)*NN + n];
  float Z = pts[(b*3+2)*NN + n];
  xyz[i*3+0]=X; xyz[i*3+1]=Y; xyz[i*3+2]=Z;
  xnrm[i] = __fadd_rn(__fadd_rn(__fmul_rn(X,X), __fmul_rn(Y,Y)), __fmul_rn(Z,Z));
}

// ---------------- farthest point sampling: float4 LDS point table ----------------
// Round-6 postmortem: the compiler rematerializes point coords from LDS every iteration
// (px/py/pz provably equal the staged LDS copies), costing 96 scalar ds_read_b32/iter.
// Fix the LDS path instead of fighting the allocator: pack points as float4 (x,y,z,pad)
// so each q is ONE ds_read_b128 (32/iter, 3x fewer LDS instructions), and the winner
// lookup is one broadcast b128. If the compiler instead promotes the 32 float4 loads to
// registers (budget unlocked by launch_bounds(128,1)), that is strictly better still.
// Arithmetic sequence and tie-break unchanged -> bit-identical FPS selections.
__global__ __launch_bounds__(128, 1) void k_fps(const float* __restrict__ xyz, float* __restrict__ new_xyz){
  __shared__ __align__(16) float4 p4[NN];
  __shared__ __align__(16) ull wkey[2][2];
  int b = blockIdx.x, t = threadIdx.x;
  int w = t >> 6, lane = t & 63;
  float dist[32];
#pragma unroll
  for (int q = 0; q < 32; ++q){
    int j = q*128 + t;
    const float* p = xyz + ((size_t)b*NN + j)*3;
    p4[j] = make_float4(p[0], p[1], p[2], 0.0f);
    dist[q] = __builtin_inff();
  }
  const float* p0 = xyz + (size_t)b*NN*3;
  float Px = p0[0], Py = p0[1], Pz = p0[2];
  __syncthreads();                      // LDS point stage visible to both waves
  for (int it = 0; it < NPp; ++it){
    if (t == 0){                        // output BEFORE update: out[it] = current P
      float* o = new_xyz + ((size_t)b*NPp + it)*3;
      o[0] = Px; o[1] = Py; o[2] = Pz;
    }
    float bv = -1.0f; int bj = 0;
#pragma unroll
    for (int q = 0; q < 32; ++q){
      float4 v = p4[q*128 + t];
      float dx = __fsub_rn(v.x, Px);
      float dy = __fsub_rn(v.y, Py);
      float dz = __fsub_rn(v.z, Pz);
      float dd = __fadd_rn(__fadd_rn(__fmul_rn(dx,dx), __fmul_rn(dy,dy)), __fmul_rn(dz,dz));
      float dm = fminf(dist[q], dd);
      dist[q] = dm;
      if (dm > bv){ bv = dm; bj = q*128 + t; }
    }
    ull bk = ((ull)__float_as_uint(bv) << 32) | (unsigned)(4095 - bj);
    // wave reduce to lane63 (key only)
#define FPS_STAGE(C) { \
    unsigned ol = (unsigned)dpp_i<C>((int)(unsigned)bk); \
    unsigned oh = (unsigned)dpp_i<C>((int)(unsigned)(bk >> 32)); \
    ull ok = ((ull)oh << 32) | ol; \
    if (ok > bk) bk = ok; }
    FPS_STAGE(0x111) FPS_STAGE(0x112) FPS_STAGE(0x114) FPS_STAGE(0x118)
    FPS_STAGE(0x142) FPS_STAGE(0x143)
#undef FPS_STAGE
    int par = it & 1;
    if (lane == 63) wkey[par][w] = bk;
    __syncthreads();
    ull k0 = wkey[par][0], k1 = wkey[par][1];
    ull kw = (k0 > k1) ? k0 : k1;
    int idx = 4095 - (int)(unsigned)(kw & 0xFFFFFFFFu);
    float4 wv = p4[idx];
    Px = wv.x; Py = wv.y; Pz = wv.z;
  }
}

// ---------------- ball query + SA convs + maxpool: MFMA split-bf16 version ----------------
__global__ __launch_bounds__(64) void k_sa(const float* __restrict__ pts,
    const float* __restrict__ xyz, const float* __restrict__ xnrm,
    const float* __restrict__ new_xyz, const float* __restrict__ w0f,
    const u16* __restrict__ w1fh, const u16* __restrict__ w1fl,
    const u16* __restrict__ w2fh, const u16* __restrict__ w2fl,
    float* __restrict__ feat, float* __restrict__ x131){
  __shared__ __align__(16) u16 hh[64*64];
  __shared__ __align__(16) u16 hl[64*64];
  __shared__ int gw[64];
  int bi = blockIdx.x;
  int lane = threadIdx.x;
  int b = bi >> 8;
  const float* q = new_xyz + (size_t)bi*3;
  float qx=q[0], qy=q[1], qz=q[2];
  float nq = __fadd_rn(__fadd_rn(__fmul_rn(qx,qx), __fmul_rn(qy,qy)), __fmul_rn(qz,qz));
  // ball query: no early exit (removes the control dependency; all loads pipeline)
  const float* pX = pts + (size_t)(b*3+0)*NN;
  const float* pY = pts + (size_t)(b*3+1)*NN;
  const float* pZ = pts + (size_t)(b*3+2)*NN;
  int cnt = 0;
  for (int base = 0; base < NN; base += 256){
#pragma unroll
    for (int u = 0; u < 4; ++u){
      int j = base + u*64 + lane;
      float X = pX[j], Y = pY[j], Z = pZ[j];
      float dot = __fadd_rn(__fadd_rn(__fmul_rn(qx,X), __fmul_rn(qy,Y)), __fmul_rn(qz,Z));
      float d2 = __fsub_rn(__fadd_rn(nq, xnrm[b*NN + j]), __fmul_rn(2.0f, dot));
      bool inb = d2 < 0.04f;
      unsigned long long m = __ballot(inb);
      int pos = cnt + (int)__popcll(m & ((1ull << lane) - 1ull));
      if (inb && pos < NSs) gw[pos] = j;
      cnt += (int)__popcll(m);
    }
  }
  int g0 = gw[0];
  if (lane >= cnt) gw[lane] = g0;
  // own sample point (lane = sample), relative to query
  int gj = gw[lane];
  const float* pp = xyz + ((size_t)b*NN + gj)*3;
  float px = pp[0]-qx, py = pp[1]-qy, pz = pp[2]-qz;
  // broadcast sample coords for each s-tile: lane needs sample s = (lane&15)+16t
  int col = lane & 15, g = lane >> 4;
  float sxv[4], syv[4], szv[4];
#pragma unroll
  for (int t2 = 0; t2 < 4; ++t2){
    int src = col + 16*t2;
    sxv[t2] = __shfl(px, src);
    syv[t2] = __shfl(py, src);
    szv[t2] = __shfl(pz, src);
  }
  // h0 A-fragments built directly in registers: elem e holds h0[s][k=kt*32+8g+e]
  i32x4 ah0[4][2], al0[4][2];
#pragma unroll
  for (int kt = 0; kt < 2; ++kt){
    float4 wrow[8];
    const float4* wp = (const float4*)(w0f + (size_t)(kt*64 + lane)*32);
#pragma unroll
    for (int e = 0; e < 8; ++e) wrow[e] = wp[e];
#pragma unroll
    for (int t2 = 0; t2 < 4; ++t2){
      unsigned hu[8], lu[8];
#pragma unroll
      for (int e = 0; e < 8; ++e){
        float a = fmaf(wrow[e].z, szv[t2], fmaf(wrow[e].y, syv[t2], wrow[e].x*sxv[t2]));
        a = fmaxf(a, 0.0f);
        bf16_split(a, hu[e], lu[e]);
      }
      i32x4 H, L;
#pragma unroll
      for (int j2 = 0; j2 < 4; ++j2){
        H[j2] = (int)(hu[2*j2] | (hu[2*j2+1] << 16));
        L[j2] = (int)(lu[2*j2] | (lu[2*j2+1] << 16));
      }
      ah0[t2][kt] = H; al0[t2][kt] = L;
    }
  }
  // conv2 via MFMA: D[s][c] = sum_k h0[s][k] * W1[k][c]; relu; split; store to swizzled LDS
#pragma unroll
  for (int ct = 0; ct < 4; ++ct){
    bf16x8 bh[2], bl[2];
#pragma unroll
    for (int kt = 0; kt < 2; ++kt){
      bh[kt] = *(const bf16x8*)(w1fh + (size_t)((ct*2+kt)*64 + lane)*8);
      bl[kt] = *(const bf16x8*)(w1fl + (size_t)((ct*2+kt)*64 + lane)*8);
    }
#pragma unroll
    for (int t2 = 0; t2 < 4; ++t2){
      f32x4 acc = {0.f,0.f,0.f,0.f};
#pragma unroll
      for (int kt = 0; kt < 2; ++kt){
        bf16x8 Ah = __builtin_bit_cast(bf16x8, ah0[t2][kt]);
        bf16x8 Al = __builtin_bit_cast(bf16x8, al0[t2][kt]);
        acc = __builtin_amdgcn_mfma_f32_16x16x32_bf16(Ah, bh[kt], acc, 0, 0, 0);
        acc = __builtin_amdgcn_mfma_f32_16x16x32_bf16(Ah, bl[kt], acc, 0, 0, 0);
        acc = __builtin_amdgcn_mfma_f32_16x16x32_bf16(Al, bh[kt], acc, 0, 0, 0);
      }
#pragma unroll
      for (int r = 0; r < 4; ++r){
        float v = fmaxf(acc[r], 0.0f);           // relu(h1)
        int s = 16*t2 + 4*g + r;                 // D row = sample (m89-verified layout)
        int cc = ct*16 + col;                    // D col = channel
        int idx = s*64 + (cc ^ ((s & 7) << 3));  // XOR swizzle, bank-balanced
        unsigned h16, l16; bf16_split(v, h16, l16);
        hh[idx] = (u16)h16; hl[idx] = (u16)l16;
      }
    }
  }
  // conv3 A-fragments from LDS (same swizzle; 8 consecutive u16 stay contiguous)
  bf16x8 a1h[4][2], a1l[4][2];
#pragma unroll
  for (int t2 = 0; t2 < 4; ++t2){
    int s = col + 16*t2;
    int sw = (s & 7) << 3;
#pragma unroll
    for (int kt = 0; kt < 2; ++kt){
      int k0 = kt*32 + 8*g;
      int idx = s*64 + (k0 ^ sw);
      a1h[t2][kt] = *(const bf16x8*)(hh + idx);
      a1l[t2][kt] = *(const bf16x8*)(hl + idx);
    }
  }
  // conv3 + samplewise maxpool per 16-channel tile
#pragma unroll
  for (int c2t = 0; c2t < 8; ++c2t){
    bf16x8 bh2[2], bl2[2];
#pragma unroll
    for (int kt = 0; kt < 2; ++kt){
      bh2[kt] = *(const bf16x8*)(w2fh + (size_t)((c2t*2+kt)*64 + lane)*8);
      bl2[kt] = *(const bf16x8*)(w2fl + (size_t)((c2t*2+kt)*64 + lane)*8);
    }
    float mx = 0.0f;                             // relu folded into max (values >= 0)
#pragma unroll
    for (int t2 = 0; t2 < 4; ++t2){
      f32x4 acc = {0.f,0.f,0.f,0.f};
#pragma unroll
      for (int kt = 0; kt < 2; ++kt){
        acc = __builtin_amdgcn_mfma_f32_16x16x32_bf16(a1h[t2][kt], bh2[kt], acc, 0, 0, 0);
        acc = __builtin_amdgcn_mfma_f32_16x16x32_bf16(a1h[t2][kt], bl2[kt], acc, 0, 0, 0);
        acc = __builtin_amdgcn_mfma_f32_16x16x32_bf16(a1l[t2][kt], bh2[kt], acc, 0, 0, 0);
      }
      mx = fmaxf(mx, fmaxf(fmaxf(acc[0], acc[1]), fmaxf(acc[2], acc[3])));
    }
    mx = fmaxf(mx, __shfl_xor(mx, 16));
    mx = fmaxf(mx, __shfl_xor(mx, 32));
    if (lane < 16){
      int c = c2t*16 + lane;
      feat[(size_t)bi*128 + c] = mx;
      x131[(size_t)bi*132 + c] = mx;
    }
  }
  if (lane < 3) x131[(size_t)bi*132 + 128 + lane] = (lane==0)?qx:((lane==1)?qy:qz);
}

// ---------------- kNN: distances in registers, u64-DPP selection, no selection LDS ----------------
template<int CIN>
__global__ __launch_bounds__(512) void k_knn3(const float* __restrict__ xT,
    const float* __restrict__ nrm, int* __restrict__ idxo){
  __shared__ __align__(16) float sch[16*256];
  int bi = blockIdx.x, t = threadIdx.x;
  int w = t >> 6, lane = t & 63;
  int b = bi >> 5;
  int coli = (bi & 31)*8 + w;
  const float* xb = xT + (size_t)b*CIN*256;
  float d0=0.f, d1=0.f, d2=0.f, d3=0.f;
  for (int m0 = 0; m0 < CIN; m0 += 16){
    int mc = (CIN - m0 < 16) ? (CIN - m0) : 16;
    for (int i = t; i < mc*64; i += 512){
      int mm = i >> 6, c4 = i & 63;
      *(float4*)(sch + mm*256 + c4*4) = *(const float4*)(xb + (size_t)(m0+mm)*256 + c4*4);
    }
    __syncthreads();
    for (int mm = 0; mm < mc; ++mm){
      float xm = sch[mm*256 + coli];
      float4 v = *(const float4*)(sch + mm*256 + 4*lane);
      d0 = fmaf(v.x, xm, d0); d1 = fmaf(v.y, xm, d1);
      d2 = fmaf(v.z, xm, d2); d3 = fmaf(v.w, xm, d3);
    }
    __syncthreads();
  }
  float ni = nrm[b*256 + coli];
  float4 dv;
  {
    int j0 = 4*lane;
    dv.x = __fsub_rn(__fadd_rn(ni, nrm[b*256 + j0+0]), __fmul_rn(2.0f, d0));
    dv.y = __fsub_rn(__fadd_rn(ni, nrm[b*256 + j0+1]), __fmul_rn(2.0f, d1));
    dv.z = __fsub_rn(__fadd_rn(ni, nrm[b*256 + j0+2]), __fmul_rn(2.0f, d2));
    dv.w = __fsub_rn(__fadd_rn(ni, nrm[b*256 + j0+3]), __fmul_rn(2.0f, d3));
  }
  for (int r = 0; r < KC; ++r){
    float bv = 3.4e38f; int bj = NPp;
    if (dv.x < bv){ bv = dv.x; bj = 4*lane+0; }
    if (dv.y < bv){ bv = dv.y; bj = 4*lane+1; }
    if (dv.z < bv){ bv = dv.z; bj = 4*lane+2; }
    if (dv.w < bv){ bv = dv.w; bj = 4*lane+3; }
    unsigned xf = __float_as_uint(bv);
    xf = (xf & 0x80000000u) ? ~xf : (xf | 0x80000000u);
    ull key = ((ull)xf << 32) | (unsigned)bj;
#define KN_STAGE(C) { \
    unsigned ol = (unsigned)dpp_i<C>((int)(unsigned)key); \
    unsigned oh = (unsigned)dpp_i<C>((int)(unsigned)(key >> 32)); \
    ull ok = ((ull)oh << 32) | ol; \
    if (ok < key) key = ok; }
    KN_STAGE(0x111) KN_STAGE(0x112) KN_STAGE(0x114) KN_STAGE(0x118)
    KN_STAGE(0x142) KN_STAGE(0x143)
#undef KN_STAGE
    int bjw = __builtin_amdgcn_readlane((int)(unsigned)key, 63);
    if (lane == 0) idxo[((size_t)b*256 + coli)*KC + r] = bjw;
    if ((bjw >> 2) == lane){
      int e = bjw & 3;
      if      (e == 0) dv.x = 3.0e38f;
      else if (e == 1) dv.y = 3.0e38f;
      else if (e == 2) dv.z = 3.0e38f;
      else             dv.w = 3.0e38f;
    }
  }
}

// ---------------- per-point dual GEMM + fused xT transpose + fused norms ----------------
template<int CIN, int COUT, int T>
__global__ __launch_bounds__(T) void k_gab(const float* __restrict__ x, int xstride,
    const float* __restrict__ wA, const float* __restrict__ wB,
    float* __restrict__ A, float* __restrict__ B, float* __restrict__ xT,
    float* __restrict__ nrm){
  constexpr int PC  = CIN + 1;
  constexpr int G   = COUT/4;
  constexpr int RS  = T/G;
  constexpr int RPT = 16/RS;
  __shared__ float xsh[16*PC];
  int bi = blockIdx.x, t = threadIdx.x;
  int g = t % G, rs = t / G;
  int i0 = bi*16;
  for (int i = t; i < 16*CIN; i += T){
    int r = i / CIN, m = i - r*CIN;
    xsh[r*PC + m] = x[(size_t)(i0+r)*xstride + m];
  }
  __syncthreads();
  {
    int bb = i0 >> 8, col0 = i0 & 255;
    float* xTb = xT + (size_t)bb*CIN*256 + col0;
    for (int i = t; i < 16*CIN; i += T){
      int m = i >> 4, r = i & 15;
      xTb[m*256 + r] = xsh[r*PC + m];
    }
  }
  if (t < 16){
    const float* xr = xsh + t*PC;
    float a = 0.0f;
    for (int m = 0; m < CIN; ++m) a = __fadd_rn(a, __fmul_rn(xr[m], xr[m]));
    nrm[i0 + t] = a;
  }
  float4 accA[RPT], accB[RPT];
#pragma unroll
  for (int rr = 0; rr < RPT; ++rr){
    accA[rr] = make_float4(0.f,0.f,0.f,0.f);
    accB[rr] = make_float4(0.f,0.f,0.f,0.f);
  }
  for (int m = 0; m < CIN; ++m){
    float4 wa = *(const float4*)(wA + (size_t)m*COUT + 4*g);
    float4 wb = *(const float4*)(wB + (size_t)m*COUT + 4*g);
#pragma unroll
    for (int rr = 0; rr < RPT; ++rr){
      float xv = xsh[(rs + rr*RS)*PC + m];
      accA[rr] = fma4s(wa, xv, accA[rr]);
      accB[rr] = fma4s(wb, xv, accB[rr]);
    }
  }
#pragma unroll
  for (int rr = 0; rr < RPT; ++rr){
    int r = i0 + rs + rr*RS;
    *(float4*)(A + (size_t)r*COUT + 4*g) = accA[rr];
    *(float4*)(B + (size_t)r*COUT + 4*g) = accB[rr];
  }
}

// ---------------- edge epilogue: out[i][c] = max_k relu(A[i][c] + B[j_ik][c]) ----------------
template<int COUT>
__global__ __launch_bounds__(256) void k_emax(const float* __restrict__ A, const float* __restrict__ Bm,
    const int* __restrict__ idx, float* __restrict__ out){
  constexpr int GT = COUT/4;
  constexpr int NC = 256/GT;
  __shared__ int js[NC*KC];
  int bi = blockIdx.x, t = threadIdx.x;
  int li = t / GT, c4 = (t % GT)*4;
  int ci = bi*NC + li;
  int rb = (ci >> 8) << 8;
  if (t < NC*KC) js[t] = idx[(size_t)bi*NC*KC + t];
  __syncthreads();
  float4 a = *(const float4*)(A + (size_t)ci*COUT + c4);
  float4 p = make_float4(0.f,0.f,0.f,0.f);
#pragma unroll
  for (int k = 0; k < KC; ++k){
    int j = js[li*KC + k];
    float4 b = *(const float4*)(Bm + (size_t)(rb + j)*COUT + c4);
    p = max4(p, add4(a, b));
  }
  *(float4*)(out + (size_t)ci*COUT + c4) = p;
}

// ---------------- T-Net edge: h0 = relu(A0+B0) then 64->128 conv + k-maxpool ----------------
__global__ __launch_bounds__(128) void k_tedge3(const float* __restrict__ A0, const float* __restrict__ B0,
    const int* __restrict__ idx, const float* __restrict__ wt1, float* __restrict__ out){
  __shared__ __align__(16) float h0s[20*68];
  __shared__ __align__(16) float smax[4*128];
  __shared__ int js[KC];
  int bi = blockIdx.x, t = threadIdx.x;
  int cg = t & 31, kg = t >> 5, k0 = kg*5;
  int rb = (bi >> 8) << 8;
  if (t < KC) js[t] = idx[(size_t)bi*KC + t];
  __syncthreads();
  for (int i = t; i < 20*64; i += 128){
    int k = i >> 6, c = i & 63;
    float v = A0[(size_t)bi*64 + c] + B0[(size_t)(rb + js[k])*64 + c];
    h0s[k*68 + c] = fmaxf(v, 0.0f);
  }
  __syncthreads();
  float4 b2[5];
#pragma unroll
  for (int kk = 0; kk < 5; ++kk) b2[kk] = make_float4(0.f,0.f,0.f,0.f);
  for (int m4 = 0; m4 < 16; ++m4){
    float4 e[5];
#pragma unroll
    for (int kk = 0; kk < 5; ++kk) e[kk] = *(const float4*)(h0s + (k0+kk)*68 + 4*m4);
#pragma unroll
    for (int mm = 0; mm < 4; ++mm){
      float4 w = *(const float4*)(wt1 + (4*m4+mm)*128 + 4*cg);
#pragma unroll
      for (int kk = 0; kk < 5; ++kk){
        float ev = (mm==0)?e[kk].x:((mm==1)?e[kk].y:((mm==2)?e[kk].z:e[kk].w));
        b2[kk] = fma4s(w, ev, b2[kk]);
      }
    }
  }
  float4 p = make_float4(0.f,0.f,0.f,0.f);
#pragma unroll
  for (int kk = 0; kk < 5; ++kk) p = max4(p, b2[kk]);
  *(float4*)(smax + kg*128 + 4*cg) = p;
  __syncthreads();
  if (kg == 0){
    float4 r = *(const float4*)(smax + 4*cg);
#pragma unroll
    for (int g = 1; g < 4; ++g) r = max4(r, *(const float4*)(smax + g*128 + 4*cg));
    *(float4*)(out + (size_t)bi*128 + 4*cg) = r;
  }
}

// ---------------- T-Net 128->1024 + pool: 8 point-chunks, atomicMax combine ----------------
__global__ __launch_bounds__(128) void k_tpool(const float* __restrict__ h, const float* __restrict__ W,
    float* __restrict__ g1024){
  int b = blockIdx.x, t = threadIdx.x;
  int c = blockIdx.y*128 + t;
  int i0 = blockIdx.z*32;
  float4 w[32];
#pragma unroll
  for (int qq = 0; qq < 32; ++qq) w[qq] = *(const float4*)(W + (size_t)c*128 + 4*qq);
  const float* hb = h + (size_t)b*NPp*128;
  float mx = 0.0f;
  for (int i = i0; i < i0 + 32; ++i){
    const float4* hr = (const float4*)(hb + (size_t)i*128);
    float a = 0.0f;
#pragma unroll
    for (int qq = 0; qq < 32; ++qq) a = fma4(w[qq], hr[qq], a);
    mx = fmaxf(mx, a);
  }
  atomicMax((int*)(g1024 + (size_t)b*1024 + c), __float_as_int(mx));
}

// ---------------- T-Net MLP + 3x3 transform applied to new_xyz ----------------
__global__ __launch_bounds__(256) void k_trest(const float* __restrict__ g1024,
    const float* __restrict__ Wg0, const float* __restrict__ Wg1,
    const float* __restrict__ Wl, const float* __restrict__ bl,
    const float* __restrict__ new_xyz, float* __restrict__ x131){
  __shared__ __align__(16) float g1[1024];
  __shared__ __align__(16) float g5[512];
  __shared__ __align__(16) float g2[256];
  __shared__ float tm[12];
  int b = blockIdx.x, t = threadIdx.x;
  for (int m = t; m < 1024; m += 256) g1[m] = g1024[(size_t)b*1024 + m];
  __syncthreads();
#pragma unroll
  for (int cc = 0; cc < 2; ++cc){
    int c = t + cc*256;
    const float4* wr = (const float4*)(Wg0 + (size_t)c*1024);
    const float4* gv = (const float4*)g1;
    float a = 0.0f;
    for (int qq = 0; qq < 256; ++qq) a = fma4(wr[qq], gv[qq], a);
    g5[c] = fmaxf(a, 0.0f);
  }
  __syncthreads();
  {
    const float4* wr = (const float4*)(Wg1 + (size_t)t*512);
    const float4* gv = (const float4*)g5;
    float a = 0.0f;
    for (int qq = 0; qq < 128; ++qq) a = fma4(wr[qq], gv[qq], a);
    g2[t] = fmaxf(a, 0.0f);
  }
  __syncthreads();
  if (t < 9){
    const float4* wr = (const float4*)(Wl + (size_t)t*256);
    const float4* gv = (const float4*)g2;
    float a = 0.0f;
#pragma unroll
    for (int qq = 0; qq < 64; ++qq) a = fma4(wr[qq], gv[qq], a);
    a += bl[t];
    if (t == 0 || t == 4 || t == 8) a += 1.0f;
    tm[t] = a;
  }
  __syncthreads();
  {
    const float* nx = new_xyz + ((size_t)b*NPp + t)*3;
    float X = nx[0], Y = nx[1], Z = nx[2];
#pragma unroll
    for (int i = 0; i < 3; ++i){
      float v = __fadd_rn(__fadd_rn(__fmul_rn(tm[i*3+0], X), __fmul_rn(tm[i*3+1], Y)), __fmul_rn(tm[i*3+2], Z));
      x131[((size_t)b*NPp + t)*132 + 128 + i] = v;
    }
  }
}

// ---------------- 896->128 conv + global max pool (atomicMax; poison is negative int) ----------------
__global__ __launch_bounds__(128) void k_dgl(const float* __restrict__ f1, const float* __restrict__ f2,
    const float* __restrict__ f3, const float* __restrict__ W, float* __restrict__ g128){
  int b = blockIdx.x, t = threadIdx.x;
  int i0 = blockIdx.y * 16;
  const float* wr = W + (size_t)t*896;
  float acc[16];
#pragma unroll
  for (int ii = 0; ii < 16; ++ii) acc[ii] = 0.0f;
  for (int q = 0; q < 32; ++q){
    float4 w = *(const float4*)(wr + 4*q);
#pragma unroll
    for (int ii = 0; ii < 16; ++ii){
      float4 v = *(const float4*)(f1 + ((size_t)b*NPp + i0 + ii)*128 + 4*q);
      acc[ii] = fma4(w, v, acc[ii]);
    }
  }
  for (int q = 0; q < 64; ++q){
    float4 w = *(const float4*)(wr + 128 + 4*q);
#pragma unroll
    for (int ii = 0; ii < 16; ++ii){
      float4 v = *(const float4*)(f2 + ((size_t)b*NPp + i0 + ii)*256 + 4*q);
      acc[ii] = fma4(w, v, acc[ii]);
    }
  }
  for (int q = 0; q < 128; ++q){
    float4 w = *(const float4*)(wr + 384 + 4*q);
#pragma unroll
    for (int ii = 0; ii < 16; ++ii){
      float4 v = *(const float4*)(f3 + ((size_t)b*NPp + i0 + ii)*512 + 4*q);
      acc[ii] = fma4(w, v, acc[ii]);
    }
  }
#pragma unroll
  for (int ii = 0; ii < 16; ++ii){
    float v = fmaxf(acc[ii], 0.0f);
    atomicMax((int*)(g128 + (size_t)b*128 + t), __float_as_int(v));
  }
}

// ---------------- classifier head ----------------
__global__ __launch_bounds__(256) void k_final(const float* __restrict__ g128,
    const float* __restrict__ W0, const float* __restrict__ W1,
    const float* __restrict__ Wc, const float* __restrict__ bc, float* __restrict__ out){
  __shared__ __align__(16) float g0[128];
  __shared__ __align__(16) float g5[512];
  __shared__ __align__(16) float g2[256];
  int b = blockIdx.x, t = threadIdx.x;
  if (t < 128) g0[t] = g128[(size_t)b*128 + t];
  __syncthreads();
#pragma unroll
  for (int cc = 0; cc < 2; ++cc){
    int c = t + cc*256;
    const float4* wr = (const float4*)(W0 + (size_t)c*128);
    const float4* gv = (const float4*)g0;
    float a = 0.0f;
#pragma unroll
    for (int qq = 0; qq < 32; ++qq) a = fma4(wr[qq], gv[qq], a);
    g5[c] = fmaxf(a, 0.0f);
  }
  __syncthreads();
  {
    const float4* wr = (const float4*)(W1 + (size_t)t*512);
    const float4* gv = (const float4*)g5;
    float a = 0.0f;
    for (int qq = 0; qq < 128; ++qq) a = fma4(wr[qq], gv[qq], a);
    g2[t] = fmaxf(a, 0.0f);
  }
  __syncthreads();
  if (t < 40){
    const float4* wr = (const float4*)(Wc + (size_t)t*256);
    const float4* gv = (const float4*)g2;
    float a = 0.0f;
#pragma unroll
    for (int qq = 0; qq < 64; ++qq) a = fma4(wr[qq], gv[qq], a);
    out[(size_t)b*40 + t] = a + bc[t];
  }
}

extern "C" void kernel_launch(void* const* d_in, const int* in_sizes, int n_in,
                              void* d_out, int out_size, void* d_ws, size_t ws_size,
                              hipStream_t stream){
  (void)in_sizes; (void)n_in; (void)out_size; (void)ws_size;
  const float* points     = (const float*)d_in[0];
  const float* sa_w0      = (const float*)d_in[1];
  const float* sa_w1      = (const float*)d_in[2];
  const float* sa_w2      = (const float*)d_in[3];
  const float* t_ec_w0    = (const float*)d_in[4];
  const float* t_ec_w1    = (const float*)d_in[5];
  const float* t_local_w  = (const float*)d_in[6];
  const float* t_g_w0     = (const float*)d_in[7];
  const float* t_g_w1     = (const float*)d_in[8];
  const float* t_lin_w    = (const float*)d_in[9];
  const float* t_lin_b    = (const float*)d_in[10];
  const float* dg_ec_w0   = (const float*)d_in[11];
  const float* dg_ec_w1   = (const float*)d_in[12];
  const float* dg_ec_w2   = (const float*)d_in[13];
  const float* dg_local_w = (const float*)d_in[14];
  const float* dg_g_w0    = (const float*)d_in[15];
  const float* dg_g_w1    = (const float*)d_in[16];
  const float* cls_w      = (const float*)d_in[17];
  const float* cls_b      = (const float*)d_in[18];
  float* out = (float*)d_out;

  float* ws     = (float*)d_ws;
  float* xyz    = ws;                    // 393216
  float* xnrm   = xyz    + 393216;       // 131072
  float* nxyz   = xnrm   + 131072;       // 24576
  float* feat   = nxyz   + 24576;        // 1048576
  float* x131   = feat   + 1048576;      // 1081344
  float* nrm    = x131   + 1081344;      // 8192
  int*   idx    = (int*)(nrm + 8192);    // 163840
  float* ht     = (float*)(idx + 163840);// 1048576 (reused as f1)
  float* g1024v = ht     + 1048576;      // 32768
  float* f2     = g1024v + 32768;        // 2097152
  float* f3     = f2     + 2097152;      // 4194304
  float* g128v  = f3     + 4194304;      // 4096
  float* wt_t1  = g128v  + 4096;         // 8192   (64x128)
  float* waT0   = wt_t1  + 8192;         // 8384   (131x64)
  float* wbT0   = waT0   + 8384;         // 8384
  float* waD0   = wbT0   + 8384;         // 16768  (131x128)
  float* wbD0   = waD0   + 16768;        // 16768
  float* waD1   = wbD0   + 16768;        // 32768  (128x256)
  float* wbD1   = waD1   + 32768;        // 32768
  float* waD2   = wbD1   + 32768;        // 131072 (256x512)
  float* wbD2   = waD2   + 131072;       // 131072
  float* Ab     = wbD2   + 131072;       // 4194304
  float* Bb     = Ab     + 4194304;      // 4194304
  float* w1Tb   = Bb     + 4194304;      // 4096   (legacy, unused by k_sa now)
  float* f1 = ht;
  float* xT = f3;                        // alias: xT lives in f3 until k_emax<512> writes f3

  // SA MFMA weight fragments alias the HEAD of Ab (16384 floats << 4194304).
  // Timeline: k_wprep2 writes -> k_sa reads -> k_gab (T-Net) is the first Ab write.
  float* w0f    = Ab;                    // 4096   ([kt][lane][e][4])
  u16*   w1fh   = (u16*)(w0f + 4096);    // 4096 u16
  u16*   w1fl   = w1fh   + 4096;         // 4096 u16
  u16*   w2fh   = w1fl   + 4096;         // 8192 u16
  u16*   w2fl   = w2fh   + 8192;         // 8192 u16

  k_prep<<<512, 256, 0, stream>>>(points, xyz, xnrm);
  k_wprep<<<787, 256, 0, stream>>>(t_ec_w0, t_ec_w1, dg_ec_w0, dg_ec_w1, dg_ec_w2, sa_w1,
                                   waT0, wbT0, wt_t1, waD0, wbD0, waD1, wbD1, waD2, wbD2, w1Tb);
  k_wprep2<<<64, 256, 0, stream>>>(sa_w0, sa_w1, sa_w2, w0f, w1fh, w1fl, w2fh, w2fl);
  k_fps<<<BB, 128, 0, stream>>>(xyz, nxyz);
  k_sa<<<BB*NPp, 64, 0, stream>>>(points, xyz, xnrm, nxyz, w0f, w1fh, w1fl, w2fh, w2fl, feat, x131);

  // T-Net branch (x = [feat, new_xyz])
  k_gab<131,64,256><<<512, 256, 0, stream>>>(x131, 132, waT0, wbT0, Ab, Bb, xT, nrm);
  k_knn3<131><<<1024, 512, 0, stream>>>(xT, nrm, idx);
  k_tedge3<<<BB*NPp, 128, 0, stream>>>(Ab, Bb, idx, wt_t1, ht);
  k_tpool<<<dim3(BB, 8, 8), 128, 0, stream>>>(ht, t_local_w, g1024v);
  k_trest<<<BB, 256, 0, stream>>>(g1024v, t_g_w0, t_g_w1, t_lin_w, t_lin_b, nxyz, x131);

  // DGCNN layer 1 (x = [feat, xyz_t], 131 dims)
  k_gab<131,128,512><<<512, 512, 0, stream>>>(x131, 132, waD0, wbD0, Ab, Bb, xT, nrm);
  k_knn3<131><<<1024, 512, 0, stream>>>(xT, nrm, idx);
  k_emax<128><<<1024, 256, 0, stream>>>(Ab, Bb, idx, f1);
  // layer 2
  k_gab<128,256,512><<<512, 512, 0, stream>>>(f1, 128, waD1, wbD1, Ab, Bb, xT, nrm);
  k_knn3<128><<<1024, 512, 0, stream>>>(xT, nrm, idx);
  k_emax<256><<<2048, 256, 0, stream>>>(Ab, Bb, idx, f2);
  // layer 3
  k_gab<256,512,512><<<512, 512, 0, stream>>>(f2, 256, waD2, wbD2, Ab, Bb, xT, nrm);
  k_knn3<256><<<1024, 512, 0, stream>>>(xT, nrm, idx);
  k_emax<512><<<4096, 256, 0, stream>>>(Ab, Bb, idx, f3);

  // local conv + global pool + head
  k_dgl<<<dim3(BB, 16), 128, 0, stream>>>(f1, f2, f3, dg_local_w, g128v);
  k_final<<<BB, 256, 0, stream>>>(g128v, dg_g_w0, dg_g_w1, cls_w, cls_b, out);
}

// Round 8
// 1261.145 us; speedup vs baseline: 1.1066x; 1.1066x over previous
//
#include <hip/hip_runtime.h>
#include <math.h>

#define BB 32
#define NN 4096
#define NPp 256
#define NSs 64
#define KC 20

typedef unsigned long long ull;
typedef unsigned short u16;
typedef short bf16x8 __attribute__((ext_vector_type(8)));
typedef float f32x4 __attribute__((ext_vector_type(4)));
typedef int i32x4 __attribute__((ext_vector_type(4)));

__device__ __forceinline__ float fma4(const float4 w, const float4 v, float a){
  a = fmaf(w.x, v.x, a); a = fmaf(w.y, v.y, a);
  a = fmaf(w.z, v.z, a); a = fmaf(w.w, v.w, a); return a;
}
__device__ __forceinline__ float4 fma4s(const float4 w, float s, float4 a){
  a.x = fmaf(w.x, s, a.x); a.y = fmaf(w.y, s, a.y);
  a.z = fmaf(w.z, s, a.z); a.w = fmaf(w.w, s, a.w); return a;
}
__device__ __forceinline__ float4 max4(float4 a, float4 b){
  a.x = fmaxf(a.x, b.x); a.y = fmaxf(a.y, b.y);
  a.z = fmaxf(a.z, b.z); a.w = fmaxf(a.w, b.w); return a;
}
__device__ __forceinline__ float4 add4(float4 a, float4 b){
  a.x += b.x; a.y += b.y; a.z += b.z; a.w += b.w; return a;
}

template<int C>
__device__ __forceinline__ int dpp_i(int x){
  return __builtin_amdgcn_update_dpp(x, x, C, 0xf, 0xf, false);
}

// split fp32 -> bf16 hi + bf16 lo (truncating; v - hi is exact in fp32)
__device__ __host__ __forceinline__ void bf16_split(float v, unsigned& h16, unsigned& l16){
  unsigned bits = __float_as_uint(v);
  h16 = bits >> 16;
  float hf = __uint_as_float(h16 << 16);
  l16 = __float_as_uint(v - hf) >> 16;
}

// ---------------- unified weight prep (all transposes/splits in one kernel) ----------------
__global__ void k_wprep(const float* __restrict__ t0, const float* __restrict__ t1,
                        const float* __restrict__ d0, const float* __restrict__ d1,
                        const float* __restrict__ d2, const float* __restrict__ saw1,
                        float* __restrict__ waT0, float* __restrict__ wbT0,
                        float* __restrict__ wt_t1,
                        float* __restrict__ waD0, float* __restrict__ wbD0,
                        float* __restrict__ waD1, float* __restrict__ wbD1,
                        float* __restrict__ waD2, float* __restrict__ wbD2,
                        float* __restrict__ w1T){
  int i = blockIdx.x*256 + threadIdx.x;
  if (i < 8384){                       // t_ec_w0: [64][262] -> A/B [131][64]
    int m = i >> 6;
    int c = i & 63;
    float bb = t0[(size_t)c*262 + m];
    float dd = t0[(size_t)c*262 + 131 + m];
    waT0[i] = __fsub_rn(bb, dd); wbT0[i] = dd;
    return;
  }
  i -= 8384;
  if (i < 8192){                       // t_ec_w1: [128][64] -> [64][128]
    int m = i >> 7, c = i & 127;
    wt_t1[i] = t1[(size_t)c*64 + m];
    return;
  }
  i -= 8192;
  if (i < 16768){                      // dg_ec_w0: [128][262] -> A/B [131][128]
    int m = i >> 7, c = i & 127;
    float bb = d0[(size_t)c*262 + m];
    float dd = d0[(size_t)c*262 + 131 + m];
    waD0[i] = __fsub_rn(bb, dd); wbD0[i] = dd;
    return;
  }
  i -= 16768;
  if (i < 32768){                      // dg_ec_w1: [256][256] -> A/B [128][256]
    int m = i >> 8, c = i & 255;
    float bb = d1[(size_t)c*256 + m];
    float dd = d1[(size_t)c*256 + 128 + m];
    waD1[i] = __fsub_rn(bb, dd); wbD1[i] = dd;
    return;
  }
  i -= 32768;
  if (i < 131072){                     // dg_ec_w2: [512][512] -> A/B [256][512]
    int m = i >> 9, c = i & 511;
    float bb = d2[(size_t)c*512 + m];
    float dd = d2[(size_t)c*512 + 256 + m];
    waD2[i] = __fsub_rn(bb, dd); wbD2[i] = dd;
    return;
  }
  i -= 131072;
  if (i < 4096){                       // sa_w1: [64][64] -> w1T[m][c] (legacy, unused)
    int m = i >> 6, c = i & 63;
    w1T[i] = saw1[(size_t)c*64 + m];
  }
}

// ---------------- SA MFMA weight prep: split-bf16 fragments in lane order ----------------
__global__ void k_wprep2(const float* __restrict__ w0, const float* __restrict__ w1,
                         const float* __restrict__ w2,
                         float* __restrict__ w0f, u16* __restrict__ w1fh, u16* __restrict__ w1fl,
                         u16* __restrict__ w2fh, u16* __restrict__ w2fl){
  int i = blockIdx.x*256 + threadIdx.x;
  if (i < 4096){                       // w0f: [kt][lane][e][4] (xyz + pad)
    int kt = i >> 11, r = i & 2047;
    int ln = r >> 5, ee = r & 31;
    int e = ee >> 2, j = ee & 3;
    int k = kt*32 + 8*(ln>>4) + e;
    w0f[i] = (j < 3) ? w0[k*3 + j] : 0.0f;
    return;
  }
  i -= 4096;
  if (i < 4096){                       // w1 frags: [ct*2+kt][lane][e], B[k][c]=w1[c][k]
    int e = i & 7, ln = (i >> 3) & 63, q = i >> 9;
    int kt = q & 1, ct = q >> 1;
    int k = kt*32 + 8*(ln>>4) + e;
    int c = ct*16 + (ln & 15);
    unsigned h16, l16; bf16_split(w1[(size_t)c*64 + k], h16, l16);
    w1fh[i] = (u16)h16; w1fl[i] = (u16)l16;
    return;
  }
  i -= 4096;
  if (i < 8192){                       // w2 frags: [c2t*2+kt][lane][e], B[k][c2]=w2[c2][k]
    int e = i & 7, ln = (i >> 3) & 63, q = i >> 9;
    int kt = q & 1, c2t = q >> 1;
    int k = kt*32 + 8*(ln>>4) + e;
    int c2 = c2t*16 + (ln & 15);
    unsigned h16, l16; bf16_split(w2[(size_t)c2*64 + k], h16, l16);
    w2fh[i] = (u16)h16; w2fl[i] = (u16)l16;
  }
}

// ---------------- transpose + point norms ----------------
__global__ void k_prep(const float* __restrict__ pts, float* __restrict__ xyz, float* __restrict__ xnrm){
  int i = blockIdx.x*256 + threadIdx.x;
  if (i >= BB*NN) return;
  int b = i >> 12, n = i & (NN-1);
  float X = pts[(b*3+0)*NN + n];
  float Y = pts[(b*3+1)*NN + n];
  float Z = pts[(b*3+2)*NN + n];
  xyz[i*3+0]=X; xyz[i*3+1]=Y; xyz[i*3+2]=Z;
  xnrm[i] = __fadd_rn(__fadd_rn(__fmul_rn(X,X), __fmul_rn(Y,Y)), __fmul_rn(Z,Z));
}

// ---------------- farthest point sampling: 4 waves + key-only reduce ----------------
// Ledger: r3 (4-wave, fat coord tail, global refetch) = 240us; r5 (2-wave, slim key
// tail, LDS b32 coords) = 214us; r7 (b128 table) = 368us (8-lane bank aliasing + 8clk
// port occupancy per b128 -- wrong fix). This combines the two measured-good halves:
// 4 waves x 16 pts/lane HALVES the dominant per-iter issue work (48 ds_read_b32 +
// ~200 VALU vs r5's 96+384), while r5's key-only DPP reduce + parity-double-buffered
// wkey keeps the tail slim (r3 proved a 4-wave single-batch barrier is acceptable).
// b32 coord reads are conflict-free (lane t -> bank t%32). Selection op order and
// tie-break (strict >, 4095-j) unchanged -> bit-identical FPS output.
__global__ __launch_bounds__(256, 1) void k_fps(const float* __restrict__ xyz, float* __restrict__ new_xyz){
  __shared__ __align__(16) float lx[NN], ly[NN], lz[NN];
  __shared__ __align__(16) ull wkey[2][4];
  int b = blockIdx.x, t = threadIdx.x;
  int w = t >> 6, lane = t & 63;
  float dist[16];
#pragma unroll
  for (int q = 0; q < 16; ++q){
    int j = q*256 + t;
    const float* p = xyz + ((size_t)b*NN + j)*3;
    lx[j] = p[0]; ly[j] = p[1]; lz[j] = p[2];
    dist[q] = __builtin_inff();
  }
  const float* p0 = xyz + (size_t)b*NN*3;
  float Px = p0[0], Py = p0[1], Pz = p0[2];
  __syncthreads();                      // LDS point stage visible to all waves
  for (int it = 0; it < NPp; ++it){
    if (t == 0){                        // output BEFORE update: out[it] = current P
      float* o = new_xyz + ((size_t)b*NPp + it)*3;
      o[0] = Px; o[1] = Py; o[2] = Pz;
    }
    float bv = -1.0f; int bj = 0;
#pragma unroll
    for (int q = 0; q < 16; ++q){
      int j = q*256 + t;
      float dx = __fsub_rn(lx[j], Px);
      float dy = __fsub_rn(ly[j], Py);
      float dz = __fsub_rn(lz[j], Pz);
      float dd = __fadd_rn(__fadd_rn(__fmul_rn(dx,dx), __fmul_rn(dy,dy)), __fmul_rn(dz,dz));
      float dm = fminf(dist[q], dd);
      dist[q] = dm;
      if (dm > bv){ bv = dm; bj = j; }
    }
    ull bk = ((ull)__float_as_uint(bv) << 32) | (unsigned)(4095 - bj);
    // wave reduce to lane63 (key only)
#define FPS_STAGE(C) { \
    unsigned ol = (unsigned)dpp_i<C>((int)(unsigned)bk); \
    unsigned oh = (unsigned)dpp_i<C>((int)(unsigned)(bk >> 32)); \
    ull ok = ((ull)oh << 32) | ol; \
    if (ok > bk) bk = ok; }
    FPS_STAGE(0x111) FPS_STAGE(0x112) FPS_STAGE(0x114) FPS_STAGE(0x118)
    FPS_STAGE(0x142) FPS_STAGE(0x143)
#undef FPS_STAGE
    int par = it & 1;
    if (lane == 63) wkey[par][w] = bk;
    __syncthreads();
    ull k0 = wkey[par][0], k1 = wkey[par][1];
    ull k2 = wkey[par][2], k3 = wkey[par][3];
    ull ka = (k0 > k1) ? k0 : k1;
    ull kb = (k2 > k3) ? k2 : k3;
    ull kw = (ka > kb) ? ka : kb;
    int idx = 4095 - (int)(unsigned)(kw & 0xFFFFFFFFu);
    Px = lx[idx]; Py = ly[idx]; Pz = lz[idx];
  }
}

// ---------------- ball query + SA convs + maxpool: MFMA split-bf16 version ----------------
__global__ __launch_bounds__(64) void k_sa(const float* __restrict__ pts,
    const float* __restrict__ xyz, const float* __restrict__ xnrm,
    const float* __restrict__ new_xyz, const float* __restrict__ w0f,
    const u16* __restrict__ w1fh, const u16* __restrict__ w1fl,
    const u16* __restrict__ w2fh, const u16* __restrict__ w2fl,
    float* __restrict__ feat, float* __restrict__ x131){
  __shared__ __align__(16) u16 hh[64*64];
  __shared__ __align__(16) u16 hl[64*64];
  __shared__ int gw[64];
  int bi = blockIdx.x;
  int lane = threadIdx.x;
  int b = bi >> 8;
  const float* q = new_xyz + (size_t)bi*3;
  float qx=q[0], qy=q[1], qz=q[2];
  float nq = __fadd_rn(__fadd_rn(__fmul_rn(qx,qx), __fmul_rn(qy,qy)), __fmul_rn(qz,qz));
  // ball query: no early exit (removes the control dependency; all loads pipeline)
  const float* pX = pts + (size_t)(b*3+0)*NN;
  const float* pY = pts + (size_t)(b*3+1)*NN;
  const float* pZ = pts + (size_t)(b*3+2)*NN;
  int cnt = 0;
  for (int base = 0; base < NN; base += 256){
#pragma unroll
    for (int u = 0; u < 4; ++u){
      int j = base + u*64 + lane;
      float X = pX[j], Y = pY[j], Z = pZ[j];
      float dot = __fadd_rn(__fadd_rn(__fmul_rn(qx,X), __fmul_rn(qy,Y)), __fmul_rn(qz,Z));
      float d2 = __fsub_rn(__fadd_rn(nq, xnrm[b*NN + j]), __fmul_rn(2.0f, dot));
      bool inb = d2 < 0.04f;
      unsigned long long m = __ballot(inb);
      int pos = cnt + (int)__popcll(m & ((1ull << lane) - 1ull));
      if (inb && pos < NSs) gw[pos] = j;
      cnt += (int)__popcll(m);
    }
  }
  int g0 = gw[0];
  if (lane >= cnt) gw[lane] = g0;
  // own sample point (lane = sample), relative to query
  int gj = gw[lane];
  const float* pp = xyz + ((size_t)b*NN + gj)*3;
  float px = pp[0]-qx, py = pp[1]-qy, pz = pp[2]-qz;
  // broadcast sample coords for each s-tile: lane needs sample s = (lane&15)+16t
  int col = lane & 15, g = lane >> 4;
  float sxv[4], syv[4], szv[4];
#pragma unroll
  for (int t2 = 0; t2 < 4; ++t2){
    int src = col + 16*t2;
    sxv[t2] = __shfl(px, src);
    syv[t2] = __shfl(py, src);
    szv[t2] = __shfl(pz, src);
  }
  // h0 A-fragments built directly in registers: elem e holds h0[s][k=kt*32+8g+e]
  i32x4 ah0[4][2], al0[4][2];
#pragma unroll
  for (int kt = 0; kt < 2; ++kt){
    float4 wrow[8];
    const float4* wp = (const float4*)(w0f + (size_t)(kt*64 + lane)*32);
#pragma unroll
    for (int e = 0; e < 8; ++e) wrow[e] = wp[e];
#pragma unroll
    for (int t2 = 0; t2 < 4; ++t2){
      unsigned hu[8], lu[8];
#pragma unroll
      for (int e = 0; e < 8; ++e){
        float a = fmaf(wrow[e].z, szv[t2], fmaf(wrow[e].y, syv[t2], wrow[e].x*sxv[t2]));
        a = fmaxf(a, 0.0f);
        bf16_split(a, hu[e], lu[e]);
      }
      i32x4 H, L;
#pragma unroll
      for (int j2 = 0; j2 < 4; ++j2){
        H[j2] = (int)(hu[2*j2] | (hu[2*j2+1] << 16));
        L[j2] = (int)(lu[2*j2] | (lu[2*j2+1] << 16));
      }
      ah0[t2][kt] = H; al0[t2][kt] = L;
    }
  }
  // conv2 via MFMA: D[s][c] = sum_k h0[s][k] * W1[k][c]; relu; split; store to swizzled LDS
#pragma unroll
  for (int ct = 0; ct < 4; ++ct){
    bf16x8 bh[2], bl[2];
#pragma unroll
    for (int kt = 0; kt < 2; ++kt){
      bh[kt] = *(const bf16x8*)(w1fh + (size_t)((ct*2+kt)*64 + lane)*8);
      bl[kt] = *(const bf16x8*)(w1fl + (size_t)((ct*2+kt)*64 + lane)*8);
    }
#pragma unroll
    for (int t2 = 0; t2 < 4; ++t2){
      f32x4 acc = {0.f,0.f,0.f,0.f};
#pragma unroll
      for (int kt = 0; kt < 2; ++kt){
        bf16x8 Ah = __builtin_bit_cast(bf16x8, ah0[t2][kt]);
        bf16x8 Al = __builtin_bit_cast(bf16x8, al0[t2][kt]);
        acc = __builtin_amdgcn_mfma_f32_16x16x32_bf16(Ah, bh[kt], acc, 0, 0, 0);
        acc = __builtin_amdgcn_mfma_f32_16x16x32_bf16(Ah, bl[kt], acc, 0, 0, 0);
        acc = __builtin_amdgcn_mfma_f32_16x16x32_bf16(Al, bh[kt], acc, 0, 0, 0);
      }
#pragma unroll
      for (int r = 0; r < 4; ++r){
        float v = fmaxf(acc[r], 0.0f);           // relu(h1)
        int s = 16*t2 + 4*g + r;                 // D row = sample (m89-verified layout)
        int cc = ct*16 + col;                    // D col = channel
        int idx = s*64 + (cc ^ ((s & 7) << 3));  // XOR swizzle, bank-balanced
        unsigned h16, l16; bf16_split(v, h16, l16);
        hh[idx] = (u16)h16; hl[idx] = (u16)l16;
      }
    }
  }
  // conv3 A-fragments from LDS (same swizzle; 8 consecutive u16 stay contiguous)
  bf16x8 a1h[4][2], a1l[4][2];
#pragma unroll
  for (int t2 = 0; t2 < 4; ++t2){
    int s = col + 16*t2;
    int sw = (s & 7) << 3;
#pragma unroll
    for (int kt = 0; kt < 2; ++kt){
      int k0 = kt*32 + 8*g;
      int idx = s*64 + (k0 ^ sw);
      a1h[t2][kt] = *(const bf16x8*)(hh + idx);
      a1l[t2][kt] = *(const bf16x8*)(hl + idx);
    }
  }
  // conv3 + samplewise maxpool per 16-channel tile
#pragma unroll
  for (int c2t = 0; c2t < 8; ++c2t){
    bf16x8 bh2[2], bl2[2];
#pragma unroll
    for (int kt = 0; kt < 2; ++kt){
      bh2[kt] = *(const bf16x8*)(w2fh + (size_t)((c2t*2+kt)*64 + lane)*8);
      bl2[kt] = *(const bf16x8*)(w2fl + (size_t)((c2t*2+kt)*64 + lane)*8);
    }
    float mx = 0.0f;                             // relu folded into max (values >= 0)
#pragma unroll
    for (int t2 = 0; t2 < 4; ++t2){
      f32x4 acc = {0.f,0.f,0.f,0.f};
#pragma unroll
      for (int kt = 0; kt < 2; ++kt){
        acc = __builtin_amdgcn_mfma_f32_16x16x32_bf16(a1h[t2][kt], bh2[kt], acc, 0, 0, 0);
        acc = __builtin_amdgcn_mfma_f32_16x16x32_bf16(a1h[t2][kt], bl2[kt], acc, 0, 0, 0);
        acc = __builtin_amdgcn_mfma_f32_16x16x32_bf16(a1l[t2][kt], bh2[kt], acc, 0, 0, 0);
      }
      mx = fmaxf(mx, fmaxf(fmaxf(acc[0], acc[1]), fmaxf(acc[2], acc[3])));
    }
    mx = fmaxf(mx, __shfl_xor(mx, 16));
    mx = fmaxf(mx, __shfl_xor(mx, 32));
    if (lane < 16){
      int c = c2t*16 + lane;
      feat[(size_t)bi*128 + c] = mx;
      x131[(size_t)bi*132 + c] = mx;
    }
  }
  if (lane < 3) x131[(size_t)bi*132 + 128 + lane] = (lane==0)?qx:((lane==1)?qy:qz);
}

// ---------------- kNN: distances in registers, u64-DPP selection, no selection LDS ----------------
template<int CIN>
__global__ __launch_bounds__(512) void k_knn3(const float* __restrict__ xT,
    const float* __restrict__ nrm, int* __restrict__ idxo){
  __shared__ __align__(16) float sch[16*256];
  int bi = blockIdx.x, t = threadIdx.x;
  int w = t >> 6, lane = t & 63;
  int b = bi >> 5;
  int coli = (bi & 31)*8 + w;
  const float* xb = xT + (size_t)b*CIN*256;
  float d0=0.f, d1=0.f, d2=0.f, d3=0.f;
  for (int m0 = 0; m0 < CIN; m0 += 16){
    int mc = (CIN - m0 < 16) ? (CIN - m0) : 16;
    for (int i = t; i < mc*64; i += 512){
      int mm = i >> 6, c4 = i & 63;
      *(float4*)(sch + mm*256 + c4*4) = *(const float4*)(xb + (size_t)(m0+mm)*256 + c4*4);
    }
    __syncthreads();
    for (int mm = 0; mm < mc; ++mm){
      float xm = sch[mm*256 + coli];
      float4 v = *(const float4*)(sch + mm*256 + 4*lane);
      d0 = fmaf(v.x, xm, d0); d1 = fmaf(v.y, xm, d1);
      d2 = fmaf(v.z, xm, d2); d3 = fmaf(v.w, xm, d3);
    }
    __syncthreads();
  }
  float ni = nrm[b*256 + coli];
  float4 dv;
  {
    int j0 = 4*lane;
    dv.x = __fsub_rn(__fadd_rn(ni, nrm[b*256 + j0+0]), __fmul_rn(2.0f, d0));
    dv.y = __fsub_rn(__fadd_rn(ni, nrm[b*256 + j0+1]), __fmul_rn(2.0f, d1));
    dv.z = __fsub_rn(__fadd_rn(ni, nrm[b*256 + j0+2]), __fmul_rn(2.0f, d2));
    dv.w = __fsub_rn(__fadd_rn(ni, nrm[b*256 + j0+3]), __fmul_rn(2.0f, d3));
  }
  for (int r = 0; r < KC; ++r){
    float bv = 3.4e38f; int bj = NPp;
    if (dv.x < bv){ bv = dv.x; bj = 4*lane+0; }
    if (dv.y < bv){ bv = dv.y; bj = 4*lane+1; }
    if (dv.z < bv){ bv = dv.z; bj = 4*lane+2; }
    if (dv.w < bv){ bv = dv.w; bj = 4*lane+3; }
    unsigned xf = __float_as_uint(bv);
    xf = (xf & 0x80000000u) ? ~xf : (xf | 0x80000000u);
    ull key = ((ull)xf << 32) | (unsigned)bj;
#define KN_STAGE(C) { \
    unsigned ol = (unsigned)dpp_i<C>((int)(unsigned)key); \
    unsigned oh = (unsigned)dpp_i<C>((int)(unsigned)(key >> 32)); \
    ull ok = ((ull)oh << 32) | ol; \
    if (ok < key) key = ok; }
    KN_STAGE(0x111) KN_STAGE(0x112) KN_STAGE(0x114) KN_STAGE(0x118)
    KN_STAGE(0x142) KN_STAGE(0x143)
#undef KN_STAGE
    int bjw = __builtin_amdgcn_readlane((int)(unsigned)key, 63);
    if (lane == 0) idxo[((size_t)b*256 + coli)*KC + r] = bjw;
    if ((bjw >> 2) == lane){
      int e = bjw & 3;
      if      (e == 0) dv.x = 3.0e38f;
      else if (e == 1) dv.y = 3.0e38f;
      else if (e == 2) dv.z = 3.0e38f;
      else             dv.w = 3.0e38f;
    }
  }
}

// ---------------- per-point dual GEMM + fused xT transpose + fused norms ----------------
template<int CIN, int COUT, int T>
__global__ __launch_bounds__(T) void k_gab(const float* __restrict__ x, int xstride,
    const float* __restrict__ wA, const float* __restrict__ wB,
    float* __restrict__ A, float* __restrict__ B, float* __restrict__ xT,
    float* __restrict__ nrm){
  constexpr int PC  = CIN + 1;
  constexpr int G   = COUT/4;
  constexpr int RS  = T/G;
  constexpr int RPT = 16/RS;
  __shared__ float xsh[16*PC];
  int bi = blockIdx.x, t = threadIdx.x;
  int g = t % G, rs = t / G;
  int i0 = bi*16;
  for (int i = t; i < 16*CIN; i += T){
    int r = i / CIN, m = i - r*CIN;
    xsh[r*PC + m] = x[(size_t)(i0+r)*xstride + m];
  }
  __syncthreads();
  {
    int bb = i0 >> 8, col0 = i0 & 255;
    float* xTb = xT + (size_t)bb*CIN*256 + col0;
    for (int i = t; i < 16*CIN; i += T){
      int m = i >> 4, r = i & 15;
      xTb[m*256 + r] = xsh[r*PC + m];
    }
  }
  if (t < 16){
    const float* xr = xsh + t*PC;
    float a = 0.0f;
    for (int m = 0; m < CIN; ++m) a = __fadd_rn(a, __fmul_rn(xr[m], xr[m]));
    nrm[i0 + t] = a;
  }
  float4 accA[RPT], accB[RPT];
#pragma unroll
  for (int rr = 0; rr < RPT; ++rr){
    accA[rr] = make_float4(0.f,0.f,0.f,0.f);
    accB[rr] = make_float4(0.f,0.f,0.f,0.f);
  }
  for (int m = 0; m < CIN; ++m){
    float4 wa = *(const float4*)(wA + (size_t)m*COUT + 4*g);
    float4 wb = *(const float4*)(wB + (size_t)m*COUT + 4*g);
#pragma unroll
    for (int rr = 0; rr < RPT; ++rr){
      float xv = xsh[(rs + rr*RS)*PC + m];
      accA[rr] = fma4s(wa, xv, accA[rr]);
      accB[rr] = fma4s(wb, xv, accB[rr]);
    }
  }
#pragma unroll
  for (int rr = 0; rr < RPT; ++rr){
    int r = i0 + rs + rr*RS;
    *(float4*)(A + (size_t)r*COUT + 4*g) = accA[rr];
    *(float4*)(B + (size_t)r*COUT + 4*g) = accB[rr];
  }
}

// ---------------- edge epilogue: out[i][c] = max_k relu(A[i][c] + B[j_ik][c]) ----------------
template<int COUT>
__global__ __launch_bounds__(256) void k_emax(const float* __restrict__ A, const float* __restrict__ Bm,
    const int* __restrict__ idx, float* __restrict__ out){
  constexpr int GT = COUT/4;
  constexpr int NC = 256/GT;
  __shared__ int js[NC*KC];
  int bi = blockIdx.x, t = threadIdx.x;
  int li = t / GT, c4 = (t % GT)*4;
  int ci = bi*NC + li;
  int rb = (ci >> 8) << 8;
  if (t < NC*KC) js[t] = idx[(size_t)bi*NC*KC + t];
  __syncthreads();
  float4 a = *(const float4*)(A + (size_t)ci*COUT + c4);
  float4 p = make_float4(0.f,0.f,0.f,0.f);
#pragma unroll
  for (int k = 0; k < KC; ++k){
    int j = js[li*KC + k];
    float4 b = *(const float4*)(Bm + (size_t)(rb + j)*COUT + c4);
    p = max4(p, add4(a, b));
  }
  *(float4*)(out + (size_t)ci*COUT + c4) = p;
}

// ---------------- T-Net edge: h0 = relu(A0+B0) then 64->128 conv + k-maxpool ----------------
__global__ __launch_bounds__(128) void k_tedge3(const float* __restrict__ A0, const float* __restrict__ B0,
    const int* __restrict__ idx, const float* __restrict__ wt1, float* __restrict__ out){
  __shared__ __align__(16) float h0s[20*68];
  __shared__ __align__(16) float smax[4*128];
  __shared__ int js[KC];
  int bi = blockIdx.x, t = threadIdx.x;
  int cg = t & 31, kg = t >> 5, k0 = kg*5;
  int rb = (bi >> 8) << 8;
  if (t < KC) js[t] = idx[(size_t)bi*KC + t];
  __syncthreads();
  for (int i = t; i < 20*64; i += 128){
    int k = i >> 6, c = i & 63;
    float v = A0[(size_t)bi*64 + c] + B0[(size_t)(rb + js[k])*64 + c];
    h0s[k*68 + c] = fmaxf(v, 0.0f);
  }
  __syncthreads();
  float4 b2[5];
#pragma unroll
  for (int kk = 0; kk < 5; ++kk) b2[kk] = make_float4(0.f,0.f,0.f,0.f);
  for (int m4 = 0; m4 < 16; ++m4){
    float4 e[5];
#pragma unroll
    for (int kk = 0; kk < 5; ++kk) e[kk] = *(const float4*)(h0s + (k0+kk)*68 + 4*m4);
#pragma unroll
    for (int mm = 0; mm < 4; ++mm){
      float4 w = *(const float4*)(wt1 + (4*m4+mm)*128 + 4*cg);
#pragma unroll
      for (int kk = 0; kk < 5; ++kk){
        float ev = (mm==0)?e[kk].x:((mm==1)?e[kk].y:((mm==2)?e[kk].z:e[kk].w));
        b2[kk] = fma4s(w, ev, b2[kk]);
      }
    }
  }
  float4 p = make_float4(0.f,0.f,0.f,0.f);
#pragma unroll
  for (int kk = 0; kk < 5; ++kk) p = max4(p, b2[kk]);
  *(float4*)(smax + kg*128 + 4*cg) = p;
  __syncthreads();
  if (kg == 0){
    float4 r = *(const float4*)(smax + 4*cg);
#pragma unroll
    for (int g = 1; g < 4; ++g) r = max4(r, *(const float4*)(smax + g*128 + 4*cg));
    *(float4*)(out + (size_t)bi*128 + 4*cg) = r;
  }
}

// ---------------- T-Net 128->1024 + pool: 8 point-chunks, atomicMax combine ----------------
__global__ __launch_bounds__(128) void k_tpool(const float* __restrict__ h, const float* __restrict__ W,
    float* __restrict__ g1024){
  int b = blockIdx.x, t = threadIdx.x;
  int c = blockIdx.y*128 + t;
  int i0 = blockIdx.z*32;
  float4 w[32];
#pragma unroll
  for (int qq = 0; qq < 32; ++qq) w[qq] = *(const float4*)(W + (size_t)c*128 + 4*qq);
  const float* hb = h + (size_t)b*NPp*128;
  float mx = 0.0f;
  for (int i = i0; i < i0 + 32; ++i){
    const float4* hr = (const float4*)(hb + (size_t)i*128);
    float a = 0.0f;
#pragma unroll
    for (int qq = 0; qq < 32; ++qq) a = fma4(w[qq], hr[qq], a);
    mx = fmaxf(mx, a);
  }
  atomicMax((int*)(g1024 + (size_t)b*1024 + c), __float_as_int(mx));
}

// ---------------- T-Net MLP + 3x3 transform applied to new_xyz ----------------
__global__ __launch_bounds__(256) void k_trest(const float* __restrict__ g1024,
    const float* __restrict__ Wg0, const float* __restrict__ Wg1,
    const float* __restrict__ Wl, const float* __restrict__ bl,
    const float* __restrict__ new_xyz, float* __restrict__ x131){
  __shared__ __align__(16) float g1[1024];
  __shared__ __align__(16) float g5[512];
  __shared__ __align__(16) float g2[256];
  __shared__ float tm[12];
  int b = blockIdx.x, t = threadIdx.x;
  for (int m = t; m < 1024; m += 256) g1[m] = g1024[(size_t)b*1024 + m];
  __syncthreads();
#pragma unroll
  for (int cc = 0; cc < 2; ++cc){
    int c = t + cc*256;
    const float4* wr = (const float4*)(Wg0 + (size_t)c*1024);
    const float4* gv = (const float4*)g1;
    float a = 0.0f;
    for (int qq = 0; qq < 256; ++qq) a = fma4(wr[qq], gv[qq], a);
    g5[c] = fmaxf(a, 0.0f);
  }
  __syncthreads();
  {
    const float4* wr = (const float4*)(Wg1 + (size_t)t*512);
    const float4* gv = (const float4*)g5;
    float a = 0.0f;
    for (int qq = 0; qq < 128; ++qq) a = fma4(wr[qq], gv[qq], a);
    g2[t] = fmaxf(a, 0.0f);
  }
  __syncthreads();
  if (t < 9){
    const float4* wr = (const float4*)(Wl + (size_t)t*256);
    const float4* gv = (const float4*)g2;
    float a = 0.0f;
#pragma unroll
    for (int qq = 0; qq < 64; ++qq) a = fma4(wr[qq], gv[qq], a);
    a += bl[t];
    if (t == 0 || t == 4 || t == 8) a += 1.0f;
    tm[t] = a;
  }
  __syncthreads();
  {
    const float* nx = new_xyz + ((size_t)b*NPp + t)*3;
    float X = nx[0], Y = nx[1], Z = nx[2];
#pragma unroll
    for (int i = 0; i < 3; ++i){
      float v = __fadd_rn(__fadd_rn(__fmul_rn(tm[i*3+0], X), __fmul_rn(tm[i*3+1], Y)), __fmul_rn(tm[i*3+2], Z));
      x131[((size_t)b*NPp + t)*132 + 128 + i] = v;
    }
  }
}

// ---------------- 896->128 conv + global max pool (atomicMax; poison is negative int) ----------------
__global__ __launch_bounds__(128) void k_dgl(const float* __restrict__ f1, const float* __restrict__ f2,
    const float* __restrict__ f3, const float* __restrict__ W, float* __restrict__ g128){
  int b = blockIdx.x, t = threadIdx.x;
  int i0 = blockIdx.y * 16;
  const float* wr = W + (size_t)t*896;
  float acc[16];
#pragma unroll
  for (int ii = 0; ii < 16; ++ii) acc[ii] = 0.0f;
  for (int q = 0; q < 32; ++q){
    float4 w = *(const float4*)(wr + 4*q);
#pragma unroll
    for (int ii = 0; ii < 16; ++ii){
      float4 v = *(const float4*)(f1 + ((size_t)b*NPp + i0 + ii)*128 + 4*q);
      acc[ii] = fma4(w, v, acc[ii]);
    }
  }
  for (int q = 0; q < 64; ++q){
    float4 w = *(const float4*)(wr + 128 + 4*q);
#pragma unroll
    for (int ii = 0; ii < 16; ++ii){
      float4 v = *(const float4*)(f2 + ((size_t)b*NPp + i0 + ii)*256 + 4*q);
      acc[ii] = fma4(w, v, acc[ii]);
    }
  }
  for (int q = 0; q < 128; ++q){
    float4 w = *(const float4*)(wr + 384 + 4*q);
#pragma unroll
    for (int ii = 0; ii < 16; ++ii){
      float4 v = *(const float4*)(f3 + ((size_t)b*NPp + i0 + ii)*512 + 4*q);
      acc[ii] = fma4(w, v, acc[ii]);
    }
  }
#pragma unroll
  for (int ii = 0; ii < 16; ++ii){
    float v = fmaxf(acc[ii], 0.0f);
    atomicMax((int*)(g128 + (size_t)b*128 + t), __float_as_int(v));
  }
}

// ---------------- classifier head ----------------
__global__ __launch_bounds__(256) void k_final(const float* __restrict__ g128,
    const float* __restrict__ W0, const float* __restrict__ W1,
    const float* __restrict__ Wc, const float* __restrict__ bc, float* __restrict__ out){
  __shared__ __align__(16) float g0[128];
  __shared__ __align__(16) float g5[512];
  __shared__ __align__(16) float g2[256];
  int b = blockIdx.x, t = threadIdx.x;
  if (t < 128) g0[t] = g128[(size_t)b*128 + t];
  __syncthreads();
#pragma unroll
  for (int cc = 0; cc < 2; ++cc){
    int c = t + cc*256;
    const float4* wr = (const float4*)(W0 + (size_t)c*128);
    const float4* gv = (const float4*)g0;
    float a = 0.0f;
#pragma unroll
    for (int qq = 0; qq < 32; ++qq) a = fma4(wr[qq], gv[qq], a);
    g5[c] = fmaxf(a, 0.0f);
  }
  __syncthreads();
  {
    const float4* wr = (const float4*)(W1 + (size_t)t*512);
    const float4* gv = (const float4*)g5;
    float a = 0.0f;
    for (int qq = 0; qq < 128; ++qq) a = fma4(wr[qq], gv[qq], a);
    g2[t] = fmaxf(a, 0.0f);
  }
  __syncthreads();
  if (t < 40){
    const float4* wr = (const float4*)(Wc + (size_t)t*256);
    const float4* gv = (const float4*)g2;
    float a = 0.0f;
#pragma unroll
    for (int qq = 0; qq < 64; ++qq) a = fma4(wr[qq], gv[qq], a);
    out[(size_t)b*40 + t] = a + bc[t];
  }
}

extern "C" void kernel_launch(void* const* d_in, const int* in_sizes, int n_in,
                              void* d_out, int out_size, void* d_ws, size_t ws_size,
                              hipStream_t stream){
  (void)in_sizes; (void)n_in; (void)out_size; (void)ws_size;
  const float* points     = (const float*)d_in[0];
  const float* sa_w0      = (const float*)d_in[1];
  const float* sa_w1      = (const float*)d_in[2];
  const float* sa_w2      = (const float*)d_in[3];
  const float* t_ec_w0    = (const float*)d_in[4];
  const float* t_ec_w1    = (const float*)d_in[5];
  const float* t_local_w  = (const float*)d_in[6];
  const float* t_g_w0     = (const float*)d_in[7];
  const float* t_g_w1     = (const float*)d_in[8];
  const float* t_lin_w    = (const float*)d_in[9];
  const float* t_lin_b    = (const float*)d_in[10];
  const float* dg_ec_w0   = (const float*)d_in[11];
  const float* dg_ec_w1   = (const float*)d_in[12];
  const float* dg_ec_w2   = (const float*)d_in[13];
  const float* dg_local_w = (const float*)d_in[14];
  const float* dg_g_w0    = (const float*)d_in[15];
  const float* dg_g_w1    = (const float*)d_in[16];
  const float* cls_w      = (const float*)d_in[17];
  const float* cls_b      = (const float*)d_in[18];
  float* out = (float*)d_out;

  float* ws     = (float*)d_ws;
  float* xyz    = ws;                    // 393216
  float* xnrm   = xyz    + 393216;       // 131072
  float* nxyz   = xnrm   + 131072;       // 24576
  float* feat   = nxyz   + 24576;        // 1048576
  float* x131   = feat   + 1048576;      // 1081344
  float* nrm    = x131   + 1081344;      // 8192
  int*   idx    = (int*)(nrm + 8192);    // 163840
  float* ht     = (float*)(idx + 163840);// 1048576 (reused as f1)
  float* g1024v = ht     + 1048576;      // 32768
  float* f2     = g1024v + 32768;        // 2097152
  float* f3     = f2     + 2097152;      // 4194304
  float* g128v  = f3     + 4194304;      // 4096
  float* wt_t1  = g128v  + 4096;         // 8192   (64x128)
  float* waT0   = wt_t1  + 8192;         // 8384   (131x64)
  float* wbT0   = waT0   + 8384;         // 8384
  float* waD0   = wbT0   + 8384;         // 16768  (131x128)
  float* wbD0   = waD0   + 16768;        // 16768
  float* waD1   = wbD0   + 16768;        // 32768  (128x256)
  float* wbD1   = waD1   + 32768;        // 32768
  float* waD2   = wbD1   + 32768;        // 131072 (256x512)
  float* wbD2   = waD2   + 131072;       // 131072
  float* Ab     = wbD2   + 131072;       // 4194304
  float* Bb     = Ab     + 4194304;      // 4194304
  float* w1Tb   = Bb     + 4194304;      // 4096   (legacy, unused by k_sa now)
  float* f1 = ht;
  float* xT = f3;                        // alias: xT lives in f3 until k_emax<512> writes f3

  // SA MFMA weight fragments alias the HEAD of Ab (16384 floats << 4194304).
  // Timeline: k_wprep2 writes -> k_sa reads -> k_gab (T-Net) is the first Ab write.
  float* w0f    = Ab;                    // 4096   ([kt][lane][e][4])
  u16*   w1fh   = (u16*)(w0f + 4096);    // 4096 u16
  u16*   w1fl   = w1fh   + 4096;         // 4096 u16
  u16*   w2fh   = w1fl   + 4096;         // 8192 u16
  u16*   w2fl   = w2fh   + 8192;         // 8192 u16

  k_prep<<<512, 256, 0, stream>>>(points, xyz, xnrm);
  k_wprep<<<787, 256, 0, stream>>>(t_ec_w0, t_ec_w1, dg_ec_w0, dg_ec_w1, dg_ec_w2, sa_w1,
                                   waT0, wbT0, wt_t1, waD0, wbD0, waD1, wbD1, waD2, wbD2, w1Tb);
  k_wprep2<<<64, 256, 0, stream>>>(sa_w0, sa_w1, sa_w2, w0f, w1fh, w1fl, w2fh, w2fl);
  k_fps<<<BB, 256, 0, stream>>>(xyz, nxyz);
  k_sa<<<BB*NPp, 64, 0, stream>>>(points, xyz, xnrm, nxyz, w0f, w1fh, w1fl, w2fh, w2fl, feat, x131);

  // T-Net branch (x = [feat, new_xyz])
  k_gab<131,64,256><<<512, 256, 0, stream>>>(x131, 132, waT0, wbT0, Ab, Bb, xT, nrm);
  k_knn3<131><<<1024, 512, 0, stream>>>(xT, nrm, idx);
  k_tedge3<<<BB*NPp, 128, 0, stream>>>(Ab, Bb, idx, wt_t1, ht);
  k_tpool<<<dim3(BB, 8, 8), 128, 0, stream>>>(ht, t_local_w, g1024v);
  k_trest<<<BB, 256, 0, stream>>>(g1024v, t_g_w0, t_g_w1, t_lin_w, t_lin_b, nxyz, x131);

  // DGCNN layer 1 (x = [feat, xyz_t], 131 dims)
  k_gab<131,128,512><<<512, 512, 0, stream>>>(x131, 132, waD0, wbD0, Ab, Bb, xT, nrm);
  k_knn3<131><<<1024, 512, 0, stream>>>(xT, nrm, idx);
  k_emax<128><<<1024, 256, 0, stream>>>(Ab, Bb, idx, f1);
  // layer 2
  k_gab<128,256,512><<<512, 512, 0, stream>>>(f1, 128, waD1, wbD1, Ab, Bb, xT, nrm);
  k_knn3<128><<<1024, 512, 0, stream>>>(xT, nrm, idx);
  k_emax<256><<<2048, 256, 0, stream>>>(Ab, Bb, idx, f2);
  // layer 3
  k_gab<256,512,512><<<512, 512, 0, stream>>>(f2, 256, waD2, wbD2, Ab, Bb, xT, nrm);
  k_knn3<256><<<1024, 512, 0, stream>>>(xT, nrm, idx);
  k_emax<512><<<4096, 256, 0, stream>>>(Ab, Bb, idx, f3);

  // local conv + global pool + head
  k_dgl<<<dim3(BB, 16), 128, 0, stream>>>(f1, f2, f3, dg_local_w, g128v);
  k_final<<<BB, 256, 0, stream>>>(g128v, dg_g_w0, dg_g_w1, cls_w, cls_b, out);
}

// Round 9
// 1241.506 us; speedup vs baseline: 1.1241x; 1.0158x over previous
//
#include <hip/hip_runtime.h>
#include <math.h>

#define BB 32
#define NN 4096
#define NPp 256
#define NSs 64
#define KC 20

typedef unsigned long long ull;
typedef unsigned short u16;
typedef short bf16x8 __attribute__((ext_vector_type(8)));
typedef float f32x4 __attribute__((ext_vector_type(4)));
typedef int i32x4 __attribute__((ext_vector_type(4)));

__device__ __forceinline__ float fma4(const float4 w, const float4 v, float a){
  a = fmaf(w.x, v.x, a); a = fmaf(w.y, v.y, a);
  a = fmaf(w.z, v.z, a); a = fmaf(w.w, v.w, a); return a;
}
__device__ __forceinline__ float4 fma4s(const float4 w, float s, float4 a){
  a.x = fmaf(w.x, s, a.x); a.y = fmaf(w.y, s, a.y);
  a.z = fmaf(w.z, s, a.z); a.w = fmaf(w.w, s, a.w); return a;
}
__device__ __forceinline__ float4 max4(float4 a, float4 b){
  a.x = fmaxf(a.x, b.x); a.y = fmaxf(a.y, b.y);
  a.z = fmaxf(a.z, b.z); a.w = fmaxf(a.w, b.w); return a;
}
__device__ __forceinline__ float4 add4(float4 a, float4 b){
  a.x += b.x; a.y += b.y; a.z += b.z; a.w += b.w; return a;
}

template<int C>
__device__ __forceinline__ int dpp_i(int x){
  return __builtin_amdgcn_update_dpp(x, x, C, 0xf, 0xf, false);
}

// split fp32 -> bf16 hi + bf16 lo (truncating; v - hi is exact in fp32)
__device__ __host__ __forceinline__ void bf16_split(float v, unsigned& h16, unsigned& l16){
  unsigned bits = __float_as_uint(v);
  h16 = bits >> 16;
  float hf = __uint_as_float(h16 << 16);
  l16 = __float_as_uint(v - hf) >> 16;
}

// ---------------- fused prep: points transpose/norms + ALL weight prep in ONE launch ----------------
// blocks [0,512): k_prep body; [512,1299): k_wprep body; [1299,1363): k_wprep2 body.
// Bodies byte-identical to the previously verified separate kernels; saves 2 launch overheads.
__global__ void k_prep_all(const float* __restrict__ pts, float* __restrict__ xyz, float* __restrict__ xnrm,
                           const float* __restrict__ t0, const float* __restrict__ t1,
                           const float* __restrict__ d0, const float* __restrict__ d1,
                           const float* __restrict__ d2, const float* __restrict__ saw1,
                           float* __restrict__ waT0, float* __restrict__ wbT0,
                           float* __restrict__ wt_t1,
                           float* __restrict__ waD0, float* __restrict__ wbD0,
                           float* __restrict__ waD1, float* __restrict__ wbD1,
                           float* __restrict__ waD2, float* __restrict__ wbD2,
                           float* __restrict__ w1T,
                           const float* __restrict__ w0, const float* __restrict__ w1,
                           const float* __restrict__ w2,
                           float* __restrict__ w0f, u16* __restrict__ w1fh, u16* __restrict__ w1fl,
                           u16* __restrict__ w2fh, u16* __restrict__ w2fl){
  int bid = blockIdx.x;
  if (bid < 512){                        // ---- k_prep ----
    int i = bid*256 + threadIdx.x;
    if (i >= BB*NN) return;
    int b = i >> 12, n = i & (NN-1);
    float X = pts[(b*3+0)*NN + n];
    float Y = pts[(b*3+1)*NN + n];
    float Z = pts[(b*3+2)*NN + n];
    xyz[i*3+0]=X; xyz[i*3+1]=Y; xyz[i*3+2]=Z;
    xnrm[i] = __fadd_rn(__fadd_rn(__fmul_rn(X,X), __fmul_rn(Y,Y)), __fmul_rn(Z,Z));
    return;
  }
  if (bid < 1299){                       // ---- k_wprep ----
    int i = (bid-512)*256 + threadIdx.x;
    if (i < 8384){                       // t_ec_w0: [64][262] -> A/B [131][64]
      int m = i >> 6;
      int c = i & 63;
      float bb = t0[(size_t)c*262 + m];
      float dd = t0[(size_t)c*262 + 131 + m];
      waT0[i] = __fsub_rn(bb, dd); wbT0[i] = dd;
      return;
    }
    i -= 8384;
    if (i < 8192){                       // t_ec_w1: [128][64] -> [64][128]
      int m = i >> 7, c = i & 127;
      wt_t1[i] = t1[(size_t)c*64 + m];
      return;
    }
    i -= 8192;
    if (i < 16768){                      // dg_ec_w0: [128][262] -> A/B [131][128]
      int m = i >> 7, c = i & 127;
      float bb = d0[(size_t)c*262 + m];
      float dd = d0[(size_t)c*262 + 131 + m];
      waD0[i] = __fsub_rn(bb, dd); wbD0[i] = dd;
      return;
    }
    i -= 16768;
    if (i < 32768){                      // dg_ec_w1: [256][256] -> A/B [128][256]
      int m = i >> 8, c = i & 255;
      float bb = d1[(size_t)c*256 + m];
      float dd = d1[(size_t)c*256 + 128 + m];
      waD1[i] = __fsub_rn(bb, dd); wbD1[i] = dd;
      return;
    }
    i -= 32768;
    if (i < 131072){                     // dg_ec_w2: [512][512] -> A/B [256][512]
      int m = i >> 9, c = i & 511;
      float bb = d2[(size_t)c*512 + m];
      float dd = d2[(size_t)c*512 + 256 + m];
      waD2[i] = __fsub_rn(bb, dd); wbD2[i] = dd;
      return;
    }
    i -= 131072;
    if (i < 4096){                       // sa_w1: [64][64] -> w1T[m][c] (legacy, unused)
      int m = i >> 6, c = i & 63;
      w1T[i] = saw1[(size_t)c*64 + m];
    }
    return;
  }
  {                                      // ---- k_wprep2 ----
    int i = (bid-1299)*256 + threadIdx.x;
    if (i < 4096){                       // w0f: [kt][lane][e][4] (xyz + pad)
      int kt = i >> 11, r = i & 2047;
      int ln = r >> 5, ee = r & 31;
      int e = ee >> 2, j = ee & 3;
      int k = kt*32 + 8*(ln>>4) + e;
      w0f[i] = (j < 3) ? w0[k*3 + j] : 0.0f;
      return;
    }
    i -= 4096;
    if (i < 4096){                       // w1 frags: [ct*2+kt][lane][e], B[k][c]=w1[c][k]
      int e = i & 7, ln = (i >> 3) & 63, q = i >> 9;
      int kt = q & 1, ct = q >> 1;
      int k = kt*32 + 8*(ln>>4) + e;
      int c = ct*16 + (ln & 15);
      unsigned h16, l16; bf16_split(w1[(size_t)c*64 + k], h16, l16);
      w1fh[i] = (u16)h16; w1fl[i] = (u16)l16;
      return;
    }
    i -= 4096;
    if (i < 8192){                       // w2 frags: [c2t*2+kt][lane][e], B[k][c2]=w2[c2][k]
      int e = i & 7, ln = (i >> 3) & 63, q = i >> 9;
      int kt = q & 1, c2t = q >> 1;
      int k = kt*32 + 8*(ln>>4) + e;
      int c2 = c2t*16 + (ln & 15);
      unsigned h16, l16; bf16_split(w2[(size_t)c2*64 + k], h16, l16);
      w2fh[i] = (u16)h16; w2fl[i] = (u16)l16;
    }
  }
}

// ---------------- farthest point sampling: 2 waves, negated-register coords, tree select ----------------
// r8 proved per-iter cost is ~90% fixed serial tail (halving per-lane work changed nothing),
// so back to r5's 2-wave shape with two tail/issue fixes:
// (1) r6 postmortem: compiler discards register coord arrays that provably EQUAL the staged
//     LDS copies and re-reads 96 ds_read_b32/iter. Store NEGATED coords in registers
//     (-x,-y,-z): not LDS-equal -> must stay resident (~155 VGPR, fits (128,1) budget).
//     dx = fadd(nx,Px) = Px-x = -(x-Px); its square is bit-identical to (x-Px)^2.
// (2) serial 32-deep select chain -> 4 independent max-key chains + 3-op merge. Keys are
//     unique (embed 4095-j), so max under any order == the old strict-> serial winner.
// LDS lx/ly/lz kept only for the uniform-address (broadcast) winner lookup.
// FPS selections remain bit-identical to all previously verified versions.
__global__ __launch_bounds__(128, 1) void k_fps(const float* __restrict__ xyz, float* __restrict__ new_xyz){
  __shared__ __align__(16) float lx[NN], ly[NN], lz[NN];
  __shared__ __align__(16) ull wkey[2][2];
  int b = blockIdx.x, t = threadIdx.x;
  int w = t >> 6, lane = t & 63;
  float nx[32], ny[32], nz[32], dist[32];
#pragma unroll
  for (int q = 0; q < 32; ++q){
    int j = q*128 + t;
    const float* p = xyz + ((size_t)b*NN + j)*3;
    float X = p[0], Y = p[1], Z = p[2];
    lx[j] = X; ly[j] = Y; lz[j] = Z;
    nx[q] = -X; ny[q] = -Y; nz[q] = -Z;
    dist[q] = __builtin_inff();
  }
  const float* p0 = xyz + (size_t)b*NN*3;
  float Px = p0[0], Py = p0[1], Pz = p0[2];
  __syncthreads();                      // LDS point stage visible to both waves
  for (int it = 0; it < NPp; ++it){
    if (t == 0){                        // output BEFORE update: out[it] = current P
      float* o = new_xyz + ((size_t)b*NPp + it)*3;
      o[0] = Px; o[1] = Py; o[2] = Pz;
    }
    ull ka0 = 0, ka1 = 0, ka2 = 0, ka3 = 0;
#pragma unroll
    for (int q = 0; q < 32; ++q){
      float dx = __fadd_rn(nx[q], Px);  // = Px - x; dx*dx == (x-Px)^2 bitwise
      float dy = __fadd_rn(ny[q], Py);
      float dz = __fadd_rn(nz[q], Pz);
      float dd = __fadd_rn(__fadd_rn(__fmul_rn(dx,dx), __fmul_rn(dy,dy)), __fmul_rn(dz,dz));
      float dm = fminf(dist[q], dd);
      dist[q] = dm;
      ull key = ((ull)__float_as_uint(dm) << 32) | (unsigned)(4095 - (q*128 + t));
      if      ((q & 3) == 0){ if (key > ka0) ka0 = key; }
      else if ((q & 3) == 1){ if (key > ka1) ka1 = key; }
      else if ((q & 3) == 2){ if (key > ka2) ka2 = key; }
      else                  { if (key > ka3) ka3 = key; }
    }
    ull kb0 = (ka0 > ka1) ? ka0 : ka1;
    ull kb1 = (ka2 > ka3) ? ka2 : ka3;
    ull bk  = (kb0 > kb1) ? kb0 : kb1;
    // wave reduce to lane63 (key only)
#define FPS_STAGE(C) { \
    unsigned ol = (unsigned)dpp_i<C>((int)(unsigned)bk); \
    unsigned oh = (unsigned)dpp_i<C>((int)(unsigned)(bk >> 32)); \
    ull ok = ((ull)oh << 32) | ol; \
    if (ok > bk) bk = ok; }
    FPS_STAGE(0x111) FPS_STAGE(0x112) FPS_STAGE(0x114) FPS_STAGE(0x118)
    FPS_STAGE(0x142) FPS_STAGE(0x143)
#undef FPS_STAGE
    int par = it & 1;
    if (lane == 63) wkey[par][w] = bk;
    __syncthreads();
    ull k0 = wkey[par][0], k1 = wkey[par][1];
    ull kw = (k0 > k1) ? k0 : k1;
    int idx = 4095 - (int)(unsigned)(kw & 0xFFFFFFFFu);
    Px = lx[idx]; Py = ly[idx]; Pz = lz[idx];
  }
}

// ---------------- ball query + SA convs + maxpool: MFMA split-bf16 version ----------------
__global__ __launch_bounds__(64) void k_sa(const float* __restrict__ pts,
    const float* __restrict__ xyz, const float* __restrict__ xnrm,
    const float* __restrict__ new_xyz, const float* __restrict__ w0f,
    const u16* __restrict__ w1fh, const u16* __restrict__ w1fl,
    const u16* __restrict__ w2fh, const u16* __restrict__ w2fl,
    float* __restrict__ feat, float* __restrict__ x131){
  __shared__ __align__(16) u16 hh[64*64];
  __shared__ __align__(16) u16 hl[64*64];
  __shared__ int gw[64];
  int bi = blockIdx.x;
  int lane = threadIdx.x;
  int b = bi >> 8;
  const float* q = new_xyz + (size_t)bi*3;
  float qx=q[0], qy=q[1], qz=q[2];
  float nq = __fadd_rn(__fadd_rn(__fmul_rn(qx,qx), __fmul_rn(qy,qy)), __fmul_rn(qz,qz));
  // ball query: no early exit (removes the control dependency; all loads pipeline)
  const float* pX = pts + (size_t)(b*3+0)*NN;
  const float* pY = pts + (size_t)(b*3+1)*NN;
  const float* pZ = pts + (size_t)(b*3+2)*NN;
  int cnt = 0;
  for (int base = 0; base < NN; base += 256){
#pragma unroll
    for (int u = 0; u < 4; ++u){
      int j = base + u*64 + lane;
      float X = pX[j], Y = pY[j], Z = pZ[j];
      float dot = __fadd_rn(__fadd_rn(__fmul_rn(qx,X), __fmul_rn(qy,Y)), __fmul_rn(qz,Z));
      float d2 = __fsub_rn(__fadd_rn(nq, xnrm[b*NN + j]), __fmul_rn(2.0f, dot));
      bool inb = d2 < 0.04f;
      unsigned long long m = __ballot(inb);
      int pos = cnt + (int)__popcll(m & ((1ull << lane) - 1ull));
      if (inb && pos < NSs) gw[pos] = j;
      cnt += (int)__popcll(m);
    }
  }
  int g0 = gw[0];
  if (lane >= cnt) gw[lane] = g0;
  // own sample point (lane = sample), relative to query
  int gj = gw[lane];
  const float* pp = xyz + ((size_t)b*NN + gj)*3;
  float px = pp[0]-qx, py = pp[1]-qy, pz = pp[2]-qz;
  // broadcast sample coords for each s-tile: lane needs sample s = (lane&15)+16t
  int col = lane & 15, g = lane >> 4;
  float sxv[4], syv[4], szv[4];
#pragma unroll
  for (int t2 = 0; t2 < 4; ++t2){
    int src = col + 16*t2;
    sxv[t2] = __shfl(px, src);
    syv[t2] = __shfl(py, src);
    szv[t2] = __shfl(pz, src);
  }
  // h0 A-fragments built directly in registers: elem e holds h0[s][k=kt*32+8g+e]
  i32x4 ah0[4][2], al0[4][2];
#pragma unroll
  for (int kt = 0; kt < 2; ++kt){
    float4 wrow[8];
    const float4* wp = (const float4*)(w0f + (size_t)(kt*64 + lane)*32);
#pragma unroll
    for (int e = 0; e < 8; ++e) wrow[e] = wp[e];
#pragma unroll
    for (int t2 = 0; t2 < 4; ++t2){
      unsigned hu[8], lu[8];
#pragma unroll
      for (int e = 0; e < 8; ++e){
        float a = fmaf(wrow[e].z, szv[t2], fmaf(wrow[e].y, syv[t2], wrow[e].x*sxv[t2]));
        a = fmaxf(a, 0.0f);
        bf16_split(a, hu[e], lu[e]);
      }
      i32x4 H, L;
#pragma unroll
      for (int j2 = 0; j2 < 4; ++j2){
        H[j2] = (int)(hu[2*j2] | (hu[2*j2+1] << 16));
        L[j2] = (int)(lu[2*j2] | (lu[2*j2+1] << 16));
      }
      ah0[t2][kt] = H; al0[t2][kt] = L;
    }
  }
  // conv2 via MFMA: D[s][c] = sum_k h0[s][k] * W1[k][c]; relu; split; store to swizzled LDS
#pragma unroll
  for (int ct = 0; ct < 4; ++ct){
    bf16x8 bh[2], bl[2];
#pragma unroll
    for (int kt = 0; kt < 2; ++kt){
      bh[kt] = *(const bf16x8*)(w1fh + (size_t)((ct*2+kt)*64 + lane)*8);
      bl[kt] = *(const bf16x8*)(w1fl + (size_t)((ct*2+kt)*64 + lane)*8);
    }
#pragma unroll
    for (int t2 = 0; t2 < 4; ++t2){
      f32x4 acc = {0.f,0.f,0.f,0.f};
#pragma unroll
      for (int kt = 0; kt < 2; ++kt){
        bf16x8 Ah = __builtin_bit_cast(bf16x8, ah0[t2][kt]);
        bf16x8 Al = __builtin_bit_cast(bf16x8, al0[t2][kt]);
        acc = __builtin_amdgcn_mfma_f32_16x16x32_bf16(Ah, bh[kt], acc, 0, 0, 0);
        acc = __builtin_amdgcn_mfma_f32_16x16x32_bf16(Ah, bl[kt], acc, 0, 0, 0);
        acc = __builtin_amdgcn_mfma_f32_16x16x32_bf16(Al, bh[kt], acc, 0, 0, 0);
      }
#pragma unroll
      for (int r = 0; r < 4; ++r){
        float v = fmaxf(acc[r], 0.0f);           // relu(h1)
        int s = 16*t2 + 4*g + r;                 // D row = sample (m89-verified layout)
        int cc = ct*16 + col;                    // D col = channel
        int idx = s*64 + (cc ^ ((s & 7) << 3));  // XOR swizzle, bank-balanced
        unsigned h16, l16; bf16_split(v, h16, l16);
        hh[idx] = (u16)h16; hl[idx] = (u16)l16;
      }
    }
  }
  // conv3 A-fragments from LDS (same swizzle; 8 consecutive u16 stay contiguous)
  bf16x8 a1h[4][2], a1l[4][2];
#pragma unroll
  for (int t2 = 0; t2 < 4; ++t2){
    int s = col + 16*t2;
    int sw = (s & 7) << 3;
#pragma unroll
    for (int kt = 0; kt < 2; ++kt){
      int k0 = kt*32 + 8*g;
      int idx = s*64 + (k0 ^ sw);
      a1h[t2][kt] = *(const bf16x8*)(hh + idx);
      a1l[t2][kt] = *(const bf16x8*)(hl + idx);
    }
  }
  // conv3 + samplewise maxpool per 16-channel tile
#pragma unroll
  for (int c2t = 0; c2t < 8; ++c2t){
    bf16x8 bh2[2], bl2[2];
#pragma unroll
    for (int kt = 0; kt < 2; ++kt){
      bh2[kt] = *(const bf16x8*)(w2fh + (size_t)((c2t*2+kt)*64 + lane)*8);
      bl2[kt] = *(const bf16x8*)(w2fl + (size_t)((c2t*2+kt)*64 + lane)*8);
    }
    float mx = 0.0f;                             // relu folded into max (values >= 0)
#pragma unroll
    for (int t2 = 0; t2 < 4; ++t2){
      f32x4 acc = {0.f,0.f,0.f,0.f};
#pragma unroll
      for (int kt = 0; kt < 2; ++kt){
        acc = __builtin_amdgcn_mfma_f32_16x16x32_bf16(a1h[t2][kt], bh2[kt], acc, 0, 0, 0);
        acc = __builtin_amdgcn_mfma_f32_16x16x32_bf16(a1h[t2][kt], bl2[kt], acc, 0, 0, 0);
        acc = __builtin_amdgcn_mfma_f32_16x16x32_bf16(a1l[t2][kt], bh2[kt], acc, 0, 0, 0);
      }
      mx = fmaxf(mx, fmaxf(fmaxf(acc[0], acc[1]), fmaxf(acc[2], acc[3])));
    }
    mx = fmaxf(mx, __shfl_xor(mx, 16));
    mx = fmaxf(mx, __shfl_xor(mx, 32));
    if (lane < 16){
      int c = c2t*16 + lane;
      feat[(size_t)bi*128 + c] = mx;
      x131[(size_t)bi*132 + c] = mx;
    }
  }
  if (lane < 3) x131[(size_t)bi*132 + 128 + lane] = (lane==0)?qx:((lane==1)?qy:qz);
}

// ---------------- kNN: distances in registers, u64-DPP selection, no selection LDS ----------------
template<int CIN>
__global__ __launch_bounds__(512) void k_knn3(const float* __restrict__ xT,
    const float* __restrict__ nrm, int* __restrict__ idxo){
  __shared__ __align__(16) float sch[16*256];
  int bi = blockIdx.x, t = threadIdx.x;
  int w = t >> 6, lane = t & 63;
  int b = bi >> 5;
  int coli = (bi & 31)*8 + w;
  const float* xb = xT + (size_t)b*CIN*256;
  float d0=0.f, d1=0.f, d2=0.f, d3=0.f;
  for (int m0 = 0; m0 < CIN; m0 += 16){
    int mc = (CIN - m0 < 16) ? (CIN - m0) : 16;
    for (int i = t; i < mc*64; i += 512){
      int mm = i >> 6, c4 = i & 63;
      *(float4*)(sch + mm*256 + c4*4) = *(const float4*)(xb + (size_t)(m0+mm)*256 + c4*4);
    }
    __syncthreads();
    for (int mm = 0; mm < mc; ++mm){
      float xm = sch[mm*256 + coli];
      float4 v = *(const float4*)(sch + mm*256 + 4*lane);
      d0 = fmaf(v.x, xm, d0); d1 = fmaf(v.y, xm, d1);
      d2 = fmaf(v.z, xm, d2); d3 = fmaf(v.w, xm, d3);
    }
    __syncthreads();
  }
  float ni = nrm[b*256 + coli];
  float4 dv;
  {
    int j0 = 4*lane;
    dv.x = __fsub_rn(__fadd_rn(ni, nrm[b*256 + j0+0]), __fmul_rn(2.0f, d0));
    dv.y = __fsub_rn(__fadd_rn(ni, nrm[b*256 + j0+1]), __fmul_rn(2.0f, d1));
    dv.z = __fsub_rn(__fadd_rn(ni, nrm[b*256 + j0+2]), __fmul_rn(2.0f, d2));
    dv.w = __fsub_rn(__fadd_rn(ni, nrm[b*256 + j0+3]), __fmul_rn(2.0f, d3));
  }
  for (int r = 0; r < KC; ++r){
    float bv = 3.4e38f; int bj = NPp;
    if (dv.x < bv){ bv = dv.x; bj = 4*lane+0; }
    if (dv.y < bv){ bv = dv.y; bj = 4*lane+1; }
    if (dv.z < bv){ bv = dv.z; bj = 4*lane+2; }
    if (dv.w < bv){ bv = dv.w; bj = 4*lane+3; }
    unsigned xf = __float_as_uint(bv);
    xf = (xf & 0x80000000u) ? ~xf : (xf | 0x80000000u);
    ull key = ((ull)xf << 32) | (unsigned)bj;
#define KN_STAGE(C) { \
    unsigned ol = (unsigned)dpp_i<C>((int)(unsigned)key); \
    unsigned oh = (unsigned)dpp_i<C>((int)(unsigned)(key >> 32)); \
    ull ok = ((ull)oh << 32) | ol; \
    if (ok < key) key = ok; }
    KN_STAGE(0x111) KN_STAGE(0x112) KN_STAGE(0x114) KN_STAGE(0x118)
    KN_STAGE(0x142) KN_STAGE(0x143)
#undef KN_STAGE
    int bjw = __builtin_amdgcn_readlane((int)(unsigned)key, 63);
    if (lane == 0) idxo[((size_t)b*256 + coli)*KC + r] = bjw;
    if ((bjw >> 2) == lane){
      int e = bjw & 3;
      if      (e == 0) dv.x = 3.0e38f;
      else if (e == 1) dv.y = 3.0e38f;
      else if (e == 2) dv.z = 3.0e38f;
      else             dv.w = 3.0e38f;
    }
  }
}

// ---------------- per-point dual GEMM + fused xT transpose + fused norms ----------------
template<int CIN, int COUT, int T>
__global__ __launch_bounds__(T) void k_gab(const float* __restrict__ x, int xstride,
    const float* __restrict__ wA, const float* __restrict__ wB,
    float* __restrict__ A, float* __restrict__ B, float* __restrict__ xT,
    float* __restrict__ nrm){
  constexpr int PC  = CIN + 1;
  constexpr int G   = COUT/4;
  constexpr int RS  = T/G;
  constexpr int RPT = 16/RS;
  __shared__ float xsh[16*PC];
  int bi = blockIdx.x, t = threadIdx.x;
  int g = t % G, rs = t / G;
  int i0 = bi*16;
  for (int i = t; i < 16*CIN; i += T){
    int r = i / CIN, m = i - r*CIN;
    xsh[r*PC + m] = x[(size_t)(i0+r)*xstride + m];
  }
  __syncthreads();
  {
    int bb = i0 >> 8, col0 = i0 & 255;
    float* xTb = xT + (size_t)bb*CIN*256 + col0;
    for (int i = t; i < 16*CIN; i += T){
      int m = i >> 4, r = i & 15;
      xTb[m*256 + r] = xsh[r*PC + m];
    }
  }
  if (t < 16){
    const float* xr = xsh + t*PC;
    float a = 0.0f;
    for (int m = 0; m < CIN; ++m) a = __fadd_rn(a, __fmul_rn(xr[m], xr[m]));
    nrm[i0 + t] = a;
  }
  float4 accA[RPT], accB[RPT];
#pragma unroll
  for (int rr = 0; rr < RPT; ++rr){
    accA[rr] = make_float4(0.f,0.f,0.f,0.f);
    accB[rr] = make_float4(0.f,0.f,0.f,0.f);
  }
  for (int m = 0; m < CIN; ++m){
    float4 wa = *(const float4*)(wA + (size_t)m*COUT + 4*g);
    float4 wb = *(const float4*)(wB + (size_t)m*COUT + 4*g);
#pragma unroll
    for (int rr = 0; rr < RPT; ++rr){
      float xv = xsh[(rs + rr*RS)*PC + m];
      accA[rr] = fma4s(wa, xv, accA[rr]);
      accB[rr] = fma4s(wb, xv, accB[rr]);
    }
  }
#pragma unroll
  for (int rr = 0; rr < RPT; ++rr){
    int r = i0 + rs + rr*RS;
    *(float4*)(A + (size_t)r*COUT + 4*g) = accA[rr];
    *(float4*)(B + (size_t)r*COUT + 4*g) = accB[rr];
  }
}

// ---------------- edge epilogue: out[i][c] = max_k relu(A[i][c] + B[j_ik][c]) ----------------
template<int COUT>
__global__ __launch_bounds__(256) void k_emax(const float* __restrict__ A, const float* __restrict__ Bm,
    const int* __restrict__ idx, float* __restrict__ out){
  constexpr int GT = COUT/4;
  constexpr int NC = 256/GT;
  __shared__ int js[NC*KC];
  int bi = blockIdx.x, t = threadIdx.x;
  int li = t / GT, c4 = (t % GT)*4;
  int ci = bi*NC + li;
  int rb = (ci >> 8) << 8;
  if (t < NC*KC) js[t] = idx[(size_t)bi*NC*KC + t];
  __syncthreads();
  float4 a = *(const float4*)(A + (size_t)ci*COUT + c4);
  float4 p = make_float4(0.f,0.f,0.f,0.f);
#pragma unroll
  for (int k = 0; k < KC; ++k){
    int j = js[li*KC + k];
    float4 b = *(const float4*)(Bm + (size_t)(rb + j)*COUT + c4);
    p = max4(p, add4(a, b));
  }
  *(float4*)(out + (size_t)ci*COUT + c4) = p;
}

// ---------------- T-Net edge: h0 = relu(A0+B0) then 64->128 conv + k-maxpool ----------------
__global__ __launch_bounds__(128) void k_tedge3(const float* __restrict__ A0, const float* __restrict__ B0,
    const int* __restrict__ idx, const float* __restrict__ wt1, float* __restrict__ out){
  __shared__ __align__(16) float h0s[20*68];
  __shared__ __align__(16) float smax[4*128];
  __shared__ int js[KC];
  int bi = blockIdx.x, t = threadIdx.x;
  int cg = t & 31, kg = t >> 5, k0 = kg*5;
  int rb = (bi >> 8) << 8;
  if (t < KC) js[t] = idx[(size_t)bi*KC + t];
  __syncthreads();
  for (int i = t; i < 20*64; i += 128){
    int k = i >> 6, c = i & 63;
    float v = A0[(size_t)bi*64 + c] + B0[(size_t)(rb + js[k])*64 + c];
    h0s[k*68 + c] = fmaxf(v, 0.0f);
  }
  __syncthreads();
  float4 b2[5];
#pragma unroll
  for (int kk = 0; kk < 5; ++kk) b2[kk] = make_float4(0.f,0.f,0.f,0.f);
  for (int m4 = 0; m4 < 16; ++m4){
    float4 e[5];
#pragma unroll
    for (int kk = 0; kk < 5; ++kk) e[kk] = *(const float4*)(h0s + (k0+kk)*68 + 4*m4);
#pragma unroll
    for (int mm = 0; mm < 4; ++mm){
      float4 w = *(const float4*)(wt1 + (4*m4+mm)*128 + 4*cg);
#pragma unroll
      for (int kk = 0; kk < 5; ++kk){
        float ev = (mm==0)?e[kk].x:((mm==1)?e[kk].y:((mm==2)?e[kk].z:e[kk].w));
        b2[kk] = fma4s(w, ev, b2[kk]);
      }
    }
  }
  float4 p = make_float4(0.f,0.f,0.f,0.f);
#pragma unroll
  for (int kk = 0; kk < 5; ++kk) p = max4(p, b2[kk]);
  *(float4*)(smax + kg*128 + 4*cg) = p;
  __syncthreads();
  if (kg == 0){
    float4 r = *(const float4*)(smax + 4*cg);
#pragma unroll
    for (int g = 1; g < 4; ++g) r = max4(r, *(const float4*)(smax + g*128 + 4*cg));
    *(float4*)(out + (size_t)bi*128 + 4*cg) = r;
  }
}

// ---------------- T-Net 128->1024 + pool: 8 point-chunks, atomicMax combine ----------------
__global__ __launch_bounds__(128) void k_tpool(const float* __restrict__ h, const float* __restrict__ W,
    float* __restrict__ g1024){
  int b = blockIdx.x, t = threadIdx.x;
  int c = blockIdx.y*128 + t;
  int i0 = blockIdx.z*32;
  float4 w[32];
#pragma unroll
  for (int qq = 0; qq < 32; ++qq) w[qq] = *(const float4*)(W + (size_t)c*128 + 4*qq);
  const float* hb = h + (size_t)b*NPp*128;
  float mx = 0.0f;
  for (int i = i0; i < i0 + 32; ++i){
    const float4* hr = (const float4*)(hb + (size_t)i*128);
    float a = 0.0f;
#pragma unroll
    for (int qq = 0; qq < 32; ++qq) a = fma4(w[qq], hr[qq], a);
    mx = fmaxf(mx, a);
  }
  atomicMax((int*)(g1024 + (size_t)b*1024 + c), __float_as_int(mx));
}

// ---------------- T-Net MLP + 3x3 transform applied to new_xyz ----------------
__global__ __launch_bounds__(256) void k_trest(const float* __restrict__ g1024,
    const float* __restrict__ Wg0, const float* __restrict__ Wg1,
    const float* __restrict__ Wl, const float* __restrict__ bl,
    const float* __restrict__ new_xyz, float* __restrict__ x131){
  __shared__ __align__(16) float g1[1024];
  __shared__ __align__(16) float g5[512];
  __shared__ __align__(16) float g2[256];
  __shared__ float tm[12];
  int b = blockIdx.x, t = threadIdx.x;
  for (int m = t; m < 1024; m += 256) g1[m] = g1024[(size_t)b*1024 + m];
  __syncthreads();
#pragma unroll
  for (int cc = 0; cc < 2; ++cc){
    int c = t + cc*256;
    const float4* wr = (const float4*)(Wg0 + (size_t)c*1024);
    const float4* gv = (const float4*)g1;
    float a = 0.0f;
    for (int qq = 0; qq < 256; ++qq) a = fma4(wr[qq], gv[qq], a);
    g5[c] = fmaxf(a, 0.0f);
  }
  __syncthreads();
  {
    const float4* wr = (const float4*)(Wg1 + (size_t)t*512);
    const float4* gv = (const float4*)g5;
    float a = 0.0f;
    for (int qq = 0; qq < 128; ++qq) a = fma4(wr[qq], gv[qq], a);
    g2[t] = fmaxf(a, 0.0f);
  }
  __syncthreads();
  if (t < 9){
    const float4* wr = (const float4*)(Wl + (size_t)t*256);
    const float4* gv = (const float4*)g2;
    float a = 0.0f;
#pragma unroll
    for (int qq = 0; qq < 64; ++qq) a = fma4(wr[qq], gv[qq], a);
    a += bl[t];
    if (t == 0 || t == 4 || t == 8) a += 1.0f;
    tm[t] = a;
  }
  __syncthreads();
  {
    const float* nx = new_xyz + ((size_t)b*NPp + t)*3;
    float X = nx[0], Y = nx[1], Z = nx[2];
#pragma unroll
    for (int i = 0; i < 3; ++i){
      float v = __fadd_rn(__fadd_rn(__fmul_rn(tm[i*3+0], X), __fmul_rn(tm[i*3+1], Y)), __fmul_rn(tm[i*3+2], Z));
      x131[((size_t)b*NPp + t)*132 + 128 + i] = v;
    }
  }
}

// ---------------- 896->128 conv + global max pool (atomicMax; poison is negative int) ----------------
__global__ __launch_bounds__(128) void k_dgl(const float* __restrict__ f1, const float* __restrict__ f2,
    const float* __restrict__ f3, const float* __restrict__ W, float* __restrict__ g128){
  int b = blockIdx.x, t = threadIdx.x;
  int i0 = blockIdx.y * 16;
  const float* wr = W + (size_t)t*896;
  float acc[16];
#pragma unroll
  for (int ii = 0; ii < 16; ++ii) acc[ii] = 0.0f;
  for (int q = 0; q < 32; ++q){
    float4 w = *(const float4*)(wr + 4*q);
#pragma unroll
    for (int ii = 0; ii < 16; ++ii){
      float4 v = *(const float4*)(f1 + ((size_t)b*NPp + i0 + ii)*128 + 4*q);
      acc[ii] = fma4(w, v, acc[ii]);
    }
  }
  for (int q = 0; q < 64; ++q){
    float4 w = *(const float4*)(wr + 128 + 4*q);
#pragma unroll
    for (int ii = 0; ii < 16; ++ii){
      float4 v = *(const float4*)(f2 + ((size_t)b*NPp + i0 + ii)*256 + 4*q);
      acc[ii] = fma4(w, v, acc[ii]);
    }
  }
  for (int q = 0; q < 128; ++q){
    float4 w = *(const float4*)(wr + 384 + 4*q);
#pragma unroll
    for (int ii = 0; ii < 16; ++ii){
      float4 v = *(const float4*)(f3 + ((size_t)b*NPp + i0 + ii)*512 + 4*q);
      acc[ii] = fma4(w, v, acc[ii]);
    }
  }
#pragma unroll
  for (int ii = 0; ii < 16; ++ii){
    float v = fmaxf(acc[ii], 0.0f);
    atomicMax((int*)(g128 + (size_t)b*128 + t), __float_as_int(v));
  }
}

// ---------------- classifier head ----------------
__global__ __launch_bounds__(256) void k_final(const float* __restrict__ g128,
    const float* __restrict__ W0, const float* __restrict__ W1,
    const float* __restrict__ Wc, const float* __restrict__ bc, float* __restrict__ out){
  __shared__ __align__(16) float g0[128];
  __shared__ __align__(16) float g5[512];
  __shared__ __align__(16) float g2[256];
  int b = blockIdx.x, t = threadIdx.x;
  if (t < 128) g0[t] = g128[(size_t)b*128 + t];
  __syncthreads();
#pragma unroll
  for (int cc = 0; cc < 2; ++cc){
    int c = t + cc*256;
    const float4* wr = (const float4*)(W0 + (size_t)c*128);
    const float4* gv = (const float4*)g0;
    float a = 0.0f;
#pragma unroll
    for (int qq = 0; qq < 32; ++qq) a = fma4(wr[qq], gv[qq], a);
    g5[c] = fmaxf(a, 0.0f);
  }
  __syncthreads();
  {
    const float4* wr = (const float4*)(W1 + (size_t)t*512);
    const float4* gv = (const float4*)g5;
    float a = 0.0f;
    for (int qq = 0; qq < 128; ++qq) a = fma4(wr[qq], gv[qq], a);
    g2[t] = fmaxf(a, 0.0f);
  }
  __syncthreads();
  if (t < 40){
    const float4* wr = (const float4*)(Wc + (size_t)t*256);
    const float4* gv = (const float4*)g2;
    float a = 0.0f;
#pragma unroll
    for (int qq = 0; qq < 64; ++qq) a = fma4(wr[qq], gv[qq], a);
    out[(size_t)b*40 + t] = a + bc[t];
  }
}

extern "C" void kernel_launch(void* const* d_in, const int* in_sizes, int n_in,
                              void* d_out, int out_size, void* d_ws, size_t ws_size,
                              hipStream_t stream){
  (void)in_sizes; (void)n_in; (void)out_size; (void)ws_size;
  const float* points     = (const float*)d_in[0];
  const float* sa_w0      = (const float*)d_in[1];
  const float* sa_w1      = (const float*)d_in[2];
  const float* sa_w2      = (const float*)d_in[3];
  const float* t_ec_w0    = (const float*)d_in[4];
  const float* t_ec_w1    = (const float*)d_in[5];
  const float* t_local_w  = (const float*)d_in[6];
  const float* t_g_w0     = (const float*)d_in[7];
  const float* t_g_w1     = (const float*)d_in[8];
  const float* t_lin_w    = (const float*)d_in[9];
  const float* t_lin_b    = (const float*)d_in[10];
  const float* dg_ec_w0   = (const float*)d_in[11];
  const float* dg_ec_w1   = (const float*)d_in[12];
  const float* dg_ec_w2   = (const float*)d_in[13];
  const float* dg_local_w = (const float*)d_in[14];
  const float* dg_g_w0    = (const float*)d_in[15];
  const float* dg_g_w1    = (const float*)d_in[16];
  const float* cls_w      = (const float*)d_in[17];
  const float* cls_b      = (const float*)d_in[18];
  float* out = (float*)d_out;

  float* ws     = (float*)d_ws;
  float* xyz    = ws;                    // 393216
  float* xnrm   = xyz    + 393216;       // 131072
  float* nxyz   = xnrm   + 131072;       // 24576
  float* feat   = nxyz   + 24576;        // 1048576
  float* x131   = feat   + 1048576;      // 1081344
  float* nrm    = x131   + 1081344;      // 8192
  int*   idx    = (int*)(nrm + 8192);    // 163840
  float* ht     = (float*)(idx + 163840);// 1048576 (reused as f1)
  float* g1024v = ht     + 1048576;      // 32768
  float* f2     = g1024v + 32768;        // 2097152
  float* f3     = f2     + 2097152;      // 4194304
  float* g128v  = f3     + 4194304;      // 4096
  float* wt_t1  = g128v  + 4096;         // 8192   (64x128)
  float* waT0   = wt_t1  + 8192;         // 8384   (131x64)
  float* wbT0   = waT0   + 8384;         // 8384
  float* waD0   = wbT0   + 8384;         // 16768  (131x128)
  float* wbD0   = waD0   + 16768;        // 16768
  float* waD1   = wbD0   + 16768;        // 32768  (128x256)
  float* wbD1   = waD1   + 32768;        // 32768
  float* waD2   = wbD1   + 32768;        // 131072 (256x512)
  float* wbD2   = waD2   + 131072;       // 131072
  float* Ab     = wbD2   + 131072;       // 4194304
  float* Bb     = Ab     + 4194304;      // 4194304
  float* w1Tb   = Bb     + 4194304;      // 4096   (legacy, unused by k_sa now)
  float* f1 = ht;
  float* xT = f3;                        // alias: xT lives in f3 until k_emax<512> writes f3

  // SA MFMA weight fragments alias the HEAD of Ab (16384 floats << 4194304).
  // Timeline: k_prep_all writes -> k_sa reads -> k_gab (T-Net) is the first Ab write.
  float* w0f    = Ab;                    // 4096   ([kt][lane][e][4])
  u16*   w1fh   = (u16*)(w0f + 4096);    // 4096 u16
  u16*   w1fl   = w1fh   + 4096;         // 4096 u16
  u16*   w2fh   = w1fl   + 4096;         // 8192 u16
  u16*   w2fl   = w2fh   + 8192;         // 8192 u16

  k_prep_all<<<1363, 256, 0, stream>>>(points, xyz, xnrm,
                                       t_ec_w0, t_ec_w1, dg_ec_w0, dg_ec_w1, dg_ec_w2, sa_w1,
                                       waT0, wbT0, wt_t1, waD0, wbD0, waD1, wbD1, waD2, wbD2, w1Tb,
                                       sa_w0, sa_w1, sa_w2, w0f, w1fh, w1fl, w2fh, w2fl);
  k_fps<<<BB, 128, 0, stream>>>(xyz, nxyz);
  k_sa<<<BB*NPp, 64, 0, stream>>>(points, xyz, xnrm, nxyz, w0f, w1fh, w1fl, w2fh, w2fl, feat, x131);

  // T-Net branch (x = [feat, new_xyz])
  k_gab<131,64,256><<<512, 256, 0, stream>>>(x131, 132, waT0, wbT0, Ab, Bb, xT, nrm);
  k_knn3<131><<<1024, 512, 0, stream>>>(xT, nrm, idx);
  k_tedge3<<<BB*NPp, 128, 0, stream>>>(Ab, Bb, idx, wt_t1, ht);
  k_tpool<<<dim3(BB, 8, 8), 128, 0, stream>>>(ht, t_local_w, g1024v);
  k_trest<<<BB, 256, 0, stream>>>(g1024v, t_g_w0, t_g_w1, t_lin_w, t_lin_b, nxyz, x131);

  // DGCNN layer 1 (x = [feat, xyz_t], 131 dims)
  k_gab<131,128,512><<<512, 512, 0, stream>>>(x131, 132, waD0, wbD0, Ab, Bb, xT, nrm);
  k_knn3<131><<<1024, 512, 0, stream>>>(xT, nrm, idx);
  k_emax<128><<<1024, 256, 0, stream>>>(Ab, Bb, idx, f1);
  // layer 2
  k_gab<128,256,512><<<512, 512, 0, stream>>>(f1, 128, waD1, wbD1, Ab, Bb, xT, nrm);
  k_knn3<128><<<1024, 512, 0, stream>>>(xT, nrm, idx);
  k_emax<256><<<2048, 256, 0, stream>>>(Ab, Bb, idx, f2);
  // layer 3
  k_gab<256,512,512><<<512, 512, 0, stream>>>(f2, 256, waD2, wbD2, Ab, Bb, xT, nrm);
  k_knn3<256><<<1024, 512, 0, stream>>>(xT, nrm, idx);
  k_emax<512><<<4096, 256, 0, stream>>>(Ab, Bb, idx, f3);

  // local conv + global pool + head
  k_dgl<<<dim3(BB, 16), 128, 0, stream>>>(f1, f2, f3, dg_local_w, g128v);
  k_final<<<BB, 256, 0, stream>>>(g128v, dg_g_w0, dg_g_w1, cls_w, cls_b, out);
}

// Round 10
// 1146.934 us; speedup vs baseline: 1.2168x; 1.0825x over previous
//
#include <hip/hip_runtime.h>
#include <math.h>

#define BB 32
#define NN 4096
#define NPp 256
#define NSs 64
#define KC 20

typedef unsigned long long ull;
typedef unsigned short u16;
typedef short bf16x8 __attribute__((ext_vector_type(8)));
typedef float f32x4 __attribute__((ext_vector_type(4)));
typedef int i32x4 __attribute__((ext_vector_type(4)));

__device__ __forceinline__ float fma4(const float4 w, const float4 v, float a){
  a = fmaf(w.x, v.x, a); a = fmaf(w.y, v.y, a);
  a = fmaf(w.z, v.z, a); a = fmaf(w.w, v.w, a); return a;
}
__device__ __forceinline__ float4 fma4s(const float4 w, float s, float4 a){
  a.x = fmaf(w.x, s, a.x); a.y = fmaf(w.y, s, a.y);
  a.z = fmaf(w.z, s, a.z); a.w = fmaf(w.w, s, a.w); return a;
}
__device__ __forceinline__ float4 max4(float4 a, float4 b){
  a.x = fmaxf(a.x, b.x); a.y = fmaxf(a.y, b.y);
  a.z = fmaxf(a.z, b.z); a.w = fmaxf(a.w, b.w); return a;
}
__device__ __forceinline__ float4 add4(float4 a, float4 b){
  a.x += b.x; a.y += b.y; a.z += b.z; a.w += b.w; return a;
}

template<int C>
__device__ __forceinline__ int dpp_i(int x){
  return __builtin_amdgcn_update_dpp(x, x, C, 0xf, 0xf, false);
}

// split fp32 -> bf16 hi + bf16 lo (truncating; v - hi is exact in fp32)
__device__ __host__ __forceinline__ void bf16_split(float v, unsigned& h16, unsigned& l16){
  unsigned bits = __float_as_uint(v);
  h16 = bits >> 16;
  float hf = __uint_as_float(h16 << 16);
  l16 = __float_as_uint(v - hf) >> 16;
}

// ---------------- fused prep: transpose/norms + weight prep + MFMA weight frags ----------------
// blocks [0,512): k_prep; [512,1299): k_wprep; [1299,1363): k_wprep2 (SA frags);
// [1363,2643): split-bf16 frags for the layer-2/3 dual-GEMM weights, computed DIRECTLY
// from d1/d2 (same arithmetic as k_wprep: A = bb-dd, B = dd) -- no intra-launch deps.
// Frag layout (mirrors the k_sa-verified mapping): [ct][kt][lane][e], value W[k][c],
// k = kt*32 + 8*(lane>>4) + e, c = ct*16 + (lane&15).
__global__ void k_prep_all(const float* __restrict__ pts, float* __restrict__ xyz, float* __restrict__ xnrm,
                           const float* __restrict__ t0, const float* __restrict__ t1,
                           const float* __restrict__ d0, const float* __restrict__ d1,
                           const float* __restrict__ d2, const float* __restrict__ saw1,
                           float* __restrict__ waT0, float* __restrict__ wbT0,
                           float* __restrict__ wt_t1,
                           float* __restrict__ waD0, float* __restrict__ wbD0,
                           float* __restrict__ waD1, float* __restrict__ wbD1,
                           float* __restrict__ waD2, float* __restrict__ wbD2,
                           float* __restrict__ w1T,
                           const float* __restrict__ w0, const float* __restrict__ w1,
                           const float* __restrict__ w2,
                           float* __restrict__ w0f, u16* __restrict__ w1fh, u16* __restrict__ w1fl,
                           u16* __restrict__ w2fh, u16* __restrict__ w2fl,
                           u16* __restrict__ wAD1h, u16* __restrict__ wAD1l,
                           u16* __restrict__ wBD1h, u16* __restrict__ wBD1l,
                           u16* __restrict__ wAD2h, u16* __restrict__ wAD2l,
                           u16* __restrict__ wBD2h, u16* __restrict__ wBD2l){
  int bid = blockIdx.x;
  if (bid < 512){                        // ---- k_prep ----
    int i = bid*256 + threadIdx.x;
    if (i >= BB*NN) return;
    int b = i >> 12, n = i & (NN-1);
    float X = pts[(b*3+0)*NN + n];
    float Y = pts[(b*3+1)*NN + n];
    float Z = pts[(b*3+2)*NN + n];
    xyz[i*3+0]=X; xyz[i*3+1]=Y; xyz[i*3+2]=Z;
    xnrm[i] = __fadd_rn(__fadd_rn(__fmul_rn(X,X), __fmul_rn(Y,Y)), __fmul_rn(Z,Z));
    return;
  }
  if (bid < 1299){                       // ---- k_wprep ----
    int i = (bid-512)*256 + threadIdx.x;
    if (i < 8384){                       // t_ec_w0: [64][262] -> A/B [131][64]
      int m = i >> 6;
      int c = i & 63;
      float bb = t0[(size_t)c*262 + m];
      float dd = t0[(size_t)c*262 + 131 + m];
      waT0[i] = __fsub_rn(bb, dd); wbT0[i] = dd;
      return;
    }
    i -= 8384;
    if (i < 8192){                       // t_ec_w1: [128][64] -> [64][128]
      int m = i >> 7, c = i & 127;
      wt_t1[i] = t1[(size_t)c*64 + m];
      return;
    }
    i -= 8192;
    if (i < 16768){                      // dg_ec_w0: [128][262] -> A/B [131][128]
      int m = i >> 7, c = i & 127;
      float bb = d0[(size_t)c*262 + m];
      float dd = d0[(size_t)c*262 + 131 + m];
      waD0[i] = __fsub_rn(bb, dd); wbD0[i] = dd;
      return;
    }
    i -= 16768;
    if (i < 32768){                      // dg_ec_w1: [256][256] -> A/B [128][256]
      int m = i >> 8, c = i & 255;
      float bb = d1[(size_t)c*256 + m];
      float dd = d1[(size_t)c*256 + 128 + m];
      waD1[i] = __fsub_rn(bb, dd); wbD1[i] = dd;
      return;
    }
    i -= 32768;
    if (i < 131072){                     // dg_ec_w2: [512][512] -> A/B [256][512]
      int m = i >> 9, c = i & 511;
      float bb = d2[(size_t)c*512 + m];
      float dd = d2[(size_t)c*512 + 256 + m];
      waD2[i] = __fsub_rn(bb, dd); wbD2[i] = dd;
      return;
    }
    i -= 131072;
    if (i < 4096){                       // sa_w1: [64][64] -> w1T[m][c] (legacy, unused)
      int m = i >> 6, c = i & 63;
      w1T[i] = saw1[(size_t)c*64 + m];
    }
    return;
  }
  if (bid < 1363){                       // ---- k_wprep2 (SA frags) ----
    int i = (bid-1299)*256 + threadIdx.x;
    if (i < 4096){                       // w0f: [kt][lane][e][4] (xyz + pad)
      int kt = i >> 11, r = i & 2047;
      int ln = r >> 5, ee = r & 31;
      int e = ee >> 2, j = ee & 3;
      int k = kt*32 + 8*(ln>>4) + e;
      w0f[i] = (j < 3) ? w0[k*3 + j] : 0.0f;
      return;
    }
    i -= 4096;
    if (i < 4096){                       // w1 frags: [ct*2+kt][lane][e], B[k][c]=w1[c][k]
      int e = i & 7, ln = (i >> 3) & 63, q = i >> 9;
      int kt = q & 1, ct = q >> 1;
      int k = kt*32 + 8*(ln>>4) + e;
      int c = ct*16 + (ln & 15);
      unsigned h16, l16; bf16_split(w1[(size_t)c*64 + k], h16, l16);
      w1fh[i] = (u16)h16; w1fl[i] = (u16)l16;
      return;
    }
    i -= 4096;
    if (i < 8192){                       // w2 frags: [c2t*2+kt][lane][e], B[k][c2]=w2[c2][k]
      int e = i & 7, ln = (i >> 3) & 63, q = i >> 9;
      int kt = q & 1, c2t = q >> 1;
      int k = kt*32 + 8*(ln>>4) + e;
      int c2 = c2t*16 + (ln & 15);
      unsigned h16, l16; bf16_split(w2[(size_t)c2*64 + k], h16, l16);
      w2fh[i] = (u16)h16; w2fl[i] = (u16)l16;
    }
    return;
  }
  {                                      // ---- layer-2/3 GEMM weight frags ----
    int i = (bid-1363)*256 + threadIdx.x;
    if (i < 32768){                      // D1 wA: [ct(16)][kt(4)][lane][e]
      int e = i & 7, ln = (i >> 3) & 63, q = i >> 9;   // q in [0,64)
      int kt = q & 3, ct = q >> 2;
      int k = kt*32 + 8*(ln>>4) + e;
      int c = ct*16 + (ln & 15);
      float bb = d1[(size_t)c*256 + k], dd = d1[(size_t)c*256 + 128 + k];
      unsigned h, l; bf16_split(__fsub_rn(bb, dd), h, l);
      wAD1h[i] = (u16)h; wAD1l[i] = (u16)l;
      return;
    }
    i -= 32768;
    if (i < 32768){                      // D1 wB
      int e = i & 7, ln = (i >> 3) & 63, q = i >> 9;
      int kt = q & 3, ct = q >> 2;
      int k = kt*32 + 8*(ln>>4) + e;
      int c = ct*16 + (ln & 15);
      float dd = d1[(size_t)c*256 + 128 + k];
      unsigned h, l; bf16_split(dd, h, l);
      wBD1h[i] = (u16)h; wBD1l[i] = (u16)l;
      return;
    }
    i -= 32768;
    if (i < 131072){                     // D2 wA: [ct(32)][kt(8)][lane][e]
      int e = i & 7, ln = (i >> 3) & 63, q = i >> 9;   // q in [0,256)
      int kt = q & 7, ct = q >> 3;
      int k = kt*32 + 8*(ln>>4) + e;
      int c = ct*16 + (ln & 15);
      float bb = d2[(size_t)c*512 + k], dd = d2[(size_t)c*512 + 256 + k];
      unsigned h, l; bf16_split(__fsub_rn(bb, dd), h, l);
      wAD2h[i] = (u16)h; wAD2l[i] = (u16)l;
      return;
    }
    i -= 131072;
    if (i < 131072){                     // D2 wB
      int e = i & 7, ln = (i >> 3) & 63, q = i >> 9;
      int kt = q & 7, ct = q >> 3;
      int k = kt*32 + 8*(ln>>4) + e;
      int c = ct*16 + (ln & 15);
      float dd = d2[(size_t)c*512 + 256 + k];
      unsigned h, l; bf16_split(dd, h, l);
      wBD2h[i] = (u16)h; wBD2l[i] = (u16)l;
    }
  }
}

// ---------------- farthest point sampling: 2 waves, key-only reduce (parked at floor) ----------------
__global__ __launch_bounds__(128, 1) void k_fps(const float* __restrict__ xyz, float* __restrict__ new_xyz){
  __shared__ __align__(16) float lx[NN], ly[NN], lz[NN];
  __shared__ __align__(16) ull wkey[2][2];
  int b = blockIdx.x, t = threadIdx.x;
  int w = t >> 6, lane = t & 63;
  float nx[32], ny[32], nz[32], dist[32];
#pragma unroll
  for (int q = 0; q < 32; ++q){
    int j = q*128 + t;
    const float* p = xyz + ((size_t)b*NN + j)*3;
    float X = p[0], Y = p[1], Z = p[2];
    lx[j] = X; ly[j] = Y; lz[j] = Z;
    nx[q] = -X; ny[q] = -Y; nz[q] = -Z;
    dist[q] = __builtin_inff();
  }
  const float* p0 = xyz + (size_t)b*NN*3;
  float Px = p0[0], Py = p0[1], Pz = p0[2];
  __syncthreads();
  for (int it = 0; it < NPp; ++it){
    if (t == 0){
      float* o = new_xyz + ((size_t)b*NPp + it)*3;
      o[0] = Px; o[1] = Py; o[2] = Pz;
    }
    ull ka0 = 0, ka1 = 0, ka2 = 0, ka3 = 0;
#pragma unroll
    for (int q = 0; q < 32; ++q){
      float dx = __fadd_rn(nx[q], Px);
      float dy = __fadd_rn(ny[q], Py);
      float dz = __fadd_rn(nz[q], Pz);
      float dd = __fadd_rn(__fadd_rn(__fmul_rn(dx,dx), __fmul_rn(dy,dy)), __fmul_rn(dz,dz));
      float dm = fminf(dist[q], dd);
      dist[q] = dm;
      ull key = ((ull)__float_as_uint(dm) << 32) | (unsigned)(4095 - (q*128 + t));
      if      ((q & 3) == 0){ if (key > ka0) ka0 = key; }
      else if ((q & 3) == 1){ if (key > ka1) ka1 = key; }
      else if ((q & 3) == 2){ if (key > ka2) ka2 = key; }
      else                  { if (key > ka3) ka3 = key; }
    }
    ull kb0 = (ka0 > ka1) ? ka0 : ka1;
    ull kb1 = (ka2 > ka3) ? ka2 : ka3;
    ull bk  = (kb0 > kb1) ? kb0 : kb1;
#define FPS_STAGE(C) { \
    unsigned ol = (unsigned)dpp_i<C>((int)(unsigned)bk); \
    unsigned oh = (unsigned)dpp_i<C>((int)(unsigned)(bk >> 32)); \
    ull ok = ((ull)oh << 32) | ol; \
    if (ok > bk) bk = ok; }
    FPS_STAGE(0x111) FPS_STAGE(0x112) FPS_STAGE(0x114) FPS_STAGE(0x118)
    FPS_STAGE(0x142) FPS_STAGE(0x143)
#undef FPS_STAGE
    int par = it & 1;
    if (lane == 63) wkey[par][w] = bk;
    __syncthreads();
    ull k0 = wkey[par][0], k1 = wkey[par][1];
    ull kw = (k0 > k1) ? k0 : k1;
    int idx = 4095 - (int)(unsigned)(kw & 0xFFFFFFFFu);
    Px = lx[idx]; Py = ly[idx]; Pz = lz[idx];
  }
}

// ---------------- ball query + SA convs + maxpool: MFMA split-bf16 (feat stores dropped) ----------------
__global__ __launch_bounds__(64) void k_sa(const float* __restrict__ pts,
    const float* __restrict__ xyz, const float* __restrict__ xnrm,
    const float* __restrict__ new_xyz, const float* __restrict__ w0f,
    const u16* __restrict__ w1fh, const u16* __restrict__ w1fl,
    const u16* __restrict__ w2fh, const u16* __restrict__ w2fl,
    float* __restrict__ x131){
  __shared__ __align__(16) u16 hh[64*64];
  __shared__ __align__(16) u16 hl[64*64];
  __shared__ int gw[64];
  int bi = blockIdx.x;
  int lane = threadIdx.x;
  int b = bi >> 8;
  const float* q = new_xyz + (size_t)bi*3;
  float qx=q[0], qy=q[1], qz=q[2];
  float nq = __fadd_rn(__fadd_rn(__fmul_rn(qx,qx), __fmul_rn(qy,qy)), __fmul_rn(qz,qz));
  const float* pX = pts + (size_t)(b*3+0)*NN;
  const float* pY = pts + (size_t)(b*3+1)*NN;
  const float* pZ = pts + (size_t)(b*3+2)*NN;
  int cnt = 0;
  for (int base = 0; base < NN; base += 256){
#pragma unroll
    for (int u = 0; u < 4; ++u){
      int j = base + u*64 + lane;
      float X = pX[j], Y = pY[j], Z = pZ[j];
      float dot = __fadd_rn(__fadd_rn(__fmul_rn(qx,X), __fmul_rn(qy,Y)), __fmul_rn(qz,Z));
      float d2 = __fsub_rn(__fadd_rn(nq, xnrm[b*NN + j]), __fmul_rn(2.0f, dot));
      bool inb = d2 < 0.04f;
      unsigned long long m = __ballot(inb);
      int pos = cnt + (int)__popcll(m & ((1ull << lane) - 1ull));
      if (inb && pos < NSs) gw[pos] = j;
      cnt += (int)__popcll(m);
    }
  }
  int g0 = gw[0];
  if (lane >= cnt) gw[lane] = g0;
  int gj = gw[lane];
  const float* pp = xyz + ((size_t)b*NN + gj)*3;
  float px = pp[0]-qx, py = pp[1]-qy, pz = pp[2]-qz;
  int col = lane & 15, g = lane >> 4;
  float sxv[4], syv[4], szv[4];
#pragma unroll
  for (int t2 = 0; t2 < 4; ++t2){
    int src = col + 16*t2;
    sxv[t2] = __shfl(px, src);
    syv[t2] = __shfl(py, src);
    szv[t2] = __shfl(pz, src);
  }
  i32x4 ah0[4][2], al0[4][2];
#pragma unroll
  for (int kt = 0; kt < 2; ++kt){
    float4 wrow[8];
    const float4* wp = (const float4*)(w0f + (size_t)(kt*64 + lane)*32);
#pragma unroll
    for (int e = 0; e < 8; ++e) wrow[e] = wp[e];
#pragma unroll
    for (int t2 = 0; t2 < 4; ++t2){
      unsigned hu[8], lu[8];
#pragma unroll
      for (int e = 0; e < 8; ++e){
        float a = fmaf(wrow[e].z, szv[t2], fmaf(wrow[e].y, syv[t2], wrow[e].x*sxv[t2]));
        a = fmaxf(a, 0.0f);
        bf16_split(a, hu[e], lu[e]);
      }
      i32x4 H, L;
#pragma unroll
      for (int j2 = 0; j2 < 4; ++j2){
        H[j2] = (int)(hu[2*j2] | (hu[2*j2+1] << 16));
        L[j2] = (int)(lu[2*j2] | (lu[2*j2+1] << 16));
      }
      ah0[t2][kt] = H; al0[t2][kt] = L;
    }
  }
#pragma unroll
  for (int ct = 0; ct < 4; ++ct){
    bf16x8 bh[2], bl[2];
#pragma unroll
    for (int kt = 0; kt < 2; ++kt){
      bh[kt] = *(const bf16x8*)(w1fh + (size_t)((ct*2+kt)*64 + lane)*8);
      bl[kt] = *(const bf16x8*)(w1fl + (size_t)((ct*2+kt)*64 + lane)*8);
    }
#pragma unroll
    for (int t2 = 0; t2 < 4; ++t2){
      f32x4 acc = {0.f,0.f,0.f,0.f};
#pragma unroll
      for (int kt = 0; kt < 2; ++kt){
        bf16x8 Ah = __builtin_bit_cast(bf16x8, ah0[t2][kt]);
        bf16x8 Al = __builtin_bit_cast(bf16x8, al0[t2][kt]);
        acc = __builtin_amdgcn_mfma_f32_16x16x32_bf16(Ah, bh[kt], acc, 0, 0, 0);
        acc = __builtin_amdgcn_mfma_f32_16x16x32_bf16(Ah, bl[kt], acc, 0, 0, 0);
        acc = __builtin_amdgcn_mfma_f32_16x16x32_bf16(Al, bh[kt], acc, 0, 0, 0);
      }
#pragma unroll
      for (int r = 0; r < 4; ++r){
        float v = fmaxf(acc[r], 0.0f);
        int s = 16*t2 + 4*g + r;
        int cc = ct*16 + col;
        int idx = s*64 + (cc ^ ((s & 7) << 3));
        unsigned h16, l16; bf16_split(v, h16, l16);
        hh[idx] = (u16)h16; hl[idx] = (u16)l16;
      }
    }
  }
  bf16x8 a1h[4][2], a1l[4][2];
#pragma unroll
  for (int t2 = 0; t2 < 4; ++t2){
    int s = col + 16*t2;
    int sw = (s & 7) << 3;
#pragma unroll
    for (int kt = 0; kt < 2; ++kt){
      int k0 = kt*32 + 8*g;
      int idx = s*64 + (k0 ^ sw);
      a1h[t2][kt] = *(const bf16x8*)(hh + idx);
      a1l[t2][kt] = *(const bf16x8*)(hl + idx);
    }
  }
#pragma unroll
  for (int c2t = 0; c2t < 8; ++c2t){
    bf16x8 bh2[2], bl2[2];
#pragma unroll
    for (int kt = 0; kt < 2; ++kt){
      bh2[kt] = *(const bf16x8*)(w2fh + (size_t)((c2t*2+kt)*64 + lane)*8);
      bl2[kt] = *(const bf16x8*)(w2fl + (size_t)((c2t*2+kt)*64 + lane)*8);
    }
    float mx = 0.0f;
#pragma unroll
    for (int t2 = 0; t2 < 4; ++t2){
      f32x4 acc = {0.f,0.f,0.f,0.f};
#pragma unroll
      for (int kt = 0; kt < 2; ++kt){
        acc = __builtin_amdgcn_mfma_f32_16x16x32_bf16(a1h[t2][kt], bh2[kt], acc, 0, 0, 0);
        acc = __builtin_amdgcn_mfma_f32_16x16x32_bf16(a1h[t2][kt], bl2[kt], acc, 0, 0, 0);
        acc = __builtin_amdgcn_mfma_f32_16x16x32_bf16(a1l[t2][kt], bh2[kt], acc, 0, 0, 0);
      }
      mx = fmaxf(mx, fmaxf(fmaxf(acc[0], acc[1]), fmaxf(acc[2], acc[3])));
    }
    mx = fmaxf(mx, __shfl_xor(mx, 16));
    mx = fmaxf(mx, __shfl_xor(mx, 32));
    if (lane < 16){
      int c = c2t*16 + lane;
      x131[(size_t)bi*132 + c] = mx;
    }
  }
  if (lane < 3) x131[(size_t)bi*132 + 128 + lane] = (lane==0)?qx:((lane==1)?qy:qz);
}

// ---------------- kNN: distances in registers, u64-DPP selection, no selection LDS ----------------
template<int CIN>
__global__ __launch_bounds__(512) void k_knn3(const float* __restrict__ xT,
    const float* __restrict__ nrm, int* __restrict__ idxo){
  __shared__ __align__(16) float sch[16*256];
  int bi = blockIdx.x, t = threadIdx.x;
  int w = t >> 6, lane = t & 63;
  int b = bi >> 5;
  int coli = (bi & 31)*8 + w;
  const float* xb = xT + (size_t)b*CIN*256;
  float d0=0.f, d1=0.f, d2=0.f, d3=0.f;
  for (int m0 = 0; m0 < CIN; m0 += 16){
    int mc = (CIN - m0 < 16) ? (CIN - m0) : 16;
    for (int i = t; i < mc*64; i += 512){
      int mm = i >> 6, c4 = i & 63;
      *(float4*)(sch + mm*256 + c4*4) = *(const float4*)(xb + (size_t)(m0+mm)*256 + c4*4);
    }
    __syncthreads();
    for (int mm = 0; mm < mc; ++mm){
      float xm = sch[mm*256 + coli];
      float4 v = *(const float4*)(sch + mm*256 + 4*lane);
      d0 = fmaf(v.x, xm, d0); d1 = fmaf(v.y, xm, d1);
      d2 = fmaf(v.z, xm, d2); d3 = fmaf(v.w, xm, d3);
    }
    __syncthreads();
  }
  float ni = nrm[b*256 + coli];
  float4 dv;
  {
    int j0 = 4*lane;
    dv.x = __fsub_rn(__fadd_rn(ni, nrm[b*256 + j0+0]), __fmul_rn(2.0f, d0));
    dv.y = __fsub_rn(__fadd_rn(ni, nrm[b*256 + j0+1]), __fmul_rn(2.0f, d1));
    dv.z = __fsub_rn(__fadd_rn(ni, nrm[b*256 + j0+2]), __fmul_rn(2.0f, d2));
    dv.w = __fsub_rn(__fadd_rn(ni, nrm[b*256 + j0+3]), __fmul_rn(2.0f, d3));
  }
  for (int r = 0; r < KC; ++r){
    float bv = 3.4e38f; int bj = NPp;
    if (dv.x < bv){ bv = dv.x; bj = 4*lane+0; }
    if (dv.y < bv){ bv = dv.y; bj = 4*lane+1; }
    if (dv.z < bv){ bv = dv.z; bj = 4*lane+2; }
    if (dv.w < bv){ bv = dv.w; bj = 4*lane+3; }
    unsigned xf = __float_as_uint(bv);
    xf = (xf & 0x80000000u) ? ~xf : (xf | 0x80000000u);
    ull key = ((ull)xf << 32) | (unsigned)bj;
#define KN_STAGE(C) { \
    unsigned ol = (unsigned)dpp_i<C>((int)(unsigned)key); \
    unsigned oh = (unsigned)dpp_i<C>((int)(unsigned)(key >> 32)); \
    ull ok = ((ull)oh << 32) | ol; \
    if (ok < key) key = ok; }
    KN_STAGE(0x111) KN_STAGE(0x112) KN_STAGE(0x114) KN_STAGE(0x118)
    KN_STAGE(0x142) KN_STAGE(0x143)
#undef KN_STAGE
    int bjw = __builtin_amdgcn_readlane((int)(unsigned)key, 63);
    if (lane == 0) idxo[((size_t)b*256 + coli)*KC + r] = bjw;
    if ((bjw >> 2) == lane){
      int e = bjw & 3;
      if      (e == 0) dv.x = 3.0e38f;
      else if (e == 1) dv.y = 3.0e38f;
      else if (e == 2) dv.z = 3.0e38f;
      else             dv.w = 3.0e38f;
    }
  }
}

// ---------------- per-point dual GEMM (scalar; used for CIN=131 layers) ----------------
template<int CIN, int COUT, int T>
__global__ __launch_bounds__(T) void k_gab(const float* __restrict__ x, int xstride,
    const float* __restrict__ wA, const float* __restrict__ wB,
    float* __restrict__ A, float* __restrict__ B, float* __restrict__ xT,
    float* __restrict__ nrm){
  constexpr int PC  = CIN + 1;
  constexpr int G   = COUT/4;
  constexpr int RS  = T/G;
  constexpr int RPT = 16/RS;
  __shared__ float xsh[16*PC];
  int bi = blockIdx.x, t = threadIdx.x;
  int g = t % G, rs = t / G;
  int i0 = bi*16;
  for (int i = t; i < 16*CIN; i += T){
    int r = i / CIN, m = i - r*CIN;
    xsh[r*PC + m] = x[(size_t)(i0+r)*xstride + m];
  }
  __syncthreads();
  {
    int bb = i0 >> 8, col0 = i0 & 255;
    float* xTb = xT + (size_t)bb*CIN*256 + col0;
    for (int i = t; i < 16*CIN; i += T){
      int m = i >> 4, r = i & 15;
      xTb[m*256 + r] = xsh[r*PC + m];
    }
  }
  if (t < 16){
    const float* xr = xsh + t*PC;
    float a = 0.0f;
    for (int m = 0; m < CIN; ++m) a = __fadd_rn(a, __fmul_rn(xr[m], xr[m]));
    nrm[i0 + t] = a;
  }
  float4 accA[RPT], accB[RPT];
#pragma unroll
  for (int rr = 0; rr < RPT; ++rr){
    accA[rr] = make_float4(0.f,0.f,0.f,0.f);
    accB[rr] = make_float4(0.f,0.f,0.f,0.f);
  }
  for (int m = 0; m < CIN; ++m){
    float4 wa = *(const float4*)(wA + (size_t)m*COUT + 4*g);
    float4 wb = *(const float4*)(wB + (size_t)m*COUT + 4*g);
#pragma unroll
    for (int rr = 0; rr < RPT; ++rr){
      float xv = xsh[(rs + rr*RS)*PC + m];
      accA[rr] = fma4s(wa, xv, accA[rr]);
      accB[rr] = fma4s(wb, xv, accB[rr]);
    }
  }
#pragma unroll
  for (int rr = 0; rr < RPT; ++rr){
    int r = i0 + rs + rr*RS;
    *(float4*)(A + (size_t)r*COUT + 4*g) = accA[rr];
    *(float4*)(B + (size_t)r*COUT + 4*g) = accB[rr];
  }
}

// ---------------- per-point dual GEMM via MFMA split-bf16 (CIN multiple of 32) ----------------
// Same verified fragment mappings as k_sa: A-frag lane l elem e = x[l&15][kt*32+8*(l>>4)+e];
// B-frag = W[k][ct*16+(l&15)] (pre-split in k_prep_all); D row = 4*(l>>4)+r, col = l&15.
// A-frags staged once per block into XOR-swizzled LDS (block index ^ row&7 -> <=2-way banks).
// xT / nrm side outputs identical to scalar k_gab.
template<int CIN, int COUT>
__global__ __launch_bounds__(512) void k_gabm(const float* __restrict__ x, int xstride,
    const u16* __restrict__ wAh, const u16* __restrict__ wAl,
    const u16* __restrict__ wBh, const u16* __restrict__ wBl,
    float* __restrict__ A, float* __restrict__ B, float* __restrict__ xT,
    float* __restrict__ nrm){
  constexpr int PC  = CIN + 1;
  constexpr int KT  = CIN / 32;
  constexpr int CT  = COUT / 16;
  constexpr int TPW = 2*CT/8;          // tiles per wave (A and B matrices)
  constexpr int KB  = CIN / 8;         // 16B blocks per row
  __shared__ float xsh[16*PC];
  __shared__ __align__(16) u16 axh[16*CIN];
  __shared__ __align__(16) u16 axl[16*CIN];
  int bi = blockIdx.x, t = threadIdx.x;
  int i0 = bi*16;
  for (int i = t; i < 16*CIN; i += 512){
    int r = i / CIN, m = i - r*CIN;
    xsh[r*PC + m] = x[(size_t)(i0+r)*xstride + m];
  }
  __syncthreads();
  {
    int bb = i0 >> 8, col0 = i0 & 255;
    float* xTb = xT + (size_t)bb*CIN*256 + col0;
    for (int i = t; i < 16*CIN; i += 512){
      int m = i >> 4, r = i & 15;
      xTb[m*256 + r] = xsh[r*PC + m];
    }
  }
  if (t < 16){
    const float* xr = xsh + t*PC;
    float a = 0.0f;
    for (int m = 0; m < CIN; ++m) a = __fadd_rn(a, __fmul_rn(xr[m], xr[m]));
    nrm[i0 + t] = a;
  }
  // A-frag split: thread t handles one 8-wide k-block of one row (16*KB <= 512)
  if (t < 16*KB){
    int r = t / KB, kb = t - r*KB;
    unsigned hu[8], lu[8];
#pragma unroll
    for (int e = 0; e < 8; ++e) bf16_split(xsh[r*PC + kb*8 + e], hu[e], lu[e]);
    i32x4 H, L;
#pragma unroll
    for (int j2 = 0; j2 < 4; ++j2){
      H[j2] = (int)(hu[2*j2] | (hu[2*j2+1] << 16));
      L[j2] = (int)(lu[2*j2] | (lu[2*j2+1] << 16));
    }
    int idx = r*CIN + ((kb ^ (r & 7)) << 3);
    *(bf16x8*)(axh + idx) = __builtin_bit_cast(bf16x8, H);
    *(bf16x8*)(axl + idx) = __builtin_bit_cast(bf16x8, L);
  }
  __syncthreads();
  int lane = t & 63, wid = t >> 6;
  int col = lane & 15, g = lane >> 4;
  int aswz = col & 7;                   // A-frag row = col
#pragma unroll
  for (int tt = 0; tt < TPW; ++tt){
    int tile = wid*TPW + tt;
    bool isB = tile >= CT;
    int ct = isB ? tile - CT : tile;
    const u16* Wh = isB ? wBh : wAh;
    const u16* Wl = isB ? wBl : wAl;
    float* Out = isB ? B : A;
    f32x4 acc = {0.f,0.f,0.f,0.f};
#pragma unroll
    for (int kt = 0; kt < KT; ++kt){
      int kb = kt*4 + g;
      int aidx = col*CIN + ((kb ^ aswz) << 3);
      bf16x8 Ah = *(const bf16x8*)(axh + aidx);
      bf16x8 Al = *(const bf16x8*)(axl + aidx);
      size_t wo = ((size_t)(ct*KT + kt)*64 + lane)*8;
      bf16x8 Bh = *(const bf16x8*)(Wh + wo);
      bf16x8 Bl = *(const bf16x8*)(Wl + wo);
      acc = __builtin_amdgcn_mfma_f32_16x16x32_bf16(Ah, Bh, acc, 0, 0, 0);
      acc = __builtin_amdgcn_mfma_f32_16x16x32_bf16(Ah, Bl, acc, 0, 0, 0);
      acc = __builtin_amdgcn_mfma_f32_16x16x32_bf16(Al, Bh, acc, 0, 0, 0);
    }
#pragma unroll
    for (int r = 0; r < 4; ++r){
      Out[(size_t)(i0 + 4*g + r)*COUT + ct*16 + col] = acc[r];
    }
  }
}

// ---------------- edge epilogue: out[i][c] = max_k relu(A[i][c] + B[j_ik][c]) ----------------
template<int COUT>
__global__ __launch_bounds__(256) void k_emax(const float* __restrict__ A, const float* __restrict__ Bm,
    const int* __restrict__ idx, float* __restrict__ out){
  constexpr int GT = COUT/4;
  constexpr int NC = 256/GT;
  __shared__ int js[NC*KC];
  int bi = blockIdx.x, t = threadIdx.x;
  int li = t / GT, c4 = (t % GT)*4;
  int ci = bi*NC + li;
  int rb = (ci >> 8) << 8;
  if (t < NC*KC) js[t] = idx[(size_t)bi*NC*KC + t];
  __syncthreads();
  float4 a = *(const float4*)(A + (size_t)ci*COUT + c4);
  float4 p = make_float4(0.f,0.f,0.f,0.f);
#pragma unroll
  for (int k = 0; k < KC; ++k){
    int j = js[li*KC + k];
    float4 b = *(const float4*)(Bm + (size_t)(rb + j)*COUT + c4);
    p = max4(p, add4(a, b));
  }
  *(float4*)(out + (size_t)ci*COUT + c4) = p;
}

// ---------------- T-Net edge: h0 = relu(A0+B0) then 64->128 conv + k-maxpool ----------------
__global__ __launch_bounds__(128) void k_tedge3(const float* __restrict__ A0, const float* __restrict__ B0,
    const int* __restrict__ idx, const float* __restrict__ wt1, float* __restrict__ out){
  __shared__ __align__(16) float h0s[20*68];
  __shared__ __align__(16) float smax[4*128];
  __shared__ int js[KC];
  int bi = blockIdx.x, t = threadIdx.x;
  int cg = t & 31, kg = t >> 5, k0 = kg*5;
  int rb = (bi >> 8) << 8;
  if (t < KC) js[t] = idx[(size_t)bi*KC + t];
  __syncthreads();
  for (int i = t; i < 20*64; i += 128){
    int k = i >> 6, c = i & 63;
    float v = A0[(size_t)bi*64 + c] + B0[(size_t)(rb + js[k])*64 + c];
    h0s[k*68 + c] = fmaxf(v, 0.0f);
  }
  __syncthreads();
  float4 b2[5];
#pragma unroll
  for (int kk = 0; kk < 5; ++kk) b2[kk] = make_float4(0.f,0.f,0.f,0.f);
  for (int m4 = 0; m4 < 16; ++m4){
    float4 e[5];
#pragma unroll
    for (int kk = 0; kk < 5; ++kk) e[kk] = *(const float4*)(h0s + (k0+kk)*68 + 4*m4);
#pragma unroll
    for (int mm = 0; mm < 4; ++mm){
      float4 w = *(const float4*)(wt1 + (4*m4+mm)*128 + 4*cg);
#pragma unroll
      for (int kk = 0; kk < 5; ++kk){
        float ev = (mm==0)?e[kk].x:((mm==1)?e[kk].y:((mm==2)?e[kk].z:e[kk].w));
        b2[kk] = fma4s(w, ev, b2[kk]);
      }
    }
  }
  float4 p = make_float4(0.f,0.f,0.f,0.f);
#pragma unroll
  for (int kk = 0; kk < 5; ++kk) p = max4(p, b2[kk]);
  *(float4*)(smax + kg*128 + 4*cg) = p;
  __syncthreads();
  if (kg == 0){
    float4 r = *(const float4*)(smax + 4*cg);
#pragma unroll
    for (int g = 1; g < 4; ++g) r = max4(r, *(const float4*)(smax + g*128 + 4*cg));
    *(float4*)(out + (size_t)bi*128 + 4*cg) = r;
  }
}

// ---------------- T-Net 128->1024 + pool: 8 point-chunks, atomicMax combine ----------------
__global__ __launch_bounds__(128) void k_tpool(const float* __restrict__ h, const float* __restrict__ W,
    float* __restrict__ g1024){
  int b = blockIdx.x, t = threadIdx.x;
  int c = blockIdx.y*128 + t;
  int i0 = blockIdx.z*32;
  float4 w[32];
#pragma unroll
  for (int qq = 0; qq < 32; ++qq) w[qq] = *(const float4*)(W + (size_t)c*128 + 4*qq);
  const float* hb = h + (size_t)b*NPp*128;
  float mx = 0.0f;
  for (int i = i0; i < i0 + 32; ++i){
    const float4* hr = (const float4*)(hb + (size_t)i*128);
    float a = 0.0f;
#pragma unroll
    for (int qq = 0; qq < 32; ++qq) a = fma4(w[qq], hr[qq], a);
    mx = fmaxf(mx, a);
  }
  atomicMax((int*)(g1024 + (size_t)b*1024 + c), __float_as_int(mx));
}

// ---------------- T-Net MLP + 3x3 transform applied to new_xyz ----------------
__global__ __launch_bounds__(256) void k_trest(const float* __restrict__ g1024,
    const float* __restrict__ Wg0, const float* __restrict__ Wg1,
    const float* __restrict__ Wl, const float* __restrict__ bl,
    const float* __restrict__ new_xyz, float* __restrict__ x131){
  __shared__ __align__(16) float g1[1024];
  __shared__ __align__(16) float g5[512];
  __shared__ __align__(16) float g2[256];
  __shared__ float tm[12];
  int b = blockIdx.x, t = threadIdx.x;
  for (int m = t; m < 1024; m += 256) g1[m] = g1024[(size_t)b*1024 + m];
  __syncthreads();
#pragma unroll
  for (int cc = 0; cc < 2; ++cc){
    int c = t + cc*256;
    const float4* wr = (const float4*)(Wg0 + (size_t)c*1024);
    const float4* gv = (const float4*)g1;
    float a = 0.0f;
    for (int qq = 0; qq < 256; ++qq) a = fma4(wr[qq], gv[qq], a);
    g5[c] = fmaxf(a, 0.0f);
  }
  __syncthreads();
  {
    const float4* wr = (const float4*)(Wg1 + (size_t)t*512);
    const float4* gv = (const float4*)g5;
    float a = 0.0f;
    for (int qq = 0; qq < 128; ++qq) a = fma4(wr[qq], gv[qq], a);
    g2[t] = fmaxf(a, 0.0f);
  }
  __syncthreads();
  if (t < 9){
    const float4* wr = (const float4*)(Wl + (size_t)t*256);
    const float4* gv = (const float4*)g2;
    float a = 0.0f;
#pragma unroll
    for (int qq = 0; qq < 64; ++qq) a = fma4(wr[qq], gv[qq], a);
    a += bl[t];
    if (t == 0 || t == 4 || t == 8) a += 1.0f;
    tm[t] = a;
  }
  __syncthreads();
  {
    const float* nx = new_xyz + ((size_t)b*NPp + t)*3;
    float X = nx[0], Y = nx[1], Z = nx[2];
#pragma unroll
    for (int i = 0; i < 3; ++i){
      float v = __fadd_rn(__fadd_rn(__fmul_rn(tm[i*3+0], X), __fmul_rn(tm[i*3+1], Y)), __fmul_rn(tm[i*3+2], Z));
      x131[((size_t)b*NPp + t)*132 + 128 + i] = v;
    }
  }
}

// ---------------- 896->128 conv + global max pool ----------------
__global__ __launch_bounds__(128) void k_dgl(const float* __restrict__ f1, const float* __restrict__ f2,
    const float* __restrict__ f3, const float* __restrict__ W, float* __restrict__ g128){
  int b = blockIdx.x, t = threadIdx.x;
  int i0 = blockIdx.y * 16;
  const float* wr = W + (size_t)t*896;
  float acc[16];
#pragma unroll
  for (int ii = 0; ii < 16; ++ii) acc[ii] = 0.0f;
  for (int q = 0; q < 32; ++q){
    float4 w = *(const float4*)(wr + 4*q);
#pragma unroll
    for (int ii = 0; ii < 16; ++ii){
      float4 v = *(const float4*)(f1 + ((size_t)b*NPp + i0 + ii)*128 + 4*q);
      acc[ii] = fma4(w, v, acc[ii]);
    }
  }
  for (int q = 0; q < 64; ++q){
    float4 w = *(const float4*)(wr + 128 + 4*q);
#pragma unroll
    for (int ii = 0; ii < 16; ++ii){
      float4 v = *(const float4*)(f2 + ((size_t)b*NPp + i0 + ii)*256 + 4*q);
      acc[ii] = fma4(w, v, acc[ii]);
    }
  }
  for (int q = 0; q < 128; ++q){
    float4 w = *(const float4*)(wr + 384 + 4*q);
#pragma unroll
    for (int ii = 0; ii < 16; ++ii){
      float4 v = *(const float4*)(f3 + ((size_t)b*NPp + i0 + ii)*512 + 4*q);
      acc[ii] = fma4(w, v, acc[ii]);
    }
  }
#pragma unroll
  for (int ii = 0; ii < 16; ++ii){
    float v = fmaxf(acc[ii], 0.0f);
    atomicMax((int*)(g128 + (size_t)b*128 + t), __float_as_int(v));
  }
}

// ---------------- classifier head ----------------
__global__ __launch_bounds__(256) void k_final(const float* __restrict__ g128,
    const float* __restrict__ W0, const float* __restrict__ W1,
    const float* __restrict__ Wc, const float* __restrict__ bc, float* __restrict__ out){
  __shared__ __align__(16) float g0[128];
  __shared__ __align__(16) float g5[512];
  __shared__ __align__(16) float g2[256];
  int b = blockIdx.x, t = threadIdx.x;
  if (t < 128) g0[t] = g128[(size_t)b*128 + t];
  __syncthreads();
#pragma unroll
  for (int cc = 0; cc < 2; ++cc){
    int c = t + cc*256;
    const float4* wr = (const float4*)(W0 + (size_t)c*128);
    const float4* gv = (const float4*)g0;
    float a = 0.0f;
#pragma unroll
    for (int qq = 0; qq < 32; ++qq) a = fma4(wr[qq], gv[qq], a);
    g5[c] = fmaxf(a, 0.0f);
  }
  __syncthreads();
  {
    const float4* wr = (const float4*)(W1 + (size_t)t*512);
    const float4* gv = (const float4*)g5;
    float a = 0.0f;
    for (int qq = 0; qq < 128; ++qq) a = fma4(wr[qq], gv[qq], a);
    g2[t] = fmaxf(a, 0.0f);
  }
  __syncthreads();
  if (t < 40){
    const float4* wr = (const float4*)(Wc + (size_t)t*256);
    const float4* gv = (const float4*)g2;
    float a = 0.0f;
#pragma unroll
    for (int qq = 0; qq < 64; ++qq) a = fma4(wr[qq], gv[qq], a);
    out[(size_t)b*40 + t] = a + bc[t];
  }
}

extern "C" void kernel_launch(void* const* d_in, const int* in_sizes, int n_in,
                              void* d_out, int out_size, void* d_ws, size_t ws_size,
                              hipStream_t stream){
  (void)in_sizes; (void)n_in; (void)out_size; (void)ws_size;
  const float* points     = (const float*)d_in[0];
  const float* sa_w0      = (const float*)d_in[1];
  const float* sa_w1      = (const float*)d_in[2];
  const float* sa_w2      = (const float*)d_in[3];
  const float* t_ec_w0    = (const float*)d_in[4];
  const float* t_ec_w1    = (const float*)d_in[5];
  const float* t_local_w  = (const float*)d_in[6];
  const float* t_g_w0     = (const float*)d_in[7];
  const float* t_g_w1     = (const float*)d_in[8];
  const float* t_lin_w    = (const float*)d_in[9];
  const float* t_lin_b    = (const float*)d_in[10];
  const float* dg_ec_w0   = (const float*)d_in[11];
  const float* dg_ec_w1   = (const float*)d_in[12];
  const float* dg_ec_w2   = (const float*)d_in[13];
  const float* dg_local_w = (const float*)d_in[14];
  const float* dg_g_w0    = (const float*)d_in[15];
  const float* dg_g_w1    = (const float*)d_in[16];
  const float* cls_w      = (const float*)d_in[17];
  const float* cls_b      = (const float*)d_in[18];
  float* out = (float*)d_out;

  float* ws     = (float*)d_ws;
  float* xyz    = ws;                    // 393216
  float* xnrm   = xyz    + 393216;       // 131072
  float* nxyz   = xnrm   + 131072;       // 24576
  float* feat   = nxyz   + 24576;        // 1048576 (dead output buffer -> reused for GEMM weight frags)
  float* x131   = feat   + 1048576;      // 1081344
  float* nrm    = x131   + 1081344;      // 8192
  int*   idx    = (int*)(nrm + 8192);    // 163840
  float* ht     = (float*)(idx + 163840);// 1048576 (reused as f1)
  float* g1024v = ht     + 1048576;      // 32768
  float* f2     = g1024v + 32768;        // 2097152
  float* f3     = f2     + 2097152;      // 4194304
  float* g128v  = f3     + 4194304;      // 4096
  float* wt_t1  = g128v  + 4096;         // 8192   (64x128)
  float* waT0   = wt_t1  + 8192;         // 8384   (131x64)
  float* wbT0   = waT0   + 8384;         // 8384
  float* waD0   = wbT0   + 8384;         // 16768  (131x128)
  float* wbD0   = waD0   + 16768;        // 16768
  float* waD1   = wbD0   + 16768;        // 32768  (128x256)
  float* wbD1   = waD1   + 32768;        // 32768
  float* waD2   = wbD1   + 32768;        // 131072 (256x512)
  float* wbD2   = waD2   + 131072;       // 131072
  float* Ab     = wbD2   + 131072;       // 4194304
  float* Bb     = Ab     + 4194304;      // 4194304
  float* w1Tb   = Bb     + 4194304;      // 4096   (legacy, unused)
  float* f1 = ht;
  float* xT = f3;                        // alias: xT lives in f3 until k_emax<512> writes f3

  // SA MFMA weight fragments alias the HEAD of Ab (k_prep_all writes -> k_sa reads ->
  // k_gab T-Net is the first Ab write).
  float* w0f    = Ab;                    // 4096   ([kt][lane][e][4])
  u16*   w1fh   = (u16*)(w0f + 4096);    // 4096 u16
  u16*   w1fl   = w1fh   + 4096;         // 4096 u16
  u16*   w2fh   = w1fl   + 4096;         // 8192 u16
  u16*   w2fl   = w2fh   + 8192;         // 8192 u16

  // Layer-2/3 GEMM weight frags live in the DEAD `feat` buffer (4MB; nothing reads it).
  // Written by k_prep_all; read by k_gabm (mid-pipeline). 655360 u16 = 1.28MB <= 4MB.
  u16* fragu  = (u16*)feat;
  u16* wAD1h  = fragu;                   // 32768
  u16* wAD1l  = wAD1h + 32768;           // 32768
  u16* wBD1h  = wAD1l + 32768;           // 32768
  u16* wBD1l  = wBD1h + 32768;           // 32768
  u16* wAD2h  = wBD1l + 32768;           // 131072
  u16* wAD2l  = wAD2h + 131072;          // 131072
  u16* wBD2h  = wAD2l + 131072;          // 131072
  u16* wBD2l  = wBD2h + 131072;          // 131072

  k_prep_all<<<2643, 256, 0, stream>>>(points, xyz, xnrm,
                                       t_ec_w0, t_ec_w1, dg_ec_w0, dg_ec_w1, dg_ec_w2, sa_w1,
                                       waT0, wbT0, wt_t1, waD0, wbD0, waD1, wbD1, waD2, wbD2, w1Tb,
                                       sa_w0, sa_w1, sa_w2, w0f, w1fh, w1fl, w2fh, w2fl,
                                       wAD1h, wAD1l, wBD1h, wBD1l, wAD2h, wAD2l, wBD2h, wBD2l);
  k_fps<<<BB, 128, 0, stream>>>(xyz, nxyz);
  k_sa<<<BB*NPp, 64, 0, stream>>>(points, xyz, xnrm, nxyz, w0f, w1fh, w1fl, w2fh, w2fl, x131);

  // T-Net branch (x = [feat, new_xyz])
  k_gab<131,64,256><<<512, 256, 0, stream>>>(x131, 132, waT0, wbT0, Ab, Bb, xT, nrm);
  k_knn3<131><<<1024, 512, 0, stream>>>(xT, nrm, idx);
  k_tedge3<<<BB*NPp, 128, 0, stream>>>(Ab, Bb, idx, wt_t1, ht);
  k_tpool<<<dim3(BB, 8, 8), 128, 0, stream>>>(ht, t_local_w, g1024v);
  k_trest<<<BB, 256, 0, stream>>>(g1024v, t_g_w0, t_g_w1, t_lin_w, t_lin_b, nxyz, x131);

  // DGCNN layer 1 (x = [feat, xyz_t], 131 dims) -- scalar (CIN not mult of 32)
  k_gab<131,128,512><<<512, 512, 0, stream>>>(x131, 132, waD0, wbD0, Ab, Bb, xT, nrm);
  k_knn3<131><<<1024, 512, 0, stream>>>(xT, nrm, idx);
  k_emax<128><<<1024, 256, 0, stream>>>(Ab, Bb, idx, f1);
  // layer 2 -- MFMA
  k_gabm<128,256><<<512, 512, 0, stream>>>(f1, 128, wAD1h, wAD1l, wBD1h, wBD1l, Ab, Bb, xT, nrm);
  k_knn3<128><<<1024, 512, 0, stream>>>(xT, nrm, idx);
  k_emax<256><<<2048, 256, 0, stream>>>(Ab, Bb, idx, f2);
  // layer 3 -- MFMA
  k_gabm<256,512><<<512, 512, 0, stream>>>(f2, 256, wAD2h, wAD2l, wBD2h, wBD2l, Ab, Bb, xT, nrm);
  k_knn3<256><<<1024, 512, 0, stream>>>(xT, nrm, idx);
  k_emax<512><<<4096, 256, 0, stream>>>(Ab, Bb, idx, f3);

  // local conv + global pool + head
  k_dgl<<<dim3(BB, 16), 128, 0, stream>>>(f1, f2, f3, dg_local_w, g128v);
  k_final<<<BB, 256, 0, stream>>>(g128v, dg_g_w0, dg_g_w1, cls_w, cls_b, out);
}

// Round 11
// 934.100 us; speedup vs baseline: 1.4941x; 1.2278x over previous
//
#include <hip/hip_runtime.h>
#include <math.h>

#define BB 32
#define NN 4096
#define NPp 256
#define NSs 64
#define KC 20

typedef unsigned long long ull;
typedef unsigned short u16;
typedef short bf16x8 __attribute__((ext_vector_type(8)));
typedef float f32x4 __attribute__((ext_vector_type(4)));
typedef int i32x4 __attribute__((ext_vector_type(4)));

__device__ __forceinline__ float fma4(const float4 w, const float4 v, float a){
  a = fmaf(w.x, v.x, a); a = fmaf(w.y, v.y, a);
  a = fmaf(w.z, v.z, a); a = fmaf(w.w, v.w, a); return a;
}
__device__ __forceinline__ float4 fma4s(const float4 w, float s, float4 a){
  a.x = fmaf(w.x, s, a.x); a.y = fmaf(w.y, s, a.y);
  a.z = fmaf(w.z, s, a.z); a.w = fmaf(w.w, s, a.w); return a;
}
__device__ __forceinline__ float4 max4(float4 a, float4 b){
  a.x = fmaxf(a.x, b.x); a.y = fmaxf(a.y, b.y);
  a.z = fmaxf(a.z, b.z); a.w = fmaxf(a.w, b.w); return a;
}
__device__ __forceinline__ float4 add4(float4 a, float4 b){
  a.x += b.x; a.y += b.y; a.z += b.z; a.w += b.w; return a;
}

template<int C>
__device__ __forceinline__ int dpp_i(int x){
  return __builtin_amdgcn_update_dpp(x, x, C, 0xf, 0xf, false);
}

// split fp32 -> bf16 hi + bf16 lo (truncating; v - hi is exact in fp32)
__device__ __host__ __forceinline__ void bf16_split(float v, unsigned& h16, unsigned& l16){
  unsigned bits = __float_as_uint(v);
  h16 = bits >> 16;
  float hf = __uint_as_float(h16 << 16);
  l16 = __float_as_uint(v - hf) >> 16;
}

// ---------------- fused prep: transpose/norms + weight prep + ALL MFMA weight frags ----------------
// blocks [0,512): k_prep; [512,1299): k_wprep; [1299,1363): SA frags;
// [1363,2643): layer-2/3 GEMM frags; [2643,3155): t_local_w (tpool) frags;
// [3155,3603): dg_local_w (dgl) frags. Frag layout everywhere (k_sa-verified):
// [ct][kt][lane][e], value W[k][c], k = kt*32 + 8*(lane>>4) + e, c = ct*16 + (lane&15).
__global__ void k_prep_all(const float* __restrict__ pts, float* __restrict__ xyz, float* __restrict__ xnrm,
                           const float* __restrict__ t0, const float* __restrict__ t1,
                           const float* __restrict__ d0, const float* __restrict__ d1,
                           const float* __restrict__ d2, const float* __restrict__ saw1,
                           float* __restrict__ waT0, float* __restrict__ wbT0,
                           float* __restrict__ wt_t1,
                           float* __restrict__ waD0, float* __restrict__ wbD0,
                           float* __restrict__ waD1, float* __restrict__ wbD1,
                           float* __restrict__ waD2, float* __restrict__ wbD2,
                           float* __restrict__ w1T,
                           const float* __restrict__ w0, const float* __restrict__ w1,
                           const float* __restrict__ w2,
                           const float* __restrict__ tl, const float* __restrict__ dgw,
                           float* __restrict__ w0f, u16* __restrict__ w1fh, u16* __restrict__ w1fl,
                           u16* __restrict__ w2fh, u16* __restrict__ w2fl,
                           u16* __restrict__ wAD1h, u16* __restrict__ wAD1l,
                           u16* __restrict__ wBD1h, u16* __restrict__ wBD1l,
                           u16* __restrict__ wAD2h, u16* __restrict__ wAD2l,
                           u16* __restrict__ wBD2h, u16* __restrict__ wBD2l,
                           u16* __restrict__ wTPh, u16* __restrict__ wTPl,
                           u16* __restrict__ wDGh, u16* __restrict__ wDGl){
  int bid = blockIdx.x;
  if (bid < 512){                        // ---- k_prep ----
    int i = bid*256 + threadIdx.x;
    if (i >= BB*NN) return;
    int b = i >> 12, n = i & (NN-1);
    float X = pts[(b*3+0)*NN + n];
    float Y = pts[(b*3+1)*NN + n];
    float Z = pts[(b*3+2)*NN + n];
    xyz[i*3+0]=X; xyz[i*3+1]=Y; xyz[i*3+2]=Z;
    xnrm[i] = __fadd_rn(__fadd_rn(__fmul_rn(X,X), __fmul_rn(Y,Y)), __fmul_rn(Z,Z));
    return;
  }
  if (bid < 1299){                       // ---- k_wprep ----
    int i = (bid-512)*256 + threadIdx.x;
    if (i < 8384){                       // t_ec_w0: [64][262] -> A/B [131][64]
      int m = i >> 6;
      int c = i & 63;
      float bb = t0[(size_t)c*262 + m];
      float dd = t0[(size_t)c*262 + 131 + m];
      waT0[i] = __fsub_rn(bb, dd); wbT0[i] = dd;
      return;
    }
    i -= 8384;
    if (i < 8192){                       // t_ec_w1: [128][64] -> [64][128]
      int m = i >> 7, c = i & 127;
      wt_t1[i] = t1[(size_t)c*64 + m];
      return;
    }
    i -= 8192;
    if (i < 16768){                      // dg_ec_w0: [128][262] -> A/B [131][128]
      int m = i >> 7, c = i & 127;
      float bb = d0[(size_t)c*262 + m];
      float dd = d0[(size_t)c*262 + 131 + m];
      waD0[i] = __fsub_rn(bb, dd); wbD0[i] = dd;
      return;
    }
    i -= 16768;
    if (i < 32768){                      // dg_ec_w1: [256][256] -> A/B [128][256]
      int m = i >> 8, c = i & 255;
      float bb = d1[(size_t)c*256 + m];
      float dd = d1[(size_t)c*256 + 128 + m];
      waD1[i] = __fsub_rn(bb, dd); wbD1[i] = dd;
      return;
    }
    i -= 32768;
    if (i < 131072){                     // dg_ec_w2: [512][512] -> A/B [256][512]
      int m = i >> 9, c = i & 511;
      float bb = d2[(size_t)c*512 + m];
      float dd = d2[(size_t)c*512 + 256 + m];
      waD2[i] = __fsub_rn(bb, dd); wbD2[i] = dd;
      return;
    }
    i -= 131072;
    if (i < 4096){                       // sa_w1: [64][64] -> w1T[m][c] (legacy, unused)
      int m = i >> 6, c = i & 63;
      w1T[i] = saw1[(size_t)c*64 + m];
    }
    return;
  }
  if (bid < 1363){                       // ---- SA frags ----
    int i = (bid-1299)*256 + threadIdx.x;
    if (i < 4096){                       // w0f: [kt][lane][e][4] (xyz + pad)
      int kt = i >> 11, r = i & 2047;
      int ln = r >> 5, ee = r & 31;
      int e = ee >> 2, j = ee & 3;
      int k = kt*32 + 8*(ln>>4) + e;
      w0f[i] = (j < 3) ? w0[k*3 + j] : 0.0f;
      return;
    }
    i -= 4096;
    if (i < 4096){                       // w1 frags
      int e = i & 7, ln = (i >> 3) & 63, q = i >> 9;
      int kt = q & 1, ct = q >> 1;
      int k = kt*32 + 8*(ln>>4) + e;
      int c = ct*16 + (ln & 15);
      unsigned h16, l16; bf16_split(w1[(size_t)c*64 + k], h16, l16);
      w1fh[i] = (u16)h16; w1fl[i] = (u16)l16;
      return;
    }
    i -= 4096;
    if (i < 8192){                       // w2 frags
      int e = i & 7, ln = (i >> 3) & 63, q = i >> 9;
      int kt = q & 1, c2t = q >> 1;
      int k = kt*32 + 8*(ln>>4) + e;
      int c2 = c2t*16 + (ln & 15);
      unsigned h16, l16; bf16_split(w2[(size_t)c2*64 + k], h16, l16);
      w2fh[i] = (u16)h16; w2fl[i] = (u16)l16;
    }
    return;
  }
  if (bid < 2643){                       // ---- layer-2/3 GEMM weight frags ----
    int i = (bid-1363)*256 + threadIdx.x;
    if (i < 32768){                      // D1 wA: [ct(16)][kt(4)][lane][e]
      int e = i & 7, ln = (i >> 3) & 63, q = i >> 9;
      int kt = q & 3, ct = q >> 2;
      int k = kt*32 + 8*(ln>>4) + e;
      int c = ct*16 + (ln & 15);
      float bb = d1[(size_t)c*256 + k], dd = d1[(size_t)c*256 + 128 + k];
      unsigned h, l; bf16_split(__fsub_rn(bb, dd), h, l);
      wAD1h[i] = (u16)h; wAD1l[i] = (u16)l;
      return;
    }
    i -= 32768;
    if (i < 32768){                      // D1 wB
      int e = i & 7, ln = (i >> 3) & 63, q = i >> 9;
      int kt = q & 3, ct = q >> 2;
      int k = kt*32 + 8*(ln>>4) + e;
      int c = ct*16 + (ln & 15);
      float dd = d1[(size_t)c*256 + 128 + k];
      unsigned h, l; bf16_split(dd, h, l);
      wBD1h[i] = (u16)h; wBD1l[i] = (u16)l;
      return;
    }
    i -= 32768;
    if (i < 131072){                     // D2 wA: [ct(32)][kt(8)][lane][e]
      int e = i & 7, ln = (i >> 3) & 63, q = i >> 9;
      int kt = q & 7, ct = q >> 3;
      int k = kt*32 + 8*(ln>>4) + e;
      int c = ct*16 + (ln & 15);
      float bb = d2[(size_t)c*512 + k], dd = d2[(size_t)c*512 + 256 + k];
      unsigned h, l; bf16_split(__fsub_rn(bb, dd), h, l);
      wAD2h[i] = (u16)h; wAD2l[i] = (u16)l;
      return;
    }
    i -= 131072;
    if (i < 131072){                     // D2 wB
      int e = i & 7, ln = (i >> 3) & 63, q = i >> 9;
      int kt = q & 7, ct = q >> 3;
      int k = kt*32 + 8*(ln>>4) + e;
      int c = ct*16 + (ln & 15);
      float dd = d2[(size_t)c*512 + 256 + k];
      unsigned h, l; bf16_split(dd, h, l);
      wBD2h[i] = (u16)h; wBD2l[i] = (u16)l;
    }
    return;
  }
  if (bid < 3155){                       // ---- t_local_w frags: [ct(64)][kt(4)][lane][e] ----
    int i = (bid-2643)*256 + threadIdx.x;  // i < 131072
    int e = i & 7, ln = (i >> 3) & 63, q = i >> 9;   // q in [0,256)
    int kt = q & 3, ct = q >> 2;
    int k = kt*32 + 8*(ln>>4) + e;                   // [0,128)
    int c = ct*16 + (ln & 15);                       // [0,1024)
    unsigned h, l; bf16_split(tl[(size_t)c*128 + k], h, l);
    wTPh[i] = (u16)h; wTPl[i] = (u16)l;
    return;
  }
  {                                      // ---- dg_local_w frags: [ct(8)][kt(28)][lane][e] ----
    int i = (bid-3155)*256 + threadIdx.x;
    if (i >= 114688) return;
    int e = i & 7, ln = (i >> 3) & 63, q = i >> 9;   // q in [0,224)
    int kt = q % 28, ct = q / 28;
    int k = kt*32 + 8*(ln>>4) + e;                   // [0,896)
    int c = ct*16 + (ln & 15);                       // [0,128)
    unsigned h, l; bf16_split(dgw[(size_t)c*896 + k], h, l);
    wDGh[i] = (u16)h; wDGl[i] = (u16)l;
  }
}

// ---------------- farthest point sampling: 2 waves, key-only reduce (parked at floor) ----------------
__global__ __launch_bounds__(128, 1) void k_fps(const float* __restrict__ xyz, float* __restrict__ new_xyz){
  __shared__ __align__(16) float lx[NN], ly[NN], lz[NN];
  __shared__ __align__(16) ull wkey[2][2];
  int b = blockIdx.x, t = threadIdx.x;
  int w = t >> 6, lane = t & 63;
  float nx[32], ny[32], nz[32], dist[32];
#pragma unroll
  for (int q = 0; q < 32; ++q){
    int j = q*128 + t;
    const float* p = xyz + ((size_t)b*NN + j)*3;
    float X = p[0], Y = p[1], Z = p[2];
    lx[j] = X; ly[j] = Y; lz[j] = Z;
    nx[q] = -X; ny[q] = -Y; nz[q] = -Z;
    dist[q] = __builtin_inff();
  }
  const float* p0 = xyz + (size_t)b*NN*3;
  float Px = p0[0], Py = p0[1], Pz = p0[2];
  __syncthreads();
  for (int it = 0; it < NPp; ++it){
    if (t == 0){
      float* o = new_xyz + ((size_t)b*NPp + it)*3;
      o[0] = Px; o[1] = Py; o[2] = Pz;
    }
    ull ka0 = 0, ka1 = 0, ka2 = 0, ka3 = 0;
#pragma unroll
    for (int q = 0; q < 32; ++q){
      float dx = __fadd_rn(nx[q], Px);
      float dy = __fadd_rn(ny[q], Py);
      float dz = __fadd_rn(nz[q], Pz);
      float dd = __fadd_rn(__fadd_rn(__fmul_rn(dx,dx), __fmul_rn(dy,dy)), __fmul_rn(dz,dz));
      float dm = fminf(dist[q], dd);
      dist[q] = dm;
      ull key = ((ull)__float_as_uint(dm) << 32) | (unsigned)(4095 - (q*128 + t));
      if      ((q & 3) == 0){ if (key > ka0) ka0 = key; }
      else if ((q & 3) == 1){ if (key > ka1) ka1 = key; }
      else if ((q & 3) == 2){ if (key > ka2) ka2 = key; }
      else                  { if (key > ka3) ka3 = key; }
    }
    ull kb0 = (ka0 > ka1) ? ka0 : ka1;
    ull kb1 = (ka2 > ka3) ? ka2 : ka3;
    ull bk  = (kb0 > kb1) ? kb0 : kb1;
#define FPS_STAGE(C) { \
    unsigned ol = (unsigned)dpp_i<C>((int)(unsigned)bk); \
    unsigned oh = (unsigned)dpp_i<C>((int)(unsigned)(bk >> 32)); \
    ull ok = ((ull)oh << 32) | ol; \
    if (ok > bk) bk = ok; }
    FPS_STAGE(0x111) FPS_STAGE(0x112) FPS_STAGE(0x114) FPS_STAGE(0x118)
    FPS_STAGE(0x142) FPS_STAGE(0x143)
#undef FPS_STAGE
    int par = it & 1;
    if (lane == 63) wkey[par][w] = bk;
    __syncthreads();
    ull k0 = wkey[par][0], k1 = wkey[par][1];
    ull kw = (k0 > k1) ? k0 : k1;
    int idx = 4095 - (int)(unsigned)(kw & 0xFFFFFFFFu);
    Px = lx[idx]; Py = ly[idx]; Pz = lz[idx];
  }
}

// ---------------- ball query + SA convs + maxpool: MFMA split-bf16 ----------------
__global__ __launch_bounds__(64) void k_sa(const float* __restrict__ pts,
    const float* __restrict__ xyz, const float* __restrict__ xnrm,
    const float* __restrict__ new_xyz, const float* __restrict__ w0f,
    const u16* __restrict__ w1fh, const u16* __restrict__ w1fl,
    const u16* __restrict__ w2fh, const u16* __restrict__ w2fl,
    float* __restrict__ x131){
  __shared__ __align__(16) u16 hh[64*64];
  __shared__ __align__(16) u16 hl[64*64];
  __shared__ int gw[64];
  int bi = blockIdx.x;
  int lane = threadIdx.x;
  int b = bi >> 8;
  const float* q = new_xyz + (size_t)bi*3;
  float qx=q[0], qy=q[1], qz=q[2];
  float nq = __fadd_rn(__fadd_rn(__fmul_rn(qx,qx), __fmul_rn(qy,qy)), __fmul_rn(qz,qz));
  const float* pX = pts + (size_t)(b*3+0)*NN;
  const float* pY = pts + (size_t)(b*3+1)*NN;
  const float* pZ = pts + (size_t)(b*3+2)*NN;
  int cnt = 0;
  for (int base = 0; base < NN; base += 256){
#pragma unroll
    for (int u = 0; u < 4; ++u){
      int j = base + u*64 + lane;
      float X = pX[j], Y = pY[j], Z = pZ[j];
      float dot = __fadd_rn(__fadd_rn(__fmul_rn(qx,X), __fmul_rn(qy,Y)), __fmul_rn(qz,Z));
      float d2 = __fsub_rn(__fadd_rn(nq, xnrm[b*NN + j]), __fmul_rn(2.0f, dot));
      bool inb = d2 < 0.04f;
      unsigned long long m = __ballot(inb);
      int pos = cnt + (int)__popcll(m & ((1ull << lane) - 1ull));
      if (inb && pos < NSs) gw[pos] = j;
      cnt += (int)__popcll(m);
    }
  }
  int g0 = gw[0];
  if (lane >= cnt) gw[lane] = g0;
  int gj = gw[lane];
  const float* pp = xyz + ((size_t)b*NN + gj)*3;
  float px = pp[0]-qx, py = pp[1]-qy, pz = pp[2]-qz;
  int col = lane & 15, g = lane >> 4;
  float sxv[4], syv[4], szv[4];
#pragma unroll
  for (int t2 = 0; t2 < 4; ++t2){
    int src = col + 16*t2;
    sxv[t2] = __shfl(px, src);
    syv[t2] = __shfl(py, src);
    szv[t2] = __shfl(pz, src);
  }
  i32x4 ah0[4][2], al0[4][2];
#pragma unroll
  for (int kt = 0; kt < 2; ++kt){
    float4 wrow[8];
    const float4* wp = (const float4*)(w0f + (size_t)(kt*64 + lane)*32);
#pragma unroll
    for (int e = 0; e < 8; ++e) wrow[e] = wp[e];
#pragma unroll
    for (int t2 = 0; t2 < 4; ++t2){
      unsigned hu[8], lu[8];
#pragma unroll
      for (int e = 0; e < 8; ++e){
        float a = fmaf(wrow[e].z, szv[t2], fmaf(wrow[e].y, syv[t2], wrow[e].x*sxv[t2]));
        a = fmaxf(a, 0.0f);
        bf16_split(a, hu[e], lu[e]);
      }
      i32x4 H, L;
#pragma unroll
      for (int j2 = 0; j2 < 4; ++j2){
        H[j2] = (int)(hu[2*j2] | (hu[2*j2+1] << 16));
        L[j2] = (int)(lu[2*j2] | (lu[2*j2+1] << 16));
      }
      ah0[t2][kt] = H; al0[t2][kt] = L;
    }
  }
#pragma unroll
  for (int ct = 0; ct < 4; ++ct){
    bf16x8 bh[2], bl[2];
#pragma unroll
    for (int kt = 0; kt < 2; ++kt){
      bh[kt] = *(const bf16x8*)(w1fh + (size_t)((ct*2+kt)*64 + lane)*8);
      bl[kt] = *(const bf16x8*)(w1fl + (size_t)((ct*2+kt)*64 + lane)*8);
    }
#pragma unroll
    for (int t2 = 0; t2 < 4; ++t2){
      f32x4 acc = {0.f,0.f,0.f,0.f};
#pragma unroll
      for (int kt = 0; kt < 2; ++kt){
        bf16x8 Ah = __builtin_bit_cast(bf16x8, ah0[t2][kt]);
        bf16x8 Al = __builtin_bit_cast(bf16x8, al0[t2][kt]);
        acc = __builtin_amdgcn_mfma_f32_16x16x32_bf16(Ah, bh[kt], acc, 0, 0, 0);
        acc = __builtin_amdgcn_mfma_f32_16x16x32_bf16(Ah, bl[kt], acc, 0, 0, 0);
        acc = __builtin_amdgcn_mfma_f32_16x16x32_bf16(Al, bh[kt], acc, 0, 0, 0);
      }
#pragma unroll
      for (int r = 0; r < 4; ++r){
        float v = fmaxf(acc[r], 0.0f);
        int s = 16*t2 + 4*g + r;
        int cc = ct*16 + col;
        int idx = s*64 + (cc ^ ((s & 7) << 3));
        unsigned h16, l16; bf16_split(v, h16, l16);
        hh[idx] = (u16)h16; hl[idx] = (u16)l16;
      }
    }
  }
  bf16x8 a1h[4][2], a1l[4][2];
#pragma unroll
  for (int t2 = 0; t2 < 4; ++t2){
    int s = col + 16*t2;
    int sw = (s & 7) << 3;
#pragma unroll
    for (int kt = 0; kt < 2; ++kt){
      int k0 = kt*32 + 8*g;
      int idx = s*64 + (k0 ^ sw);
      a1h[t2][kt] = *(const bf16x8*)(hh + idx);
      a1l[t2][kt] = *(const bf16x8*)(hl + idx);
    }
  }
#pragma unroll
  for (int c2t = 0; c2t < 8; ++c2t){
    bf16x8 bh2[2], bl2[2];
#pragma unroll
    for (int kt = 0; kt < 2; ++kt){
      bh2[kt] = *(const bf16x8*)(w2fh + (size_t)((c2t*2+kt)*64 + lane)*8);
      bl2[kt] = *(const bf16x8*)(w2fl + (size_t)((c2t*2+kt)*64 + lane)*8);
    }
    float mx = 0.0f;
#pragma unroll
    for (int t2 = 0; t2 < 4; ++t2){
      f32x4 acc = {0.f,0.f,0.f,0.f};
#pragma unroll
      for (int kt = 0; kt < 2; ++kt){
        acc = __builtin_amdgcn_mfma_f32_16x16x32_bf16(a1h[t2][kt], bh2[kt], acc, 0, 0, 0);
        acc = __builtin_amdgcn_mfma_f32_16x16x32_bf16(a1h[t2][kt], bl2[kt], acc, 0, 0, 0);
        acc = __builtin_amdgcn_mfma_f32_16x16x32_bf16(a1l[t2][kt], bh2[kt], acc, 0, 0, 0);
      }
      mx = fmaxf(mx, fmaxf(fmaxf(acc[0], acc[1]), fmaxf(acc[2], acc[3])));
    }
    mx = fmaxf(mx, __shfl_xor(mx, 16));
    mx = fmaxf(mx, __shfl_xor(mx, 32));
    if (lane < 16){
      int c = c2t*16 + lane;
      x131[(size_t)bi*132 + c] = mx;
    }
  }
  if (lane < 3) x131[(size_t)bi*132 + 128 + lane] = (lane==0)?qx:((lane==1)?qy:qz);
}

// ---------------- kNN: distances in registers, u64-DPP selection, no selection LDS ----------------
template<int CIN>
__global__ __launch_bounds__(512) void k_knn3(const float* __restrict__ xT,
    const float* __restrict__ nrm, int* __restrict__ idxo){
  __shared__ __align__(16) float sch[16*256];
  int bi = blockIdx.x, t = threadIdx.x;
  int w = t >> 6, lane = t & 63;
  int b = bi >> 5;
  int coli = (bi & 31)*8 + w;
  const float* xb = xT + (size_t)b*CIN*256;
  float d0=0.f, d1=0.f, d2=0.f, d3=0.f;
  for (int m0 = 0; m0 < CIN; m0 += 16){
    int mc = (CIN - m0 < 16) ? (CIN - m0) : 16;
    for (int i = t; i < mc*64; i += 512){
      int mm = i >> 6, c4 = i & 63;
      *(float4*)(sch + mm*256 + c4*4) = *(const float4*)(xb + (size_t)(m0+mm)*256 + c4*4);
    }
    __syncthreads();
    for (int mm = 0; mm < mc; ++mm){
      float xm = sch[mm*256 + coli];
      float4 v = *(const float4*)(sch + mm*256 + 4*lane);
      d0 = fmaf(v.x, xm, d0); d1 = fmaf(v.y, xm, d1);
      d2 = fmaf(v.z, xm, d2); d3 = fmaf(v.w, xm, d3);
    }
    __syncthreads();
  }
  float ni = nrm[b*256 + coli];
  float4 dv;
  {
    int j0 = 4*lane;
    dv.x = __fsub_rn(__fadd_rn(ni, nrm[b*256 + j0+0]), __fmul_rn(2.0f, d0));
    dv.y = __fsub_rn(__fadd_rn(ni, nrm[b*256 + j0+1]), __fmul_rn(2.0f, d1));
    dv.z = __fsub_rn(__fadd_rn(ni, nrm[b*256 + j0+2]), __fmul_rn(2.0f, d2));
    dv.w = __fsub_rn(__fadd_rn(ni, nrm[b*256 + j0+3]), __fmul_rn(2.0f, d3));
  }
  for (int r = 0; r < KC; ++r){
    float bv = 3.4e38f; int bj = NPp;
    if (dv.x < bv){ bv = dv.x; bj = 4*lane+0; }
    if (dv.y < bv){ bv = dv.y; bj = 4*lane+1; }
    if (dv.z < bv){ bv = dv.z; bj = 4*lane+2; }
    if (dv.w < bv){ bv = dv.w; bj = 4*lane+3; }
    unsigned xf = __float_as_uint(bv);
    xf = (xf & 0x80000000u) ? ~xf : (xf | 0x80000000u);
    ull key = ((ull)xf << 32) | (unsigned)bj;
#define KN_STAGE(C) { \
    unsigned ol = (unsigned)dpp_i<C>((int)(unsigned)key); \
    unsigned oh = (unsigned)dpp_i<C>((int)(unsigned)(key >> 32)); \
    ull ok = ((ull)oh << 32) | ol; \
    if (ok < key) key = ok; }
    KN_STAGE(0x111) KN_STAGE(0x112) KN_STAGE(0x114) KN_STAGE(0x118)
    KN_STAGE(0x142) KN_STAGE(0x143)
#undef KN_STAGE
    int bjw = __builtin_amdgcn_readlane((int)(unsigned)key, 63);
    if (lane == 0) idxo[((size_t)b*256 + coli)*KC + r] = bjw;
    if ((bjw >> 2) == lane){
      int e = bjw & 3;
      if      (e == 0) dv.x = 3.0e38f;
      else if (e == 1) dv.y = 3.0e38f;
      else if (e == 2) dv.z = 3.0e38f;
      else             dv.w = 3.0e38f;
    }
  }
}

// ---------------- per-point dual GEMM (scalar; used for CIN=131 layers) ----------------
template<int CIN, int COUT, int T>
__global__ __launch_bounds__(T) void k_gab(const float* __restrict__ x, int xstride,
    const float* __restrict__ wA, const float* __restrict__ wB,
    float* __restrict__ A, float* __restrict__ B, float* __restrict__ xT,
    float* __restrict__ nrm){
  constexpr int PC  = CIN + 1;
  constexpr int G   = COUT/4;
  constexpr int RS  = T/G;
  constexpr int RPT = 16/RS;
  __shared__ float xsh[16*PC];
  int bi = blockIdx.x, t = threadIdx.x;
  int g = t % G, rs = t / G;
  int i0 = bi*16;
  for (int i = t; i < 16*CIN; i += T){
    int r = i / CIN, m = i - r*CIN;
    xsh[r*PC + m] = x[(size_t)(i0+r)*xstride + m];
  }
  __syncthreads();
  {
    int bb = i0 >> 8, col0 = i0 & 255;
    float* xTb = xT + (size_t)bb*CIN*256 + col0;
    for (int i = t; i < 16*CIN; i += T){
      int m = i >> 4, r = i & 15;
      xTb[m*256 + r] = xsh[r*PC + m];
    }
  }
  if (t < 16){
    const float* xr = xsh + t*PC;
    float a = 0.0f;
    for (int m = 0; m < CIN; ++m) a = __fadd_rn(a, __fmul_rn(xr[m], xr[m]));
    nrm[i0 + t] = a;
  }
  float4 accA[RPT], accB[RPT];
#pragma unroll
  for (int rr = 0; rr < RPT; ++rr){
    accA[rr] = make_float4(0.f,0.f,0.f,0.f);
    accB[rr] = make_float4(0.f,0.f,0.f,0.f);
  }
  for (int m = 0; m < CIN; ++m){
    float4 wa = *(const float4*)(wA + (size_t)m*COUT + 4*g);
    float4 wb = *(const float4*)(wB + (size_t)m*COUT + 4*g);
#pragma unroll
    for (int rr = 0; rr < RPT; ++rr){
      float xv = xsh[(rs + rr*RS)*PC + m];
      accA[rr] = fma4s(wa, xv, accA[rr]);
      accB[rr] = fma4s(wb, xv, accB[rr]);
    }
  }
#pragma unroll
  for (int rr = 0; rr < RPT; ++rr){
    int r = i0 + rs + rr*RS;
    *(float4*)(A + (size_t)r*COUT + 4*g) = accA[rr];
    *(float4*)(B + (size_t)r*COUT + 4*g) = accB[rr];
  }
}

// ---------------- per-point dual GEMM via MFMA split-bf16 (CIN multiple of 32) ----------------
template<int CIN, int COUT>
__global__ __launch_bounds__(512) void k_gabm(const float* __restrict__ x, int xstride,
    const u16* __restrict__ wAh, const u16* __restrict__ wAl,
    const u16* __restrict__ wBh, const u16* __restrict__ wBl,
    float* __restrict__ A, float* __restrict__ B, float* __restrict__ xT,
    float* __restrict__ nrm){
  constexpr int PC  = CIN + 1;
  constexpr int KT  = CIN / 32;
  constexpr int CT  = COUT / 16;
  constexpr int TPW = 2*CT/8;
  constexpr int KB  = CIN / 8;
  __shared__ float xsh[16*PC];
  __shared__ __align__(16) u16 axh[16*CIN];
  __shared__ __align__(16) u16 axl[16*CIN];
  int bi = blockIdx.x, t = threadIdx.x;
  int i0 = bi*16;
  for (int i = t; i < 16*CIN; i += 512){
    int r = i / CIN, m = i - r*CIN;
    xsh[r*PC + m] = x[(size_t)(i0+r)*xstride + m];
  }
  __syncthreads();
  {
    int bb = i0 >> 8, col0 = i0 & 255;
    float* xTb = xT + (size_t)bb*CIN*256 + col0;
    for (int i = t; i < 16*CIN; i += 512){
      int m = i >> 4, r = i & 15;
      xTb[m*256 + r] = xsh[r*PC + m];
    }
  }
  if (t < 16){
    const float* xr = xsh + t*PC;
    float a = 0.0f;
    for (int m = 0; m < CIN; ++m) a = __fadd_rn(a, __fmul_rn(xr[m], xr[m]));
    nrm[i0 + t] = a;
  }
  if (t < 16*KB){
    int r = t / KB, kb = t - r*KB;
    unsigned hu[8], lu[8];
#pragma unroll
    for (int e = 0; e < 8; ++e) bf16_split(xsh[r*PC + kb*8 + e], hu[e], lu[e]);
    i32x4 H, L;
#pragma unroll
    for (int j2 = 0; j2 < 4; ++j2){
      H[j2] = (int)(hu[2*j2] | (hu[2*j2+1] << 16));
      L[j2] = (int)(lu[2*j2] | (lu[2*j2+1] << 16));
    }
    int idx = r*CIN + ((kb ^ (r & 7)) << 3);
    *(bf16x8*)(axh + idx) = __builtin_bit_cast(bf16x8, H);
    *(bf16x8*)(axl + idx) = __builtin_bit_cast(bf16x8, L);
  }
  __syncthreads();
  int lane = t & 63, wid = t >> 6;
  int col = lane & 15, g = lane >> 4;
  int aswz = col & 7;
#pragma unroll
  for (int tt = 0; tt < TPW; ++tt){
    int tile = wid*TPW + tt;
    bool isB = tile >= CT;
    int ct = isB ? tile - CT : tile;
    const u16* Wh = isB ? wBh : wAh;
    const u16* Wl = isB ? wBl : wAl;
    float* Out = isB ? B : A;
    f32x4 acc = {0.f,0.f,0.f,0.f};
#pragma unroll
    for (int kt = 0; kt < KT; ++kt){
      int kb = kt*4 + g;
      int aidx = col*CIN + ((kb ^ aswz) << 3);
      bf16x8 Ah = *(const bf16x8*)(axh + aidx);
      bf16x8 Al = *(const bf16x8*)(axl + aidx);
      size_t wo = ((size_t)(ct*KT + kt)*64 + lane)*8;
      bf16x8 Bh = *(const bf16x8*)(Wh + wo);
      bf16x8 Bl = *(const bf16x8*)(Wl + wo);
      acc = __builtin_amdgcn_mfma_f32_16x16x32_bf16(Ah, Bh, acc, 0, 0, 0);
      acc = __builtin_amdgcn_mfma_f32_16x16x32_bf16(Ah, Bl, acc, 0, 0, 0);
      acc = __builtin_amdgcn_mfma_f32_16x16x32_bf16(Al, Bh, acc, 0, 0, 0);
    }
#pragma unroll
    for (int r = 0; r < 4; ++r){
      Out[(size_t)(i0 + 4*g + r)*COUT + ct*16 + col] = acc[r];
    }
  }
}

// ---------------- T-Net 128->1024 GEMM + pool via MFMA split-bf16 ----------------
// D[i][c] = sum_k h[i][k]*W[c][k]; relu folded into max (init 0); per-block max over
// 16 points via fmax(acc)+shfl_xor(16,32); one atomicMax per (b,c) per block.
__global__ __launch_bounds__(512) void k_tpoolm(const float* __restrict__ h,
    const u16* __restrict__ Wh, const u16* __restrict__ Wl, float* __restrict__ g1024){
  __shared__ __align__(16) u16 ahh[16*128];
  __shared__ __align__(16) u16 ahl[16*128];
  int b = blockIdx.x, i0 = blockIdx.y*16;
  int t = threadIdx.x;
  if (t < 256){
    int r = t >> 4, kb = t & 15;
    const float* hr = h + ((size_t)b*NPp + i0 + r)*128 + kb*8;
    unsigned hu[8], lu[8];
#pragma unroll
    for (int e = 0; e < 8; ++e) bf16_split(hr[e], hu[e], lu[e]);
    i32x4 H, L;
#pragma unroll
    for (int j2 = 0; j2 < 4; ++j2){
      H[j2] = (int)(hu[2*j2] | (hu[2*j2+1] << 16));
      L[j2] = (int)(lu[2*j2] | (lu[2*j2+1] << 16));
    }
    int idx = r*128 + ((kb ^ (r & 7)) << 3);
    *(bf16x8*)(ahh + idx) = __builtin_bit_cast(bf16x8, H);
    *(bf16x8*)(ahl + idx) = __builtin_bit_cast(bf16x8, L);
  }
  __syncthreads();
  int lane = t & 63, wid = t >> 6;
  int col = lane & 15, g = lane >> 4;
  int aswz = col & 7;
#pragma unroll
  for (int tt = 0; tt < 8; ++tt){
    int ct = wid*8 + tt;
    f32x4 acc = {0.f,0.f,0.f,0.f};
#pragma unroll
    for (int kt = 0; kt < 4; ++kt){
      int kb = kt*4 + g;
      int aidx = col*128 + ((kb ^ aswz) << 3);
      bf16x8 Ah = *(const bf16x8*)(ahh + aidx);
      bf16x8 Al = *(const bf16x8*)(ahl + aidx);
      size_t wo = ((size_t)(ct*4 + kt)*64 + lane)*8;
      bf16x8 Bh = *(const bf16x8*)(Wh + wo);
      bf16x8 Bl = *(const bf16x8*)(Wl + wo);
      acc = __builtin_amdgcn_mfma_f32_16x16x32_bf16(Ah, Bh, acc, 0, 0, 0);
      acc = __builtin_amdgcn_mfma_f32_16x16x32_bf16(Ah, Bl, acc, 0, 0, 0);
      acc = __builtin_amdgcn_mfma_f32_16x16x32_bf16(Al, Bh, acc, 0, 0, 0);
    }
    float mx = fmaxf(fmaxf(acc[0], acc[1]), fmaxf(acc[2], acc[3]));
    mx = fmaxf(mx, 0.0f);
    mx = fmaxf(mx, __shfl_xor(mx, 16));
    mx = fmaxf(mx, __shfl_xor(mx, 32));
    if (lane < 16) atomicMax((int*)(g1024 + (size_t)b*1024 + ct*16 + lane), __float_as_int(mx));
  }
}

// ---------------- 896->128 conv + global pool via MFMA split-bf16 ----------------
// K segmented over f1(128)/f2(256)/f3(512); segment boundaries are 8-aligned so each
// 16B k-block lives in one segment. Same pool/atomicMax pattern as k_tpoolm.
__global__ __launch_bounds__(512) void k_dglm(const float* __restrict__ f1, const float* __restrict__ f2,
    const float* __restrict__ f3, const u16* __restrict__ Wh, const u16* __restrict__ Wl,
    float* __restrict__ g128){
  __shared__ __align__(16) u16 ahh[16*896];
  __shared__ __align__(16) u16 ahl[16*896];
  int b = blockIdx.x, i0 = blockIdx.y*16;
  int t = threadIdx.x;
  for (int i = t; i < 16*112; i += 512){
    int r = i / 112, kb = i - r*112;
    int k0 = kb*8;
    const float* src;
    if (k0 < 128)      src = f1 + ((size_t)b*NPp + i0 + r)*128 + k0;
    else if (k0 < 384) src = f2 + ((size_t)b*NPp + i0 + r)*256 + (k0-128);
    else               src = f3 + ((size_t)b*NPp + i0 + r)*512 + (k0-384);
    unsigned hu[8], lu[8];
#pragma unroll
    for (int e = 0; e < 8; ++e) bf16_split(src[e], hu[e], lu[e]);
    i32x4 H, L;
#pragma unroll
    for (int j2 = 0; j2 < 4; ++j2){
      H[j2] = (int)(hu[2*j2] | (hu[2*j2+1] << 16));
      L[j2] = (int)(lu[2*j2] | (lu[2*j2+1] << 16));
    }
    int idx = r*896 + ((kb ^ (r & 7)) << 3);
    *(bf16x8*)(ahh + idx) = __builtin_bit_cast(bf16x8, H);
    *(bf16x8*)(ahl + idx) = __builtin_bit_cast(bf16x8, L);
  }
  __syncthreads();
  int lane = t & 63, wid = t >> 6;  // wid = ct (8 waves, 8 c-tiles)
  int col = lane & 15, g = lane >> 4;
  int aswz = col & 7;
  f32x4 acc = {0.f,0.f,0.f,0.f};
#pragma unroll
  for (int kt = 0; kt < 28; ++kt){
    int kb = kt*4 + g;
    int aidx = col*896 + ((kb ^ aswz) << 3);
    bf16x8 Ah = *(const bf16x8*)(ahh + aidx);
    bf16x8 Al = *(const bf16x8*)(ahl + aidx);
    size_t wo = ((size_t)(wid*28 + kt)*64 + lane)*8;
    bf16x8 Bh = *(const bf16x8*)(Wh + wo);
    bf16x8 Bl = *(const bf16x8*)(Wl + wo);
    acc = __builtin_amdgcn_mfma_f32_16x16x32_bf16(Ah, Bh, acc, 0, 0, 0);
    acc = __builtin_amdgcn_mfma_f32_16x16x32_bf16(Ah, Bl, acc, 0, 0, 0);
    acc = __builtin_amdgcn_mfma_f32_16x16x32_bf16(Al, Bh, acc, 0, 0, 0);
  }
  float mx = fmaxf(fmaxf(acc[0], acc[1]), fmaxf(acc[2], acc[3]));
  mx = fmaxf(mx, 0.0f);
  mx = fmaxf(mx, __shfl_xor(mx, 16));
  mx = fmaxf(mx, __shfl_xor(mx, 32));
  if (lane < 16) atomicMax((int*)(g128 + (size_t)b*128 + wid*16 + lane), __float_as_int(mx));
}

// ---------------- edge epilogue: out[i][c] = max_k relu(A[i][c] + B[j_ik][c]) ----------------
template<int COUT>
__global__ __launch_bounds__(256) void k_emax(const float* __restrict__ A, const float* __restrict__ Bm,
    const int* __restrict__ idx, float* __restrict__ out){
  constexpr int GT = COUT/4;
  constexpr int NC = 256/GT;
  __shared__ int js[NC*KC];
  int bi = blockIdx.x, t = threadIdx.x;
  int li = t / GT, c4 = (t % GT)*4;
  int ci = bi*NC + li;
  int rb = (ci >> 8) << 8;
  if (t < NC*KC) js[t] = idx[(size_t)bi*NC*KC + t];
  __syncthreads();
  float4 a = *(const float4*)(A + (size_t)ci*COUT + c4);
  float4 p = make_float4(0.f,0.f,0.f,0.f);
#pragma unroll
  for (int k = 0; k < KC; ++k){
    int j = js[li*KC + k];
    float4 b = *(const float4*)(Bm + (size_t)(rb + j)*COUT + c4);
    p = max4(p, add4(a, b));
  }
  *(float4*)(out + (size_t)ci*COUT + c4) = p;
}

// ---------------- T-Net edge: h0 = relu(A0+B0) then 64->128 conv + k-maxpool ----------------
__global__ __launch_bounds__(128) void k_tedge3(const float* __restrict__ A0, const float* __restrict__ B0,
    const int* __restrict__ idx, const float* __restrict__ wt1, float* __restrict__ out){
  __shared__ __align__(16) float h0s[20*68];
  __shared__ __align__(16) float smax[4*128];
  __shared__ int js[KC];
  int bi = blockIdx.x, t = threadIdx.x;
  int cg = t & 31, kg = t >> 5, k0 = kg*5;
  int rb = (bi >> 8) << 8;
  if (t < KC) js[t] = idx[(size_t)bi*KC + t];
  __syncthreads();
  for (int i = t; i < 20*64; i += 128){
    int k = i >> 6, c = i & 63;
    float v = A0[(size_t)bi*64 + c] + B0[(size_t)(rb + js[k])*64 + c];
    h0s[k*68 + c] = fmaxf(v, 0.0f);
  }
  __syncthreads();
  float4 b2[5];
#pragma unroll
  for (int kk = 0; kk < 5; ++kk) b2[kk] = make_float4(0.f,0.f,0.f,0.f);
  for (int m4 = 0; m4 < 16; ++m4){
    float4 e[5];
#pragma unroll
    for (int kk = 0; kk < 5; ++kk) e[kk] = *(const float4*)(h0s + (k0+kk)*68 + 4*m4);
#pragma unroll
    for (int mm = 0; mm < 4; ++mm){
      float4 w = *(const float4*)(wt1 + (4*m4+mm)*128 + 4*cg);
#pragma unroll
      for (int kk = 0; kk < 5; ++kk){
        float ev = (mm==0)?e[kk].x:((mm==1)?e[kk].y:((mm==2)?e[kk].z:e[kk].w));
        b2[kk] = fma4s(w, ev, b2[kk]);
      }
    }
  }
  float4 p = make_float4(0.f,0.f,0.f,0.f);
#pragma unroll
  for (int kk = 0; kk < 5; ++kk) p = max4(p, b2[kk]);
  *(float4*)(smax + kg*128 + 4*cg) = p;
  __syncthreads();
  if (kg == 0){
    float4 r = *(const float4*)(smax + 4*cg);
#pragma unroll
    for (int g = 1; g < 4; ++g) r = max4(r, *(const float4*)(smax + g*128 + 4*cg));
    *(float4*)(out + (size_t)bi*128 + 4*cg) = r;
  }
}

// ---------------- T-Net MLP + 3x3 transform applied to new_xyz ----------------
__global__ __launch_bounds__(256) void k_trest(const float* __restrict__ g1024,
    const float* __restrict__ Wg0, const float* __restrict__ Wg1,
    const float* __restrict__ Wl, const float* __restrict__ bl,
    const float* __restrict__ new_xyz, float* __restrict__ x131){
  __shared__ __align__(16) float g1[1024];
  __shared__ __align__(16) float g5[512];
  __shared__ __align__(16) float g2[256];
  __shared__ float tm[12];
  int b = blockIdx.x, t = threadIdx.x;
  for (int m = t; m < 1024; m += 256) g1[m] = g1024[(size_t)b*1024 + m];
  __syncthreads();
#pragma unroll
  for (int cc = 0; cc < 2; ++cc){
    int c = t + cc*256;
    const float4* wr = (const float4*)(Wg0 + (size_t)c*1024);
    const float4* gv = (const float4*)g1;
    float a = 0.0f;
    for (int qq = 0; qq < 256; ++qq) a = fma4(wr[qq], gv[qq], a);
    g5[c] = fmaxf(a, 0.0f);
  }
  __syncthreads();
  {
    const float4* wr = (const float4*)(Wg1 + (size_t)t*512);
    const float4* gv = (const float4*)g5;
    float a = 0.0f;
    for (int qq = 0; qq < 128; ++qq) a = fma4(wr[qq], gv[qq], a);
    g2[t] = fmaxf(a, 0.0f);
  }
  __syncthreads();
  if (t < 9){
    const float4* wr = (const float4*)(Wl + (size_t)t*256);
    const float4* gv = (const float4*)g2;
    float a = 0.0f;
#pragma unroll
    for (int qq = 0; qq < 64; ++qq) a = fma4(wr[qq], gv[qq], a);
    a += bl[t];
    if (t == 0 || t == 4 || t == 8) a += 1.0f;
    tm[t] = a;
  }
  __syncthreads();
  {
    const float* nx = new_xyz + ((size_t)b*NPp + t)*3;
    float X = nx[0], Y = nx[1], Z = nx[2];
#pragma unroll
    for (int i = 0; i < 3; ++i){
      float v = __fadd_rn(__fadd_rn(__fmul_rn(tm[i*3+0], X), __fmul_rn(tm[i*3+1], Y)), __fmul_rn(tm[i*3+2], Z));
      x131[((size_t)b*NPp + t)*132 + 128 + i] = v;
    }
  }
}

// ---------------- classifier head ----------------
__global__ __launch_bounds__(256) void k_final(const float* __restrict__ g128,
    const float* __restrict__ W0, const float* __restrict__ W1,
    const float* __restrict__ Wc, const float* __restrict__ bc, float* __restrict__ out){
  __shared__ __align__(16) float g0[128];
  __shared__ __align__(16) float g5[512];
  __shared__ __align__(16) float g2[256];
  int b = blockIdx.x, t = threadIdx.x;
  if (t < 128) g0[t] = g128[(size_t)b*128 + t];
  __syncthreads();
#pragma unroll
  for (int cc = 0; cc < 2; ++cc){
    int c = t + cc*256;
    const float4* wr = (const float4*)(W0 + (size_t)c*128);
    const float4* gv = (const float4*)g0;
    float a = 0.0f;
#pragma unroll
    for (int qq = 0; qq < 32; ++qq) a = fma4(wr[qq], gv[qq], a);
    g5[c] = fmaxf(a, 0.0f);
  }
  __syncthreads();
  {
    const float4* wr = (const float4*)(W1 + (size_t)t*512);
    const float4* gv = (const float4*)g5;
    float a = 0.0f;
    for (int qq = 0; qq < 128; ++qq) a = fma4(wr[qq], gv[qq], a);
    g2[t] = fmaxf(a, 0.0f);
  }
  __syncthreads();
  if (t < 40){
    const float4* wr = (const float4*)(Wc + (size_t)t*256);
    const float4* gv = (const float4*)g2;
    float a = 0.0f;
#pragma unroll
    for (int qq = 0; qq < 64; ++qq) a = fma4(wr[qq], gv[qq], a);
    out[(size_t)b*40 + t] = a + bc[t];
  }
}

extern "C" void kernel_launch(void* const* d_in, const int* in_sizes, int n_in,
                              void* d_out, int out_size, void* d_ws, size_t ws_size,
                              hipStream_t stream){
  (void)in_sizes; (void)n_in; (void)out_size; (void)ws_size;
  const float* points     = (const float*)d_in[0];
  const float* sa_w0      = (const float*)d_in[1];
  const float* sa_w1      = (const float*)d_in[2];
  const float* sa_w2      = (const float*)d_in[3];
  const float* t_ec_w0    = (const float*)d_in[4];
  const float* t_ec_w1    = (const float*)d_in[5];
  const float* t_local_w  = (const float*)d_in[6];
  const float* t_g_w0     = (const float*)d_in[7];
  const float* t_g_w1     = (const float*)d_in[8];
  const float* t_lin_w    = (const float*)d_in[9];
  const float* t_lin_b    = (const float*)d_in[10];
  const float* dg_ec_w0   = (const float*)d_in[11];
  const float* dg_ec_w1   = (const float*)d_in[12];
  const float* dg_ec_w2   = (const float*)d_in[13];
  const float* dg_local_w = (const float*)d_in[14];
  const float* dg_g_w0    = (const float*)d_in[15];
  const float* dg_g_w1    = (const float*)d_in[16];
  const float* cls_w      = (const float*)d_in[17];
  const float* cls_b      = (const float*)d_in[18];
  float* out = (float*)d_out;

  float* ws     = (float*)d_ws;
  float* xyz    = ws;                    // 393216
  float* xnrm   = xyz    + 393216;       // 131072
  float* nxyz   = xnrm   + 131072;       // 24576
  float* feat   = nxyz   + 24576;        // 1048576 (dead output buffer -> MFMA weight frags)
  float* x131   = feat   + 1048576;      // 1081344
  float* nrm    = x131   + 1081344;      // 8192
  int*   idx    = (int*)(nrm + 8192);    // 163840
  float* ht     = (float*)(idx + 163840);// 1048576 (reused as f1)
  float* g1024v = ht     + 1048576;      // 32768
  float* f2     = g1024v + 32768;        // 2097152
  float* f3     = f2     + 2097152;      // 4194304
  float* g128v  = f3     + 4194304;      // 4096
  float* wt_t1  = g128v  + 4096;         // 8192   (64x128)
  float* waT0   = wt_t1  + 8192;         // 8384   (131x64)
  float* wbT0   = waT0   + 8384;         // 8384
  float* waD0   = wbT0   + 8384;         // 16768  (131x128)
  float* wbD0   = waD0   + 16768;        // 16768
  float* waD1   = wbD0   + 16768;        // 32768  (128x256)
  float* wbD1   = waD1   + 32768;        // 32768
  float* waD2   = wbD1   + 32768;        // 131072 (256x512)
  float* wbD2   = waD2   + 131072;       // 131072
  float* Ab     = wbD2   + 131072;       // 4194304
  float* Bb     = Ab     + 4194304;      // 4194304
  float* w1Tb   = Bb     + 4194304;      // 4096   (legacy, unused)
  float* f1 = ht;
  float* xT = f3;                        // alias: xT lives in f3 until k_emax<512> writes f3

  // SA MFMA weight fragments alias the HEAD of Ab (k_prep_all writes -> k_sa reads ->
  // k_gab T-Net is the first Ab write).
  float* w0f    = Ab;                    // 4096   ([kt][lane][e][4])
  u16*   w1fh   = (u16*)(w0f + 4096);    // 4096 u16
  u16*   w1fl   = w1fh   + 4096;         // 4096 u16
  u16*   w2fh   = w1fl   + 4096;         // 8192 u16
  u16*   w2fl   = w2fh   + 8192;         // 8192 u16

  // All GEMM weight frags live in the DEAD `feat` buffer (4MB; nothing reads it).
  // Total 1146880 u16 = 2.29MB <= 4MB.
  u16* fragu  = (u16*)feat;
  u16* wAD1h  = fragu;                   // 32768
  u16* wAD1l  = wAD1h + 32768;           // 32768
  u16* wBD1h  = wAD1l + 32768;           // 32768
  u16* wBD1l  = wBD1h + 32768;           // 32768
  u16* wAD2h  = wBD1l + 32768;           // 131072
  u16* wAD2l  = wAD2h + 131072;          // 131072
  u16* wBD2h  = wAD2l + 131072;          // 131072
  u16* wBD2l  = wBD2h + 131072;          // 131072
  u16* wTPh   = wBD2l + 131072;          // 131072 (t_local_w frags)
  u16* wTPl   = wTPh  + 131072;          // 131072
  u16* wDGh   = wTPl  + 131072;          // 114688 (dg_local_w frags)
  u16* wDGl   = wDGh  + 114688;          // 114688

  k_prep_all<<<3603, 256, 0, stream>>>(points, xyz, xnrm,
                                       t_ec_w0, t_ec_w1, dg_ec_w0, dg_ec_w1, dg_ec_w2, sa_w1,
                                       waT0, wbT0, wt_t1, waD0, wbD0, waD1, wbD1, waD2, wbD2, w1Tb,
                                       sa_w0, sa_w1, sa_w2, t_local_w, dg_local_w,
                                       w0f, w1fh, w1fl, w2fh, w2fl,
                                       wAD1h, wAD1l, wBD1h, wBD1l, wAD2h, wAD2l, wBD2h, wBD2l,
                                       wTPh, wTPl, wDGh, wDGl);
  k_fps<<<BB, 128, 0, stream>>>(xyz, nxyz);
  k_sa<<<BB*NPp, 64, 0, stream>>>(points, xyz, xnrm, nxyz, w0f, w1fh, w1fl, w2fh, w2fl, x131);

  // T-Net branch (x = [feat, new_xyz])
  k_gab<131,64,256><<<512, 256, 0, stream>>>(x131, 132, waT0, wbT0, Ab, Bb, xT, nrm);
  k_knn3<131><<<1024, 512, 0, stream>>>(xT, nrm, idx);
  k_tedge3<<<BB*NPp, 128, 0, stream>>>(Ab, Bb, idx, wt_t1, ht);
  k_tpoolm<<<dim3(BB, 16), 512, 0, stream>>>(ht, wTPh, wTPl, g1024v);
  k_trest<<<BB, 256, 0, stream>>>(g1024v, t_g_w0, t_g_w1, t_lin_w, t_lin_b, nxyz, x131);

  // DGCNN layer 1 (x = [feat, xyz_t], 131 dims) -- scalar (CIN not mult of 32)
  k_gab<131,128,512><<<512, 512, 0, stream>>>(x131, 132, waD0, wbD0, Ab, Bb, xT, nrm);
  k_knn3<131><<<1024, 512, 0, stream>>>(xT, nrm, idx);
  k_emax<128><<<1024, 256, 0, stream>>>(Ab, Bb, idx, f1);
  // layer 2 -- MFMA
  k_gabm<128,256><<<512, 512, 0, stream>>>(f1, 128, wAD1h, wAD1l, wBD1h, wBD1l, Ab, Bb, xT, nrm);
  k_knn3<128><<<1024, 512, 0, stream>>>(xT, nrm, idx);
  k_emax<256><<<2048, 256, 0, stream>>>(Ab, Bb, idx, f2);
  // layer 3 -- MFMA
  k_gabm<256,512><<<512, 512, 0, stream>>>(f2, 256, wAD2h, wAD2l, wBD2h, wBD2l, Ab, Bb, xT, nrm);
  k_knn3<256><<<1024, 512, 0, stream>>>(xT, nrm, idx);
  k_emax<512><<<4096, 256, 0, stream>>>(Ab, Bb, idx, f3);

  // local conv (MFMA) + global pool + head
  k_dglm<<<dim3(BB, 16), 512, 0, stream>>>(f1, f2, f3, wDGh, wDGl, g128v);
  k_final<<<BB, 256, 0, stream>>>(g128v, dg_g_w0, dg_g_w1, cls_w, cls_b, out);
}

// Round 12
// 872.129 us; speedup vs baseline: 1.6002x; 1.0711x over previous
//
#include <hip/hip_runtime.h>
#include <math.h>

#define BB 32
#define NN 4096
#define NPp 256
#define NSs 64
#define KC 20

typedef unsigned long long ull;
typedef unsigned short u16;
typedef short bf16x8 __attribute__((ext_vector_type(8)));
typedef float f32x4 __attribute__((ext_vector_type(4)));
typedef int i32x4 __attribute__((ext_vector_type(4)));

__device__ __forceinline__ float fma4(const float4 w, const float4 v, float a){
  a = fmaf(w.x, v.x, a); a = fmaf(w.y, v.y, a);
  a = fmaf(w.z, v.z, a); a = fmaf(w.w, v.w, a); return a;
}
__device__ __forceinline__ float4 fma4s(const float4 w, float s, float4 a){
  a.x = fmaf(w.x, s, a.x); a.y = fmaf(w.y, s, a.y);
  a.z = fmaf(w.z, s, a.z); a.w = fmaf(w.w, s, a.w); return a;
}
__device__ __forceinline__ float4 max4(float4 a, float4 b){
  a.x = fmaxf(a.x, b.x); a.y = fmaxf(a.y, b.y);
  a.z = fmaxf(a.z, b.z); a.w = fmaxf(a.w, b.w); return a;
}
__device__ __forceinline__ float4 add4(float4 a, float4 b){
  a.x += b.x; a.y += b.y; a.z += b.z; a.w += b.w; return a;
}

template<int C>
__device__ __forceinline__ int dpp_i(int x){
  return __builtin_amdgcn_update_dpp(x, x, C, 0xf, 0xf, false);
}

// split fp32 -> bf16 hi + bf16 lo (truncating; v - hi is exact in fp32)
__device__ __host__ __forceinline__ void bf16_split(float v, unsigned& h16, unsigned& l16){
  unsigned bits = __float_as_uint(v);
  h16 = bits >> 16;
  float hf = __uint_as_float(h16 << 16);
  l16 = __float_as_uint(v - hf) >> 16;
}

// ---------------- fused prep: transpose/norms + weight prep + ALL MFMA weight frags ----------------
// blocks [0,512): k_prep; [512,1299): k_wprep; [1299,1363): SA frags;
// [1363,2643): layer-2/3 GEMM frags; [2643,3155): t_local_w frags;
// [3155,3603): dg_local_w frags; [3603,3635): t_ec_w1 (tedge) frags.
// Frag layout everywhere (k_sa-verified): [ct][kt][lane][e], value W[k][c],
// k = kt*32 + 8*(lane>>4) + e, c = ct*16 + (lane&15).
__global__ void k_prep_all(const float* __restrict__ pts, float* __restrict__ xyz, float* __restrict__ xnrm,
                           const float* __restrict__ t0, const float* __restrict__ t1,
                           const float* __restrict__ d0, const float* __restrict__ d1,
                           const float* __restrict__ d2, const float* __restrict__ saw1,
                           float* __restrict__ waT0, float* __restrict__ wbT0,
                           float* __restrict__ wt_t1,
                           float* __restrict__ waD0, float* __restrict__ wbD0,
                           float* __restrict__ waD1, float* __restrict__ wbD1,
                           float* __restrict__ waD2, float* __restrict__ wbD2,
                           float* __restrict__ w1T,
                           const float* __restrict__ w0, const float* __restrict__ w1,
                           const float* __restrict__ w2,
                           const float* __restrict__ tl, const float* __restrict__ dgw,
                           float* __restrict__ w0f, u16* __restrict__ w1fh, u16* __restrict__ w1fl,
                           u16* __restrict__ w2fh, u16* __restrict__ w2fl,
                           u16* __restrict__ wAD1h, u16* __restrict__ wAD1l,
                           u16* __restrict__ wBD1h, u16* __restrict__ wBD1l,
                           u16* __restrict__ wAD2h, u16* __restrict__ wAD2l,
                           u16* __restrict__ wBD2h, u16* __restrict__ wBD2l,
                           u16* __restrict__ wTPh, u16* __restrict__ wTPl,
                           u16* __restrict__ wDGh, u16* __restrict__ wDGl,
                           u16* __restrict__ wTEh, u16* __restrict__ wTEl){
  int bid = blockIdx.x;
  if (bid < 512){                        // ---- k_prep ----
    int i = bid*256 + threadIdx.x;
    if (i >= BB*NN) return;
    int b = i >> 12, n = i & (NN-1);
    float X = pts[(b*3+0)*NN + n];
    float Y = pts[(b*3+1)*NN + n];
    float Z = pts[(b*3+2)*NN + n];
    xyz[i*3+0]=X; xyz[i*3+1]=Y; xyz[i*3+2]=Z;
    xnrm[i] = __fadd_rn(__fadd_rn(__fmul_rn(X,X), __fmul_rn(Y,Y)), __fmul_rn(Z,Z));
    return;
  }
  if (bid < 1299){                       // ---- k_wprep ----
    int i = (bid-512)*256 + threadIdx.x;
    if (i < 8384){                       // t_ec_w0: [64][262] -> A/B [131][64]
      int m = i >> 6;
      int c = i & 63;
      float bb = t0[(size_t)c*262 + m];
      float dd = t0[(size_t)c*262 + 131 + m];
      waT0[i] = __fsub_rn(bb, dd); wbT0[i] = dd;
      return;
    }
    i -= 8384;
    if (i < 8192){                       // t_ec_w1: [128][64] -> [64][128]
      int m = i >> 7, c = i & 127;
      wt_t1[i] = t1[(size_t)c*64 + m];
      return;
    }
    i -= 8192;
    if (i < 16768){                      // dg_ec_w0: [128][262] -> A/B [131][128]
      int m = i >> 7, c = i & 127;
      float bb = d0[(size_t)c*262 + m];
      float dd = d0[(size_t)c*262 + 131 + m];
      waD0[i] = __fsub_rn(bb, dd); wbD0[i] = dd;
      return;
    }
    i -= 16768;
    if (i < 32768){                      // dg_ec_w1: [256][256] -> A/B [128][256]
      int m = i >> 8, c = i & 255;
      float bb = d1[(size_t)c*256 + m];
      float dd = d1[(size_t)c*256 + 128 + m];
      waD1[i] = __fsub_rn(bb, dd); wbD1[i] = dd;
      return;
    }
    i -= 32768;
    if (i < 131072){                     // dg_ec_w2: [512][512] -> A/B [256][512]
      int m = i >> 9, c = i & 511;
      float bb = d2[(size_t)c*512 + m];
      float dd = d2[(size_t)c*512 + 256 + m];
      waD2[i] = __fsub_rn(bb, dd); wbD2[i] = dd;
      return;
    }
    i -= 131072;
    if (i < 4096){                       // sa_w1 (legacy, unused)
      int m = i >> 6, c = i & 63;
      w1T[i] = saw1[(size_t)c*64 + m];
    }
    return;
  }
  if (bid < 1363){                       // ---- SA frags ----
    int i = (bid-1299)*256 + threadIdx.x;
    if (i < 4096){                       // w0f: [kt][lane][e][4] (xyz + pad)
      int kt = i >> 11, r = i & 2047;
      int ln = r >> 5, ee = r & 31;
      int e = ee >> 2, j = ee & 3;
      int k = kt*32 + 8*(ln>>4) + e;
      w0f[i] = (j < 3) ? w0[k*3 + j] : 0.0f;
      return;
    }
    i -= 4096;
    if (i < 4096){                       // w1 frags
      int e = i & 7, ln = (i >> 3) & 63, q = i >> 9;
      int kt = q & 1, ct = q >> 1;
      int k = kt*32 + 8*(ln>>4) + e;
      int c = ct*16 + (ln & 15);
      unsigned h16, l16; bf16_split(w1[(size_t)c*64 + k], h16, l16);
      w1fh[i] = (u16)h16; w1fl[i] = (u16)l16;
      return;
    }
    i -= 4096;
    if (i < 8192){                       // w2 frags
      int e = i & 7, ln = (i >> 3) & 63, q = i >> 9;
      int kt = q & 1, c2t = q >> 1;
      int k = kt*32 + 8*(ln>>4) + e;
      int c2 = c2t*16 + (ln & 15);
      unsigned h16, l16; bf16_split(w2[(size_t)c2*64 + k], h16, l16);
      w2fh[i] = (u16)h16; w2fl[i] = (u16)l16;
    }
    return;
  }
  if (bid < 2643){                       // ---- layer-2/3 GEMM weight frags ----
    int i = (bid-1363)*256 + threadIdx.x;
    if (i < 32768){                      // D1 wA: [ct(16)][kt(4)][lane][e]
      int e = i & 7, ln = (i >> 3) & 63, q = i >> 9;
      int kt = q & 3, ct = q >> 2;
      int k = kt*32 + 8*(ln>>4) + e;
      int c = ct*16 + (ln & 15);
      float bb = d1[(size_t)c*256 + k], dd = d1[(size_t)c*256 + 128 + k];
      unsigned h, l; bf16_split(__fsub_rn(bb, dd), h, l);
      wAD1h[i] = (u16)h; wAD1l[i] = (u16)l;
      return;
    }
    i -= 32768;
    if (i < 32768){                      // D1 wB
      int e = i & 7, ln = (i >> 3) & 63, q = i >> 9;
      int kt = q & 3, ct = q >> 2;
      int k = kt*32 + 8*(ln>>4) + e;
      int c = ct*16 + (ln & 15);
      float dd = d1[(size_t)c*256 + 128 + k];
      unsigned h, l; bf16_split(dd, h, l);
      wBD1h[i] = (u16)h; wBD1l[i] = (u16)l;
      return;
    }
    i -= 32768;
    if (i < 131072){                     // D2 wA: [ct(32)][kt(8)][lane][e]
      int e = i & 7, ln = (i >> 3) & 63, q = i >> 9;
      int kt = q & 7, ct = q >> 3;
      int k = kt*32 + 8*(ln>>4) + e;
      int c = ct*16 + (ln & 15);
      float bb = d2[(size_t)c*512 + k], dd = d2[(size_t)c*512 + 256 + k];
      unsigned h, l; bf16_split(__fsub_rn(bb, dd), h, l);
      wAD2h[i] = (u16)h; wAD2l[i] = (u16)l;
      return;
    }
    i -= 131072;
    if (i < 131072){                     // D2 wB
      int e = i & 7, ln = (i >> 3) & 63, q = i >> 9;
      int kt = q & 7, ct = q >> 3;
      int k = kt*32 + 8*(ln>>4) + e;
      int c = ct*16 + (ln & 15);
      float dd = d2[(size_t)c*512 + 256 + k];
      unsigned h, l; bf16_split(dd, h, l);
      wBD2h[i] = (u16)h; wBD2l[i] = (u16)l;
    }
    return;
  }
  if (bid < 3155){                       // ---- t_local_w frags: [ct(64)][kt(4)][lane][e] ----
    int i = (bid-2643)*256 + threadIdx.x;  // i < 131072
    int e = i & 7, ln = (i >> 3) & 63, q = i >> 9;   // q in [0,256)
    int kt = q & 3, ct = q >> 2;
    int k = kt*32 + 8*(ln>>4) + e;                   // [0,128)
    int c = ct*16 + (ln & 15);                       // [0,1024)
    unsigned h, l; bf16_split(tl[(size_t)c*128 + k], h, l);
    wTPh[i] = (u16)h; wTPl[i] = (u16)l;
    return;
  }
  if (bid < 3603){                       // ---- dg_local_w frags: [ct(8)][kt(28)][lane][e] ----
    int i = (bid-3155)*256 + threadIdx.x;
    if (i >= 114688) return;
    int e = i & 7, ln = (i >> 3) & 63, q = i >> 9;   // q in [0,224)
    int kt = q % 28, ct = q / 28;
    int k = kt*32 + 8*(ln>>4) + e;                   // [0,896)
    int c = ct*16 + (ln & 15);                       // [0,128)
    unsigned h, l; bf16_split(dgw[(size_t)c*896 + k], h, l);
    wDGh[i] = (u16)h; wDGl[i] = (u16)l;
    return;
  }
  {                                      // ---- t_ec_w1 (tedge) frags: [ct(8)][kt(2)][lane][e] ----
    int i = (bid-3603)*256 + threadIdx.x;  // i < 8192
    int e = i & 7, ln = (i >> 3) & 63, q = i >> 9;   // q in [0,16)
    int kt = q & 1, ct = q >> 1;
    int k = kt*32 + 8*(ln>>4) + e;                   // [0,64)
    int c = ct*16 + (ln & 15);                       // [0,128)
    unsigned h, l; bf16_split(t1[(size_t)c*64 + k], h, l);
    wTEh[i] = (u16)h; wTEl[i] = (u16)l;
  }
}

// ---------------- farthest point sampling: 2 waves, key-only reduce (parked at floor) ----------------
__global__ __launch_bounds__(128, 1) void k_fps(const float* __restrict__ xyz, float* __restrict__ new_xyz){
  __shared__ __align__(16) float lx[NN], ly[NN], lz[NN];
  __shared__ __align__(16) ull wkey[2][2];
  int b = blockIdx.x, t = threadIdx.x;
  int w = t >> 6, lane = t & 63;
  float nx[32], ny[32], nz[32], dist[32];
#pragma unroll
  for (int q = 0; q < 32; ++q){
    int j = q*128 + t;
    const float* p = xyz + ((size_t)b*NN + j)*3;
    float X = p[0], Y = p[1], Z = p[2];
    lx[j] = X; ly[j] = Y; lz[j] = Z;
    nx[q] = -X; ny[q] = -Y; nz[q] = -Z;
    dist[q] = __builtin_inff();
  }
  const float* p0 = xyz + (size_t)b*NN*3;
  float Px = p0[0], Py = p0[1], Pz = p0[2];
  __syncthreads();
  for (int it = 0; it < NPp; ++it){
    if (t == 0){
      float* o = new_xyz + ((size_t)b*NPp + it)*3;
      o[0] = Px; o[1] = Py; o[2] = Pz;
    }
    ull ka0 = 0, ka1 = 0, ka2 = 0, ka3 = 0;
#pragma unroll
    for (int q = 0; q < 32; ++q){
      float dx = __fadd_rn(nx[q], Px);
      float dy = __fadd_rn(ny[q], Py);
      float dz = __fadd_rn(nz[q], Pz);
      float dd = __fadd_rn(__fadd_rn(__fmul_rn(dx,dx), __fmul_rn(dy,dy)), __fmul_rn(dz,dz));
      float dm = fminf(dist[q], dd);
      dist[q] = dm;
      ull key = ((ull)__float_as_uint(dm) << 32) | (unsigned)(4095 - (q*128 + t));
      if      ((q & 3) == 0){ if (key > ka0) ka0 = key; }
      else if ((q & 3) == 1){ if (key > ka1) ka1 = key; }
      else if ((q & 3) == 2){ if (key > ka2) ka2 = key; }
      else                  { if (key > ka3) ka3 = key; }
    }
    ull kb0 = (ka0 > ka1) ? ka0 : ka1;
    ull kb1 = (ka2 > ka3) ? ka2 : ka3;
    ull bk  = (kb0 > kb1) ? kb0 : kb1;
#define FPS_STAGE(C) { \
    unsigned ol = (unsigned)dpp_i<C>((int)(unsigned)bk); \
    unsigned oh = (unsigned)dpp_i<C>((int)(unsigned)(bk >> 32)); \
    ull ok = ((ull)oh << 32) | ol; \
    if (ok > bk) bk = ok; }
    FPS_STAGE(0x111) FPS_STAGE(0x112) FPS_STAGE(0x114) FPS_STAGE(0x118)
    FPS_STAGE(0x142) FPS_STAGE(0x143)
#undef FPS_STAGE
    int par = it & 1;
    if (lane == 63) wkey[par][w] = bk;
    __syncthreads();
    ull k0 = wkey[par][0], k1 = wkey[par][1];
    ull kw = (k0 > k1) ? k0 : k1;
    int idx = 4095 - (int)(unsigned)(kw & 0xFFFFFFFFu);
    Px = lx[idx]; Py = ly[idx]; Pz = lz[idx];
  }
}

// ---------------- ball query + SA convs + maxpool: MFMA split-bf16 ----------------
__global__ __launch_bounds__(64) void k_sa(const float* __restrict__ pts,
    const float* __restrict__ xyz, const float* __restrict__ xnrm,
    const float* __restrict__ new_xyz, const float* __restrict__ w0f,
    const u16* __restrict__ w1fh, const u16* __restrict__ w1fl,
    const u16* __restrict__ w2fh, const u16* __restrict__ w2fl,
    float* __restrict__ x131){
  __shared__ __align__(16) u16 hh[64*64];
  __shared__ __align__(16) u16 hl[64*64];
  __shared__ int gw[64];
  int bi = blockIdx.x;
  int lane = threadIdx.x;
  int b = bi >> 8;
  const float* q = new_xyz + (size_t)bi*3;
  float qx=q[0], qy=q[1], qz=q[2];
  float nq = __fadd_rn(__fadd_rn(__fmul_rn(qx,qx), __fmul_rn(qy,qy)), __fmul_rn(qz,qz));
  const float* pX = pts + (size_t)(b*3+0)*NN;
  const float* pY = pts + (size_t)(b*3+1)*NN;
  const float* pZ = pts + (size_t)(b*3+2)*NN;
  int cnt = 0;
  for (int base = 0; base < NN; base += 256){
#pragma unroll
    for (int u = 0; u < 4; ++u){
      int j = base + u*64 + lane;
      float X = pX[j], Y = pY[j], Z = pZ[j];
      float dot = __fadd_rn(__fadd_rn(__fmul_rn(qx,X), __fmul_rn(qy,Y)), __fmul_rn(qz,Z));
      float d2 = __fsub_rn(__fadd_rn(nq, xnrm[b*NN + j]), __fmul_rn(2.0f, dot));
      bool inb = d2 < 0.04f;
      unsigned long long m = __ballot(inb);
      int pos = cnt + (int)__popcll(m & ((1ull << lane) - 1ull));
      if (inb && pos < NSs) gw[pos] = j;
      cnt += (int)__popcll(m);
    }
  }
  int g0 = gw[0];
  if (lane >= cnt) gw[lane] = g0;
  int gj = gw[lane];
  const float* pp = xyz + ((size_t)b*NN + gj)*3;
  float px = pp[0]-qx, py = pp[1]-qy, pz = pp[2]-qz;
  int col = lane & 15, g = lane >> 4;
  float sxv[4], syv[4], szv[4];
#pragma unroll
  for (int t2 = 0; t2 < 4; ++t2){
    int src = col + 16*t2;
    sxv[t2] = __shfl(px, src);
    syv[t2] = __shfl(py, src);
    szv[t2] = __shfl(pz, src);
  }
  i32x4 ah0[4][2], al0[4][2];
#pragma unroll
  for (int kt = 0; kt < 2; ++kt){
    float4 wrow[8];
    const float4* wp = (const float4*)(w0f + (size_t)(kt*64 + lane)*32);
#pragma unroll
    for (int e = 0; e < 8; ++e) wrow[e] = wp[e];
#pragma unroll
    for (int t2 = 0; t2 < 4; ++t2){
      unsigned hu[8], lu[8];
#pragma unroll
      for (int e = 0; e < 8; ++e){
        float a = fmaf(wrow[e].z, szv[t2], fmaf(wrow[e].y, syv[t2], wrow[e].x*sxv[t2]));
        a = fmaxf(a, 0.0f);
        bf16_split(a, hu[e], lu[e]);
      }
      i32x4 H, L;
#pragma unroll
      for (int j2 = 0; j2 < 4; ++j2){
        H[j2] = (int)(hu[2*j2] | (hu[2*j2+1] << 16));
        L[j2] = (int)(lu[2*j2] | (lu[2*j2+1] << 16));
      }
      ah0[t2][kt] = H; al0[t2][kt] = L;
    }
  }
#pragma unroll
  for (int ct = 0; ct < 4; ++ct){
    bf16x8 bh[2], bl[2];
#pragma unroll
    for (int kt = 0; kt < 2; ++kt){
      bh[kt] = *(const bf16x8*)(w1fh + (size_t)((ct*2+kt)*64 + lane)*8);
      bl[kt] = *(const bf16x8*)(w1fl + (size_t)((ct*2+kt)*64 + lane)*8);
    }
#pragma unroll
    for (int t2 = 0; t2 < 4; ++t2){
      f32x4 acc = {0.f,0.f,0.f,0.f};
#pragma unroll
      for (int kt = 0; kt < 2; ++kt){
        bf16x8 Ah = __builtin_bit_cast(bf16x8, ah0[t2][kt]);
        bf16x8 Al = __builtin_bit_cast(bf16x8, al0[t2][kt]);
        acc = __builtin_amdgcn_mfma_f32_16x16x32_bf16(Ah, bh[kt], acc, 0, 0, 0);
        acc = __builtin_amdgcn_mfma_f32_16x16x32_bf16(Ah, bl[kt], acc, 0, 0, 0);
        acc = __builtin_amdgcn_mfma_f32_16x16x32_bf16(Al, bh[kt], acc, 0, 0, 0);
      }
#pragma unroll
      for (int r = 0; r < 4; ++r){
        float v = fmaxf(acc[r], 0.0f);
        int s = 16*t2 + 4*g + r;
        int cc = ct*16 + col;
        int idx = s*64 + (cc ^ ((s & 7) << 3));
        unsigned h16, l16; bf16_split(v, h16, l16);
        hh[idx] = (u16)h16; hl[idx] = (u16)l16;
      }
    }
  }
  bf16x8 a1h[4][2], a1l[4][2];
#pragma unroll
  for (int t2 = 0; t2 < 4; ++t2){
    int s = col + 16*t2;
    int sw = (s & 7) << 3;
#pragma unroll
    for (int kt = 0; kt < 2; ++kt){
      int k0 = kt*32 + 8*g;
      int idx = s*64 + (k0 ^ sw);
      a1h[t2][kt] = *(const bf16x8*)(hh + idx);
      a1l[t2][kt] = *(const bf16x8*)(hl + idx);
    }
  }
#pragma unroll
  for (int c2t = 0; c2t < 8; ++c2t){
    bf16x8 bh2[2], bl2[2];
#pragma unroll
    for (int kt = 0; kt < 2; ++kt){
      bh2[kt] = *(const bf16x8*)(w2fh + (size_t)((c2t*2+kt)*64 + lane)*8);
      bl2[kt] = *(const bf16x8*)(w2fl + (size_t)((c2t*2+kt)*64 + lane)*8);
    }
    float mx = 0.0f;
#pragma unroll
    for (int t2 = 0; t2 < 4; ++t2){
      f32x4 acc = {0.f,0.f,0.f,0.f};
#pragma unroll
      for (int kt = 0; kt < 2; ++kt){
        acc = __builtin_amdgcn_mfma_f32_16x16x32_bf16(a1h[t2][kt], bh2[kt], acc, 0, 0, 0);
        acc = __builtin_amdgcn_mfma_f32_16x16x32_bf16(a1h[t2][kt], bl2[kt], acc, 0, 0, 0);
        acc = __builtin_amdgcn_mfma_f32_16x16x32_bf16(a1l[t2][kt], bh2[kt], acc, 0, 0, 0);
      }
      mx = fmaxf(mx, fmaxf(fmaxf(acc[0], acc[1]), fmaxf(acc[2], acc[3])));
    }
    mx = fmaxf(mx, __shfl_xor(mx, 16));
    mx = fmaxf(mx, __shfl_xor(mx, 32));
    if (lane < 16){
      int c = c2t*16 + lane;
      x131[(size_t)bi*132 + c] = mx;
    }
  }
  if (lane < 3) x131[(size_t)bi*132 + 128 + lane] = (lane==0)?qx:((lane==1)?qy:qz);
}

// ---------------- kNN: distances in registers, u64-DPP selection, no selection LDS ----------------
template<int CIN>
__global__ __launch_bounds__(512) void k_knn3(const float* __restrict__ xT,
    const float* __restrict__ nrm, int* __restrict__ idxo){
  __shared__ __align__(16) float sch[16*256];
  int bi = blockIdx.x, t = threadIdx.x;
  int w = t >> 6, lane = t & 63;
  int b = bi >> 5;
  int coli = (bi & 31)*8 + w;
  const float* xb = xT + (size_t)b*CIN*256;
  float d0=0.f, d1=0.f, d2=0.f, d3=0.f;
  for (int m0 = 0; m0 < CIN; m0 += 16){
    int mc = (CIN - m0 < 16) ? (CIN - m0) : 16;
    for (int i = t; i < mc*64; i += 512){
      int mm = i >> 6, c4 = i & 63;
      *(float4*)(sch + mm*256 + c4*4) = *(const float4*)(xb + (size_t)(m0+mm)*256 + c4*4);
    }
    __syncthreads();
    for (int mm = 0; mm < mc; ++mm){
      float xm = sch[mm*256 + coli];
      float4 v = *(const float4*)(sch + mm*256 + 4*lane);
      d0 = fmaf(v.x, xm, d0); d1 = fmaf(v.y, xm, d1);
      d2 = fmaf(v.z, xm, d2); d3 = fmaf(v.w, xm, d3);
    }
    __syncthreads();
  }
  float ni = nrm[b*256 + coli];
  float4 dv;
  {
    int j0 = 4*lane;
    dv.x = __fsub_rn(__fadd_rn(ni, nrm[b*256 + j0+0]), __fmul_rn(2.0f, d0));
    dv.y = __fsub_rn(__fadd_rn(ni, nrm[b*256 + j0+1]), __fmul_rn(2.0f, d1));
    dv.z = __fsub_rn(__fadd_rn(ni, nrm[b*256 + j0+2]), __fmul_rn(2.0f, d2));
    dv.w = __fsub_rn(__fadd_rn(ni, nrm[b*256 + j0+3]), __fmul_rn(2.0f, d3));
  }
  for (int r = 0; r < KC; ++r){
    float bv = 3.4e38f; int bj = NPp;
    if (dv.x < bv){ bv = dv.x; bj = 4*lane+0; }
    if (dv.y < bv){ bv = dv.y; bj = 4*lane+1; }
    if (dv.z < bv){ bv = dv.z; bj = 4*lane+2; }
    if (dv.w < bv){ bv = dv.w; bj = 4*lane+3; }
    unsigned xf = __float_as_uint(bv);
    xf = (xf & 0x80000000u) ? ~xf : (xf | 0x80000000u);
    ull key = ((ull)xf << 32) | (unsigned)bj;
#define KN_STAGE(C) { \
    unsigned ol = (unsigned)dpp_i<C>((int)(unsigned)key); \
    unsigned oh = (unsigned)dpp_i<C>((int)(unsigned)(key >> 32)); \
    ull ok = ((ull)oh << 32) | ol; \
    if (ok < key) key = ok; }
    KN_STAGE(0x111) KN_STAGE(0x112) KN_STAGE(0x114) KN_STAGE(0x118)
    KN_STAGE(0x142) KN_STAGE(0x143)
#undef KN_STAGE
    int bjw = __builtin_amdgcn_readlane((int)(unsigned)key, 63);
    if (lane == 0) idxo[((size_t)b*256 + coli)*KC + r] = bjw;
    if ((bjw >> 2) == lane){
      int e = bjw & 3;
      if      (e == 0) dv.x = 3.0e38f;
      else if (e == 1) dv.y = 3.0e38f;
      else if (e == 2) dv.z = 3.0e38f;
      else             dv.w = 3.0e38f;
    }
  }
}

// ---------------- per-point dual GEMM (scalar; used for CIN=131 layers) ----------------
template<int CIN, int COUT, int T>
__global__ __launch_bounds__(T) void k_gab(const float* __restrict__ x, int xstride,
    const float* __restrict__ wA, const float* __restrict__ wB,
    float* __restrict__ A, float* __restrict__ B, float* __restrict__ xT,
    float* __restrict__ nrm){
  constexpr int PC  = CIN + 1;
  constexpr int G   = COUT/4;
  constexpr int RS  = T/G;
  constexpr int RPT = 16/RS;
  __shared__ float xsh[16*PC];
  int bi = blockIdx.x, t = threadIdx.x;
  int g = t % G, rs = t / G;
  int i0 = bi*16;
  for (int i = t; i < 16*CIN; i += T){
    int r = i / CIN, m = i - r*CIN;
    xsh[r*PC + m] = x[(size_t)(i0+r)*xstride + m];
  }
  __syncthreads();
  {
    int bb = i0 >> 8, col0 = i0 & 255;
    float* xTb = xT + (size_t)bb*CIN*256 + col0;
    for (int i = t; i < 16*CIN; i += T){
      int m = i >> 4, r = i & 15;
      xTb[m*256 + r] = xsh[r*PC + m];
    }
  }
  if (t < 16){
    const float* xr = xsh + t*PC;
    float a = 0.0f;
    for (int m = 0; m < CIN; ++m) a = __fadd_rn(a, __fmul_rn(xr[m], xr[m]));
    nrm[i0 + t] = a;
  }
  float4 accA[RPT], accB[RPT];
#pragma unroll
  for (int rr = 0; rr < RPT; ++rr){
    accA[rr] = make_float4(0.f,0.f,0.f,0.f);
    accB[rr] = make_float4(0.f,0.f,0.f,0.f);
  }
  for (int m = 0; m < CIN; ++m){
    float4 wa = *(const float4*)(wA + (size_t)m*COUT + 4*g);
    float4 wb = *(const float4*)(wB + (size_t)m*COUT + 4*g);
#pragma unroll
    for (int rr = 0; rr < RPT; ++rr){
      float xv = xsh[(rs + rr*RS)*PC + m];
      accA[rr] = fma4s(wa, xv, accA[rr]);
      accB[rr] = fma4s(wb, xv, accB[rr]);
    }
  }
#pragma unroll
  for (int rr = 0; rr < RPT; ++rr){
    int r = i0 + rs + rr*RS;
    *(float4*)(A + (size_t)r*COUT + 4*g) = accA[rr];
    *(float4*)(B + (size_t)r*COUT + 4*g) = accB[rr];
  }
}

// ---------------- per-point dual GEMM via MFMA split-bf16 (CIN multiple of 32) ----------------
template<int CIN, int COUT>
__global__ __launch_bounds__(512) void k_gabm(const float* __restrict__ x, int xstride,
    const u16* __restrict__ wAh, const u16* __restrict__ wAl,
    const u16* __restrict__ wBh, const u16* __restrict__ wBl,
    float* __restrict__ A, float* __restrict__ B, float* __restrict__ xT,
    float* __restrict__ nrm){
  constexpr int PC  = CIN + 1;
  constexpr int KT  = CIN / 32;
  constexpr int CT  = COUT / 16;
  constexpr int TPW = 2*CT/8;
  constexpr int KB  = CIN / 8;
  __shared__ float xsh[16*PC];
  __shared__ __align__(16) u16 axh[16*CIN];
  __shared__ __align__(16) u16 axl[16*CIN];
  int bi = blockIdx.x, t = threadIdx.x;
  int i0 = bi*16;
  for (int i = t; i < 16*CIN; i += 512){
    int r = i / CIN, m = i - r*CIN;
    xsh[r*PC + m] = x[(size_t)(i0+r)*xstride + m];
  }
  __syncthreads();
  {
    int bb = i0 >> 8, col0 = i0 & 255;
    float* xTb = xT + (size_t)bb*CIN*256 + col0;
    for (int i = t; i < 16*CIN; i += 512){
      int m = i >> 4, r = i & 15;
      xTb[m*256 + r] = xsh[r*PC + m];
    }
  }
  if (t < 16){
    const float* xr = xsh + t*PC;
    float a = 0.0f;
    for (int m = 0; m < CIN; ++m) a = __fadd_rn(a, __fmul_rn(xr[m], xr[m]));
    nrm[i0 + t] = a;
  }
  if (t < 16*KB){
    int r = t / KB, kb = t - r*KB;
    unsigned hu[8], lu[8];
#pragma unroll
    for (int e = 0; e < 8; ++e) bf16_split(xsh[r*PC + kb*8 + e], hu[e], lu[e]);
    i32x4 H, L;
#pragma unroll
    for (int j2 = 0; j2 < 4; ++j2){
      H[j2] = (int)(hu[2*j2] | (hu[2*j2+1] << 16));
      L[j2] = (int)(lu[2*j2] | (lu[2*j2+1] << 16));
    }
    int idx = r*CIN + ((kb ^ (r & 7)) << 3);
    *(bf16x8*)(axh + idx) = __builtin_bit_cast(bf16x8, H);
    *(bf16x8*)(axl + idx) = __builtin_bit_cast(bf16x8, L);
  }
  __syncthreads();
  int lane = t & 63, wid = t >> 6;
  int col = lane & 15, g = lane >> 4;
  int aswz = col & 7;
#pragma unroll
  for (int tt = 0; tt < TPW; ++tt){
    int tile = wid*TPW + tt;
    bool isB = tile >= CT;
    int ct = isB ? tile - CT : tile;
    const u16* Wh = isB ? wBh : wAh;
    const u16* Wl = isB ? wBl : wAl;
    float* Out = isB ? B : A;
    f32x4 acc = {0.f,0.f,0.f,0.f};
#pragma unroll
    for (int kt = 0; kt < KT; ++kt){
      int kb = kt*4 + g;
      int aidx = col*CIN + ((kb ^ aswz) << 3);
      bf16x8 Ah = *(const bf16x8*)(axh + aidx);
      bf16x8 Al = *(const bf16x8*)(axl + aidx);
      size_t wo = ((size_t)(ct*KT + kt)*64 + lane)*8;
      bf16x8 Bh = *(const bf16x8*)(Wh + wo);
      bf16x8 Bl = *(const bf16x8*)(Wl + wo);
      acc = __builtin_amdgcn_mfma_f32_16x16x32_bf16(Ah, Bh, acc, 0, 0, 0);
      acc = __builtin_amdgcn_mfma_f32_16x16x32_bf16(Ah, Bl, acc, 0, 0, 0);
      acc = __builtin_amdgcn_mfma_f32_16x16x32_bf16(Al, Bh, acc, 0, 0, 0);
    }
#pragma unroll
    for (int r = 0; r < 4; ++r){
      Out[(size_t)(i0 + 4*g + r)*COUT + ct*16 + col] = acc[r];
    }
  }
}

// ---------------- T-Net 128->1024 GEMM + pool via MFMA split-bf16 ----------------
__global__ __launch_bounds__(512) void k_tpoolm(const float* __restrict__ h,
    const u16* __restrict__ Wh, const u16* __restrict__ Wl, float* __restrict__ g1024){
  __shared__ __align__(16) u16 ahh[16*128];
  __shared__ __align__(16) u16 ahl[16*128];
  int b = blockIdx.x, i0 = blockIdx.y*16;
  int t = threadIdx.x;
  if (t < 256){
    int r = t >> 4, kb = t & 15;
    const float* hr = h + ((size_t)b*NPp + i0 + r)*128 + kb*8;
    unsigned hu[8], lu[8];
#pragma unroll
    for (int e = 0; e < 8; ++e) bf16_split(hr[e], hu[e], lu[e]);
    i32x4 H, L;
#pragma unroll
    for (int j2 = 0; j2 < 4; ++j2){
      H[j2] = (int)(hu[2*j2] | (hu[2*j2+1] << 16));
      L[j2] = (int)(lu[2*j2] | (lu[2*j2+1] << 16));
    }
    int idx = r*128 + ((kb ^ (r & 7)) << 3);
    *(bf16x8*)(ahh + idx) = __builtin_bit_cast(bf16x8, H);
    *(bf16x8*)(ahl + idx) = __builtin_bit_cast(bf16x8, L);
  }
  __syncthreads();
  int lane = t & 63, wid = t >> 6;
  int col = lane & 15, g = lane >> 4;
  int aswz = col & 7;
#pragma unroll
  for (int tt = 0; tt < 8; ++tt){
    int ct = wid*8 + tt;
    f32x4 acc = {0.f,0.f,0.f,0.f};
#pragma unroll
    for (int kt = 0; kt < 4; ++kt){
      int kb = kt*4 + g;
      int aidx = col*128 + ((kb ^ aswz) << 3);
      bf16x8 Ah = *(const bf16x8*)(ahh + aidx);
      bf16x8 Al = *(const bf16x8*)(ahl + aidx);
      size_t wo = ((size_t)(ct*4 + kt)*64 + lane)*8;
      bf16x8 Bh = *(const bf16x8*)(Wh + wo);
      bf16x8 Bl = *(const bf16x8*)(Wl + wo);
      acc = __builtin_amdgcn_mfma_f32_16x16x32_bf16(Ah, Bh, acc, 0, 0, 0);
      acc = __builtin_amdgcn_mfma_f32_16x16x32_bf16(Ah, Bl, acc, 0, 0, 0);
      acc = __builtin_amdgcn_mfma_f32_16x16x32_bf16(Al, Bh, acc, 0, 0, 0);
    }
    float mx = fmaxf(fmaxf(acc[0], acc[1]), fmaxf(acc[2], acc[3]));
    mx = fmaxf(mx, 0.0f);
    mx = fmaxf(mx, __shfl_xor(mx, 16));
    mx = fmaxf(mx, __shfl_xor(mx, 32));
    if (lane < 16) atomicMax((int*)(g1024 + (size_t)b*1024 + ct*16 + lane), __float_as_int(mx));
  }
}

// ---------------- 896->128 conv + global pool via MFMA split-bf16 ----------------
__global__ __launch_bounds__(512) void k_dglm(const float* __restrict__ f1, const float* __restrict__ f2,
    const float* __restrict__ f3, const u16* __restrict__ Wh, const u16* __restrict__ Wl,
    float* __restrict__ g128){
  __shared__ __align__(16) u16 ahh[16*896];
  __shared__ __align__(16) u16 ahl[16*896];
  int b = blockIdx.x, i0 = blockIdx.y*16;
  int t = threadIdx.x;
  for (int i = t; i < 16*112; i += 512){
    int r = i / 112, kb = i - r*112;
    int k0 = kb*8;
    const float* src;
    if (k0 < 128)      src = f1 + ((size_t)b*NPp + i0 + r)*128 + k0;
    else if (k0 < 384) src = f2 + ((size_t)b*NPp + i0 + r)*256 + (k0-128);
    else               src = f3 + ((size_t)b*NPp + i0 + r)*512 + (k0-384);
    unsigned hu[8], lu[8];
#pragma unroll
    for (int e = 0; e < 8; ++e) bf16_split(src[e], hu[e], lu[e]);
    i32x4 H, L;
#pragma unroll
    for (int j2 = 0; j2 < 4; ++j2){
      H[j2] = (int)(hu[2*j2] | (hu[2*j2+1] << 16));
      L[j2] = (int)(lu[2*j2] | (lu[2*j2+1] << 16));
    }
    int idx = r*896 + ((kb ^ (r & 7)) << 3);
    *(bf16x8*)(ahh + idx) = __builtin_bit_cast(bf16x8, H);
    *(bf16x8*)(ahl + idx) = __builtin_bit_cast(bf16x8, L);
  }
  __syncthreads();
  int lane = t & 63, wid = t >> 6;
  int col = lane & 15, g = lane >> 4;
  int aswz = col & 7;
  f32x4 acc = {0.f,0.f,0.f,0.f};
#pragma unroll
  for (int kt = 0; kt < 28; ++kt){
    int kb = kt*4 + g;
    int aidx = col*896 + ((kb ^ aswz) << 3);
    bf16x8 Ah = *(const bf16x8*)(ahh + aidx);
    bf16x8 Al = *(const bf16x8*)(ahl + aidx);
    size_t wo = ((size_t)(wid*28 + kt)*64 + lane)*8;
    bf16x8 Bh = *(const bf16x8*)(Wh + wo);
    bf16x8 Bl = *(const bf16x8*)(Wl + wo);
    acc = __builtin_amdgcn_mfma_f32_16x16x32_bf16(Ah, Bh, acc, 0, 0, 0);
    acc = __builtin_amdgcn_mfma_f32_16x16x32_bf16(Ah, Bl, acc, 0, 0, 0);
    acc = __builtin_amdgcn_mfma_f32_16x16x32_bf16(Al, Bh, acc, 0, 0, 0);
  }
  float mx = fmaxf(fmaxf(acc[0], acc[1]), fmaxf(acc[2], acc[3]));
  mx = fmaxf(mx, 0.0f);
  mx = fmaxf(mx, __shfl_xor(mx, 16));
  mx = fmaxf(mx, __shfl_xor(mx, 32));
  if (lane < 16) atomicMax((int*)(g128 + (size_t)b*128 + wid*16 + lane), __float_as_int(mx));
}

// ---------------- T-Net edge via MFMA: h0=relu(A0+B0[j_k]) -> [20x64]@[64x128] -> col-max ----------------
// h0 staged split-bf16 in XOR-swizzled LDS as [32][64], rows 20-31 ZEROED: pad rows give
// D=0, and the max is relu-folded (init 0), so zero rows are no-ops -> no masking.
// Wave w owns ct = 4w..4w+3 and both 16-row M-tiles (8 tiles, 48 MFMA/wave).
// Row-swizzle on read: row = m*16+col => swz = col&7 (16 == 0 mod 8).
__global__ __launch_bounds__(128) void k_tedge3m(const float* __restrict__ A0, const float* __restrict__ B0,
    const int* __restrict__ idx, const u16* __restrict__ Wh, const u16* __restrict__ Wl,
    float* __restrict__ out){
  __shared__ __align__(16) u16 hh[32*64];
  __shared__ __align__(16) u16 hl[32*64];
  __shared__ int js[KC];
  int bi = blockIdx.x, t = threadIdx.x;
  int rb = (bi >> 8) << 8;
  if (t < KC) js[t] = idx[(size_t)bi*KC + t];
  __syncthreads();
  for (int i = t; i < 256; i += 128){
    int r = i >> 3, kb = i & 7;
    i32x4 H = {0,0,0,0}, L = {0,0,0,0};
    if (r < KC){
      const float* a = A0 + (size_t)bi*64 + kb*8;
      const float* bm = B0 + (size_t)(rb + js[r])*64 + kb*8;
      unsigned hu[8], lu[8];
#pragma unroll
      for (int e = 0; e < 8; ++e){
        float v = fmaxf(a[e] + bm[e], 0.0f);
        bf16_split(v, hu[e], lu[e]);
      }
#pragma unroll
      for (int j2 = 0; j2 < 4; ++j2){
        H[j2] = (int)(hu[2*j2] | (hu[2*j2+1] << 16));
        L[j2] = (int)(lu[2*j2] | (lu[2*j2+1] << 16));
      }
    }
    int idx2 = r*64 + ((kb ^ (r & 7)) << 3);
    *(bf16x8*)(hh + idx2) = __builtin_bit_cast(bf16x8, H);
    *(bf16x8*)(hl + idx2) = __builtin_bit_cast(bf16x8, L);
  }
  __syncthreads();
  int lane = t & 63, wv = t >> 6;
  int col = lane & 15, g = lane >> 4;
  int aswz = col & 7;
#pragma unroll
  for (int tt = 0; tt < 4; ++tt){
    int ct = wv*4 + tt;
    float mx = 0.0f;                     // relu fold (matches scalar p init 0)
#pragma unroll
    for (int m = 0; m < 2; ++m){
      f32x4 acc = {0.f,0.f,0.f,0.f};
#pragma unroll
      for (int kt = 0; kt < 2; ++kt){
        int kb = kt*4 + g;
        int aidx = (m*16 + col)*64 + ((kb ^ aswz) << 3);
        bf16x8 Ah = *(const bf16x8*)(hh + aidx);
        bf16x8 Al = *(const bf16x8*)(hl + aidx);
        size_t wo = ((size_t)(ct*2 + kt)*64 + lane)*8;
        bf16x8 Bh = *(const bf16x8*)(Wh + wo);
        bf16x8 Bl = *(const bf16x8*)(Wl + wo);
        acc = __builtin_amdgcn_mfma_f32_16x16x32_bf16(Ah, Bh, acc, 0, 0, 0);
        acc = __builtin_amdgcn_mfma_f32_16x16x32_bf16(Ah, Bl, acc, 0, 0, 0);
        acc = __builtin_amdgcn_mfma_f32_16x16x32_bf16(Al, Bh, acc, 0, 0, 0);
      }
      mx = fmaxf(mx, fmaxf(fmaxf(acc[0], acc[1]), fmaxf(acc[2], acc[3])));
    }
    mx = fmaxf(mx, __shfl_xor(mx, 16));
    mx = fmaxf(mx, __shfl_xor(mx, 32));
    if (lane < 16) out[(size_t)bi*128 + ct*16 + col] = mx;
  }
}

// ---------------- edge epilogue: out[i][c] = max_k relu(A[i][c] + B[j_ik][c]) ----------------
template<int COUT>
__global__ __launch_bounds__(256) void k_emax(const float* __restrict__ A, const float* __restrict__ Bm,
    const int* __restrict__ idx, float* __restrict__ out){
  constexpr int GT = COUT/4;
  constexpr int NC = 256/GT;
  __shared__ int js[NC*KC];
  int bi = blockIdx.x, t = threadIdx.x;
  int li = t / GT, c4 = (t % GT)*4;
  int ci = bi*NC + li;
  int rb = (ci >> 8) << 8;
  if (t < NC*KC) js[t] = idx[(size_t)bi*NC*KC + t];
  __syncthreads();
  float4 a = *(const float4*)(A + (size_t)ci*COUT + c4);
  float4 p = make_float4(0.f,0.f,0.f,0.f);
#pragma unroll
  for (int k = 0; k < KC; ++k){
    int j = js[li*KC + k];
    float4 b = *(const float4*)(Bm + (size_t)(rb + j)*COUT + c4);
    p = max4(p, add4(a, b));
  }
  *(float4*)(out + (size_t)ci*COUT + c4) = p;
}

// ---------------- T-Net MLP + 3x3 transform applied to new_xyz ----------------
__global__ __launch_bounds__(256) void k_trest(const float* __restrict__ g1024,
    const float* __restrict__ Wg0, const float* __restrict__ Wg1,
    const float* __restrict__ Wl, const float* __restrict__ bl,
    const float* __restrict__ new_xyz, float* __restrict__ x131){
  __shared__ __align__(16) float g1[1024];
  __shared__ __align__(16) float g5[512];
  __shared__ __align__(16) float g2[256];
  __shared__ float tm[12];
  int b = blockIdx.x, t = threadIdx.x;
  for (int m = t; m < 1024; m += 256) g1[m] = g1024[(size_t)b*1024 + m];
  __syncthreads();
#pragma unroll
  for (int cc = 0; cc < 2; ++cc){
    int c = t + cc*256;
    const float4* wr = (const float4*)(Wg0 + (size_t)c*1024);
    const float4* gv = (const float4*)g1;
    float a = 0.0f;
    for (int qq = 0; qq < 256; ++qq) a = fma4(wr[qq], gv[qq], a);
    g5[c] = fmaxf(a, 0.0f);
  }
  __syncthreads();
  {
    const float4* wr = (const float4*)(Wg1 + (size_t)t*512);
    const float4* gv = (const float4*)g5;
    float a = 0.0f;
    for (int qq = 0; qq < 128; ++qq) a = fma4(wr[qq], gv[qq], a);
    g2[t] = fmaxf(a, 0.0f);
  }
  __syncthreads();
  if (t < 9){
    const float4* wr = (const float4*)(Wl + (size_t)t*256);
    const float4* gv = (const float4*)g2;
    float a = 0.0f;
#pragma unroll
    for (int qq = 0; qq < 64; ++qq) a = fma4(wr[qq], gv[qq], a);
    a += bl[t];
    if (t == 0 || t == 4 || t == 8) a += 1.0f;
    tm[t] = a;
  }
  __syncthreads();
  {
    const float* nx = new_xyz + ((size_t)b*NPp + t)*3;
    float X = nx[0], Y = nx[1], Z = nx[2];
#pragma unroll
    for (int i = 0; i < 3; ++i){
      float v = __fadd_rn(__fadd_rn(__fmul_rn(tm[i*3+0], X), __fmul_rn(tm[i*3+1], Y)), __fmul_rn(tm[i*3+2], Z));
      x131[((size_t)b*NPp + t)*132 + 128 + i] = v;
    }
  }
}

// ---------------- classifier head ----------------
__global__ __launch_bounds__(256) void k_final(const float* __restrict__ g128,
    const float* __restrict__ W0, const float* __restrict__ W1,
    const float* __restrict__ Wc, const float* __restrict__ bc, float* __restrict__ out){
  __shared__ __align__(16) float g0[128];
  __shared__ __align__(16) float g5[512];
  __shared__ __align__(16) float g2[256];
  int b = blockIdx.x, t = threadIdx.x;
  if (t < 128) g0[t] = g128[(size_t)b*128 + t];
  __syncthreads();
#pragma unroll
  for (int cc = 0; cc < 2; ++cc){
    int c = t + cc*256;
    const float4* wr = (const float4*)(W0 + (size_t)c*128);
    const float4* gv = (const float4*)g0;
    float a = 0.0f;
#pragma unroll
    for (int qq = 0; qq < 32; ++qq) a = fma4(wr[qq], gv[qq], a);
    g5[c] = fmaxf(a, 0.0f);
  }
  __syncthreads();
  {
    const float4* wr = (const float4*)(W1 + (size_t)t*512);
    const float4* gv = (const float4*)g5;
    float a = 0.0f;
    for (int qq = 0; qq < 128; ++qq) a = fma4(wr[qq], gv[qq], a);
    g2[t] = fmaxf(a, 0.0f);
  }
  __syncthreads();
  if (t < 40){
    const float4* wr = (const float4*)(Wc + (size_t)t*256);
    const float4* gv = (const float4*)g2;
    float a = 0.0f;
#pragma unroll
    for (int qq = 0; qq < 64; ++qq) a = fma4(wr[qq], gv[qq], a);
    out[(size_t)b*40 + t] = a + bc[t];
  }
}

extern "C" void kernel_launch(void* const* d_in, const int* in_sizes, int n_in,
                              void* d_out, int out_size, void* d_ws, size_t ws_size,
                              hipStream_t stream){
  (void)in_sizes; (void)n_in; (void)out_size; (void)ws_size;
  const float* points     = (const float*)d_in[0];
  const float* sa_w0      = (const float*)d_in[1];
  const float* sa_w1      = (const float*)d_in[2];
  const float* sa_w2      = (const float*)d_in[3];
  const float* t_ec_w0    = (const float*)d_in[4];
  const float* t_ec_w1    = (const float*)d_in[5];
  const float* t_local_w  = (const float*)d_in[6];
  const float* t_g_w0     = (const float*)d_in[7];
  const float* t_g_w1     = (const float*)d_in[8];
  const float* t_lin_w    = (const float*)d_in[9];
  const float* t_lin_b    = (const float*)d_in[10];
  const float* dg_ec_w0   = (const float*)d_in[11];
  const float* dg_ec_w1   = (const float*)d_in[12];
  const float* dg_ec_w2   = (const float*)d_in[13];
  const float* dg_local_w = (const float*)d_in[14];
  const float* dg_g_w0    = (const float*)d_in[15];
  const float* dg_g_w1    = (const float*)d_in[16];
  const float* cls_w      = (const float*)d_in[17];
  const float* cls_b      = (const float*)d_in[18];
  float* out = (float*)d_out;

  float* ws     = (float*)d_ws;
  float* xyz    = ws;                    // 393216
  float* xnrm   = xyz    + 393216;       // 131072
  float* nxyz   = xnrm   + 131072;       // 24576
  float* feat   = nxyz   + 24576;        // 1048576 (dead output buffer -> MFMA weight frags)
  float* x131   = feat   + 1048576;      // 1081344
  float* nrm    = x131   + 1081344;      // 8192
  int*   idx    = (int*)(nrm + 8192);    // 163840
  float* ht     = (float*)(idx + 163840);// 1048576 (reused as f1)
  float* g1024v = ht     + 1048576;      // 32768
  float* f2     = g1024v + 32768;        // 2097152
  float* f3     = f2     + 2097152;      // 4194304
  float* g128v  = f3     + 4194304;      // 4096
  float* wt_t1  = g128v  + 4096;         // 8192   (64x128)
  float* waT0   = wt_t1  + 8192;         // 8384   (131x64)
  float* wbT0   = waT0   + 8384;         // 8384
  float* waD0   = wbT0   + 8384;         // 16768  (131x128)
  float* wbD0   = waD0   + 16768;        // 16768
  float* waD1   = wbD0   + 16768;        // 32768  (128x256)
  float* wbD1   = waD1   + 32768;        // 32768
  float* waD2   = wbD1   + 32768;        // 131072 (256x512)
  float* wbD2   = waD2   + 131072;       // 131072
  float* Ab     = wbD2   + 131072;       // 4194304
  float* Bb     = Ab     + 4194304;      // 4194304
  float* w1Tb   = Bb     + 4194304;      // 4096   (legacy, unused)
  float* f1 = ht;
  float* xT = f3;                        // alias: xT lives in f3 until k_emax<512> writes f3

  // SA MFMA weight fragments alias the HEAD of Ab.
  float* w0f    = Ab;                    // 4096   ([kt][lane][e][4])
  u16*   w1fh   = (u16*)(w0f + 4096);    // 4096 u16
  u16*   w1fl   = w1fh   + 4096;         // 4096 u16
  u16*   w2fh   = w1fl   + 4096;         // 8192 u16
  u16*   w2fl   = w2fh   + 8192;         // 8192 u16

  // All GEMM weight frags live in the DEAD `feat` buffer (4MB; nothing reads it).
  // Total 1163264 u16 = 2.33MB <= 4MB.
  u16* fragu  = (u16*)feat;
  u16* wAD1h  = fragu;                   // 32768
  u16* wAD1l  = wAD1h + 32768;           // 32768
  u16* wBD1h  = wAD1l + 32768;           // 32768
  u16* wBD1l  = wBD1h + 32768;           // 32768
  u16* wAD2h  = wBD1l + 32768;           // 131072
  u16* wAD2l  = wAD2h + 131072;          // 131072
  u16* wBD2h  = wAD2l + 131072;          // 131072
  u16* wBD2l  = wBD2h + 131072;          // 131072
  u16* wTPh   = wBD2l + 131072;          // 131072 (t_local_w frags)
  u16* wTPl   = wTPh  + 131072;          // 131072
  u16* wDGh   = wTPl  + 131072;          // 114688 (dg_local_w frags)
  u16* wDGl   = wDGh  + 114688;          // 114688
  u16* wTEh   = wDGl  + 114688;          // 8192   (t_ec_w1 tedge frags)
  u16* wTEl   = wTEh  + 8192;            // 8192

  k_prep_all<<<3635, 256, 0, stream>>>(points, xyz, xnrm,
                                       t_ec_w0, t_ec_w1, dg_ec_w0, dg_ec_w1, dg_ec_w2, sa_w1,
                                       waT0, wbT0, wt_t1, waD0, wbD0, waD1, wbD1, waD2, wbD2, w1Tb,
                                       sa_w0, sa_w1, sa_w2, t_local_w, dg_local_w,
                                       w0f, w1fh, w1fl, w2fh, w2fl,
                                       wAD1h, wAD1l, wBD1h, wBD1l, wAD2h, wAD2l, wBD2h, wBD2l,
                                       wTPh, wTPl, wDGh, wDGl, wTEh, wTEl);
  k_fps<<<BB, 128, 0, stream>>>(xyz, nxyz);
  k_sa<<<BB*NPp, 64, 0, stream>>>(points, xyz, xnrm, nxyz, w0f, w1fh, w1fl, w2fh, w2fl, x131);

  // T-Net branch (x = [feat, new_xyz])
  k_gab<131,64,256><<<512, 256, 0, stream>>>(x131, 132, waT0, wbT0, Ab, Bb, xT, nrm);
  k_knn3<131><<<1024, 512, 0, stream>>>(xT, nrm, idx);
  k_tedge3m<<<BB*NPp, 128, 0, stream>>>(Ab, Bb, idx, wTEh, wTEl, ht);
  k_tpoolm<<<dim3(BB, 16), 512, 0, stream>>>(ht, wTPh, wTPl, g1024v);
  k_trest<<<BB, 256, 0, stream>>>(g1024v, t_g_w0, t_g_w1, t_lin_w, t_lin_b, nxyz, x131);

  // DGCNN layer 1 (x = [feat, xyz_t], 131 dims) -- scalar (CIN not mult of 32)
  k_gab<131,128,512><<<512, 512, 0, stream>>>(x131, 132, waD0, wbD0, Ab, Bb, xT, nrm);
  k_knn3<131><<<1024, 512, 0, stream>>>(xT, nrm, idx);
  k_emax<128><<<1024, 256, 0, stream>>>(Ab, Bb, idx, f1);
  // layer 2 -- MFMA
  k_gabm<128,256><<<512, 512, 0, stream>>>(f1, 128, wAD1h, wAD1l, wBD1h, wBD1l, Ab, Bb, xT, nrm);
  k_knn3<128><<<1024, 512, 0, stream>>>(xT, nrm, idx);
  k_emax<256><<<2048, 256, 0, stream>>>(Ab, Bb, idx, f2);
  // layer 3 -- MFMA
  k_gabm<256,512><<<512, 512, 0, stream>>>(f2, 256, wAD2h, wAD2l, wBD2h, wBD2l, Ab, Bb, xT, nrm);
  k_knn3<256><<<1024, 512, 0, stream>>>(xT, nrm, idx);
  k_emax<512><<<4096, 256, 0, stream>>>(Ab, Bb, idx, f3);

  // local conv (MFMA) + global pool + head
  k_dglm<<<dim3(BB, 16), 512, 0, stream>>>(f1, f2, f3, wDGh, wDGl, g128v);
  k_final<<<BB, 256, 0, stream>>>(g128v, dg_g_w0, dg_g_w1, cls_w, cls_b, out);
}

// Round 13
// 843.101 us; speedup vs baseline: 1.6553x; 1.0344x over previous
//
#include <hip/hip_runtime.h>
#include <math.h>

#define BB 32
#define NN 4096
#define NPp 256
#define NSs 64
#define KC 20

typedef unsigned long long ull;
typedef unsigned short u16;
typedef short bf16x8 __attribute__((ext_vector_type(8)));
typedef float f32x4 __attribute__((ext_vector_type(4)));
typedef int i32x4 __attribute__((ext_vector_type(4)));

__device__ __forceinline__ float fma4(const float4 w, const float4 v, float a){
  a = fmaf(w.x, v.x, a); a = fmaf(w.y, v.y, a);
  a = fmaf(w.z, v.z, a); a = fmaf(w.w, v.w, a); return a;
}
__device__ __forceinline__ float4 fma4s(const float4 w, float s, float4 a){
  a.x = fmaf(w.x, s, a.x); a.y = fmaf(w.y, s, a.y);
  a.z = fmaf(w.z, s, a.z); a.w = fmaf(w.w, s, a.w); return a;
}
__device__ __forceinline__ float4 max4(float4 a, float4 b){
  a.x = fmaxf(a.x, b.x); a.y = fmaxf(a.y, b.y);
  a.z = fmaxf(a.z, b.z); a.w = fmaxf(a.w, b.w); return a;
}
__device__ __forceinline__ float4 add4(float4 a, float4 b){
  a.x += b.x; a.y += b.y; a.z += b.z; a.w += b.w; return a;
}

template<int C>
__device__ __forceinline__ int dpp_i(int x){
  return __builtin_amdgcn_update_dpp(x, x, C, 0xf, 0xf, false);
}

// split fp32 -> bf16 hi + bf16 lo (truncating; v - hi is exact in fp32)
__device__ __host__ __forceinline__ void bf16_split(float v, unsigned& h16, unsigned& l16){
  unsigned bits = __float_as_uint(v);
  h16 = bits >> 16;
  float hf = __uint_as_float(h16 << 16);
  l16 = __float_as_uint(v - hf) >> 16;
}

// ---------------- fused prep: transpose/norms + weight prep + ALL MFMA weight frags ----------------
// blocks [0,512): k_prep; [512,1299): k_wprep; [1299,1363): SA frags;
// [1363,2643): layer-2/3 GEMM frags; [2643,3155): t_local_w frags;
// [3155,3603): dg_local_w frags; [3603,3635): t_ec_w1 (tedge) frags;
// [3635,3875): PADDED t_ec_w0 / dg_ec_w0 frags (CINP=160, k>=131 zeroed -> exact no-ops).
// Frag layout everywhere (k_sa-verified): [ct][kt][lane][e], value W[k][c],
// k = kt*32 + 8*(lane>>4) + e, c = ct*16 + (lane&15).
__global__ void k_prep_all(const float* __restrict__ pts, float* __restrict__ xyz, float* __restrict__ xnrm,
                           const float* __restrict__ t0, const float* __restrict__ t1,
                           const float* __restrict__ d0, const float* __restrict__ d1,
                           const float* __restrict__ d2, const float* __restrict__ saw1,
                           float* __restrict__ waT0, float* __restrict__ wbT0,
                           float* __restrict__ wt_t1,
                           float* __restrict__ waD0, float* __restrict__ wbD0,
                           float* __restrict__ waD1, float* __restrict__ wbD1,
                           float* __restrict__ waD2, float* __restrict__ wbD2,
                           float* __restrict__ w1T,
                           const float* __restrict__ w0, const float* __restrict__ w1,
                           const float* __restrict__ w2,
                           const float* __restrict__ tl, const float* __restrict__ dgw,
                           float* __restrict__ w0f, u16* __restrict__ w1fh, u16* __restrict__ w1fl,
                           u16* __restrict__ w2fh, u16* __restrict__ w2fl,
                           u16* __restrict__ wAD1h, u16* __restrict__ wAD1l,
                           u16* __restrict__ wBD1h, u16* __restrict__ wBD1l,
                           u16* __restrict__ wAD2h, u16* __restrict__ wAD2l,
                           u16* __restrict__ wBD2h, u16* __restrict__ wBD2l,
                           u16* __restrict__ wTPh, u16* __restrict__ wTPl,
                           u16* __restrict__ wDGh, u16* __restrict__ wDGl,
                           u16* __restrict__ wTEh, u16* __restrict__ wTEl,
                           u16* __restrict__ wAT0h, u16* __restrict__ wAT0l,
                           u16* __restrict__ wBT0h, u16* __restrict__ wBT0l,
                           u16* __restrict__ wAD0h, u16* __restrict__ wAD0l,
                           u16* __restrict__ wBD0h, u16* __restrict__ wBD0l){
  int bid = blockIdx.x;
  if (bid < 512){                        // ---- k_prep ----
    int i = bid*256 + threadIdx.x;
    if (i >= BB*NN) return;
    int b = i >> 12, n = i & (NN-1);
    float X = pts[(b*3+0)*NN + n];
    float Y = pts[(b*3+1)*NN + n];
    float Z = pts[(b*3+2)*NN + n];
    xyz[i*3+0]=X; xyz[i*3+1]=Y; xyz[i*3+2]=Z;
    xnrm[i] = __fadd_rn(__fadd_rn(__fmul_rn(X,X), __fmul_rn(Y,Y)), __fmul_rn(Z,Z));
    return;
  }
  if (bid < 1299){                       // ---- k_wprep (legacy buffers; some now unused) ----
    int i = (bid-512)*256 + threadIdx.x;
    if (i < 8384){
      int m = i >> 6;
      int c = i & 63;
      float bb = t0[(size_t)c*262 + m];
      float dd = t0[(size_t)c*262 + 131 + m];
      waT0[i] = __fsub_rn(bb, dd); wbT0[i] = dd;
      return;
    }
    i -= 8384;
    if (i < 8192){
      int m = i >> 7, c = i & 127;
      wt_t1[i] = t1[(size_t)c*64 + m];
      return;
    }
    i -= 8192;
    if (i < 16768){
      int m = i >> 7, c = i & 127;
      float bb = d0[(size_t)c*262 + m];
      float dd = d0[(size_t)c*262 + 131 + m];
      waD0[i] = __fsub_rn(bb, dd); wbD0[i] = dd;
      return;
    }
    i -= 16768;
    if (i < 32768){
      int m = i >> 8, c = i & 255;
      float bb = d1[(size_t)c*256 + m];
      float dd = d1[(size_t)c*256 + 128 + m];
      waD1[i] = __fsub_rn(bb, dd); wbD1[i] = dd;
      return;
    }
    i -= 32768;
    if (i < 131072){
      int m = i >> 9, c = i & 511;
      float bb = d2[(size_t)c*512 + m];
      float dd = d2[(size_t)c*512 + 256 + m];
      waD2[i] = __fsub_rn(bb, dd); wbD2[i] = dd;
      return;
    }
    i -= 131072;
    if (i < 4096){
      int m = i >> 6, c = i & 63;
      w1T[i] = saw1[(size_t)c*64 + m];
    }
    return;
  }
  if (bid < 1363){                       // ---- SA frags ----
    int i = (bid-1299)*256 + threadIdx.x;
    if (i < 4096){                       // w0f: [kt][lane][e][4] (xyz + pad)
      int kt = i >> 11, r = i & 2047;
      int ln = r >> 5, ee = r & 31;
      int e = ee >> 2, j = ee & 3;
      int k = kt*32 + 8*(ln>>4) + e;
      w0f[i] = (j < 3) ? w0[k*3 + j] : 0.0f;
      return;
    }
    i -= 4096;
    if (i < 4096){                       // w1 frags
      int e = i & 7, ln = (i >> 3) & 63, q = i >> 9;
      int kt = q & 1, ct = q >> 1;
      int k = kt*32 + 8*(ln>>4) + e;
      int c = ct*16 + (ln & 15);
      unsigned h16, l16; bf16_split(w1[(size_t)c*64 + k], h16, l16);
      w1fh[i] = (u16)h16; w1fl[i] = (u16)l16;
      return;
    }
    i -= 4096;
    if (i < 8192){                       // w2 frags
      int e = i & 7, ln = (i >> 3) & 63, q = i >> 9;
      int kt = q & 1, c2t = q >> 1;
      int k = kt*32 + 8*(ln>>4) + e;
      int c2 = c2t*16 + (ln & 15);
      unsigned h16, l16; bf16_split(w2[(size_t)c2*64 + k], h16, l16);
      w2fh[i] = (u16)h16; w2fl[i] = (u16)l16;
    }
    return;
  }
  if (bid < 2643){                       // ---- layer-2/3 GEMM weight frags ----
    int i = (bid-1363)*256 + threadIdx.x;
    if (i < 32768){                      // D1 wA: [ct(16)][kt(4)][lane][e]
      int e = i & 7, ln = (i >> 3) & 63, q = i >> 9;
      int kt = q & 3, ct = q >> 2;
      int k = kt*32 + 8*(ln>>4) + e;
      int c = ct*16 + (ln & 15);
      float bb = d1[(size_t)c*256 + k], dd = d1[(size_t)c*256 + 128 + k];
      unsigned h, l; bf16_split(__fsub_rn(bb, dd), h, l);
      wAD1h[i] = (u16)h; wAD1l[i] = (u16)l;
      return;
    }
    i -= 32768;
    if (i < 32768){                      // D1 wB
      int e = i & 7, ln = (i >> 3) & 63, q = i >> 9;
      int kt = q & 3, ct = q >> 2;
      int k = kt*32 + 8*(ln>>4) + e;
      int c = ct*16 + (ln & 15);
      float dd = d1[(size_t)c*256 + 128 + k];
      unsigned h, l; bf16_split(dd, h, l);
      wBD1h[i] = (u16)h; wBD1l[i] = (u16)l;
      return;
    }
    i -= 32768;
    if (i < 131072){                     // D2 wA: [ct(32)][kt(8)][lane][e]
      int e = i & 7, ln = (i >> 3) & 63, q = i >> 9;
      int kt = q & 7, ct = q >> 3;
      int k = kt*32 + 8*(ln>>4) + e;
      int c = ct*16 + (ln & 15);
      float bb = d2[(size_t)c*512 + k], dd = d2[(size_t)c*512 + 256 + k];
      unsigned h, l; bf16_split(__fsub_rn(bb, dd), h, l);
      wAD2h[i] = (u16)h; wAD2l[i] = (u16)l;
      return;
    }
    i -= 131072;
    if (i < 131072){                     // D2 wB
      int e = i & 7, ln = (i >> 3) & 63, q = i >> 9;
      int kt = q & 7, ct = q >> 3;
      int k = kt*32 + 8*(ln>>4) + e;
      int c = ct*16 + (ln & 15);
      float dd = d2[(size_t)c*512 + 256 + k];
      unsigned h, l; bf16_split(dd, h, l);
      wBD2h[i] = (u16)h; wBD2l[i] = (u16)l;
    }
    return;
  }
  if (bid < 3155){                       // ---- t_local_w frags: [ct(64)][kt(4)][lane][e] ----
    int i = (bid-2643)*256 + threadIdx.x;
    int e = i & 7, ln = (i >> 3) & 63, q = i >> 9;
    int kt = q & 3, ct = q >> 2;
    int k = kt*32 + 8*(ln>>4) + e;
    int c = ct*16 + (ln & 15);
    unsigned h, l; bf16_split(tl[(size_t)c*128 + k], h, l);
    wTPh[i] = (u16)h; wTPl[i] = (u16)l;
    return;
  }
  if (bid < 3603){                       // ---- dg_local_w frags: [ct(8)][kt(28)][lane][e] ----
    int i = (bid-3155)*256 + threadIdx.x;
    if (i >= 114688) return;
    int e = i & 7, ln = (i >> 3) & 63, q = i >> 9;
    int kt = q % 28, ct = q / 28;
    int k = kt*32 + 8*(ln>>4) + e;
    int c = ct*16 + (ln & 15);
    unsigned h, l; bf16_split(dgw[(size_t)c*896 + k], h, l);
    wDGh[i] = (u16)h; wDGl[i] = (u16)l;
    return;
  }
  if (bid < 3635){                       // ---- t_ec_w1 (tedge) frags: [ct(8)][kt(2)][lane][e] ----
    int i = (bid-3603)*256 + threadIdx.x;
    int e = i & 7, ln = (i >> 3) & 63, q = i >> 9;
    int kt = q & 1, ct = q >> 1;
    int k = kt*32 + 8*(ln>>4) + e;
    int c = ct*16 + (ln & 15);
    unsigned h, l; bf16_split(t1[(size_t)c*64 + k], h, l);
    wTEh[i] = (u16)h; wTEl[i] = (u16)l;
    return;
  }
  {                                      // ---- PADDED t_ec_w0 / dg_ec_w0 frags (CINP=160) ----
    int i = (bid-3635)*256 + threadIdx.x;
    if (i < 10240){                      // T0 wA: [ct(4)][kt(5)][lane][e]
      int e = i & 7, ln = (i >> 3) & 63, q = i >> 9;   // q in [0,20)
      int kt = q % 5, ct = q / 5;
      int k = kt*32 + 8*(ln>>4) + e;
      int c = ct*16 + (ln & 15);
      float v = 0.0f;
      if (k < 131) v = __fsub_rn(t0[(size_t)c*262 + k], t0[(size_t)c*262 + 131 + k]);
      unsigned h, l; bf16_split(v, h, l);
      wAT0h[i] = (u16)h; wAT0l[i] = (u16)l;
      return;
    }
    i -= 10240;
    if (i < 10240){                      // T0 wB
      int e = i & 7, ln = (i >> 3) & 63, q = i >> 9;
      int kt = q % 5, ct = q / 5;
      int k = kt*32 + 8*(ln>>4) + e;
      int c = ct*16 + (ln & 15);
      float v = (k < 131) ? t0[(size_t)c*262 + 131 + k] : 0.0f;
      unsigned h, l; bf16_split(v, h, l);
      wBT0h[i] = (u16)h; wBT0l[i] = (u16)l;
      return;
    }
    i -= 10240;
    if (i < 20480){                      // D0 wA: [ct(8)][kt(5)][lane][e]
      int e = i & 7, ln = (i >> 3) & 63, q = i >> 9;   // q in [0,40)
      int kt = q % 5, ct = q / 5;
      int k = kt*32 + 8*(ln>>4) + e;
      int c = ct*16 + (ln & 15);
      float v = 0.0f;
      if (k < 131) v = __fsub_rn(d0[(size_t)c*262 + k], d0[(size_t)c*262 + 131 + k]);
      unsigned h, l; bf16_split(v, h, l);
      wAD0h[i] = (u16)h; wAD0l[i] = (u16)l;
      return;
    }
    i -= 20480;
    if (i < 20480){                      // D0 wB
      int e = i & 7, ln = (i >> 3) & 63, q = i >> 9;
      int kt = q % 5, ct = q / 5;
      int k = kt*32 + 8*(ln>>4) + e;
      int c = ct*16 + (ln & 15);
      float v = (k < 131) ? d0[(size_t)c*262 + 131 + k] : 0.0f;
      unsigned h, l; bf16_split(v, h, l);
      wBD0h[i] = (u16)h; wBD0l[i] = (u16)l;
    }
  }
}

// ---------------- farthest point sampling: 2 waves, key-only reduce (parked at floor) ----------------
__global__ __launch_bounds__(128, 1) void k_fps(const float* __restrict__ xyz, float* __restrict__ new_xyz){
  __shared__ __align__(16) float lx[NN], ly[NN], lz[NN];
  __shared__ __align__(16) ull wkey[2][2];
  int b = blockIdx.x, t = threadIdx.x;
  int w = t >> 6, lane = t & 63;
  float nx[32], ny[32], nz[32], dist[32];
#pragma unroll
  for (int q = 0; q < 32; ++q){
    int j = q*128 + t;
    const float* p = xyz + ((size_t)b*NN + j)*3;
    float X = p[0], Y = p[1], Z = p[2];
    lx[j] = X; ly[j] = Y; lz[j] = Z;
    nx[q] = -X; ny[q] = -Y; nz[q] = -Z;
    dist[q] = __builtin_inff();
  }
  const float* p0 = xyz + (size_t)b*NN*3;
  float Px = p0[0], Py = p0[1], Pz = p0[2];
  __syncthreads();
  for (int it = 0; it < NPp; ++it){
    if (t == 0){
      float* o = new_xyz + ((size_t)b*NPp + it)*3;
      o[0] = Px; o[1] = Py; o[2] = Pz;
    }
    ull ka0 = 0, ka1 = 0, ka2 = 0, ka3 = 0;
#pragma unroll
    for (int q = 0; q < 32; ++q){
      float dx = __fadd_rn(nx[q], Px);
      float dy = __fadd_rn(ny[q], Py);
      float dz = __fadd_rn(nz[q], Pz);
      float dd = __fadd_rn(__fadd_rn(__fmul_rn(dx,dx), __fmul_rn(dy,dy)), __fmul_rn(dz,dz));
      float dm = fminf(dist[q], dd);
      dist[q] = dm;
      ull key = ((ull)__float_as_uint(dm) << 32) | (unsigned)(4095 - (q*128 + t));
      if      ((q & 3) == 0){ if (key > ka0) ka0 = key; }
      else if ((q & 3) == 1){ if (key > ka1) ka1 = key; }
      else if ((q & 3) == 2){ if (key > ka2) ka2 = key; }
      else                  { if (key > ka3) ka3 = key; }
    }
    ull kb0 = (ka0 > ka1) ? ka0 : ka1;
    ull kb1 = (ka2 > ka3) ? ka2 : ka3;
    ull bk  = (kb0 > kb1) ? kb0 : kb1;
#define FPS_STAGE(C) { \
    unsigned ol = (unsigned)dpp_i<C>((int)(unsigned)bk); \
    unsigned oh = (unsigned)dpp_i<C>((int)(unsigned)(bk >> 32)); \
    ull ok = ((ull)oh << 32) | ol; \
    if (ok > bk) bk = ok; }
    FPS_STAGE(0x111) FPS_STAGE(0x112) FPS_STAGE(0x114) FPS_STAGE(0x118)
    FPS_STAGE(0x142) FPS_STAGE(0x143)
#undef FPS_STAGE
    int par = it & 1;
    if (lane == 63) wkey[par][w] = bk;
    __syncthreads();
    ull k0 = wkey[par][0], k1 = wkey[par][1];
    ull kw = (k0 > k1) ? k0 : k1;
    int idx = 4095 - (int)(unsigned)(kw & 0xFFFFFFFFu);
    Px = lx[idx]; Py = ly[idx]; Pz = lz[idx];
  }
}

// ---------------- ball query + SA convs + maxpool: MFMA split-bf16 ----------------
__global__ __launch_bounds__(64) void k_sa(const float* __restrict__ pts,
    const float* __restrict__ xyz, const float* __restrict__ xnrm,
    const float* __restrict__ new_xyz, const float* __restrict__ w0f,
    const u16* __restrict__ w1fh, const u16* __restrict__ w1fl,
    const u16* __restrict__ w2fh, const u16* __restrict__ w2fl,
    float* __restrict__ x131){
  __shared__ __align__(16) u16 hh[64*64];
  __shared__ __align__(16) u16 hl[64*64];
  __shared__ int gw[64];
  int bi = blockIdx.x;
  int lane = threadIdx.x;
  int b = bi >> 8;
  const float* q = new_xyz + (size_t)bi*3;
  float qx=q[0], qy=q[1], qz=q[2];
  float nq = __fadd_rn(__fadd_rn(__fmul_rn(qx,qx), __fmul_rn(qy,qy)), __fmul_rn(qz,qz));
  const float* pX = pts + (size_t)(b*3+0)*NN;
  const float* pY = pts + (size_t)(b*3+1)*NN;
  const float* pZ = pts + (size_t)(b*3+2)*NN;
  int cnt = 0;
  for (int base = 0; base < NN; base += 256){
#pragma unroll
    for (int u = 0; u < 4; ++u){
      int j = base + u*64 + lane;
      float X = pX[j], Y = pY[j], Z = pZ[j];
      float dot = __fadd_rn(__fadd_rn(__fmul_rn(qx,X), __fmul_rn(qy,Y)), __fmul_rn(qz,Z));
      float d2 = __fsub_rn(__fadd_rn(nq, xnrm[b*NN + j]), __fmul_rn(2.0f, dot));
      bool inb = d2 < 0.04f;
      unsigned long long m = __ballot(inb);
      int pos = cnt + (int)__popcll(m & ((1ull << lane) - 1ull));
      if (inb && pos < NSs) gw[pos] = j;
      cnt += (int)__popcll(m);
    }
  }
  int g0 = gw[0];
  if (lane >= cnt) gw[lane] = g0;
  int gj = gw[lane];
  const float* pp = xyz + ((size_t)b*NN + gj)*3;
  float px = pp[0]-qx, py = pp[1]-qy, pz = pp[2]-qz;
  int col = lane & 15, g = lane >> 4;
  float sxv[4], syv[4], szv[4];
#pragma unroll
  for (int t2 = 0; t2 < 4; ++t2){
    int src = col + 16*t2;
    sxv[t2] = __shfl(px, src);
    syv[t2] = __shfl(py, src);
    szv[t2] = __shfl(pz, src);
  }
  i32x4 ah0[4][2], al0[4][2];
#pragma unroll
  for (int kt = 0; kt < 2; ++kt){
    float4 wrow[8];
    const float4* wp = (const float4*)(w0f + (size_t)(kt*64 + lane)*32);
#pragma unroll
    for (int e = 0; e < 8; ++e) wrow[e] = wp[e];
#pragma unroll
    for (int t2 = 0; t2 < 4; ++t2){
      unsigned hu[8], lu[8];
#pragma unroll
      for (int e = 0; e < 8; ++e){
        float a = fmaf(wrow[e].z, szv[t2], fmaf(wrow[e].y, syv[t2], wrow[e].x*sxv[t2]));
        a = fmaxf(a, 0.0f);
        bf16_split(a, hu[e], lu[e]);
      }
      i32x4 H, L;
#pragma unroll
      for (int j2 = 0; j2 < 4; ++j2){
        H[j2] = (int)(hu[2*j2] | (hu[2*j2+1] << 16));
        L[j2] = (int)(lu[2*j2] | (lu[2*j2+1] << 16));
      }
      ah0[t2][kt] = H; al0[t2][kt] = L;
    }
  }
#pragma unroll
  for (int ct = 0; ct < 4; ++ct){
    bf16x8 bh[2], bl[2];
#pragma unroll
    for (int kt = 0; kt < 2; ++kt){
      bh[kt] = *(const bf16x8*)(w1fh + (size_t)((ct*2+kt)*64 + lane)*8);
      bl[kt] = *(const bf16x8*)(w1fl + (size_t)((ct*2+kt)*64 + lane)*8);
    }
#pragma unroll
    for (int t2 = 0; t2 < 4; ++t2){
      f32x4 acc = {0.f,0.f,0.f,0.f};
#pragma unroll
      for (int kt = 0; kt < 2; ++kt){
        bf16x8 Ah = __builtin_bit_cast(bf16x8, ah0[t2][kt]);
        bf16x8 Al = __builtin_bit_cast(bf16x8, al0[t2][kt]);
        acc = __builtin_amdgcn_mfma_f32_16x16x32_bf16(Ah, bh[kt], acc, 0, 0, 0);
        acc = __builtin_amdgcn_mfma_f32_16x16x32_bf16(Ah, bl[kt], acc, 0, 0, 0);
        acc = __builtin_amdgcn_mfma_f32_16x16x32_bf16(Al, bh[kt], acc, 0, 0, 0);
      }
#pragma unroll
      for (int r = 0; r < 4; ++r){
        float v = fmaxf(acc[r], 0.0f);
        int s = 16*t2 + 4*g + r;
        int cc = ct*16 + col;
        int idx = s*64 + (cc ^ ((s & 7) << 3));
        unsigned h16, l16; bf16_split(v, h16, l16);
        hh[idx] = (u16)h16; hl[idx] = (u16)l16;
      }
    }
  }
  bf16x8 a1h[4][2], a1l[4][2];
#pragma unroll
  for (int t2 = 0; t2 < 4; ++t2){
    int s = col + 16*t2;
    int sw = (s & 7) << 3;
#pragma unroll
    for (int kt = 0; kt < 2; ++kt){
      int k0 = kt*32 + 8*g;
      int idx = s*64 + (k0 ^ sw);
      a1h[t2][kt] = *(const bf16x8*)(hh + idx);
      a1l[t2][kt] = *(const bf16x8*)(hl + idx);
    }
  }
#pragma unroll
  for (int c2t = 0; c2t < 8; ++c2t){
    bf16x8 bh2[2], bl2[2];
#pragma unroll
    for (int kt = 0; kt < 2; ++kt){
      bh2[kt] = *(const bf16x8*)(w2fh + (size_t)((c2t*2+kt)*64 + lane)*8);
      bl2[kt] = *(const bf16x8*)(w2fl + (size_t)((c2t*2+kt)*64 + lane)*8);
    }
    float mx = 0.0f;
#pragma unroll
    for (int t2 = 0; t2 < 4; ++t2){
      f32x4 acc = {0.f,0.f,0.f,0.f};
#pragma unroll
      for (int kt = 0; kt < 2; ++kt){
        acc = __builtin_amdgcn_mfma_f32_16x16x32_bf16(a1h[t2][kt], bh2[kt], acc, 0, 0, 0);
        acc = __builtin_amdgcn_mfma_f32_16x16x32_bf16(a1h[t2][kt], bl2[kt], acc, 0, 0, 0);
        acc = __builtin_amdgcn_mfma_f32_16x16x32_bf16(a1l[t2][kt], bh2[kt], acc, 0, 0, 0);
      }
      mx = fmaxf(mx, fmaxf(fmaxf(acc[0], acc[1]), fmaxf(acc[2], acc[3])));
    }
    mx = fmaxf(mx, __shfl_xor(mx, 16));
    mx = fmaxf(mx, __shfl_xor(mx, 32));
    if (lane < 16){
      int c = c2t*16 + lane;
      x131[(size_t)bi*132 + c] = mx;
    }
  }
  if (lane < 3) x131[(size_t)bi*132 + 128 + lane] = (lane==0)?qx:((lane==1)?qy:qz);
}

// ---------------- kNN: distances in registers, u64-DPP selection, no selection LDS ----------------
template<int CIN>
__global__ __launch_bounds__(512) void k_knn3(const float* __restrict__ xT,
    const float* __restrict__ nrm, int* __restrict__ idxo){
  __shared__ __align__(16) float sch[16*256];
  int bi = blockIdx.x, t = threadIdx.x;
  int w = t >> 6, lane = t & 63;
  int b = bi >> 5;
  int coli = (bi & 31)*8 + w;
  const float* xb = xT + (size_t)b*CIN*256;
  float d0=0.f, d1=0.f, d2=0.f, d3=0.f;
  for (int m0 = 0; m0 < CIN; m0 += 16){
    int mc = (CIN - m0 < 16) ? (CIN - m0) : 16;
    for (int i = t; i < mc*64; i += 512){
      int mm = i >> 6, c4 = i & 63;
      *(float4*)(sch + mm*256 + c4*4) = *(const float4*)(xb + (size_t)(m0+mm)*256 + c4*4);
    }
    __syncthreads();
    for (int mm = 0; mm < mc; ++mm){
      float xm = sch[mm*256 + coli];
      float4 v = *(const float4*)(sch + mm*256 + 4*lane);
      d0 = fmaf(v.x, xm, d0); d1 = fmaf(v.y, xm, d1);
      d2 = fmaf(v.z, xm, d2); d3 = fmaf(v.w, xm, d3);
    }
    __syncthreads();
  }
  float ni = nrm[b*256 + coli];
  float4 dv;
  {
    int j0 = 4*lane;
    dv.x = __fsub_rn(__fadd_rn(ni, nrm[b*256 + j0+0]), __fmul_rn(2.0f, d0));
    dv.y = __fsub_rn(__fadd_rn(ni, nrm[b*256 + j0+1]), __fmul_rn(2.0f, d1));
    dv.z = __fsub_rn(__fadd_rn(ni, nrm[b*256 + j0+2]), __fmul_rn(2.0f, d2));
    dv.w = __fsub_rn(__fadd_rn(ni, nrm[b*256 + j0+3]), __fmul_rn(2.0f, d3));
  }
  for (int r = 0; r < KC; ++r){
    float bv = 3.4e38f; int bj = NPp;
    if (dv.x < bv){ bv = dv.x; bj = 4*lane+0; }
    if (dv.y < bv){ bv = dv.y; bj = 4*lane+1; }
    if (dv.z < bv){ bv = dv.z; bj = 4*lane+2; }
    if (dv.w < bv){ bv = dv.w; bj = 4*lane+3; }
    unsigned xf = __float_as_uint(bv);
    xf = (xf & 0x80000000u) ? ~xf : (xf | 0x80000000u);
    ull key = ((ull)xf << 32) | (unsigned)bj;
#define KN_STAGE(C) { \
    unsigned ol = (unsigned)dpp_i<C>((int)(unsigned)key); \
    unsigned oh = (unsigned)dpp_i<C>((int)(unsigned)(key >> 32)); \
    ull ok = ((ull)oh << 32) | ol; \
    if (ok < key) key = ok; }
    KN_STAGE(0x111) KN_STAGE(0x112) KN_STAGE(0x114) KN_STAGE(0x118)
    KN_STAGE(0x142) KN_STAGE(0x143)
#undef KN_STAGE
    int bjw = __builtin_amdgcn_readlane((int)(unsigned)key, 63);
    if (lane == 0) idxo[((size_t)b*256 + coli)*KC + r] = bjw;
    if ((bjw >> 2) == lane){
      int e = bjw & 3;
      if      (e == 0) dv.x = 3.0e38f;
      else if (e == 1) dv.y = 3.0e38f;
      else if (e == 2) dv.z = 3.0e38f;
      else             dv.w = 3.0e38f;
    }
  }
}

// ---------------- per-point dual GEMM via MFMA split-bf16 (CIN multiple of 32) ----------------
template<int CIN, int COUT>
__global__ __launch_bounds__(512) void k_gabm(const float* __restrict__ x, int xstride,
    const u16* __restrict__ wAh, const u16* __restrict__ wAl,
    const u16* __restrict__ wBh, const u16* __restrict__ wBl,
    float* __restrict__ A, float* __restrict__ B, float* __restrict__ xT,
    float* __restrict__ nrm){
  constexpr int PC  = CIN + 1;
  constexpr int KT  = CIN / 32;
  constexpr int CT  = COUT / 16;
  constexpr int TPW = 2*CT/8;
  constexpr int KB  = CIN / 8;
  __shared__ float xsh[16*PC];
  __shared__ __align__(16) u16 axh[16*CIN];
  __shared__ __align__(16) u16 axl[16*CIN];
  int bi = blockIdx.x, t = threadIdx.x;
  int i0 = bi*16;
  for (int i = t; i < 16*CIN; i += 512){
    int r = i / CIN, m = i - r*CIN;
    xsh[r*PC + m] = x[(size_t)(i0+r)*xstride + m];
  }
  __syncthreads();
  {
    int bb = i0 >> 8, col0 = i0 & 255;
    float* xTb = xT + (size_t)bb*CIN*256 + col0;
    for (int i = t; i < 16*CIN; i += 512){
      int m = i >> 4, r = i & 15;
      xTb[m*256 + r] = xsh[r*PC + m];
    }
  }
  if (t < 16){
    const float* xr = xsh + t*PC;
    float a = 0.0f;
    for (int m = 0; m < CIN; ++m) a = __fadd_rn(a, __fmul_rn(xr[m], xr[m]));
    nrm[i0 + t] = a;
  }
  if (t < 16*KB){
    int r = t / KB, kb = t - r*KB;
    unsigned hu[8], lu[8];
#pragma unroll
    for (int e = 0; e < 8; ++e) bf16_split(xsh[r*PC + kb*8 + e], hu[e], lu[e]);
    i32x4 H, L;
#pragma unroll
    for (int j2 = 0; j2 < 4; ++j2){
      H[j2] = (int)(hu[2*j2] | (hu[2*j2+1] << 16));
      L[j2] = (int)(lu[2*j2] | (lu[2*j2+1] << 16));
    }
    int idx = r*CIN + ((kb ^ (r & 7)) << 3);
    *(bf16x8*)(axh + idx) = __builtin_bit_cast(bf16x8, H);
    *(bf16x8*)(axl + idx) = __builtin_bit_cast(bf16x8, L);
  }
  __syncthreads();
  int lane = t & 63, wid = t >> 6;
  int col = lane & 15, g = lane >> 4;
  int aswz = col & 7;
#pragma unroll
  for (int tt = 0; tt < TPW; ++tt){
    int tile = wid*TPW + tt;
    bool isB = tile >= CT;
    int ct = isB ? tile - CT : tile;
    const u16* Wh = isB ? wBh : wAh;
    const u16* Wl = isB ? wBl : wAl;
    float* Out = isB ? B : A;
    f32x4 acc = {0.f,0.f,0.f,0.f};
#pragma unroll
    for (int kt = 0; kt < KT; ++kt){
      int kb = kt*4 + g;
      int aidx = col*CIN + ((kb ^ aswz) << 3);
      bf16x8 Ah = *(const bf16x8*)(axh + aidx);
      bf16x8 Al = *(const bf16x8*)(axl + aidx);
      size_t wo = ((size_t)(ct*KT + kt)*64 + lane)*8;
      bf16x8 Bh = *(const bf16x8*)(Wh + wo);
      bf16x8 Bl = *(const bf16x8*)(Wl + wo);
      acc = __builtin_amdgcn_mfma_f32_16x16x32_bf16(Ah, Bh, acc, 0, 0, 0);
      acc = __builtin_amdgcn_mfma_f32_16x16x32_bf16(Ah, Bl, acc, 0, 0, 0);
      acc = __builtin_amdgcn_mfma_f32_16x16x32_bf16(Al, Bh, acc, 0, 0, 0);
    }
#pragma unroll
    for (int r = 0; r < 4; ++r){
      Out[(size_t)(i0 + 4*g + r)*COUT + ct*16 + col] = acc[r];
    }
  }
}

// ---------------- per-point dual GEMM via MFMA, K zero-padded (CIN=131 -> CINP=160) ----------------
// Zero A-columns / zero B-rows contribute exactly 0 to the accumulation -> matches the
// scalar kernel up to split-bf16 rounding. KB=20 is not a power of two, so the XOR
// swizzle uses the low 2 bits only (&3): kb^swz stays inside its 4-block group (<KB).
template<int CIN, int CINP, int COUT>
__global__ __launch_bounds__(512) void k_gabp(const float* __restrict__ x, int xstride,
    const u16* __restrict__ wAh, const u16* __restrict__ wAl,
    const u16* __restrict__ wBh, const u16* __restrict__ wBl,
    float* __restrict__ A, float* __restrict__ B, float* __restrict__ xT,
    float* __restrict__ nrm){
  constexpr int PC  = CIN + 1;
  constexpr int KT  = CINP / 32;       // 5
  constexpr int CT  = COUT / 16;
  constexpr int TPW = 2*CT/8;          // 1 (COUT=64) or 2 (COUT=128)
  constexpr int KB  = CINP / 8;        // 20
  __shared__ float xsh[16*PC];
  __shared__ __align__(16) u16 axh[16*CINP];
  __shared__ __align__(16) u16 axl[16*CINP];
  int bi = blockIdx.x, t = threadIdx.x;
  int i0 = bi*16;
  for (int i = t; i < 16*CIN; i += 512){
    int r = i / CIN, m = i - r*CIN;
    xsh[r*PC + m] = x[(size_t)(i0+r)*xstride + m];
  }
  __syncthreads();
  {
    int bb = i0 >> 8, col0 = i0 & 255;
    float* xTb = xT + (size_t)bb*CIN*256 + col0;
    for (int i = t; i < 16*CIN; i += 512){
      int m = i >> 4, r = i & 15;
      xTb[m*256 + r] = xsh[r*PC + m];
    }
  }
  if (t < 16){
    const float* xr = xsh + t*PC;
    float a = 0.0f;
    for (int m = 0; m < CIN; ++m) a = __fadd_rn(a, __fmul_rn(xr[m], xr[m]));
    nrm[i0 + t] = a;
  }
  if (t < 16*KB){
    int r = t / KB, kb = t - r*KB;
    unsigned hu[8], lu[8];
#pragma unroll
    for (int e = 0; e < 8; ++e){
      int m = kb*8 + e;
      float v = (m < CIN) ? xsh[r*PC + m] : 0.0f;
      bf16_split(v, hu[e], lu[e]);
    }
    i32x4 H, L;
#pragma unroll
    for (int j2 = 0; j2 < 4; ++j2){
      H[j2] = (int)(hu[2*j2] | (hu[2*j2+1] << 16));
      L[j2] = (int)(lu[2*j2] | (lu[2*j2+1] << 16));
    }
    int idx = r*CINP + ((kb ^ (r & 3)) << 3);
    *(bf16x8*)(axh + idx) = __builtin_bit_cast(bf16x8, H);
    *(bf16x8*)(axl + idx) = __builtin_bit_cast(bf16x8, L);
  }
  __syncthreads();
  int lane = t & 63, wid = t >> 6;
  int col = lane & 15, g = lane >> 4;
  int aswz = col & 3;
#pragma unroll
  for (int tt = 0; tt < TPW; ++tt){
    int tile = wid*TPW + tt;
    bool isB = tile >= CT;
    int ct = isB ? tile - CT : tile;
    const u16* Wh = isB ? wBh : wAh;
    const u16* Wl = isB ? wBl : wAl;
    float* Out = isB ? B : A;
    f32x4 acc = {0.f,0.f,0.f,0.f};
#pragma unroll
    for (int kt = 0; kt < KT; ++kt){
      int kb = kt*4 + g;
      int aidx = col*CINP + ((kb ^ aswz) << 3);
      bf16x8 Ah = *(const bf16x8*)(axh + aidx);
      bf16x8 Al = *(const bf16x8*)(axl + aidx);
      size_t wo = ((size_t)(ct*KT + kt)*64 + lane)*8;
      bf16x8 Bh = *(const bf16x8*)(Wh + wo);
      bf16x8 Bl = *(const bf16x8*)(Wl + wo);
      acc = __builtin_amdgcn_mfma_f32_16x16x32_bf16(Ah, Bh, acc, 0, 0, 0);
      acc = __builtin_amdgcn_mfma_f32_16x16x32_bf16(Ah, Bl, acc, 0, 0, 0);
      acc = __builtin_amdgcn_mfma_f32_16x16x32_bf16(Al, Bh, acc, 0, 0, 0);
    }
#pragma unroll
    for (int r = 0; r < 4; ++r){
      Out[(size_t)(i0 + 4*g + r)*COUT + ct*16 + col] = acc[r];
    }
  }
}

// ---------------- T-Net 128->1024 GEMM + pool via MFMA split-bf16 ----------------
__global__ __launch_bounds__(512) void k_tpoolm(const float* __restrict__ h,
    const u16* __restrict__ Wh, const u16* __restrict__ Wl, float* __restrict__ g1024){
  __shared__ __align__(16) u16 ahh[16*128];
  __shared__ __align__(16) u16 ahl[16*128];
  int b = blockIdx.x, i0 = blockIdx.y*16;
  int t = threadIdx.x;
  if (t < 256){
    int r = t >> 4, kb = t & 15;
    const float* hr = h + ((size_t)b*NPp + i0 + r)*128 + kb*8;
    unsigned hu[8], lu[8];
#pragma unroll
    for (int e = 0; e < 8; ++e) bf16_split(hr[e], hu[e], lu[e]);
    i32x4 H, L;
#pragma unroll
    for (int j2 = 0; j2 < 4; ++j2){
      H[j2] = (int)(hu[2*j2] | (hu[2*j2+1] << 16));
      L[j2] = (int)(lu[2*j2] | (lu[2*j2+1] << 16));
    }
    int idx = r*128 + ((kb ^ (r & 7)) << 3);
    *(bf16x8*)(ahh + idx) = __builtin_bit_cast(bf16x8, H);
    *(bf16x8*)(ahl + idx) = __builtin_bit_cast(bf16x8, L);
  }
  __syncthreads();
  int lane = t & 63, wid = t >> 6;
  int col = lane & 15, g = lane >> 4;
  int aswz = col & 7;
#pragma unroll
  for (int tt = 0; tt < 8; ++tt){
    int ct = wid*8 + tt;
    f32x4 acc = {0.f,0.f,0.f,0.f};
#pragma unroll
    for (int kt = 0; kt < 4; ++kt){
      int kb = kt*4 + g;
      int aidx = col*128 + ((kb ^ aswz) << 3);
      bf16x8 Ah = *(const bf16x8*)(ahh + aidx);
      bf16x8 Al = *(const bf16x8*)(ahl + aidx);
      size_t wo = ((size_t)(ct*4 + kt)*64 + lane)*8;
      bf16x8 Bh = *(const bf16x8*)(Wh + wo);
      bf16x8 Bl = *(const bf16x8*)(Wl + wo);
      acc = __builtin_amdgcn_mfma_f32_16x16x32_bf16(Ah, Bh, acc, 0, 0, 0);
      acc = __builtin_amdgcn_mfma_f32_16x16x32_bf16(Ah, Bl, acc, 0, 0, 0);
      acc = __builtin_amdgcn_mfma_f32_16x16x32_bf16(Al, Bh, acc, 0, 0, 0);
    }
    float mx = fmaxf(fmaxf(acc[0], acc[1]), fmaxf(acc[2], acc[3]));
    mx = fmaxf(mx, 0.0f);
    mx = fmaxf(mx, __shfl_xor(mx, 16));
    mx = fmaxf(mx, __shfl_xor(mx, 32));
    if (lane < 16) atomicMax((int*)(g1024 + (size_t)b*1024 + ct*16 + lane), __float_as_int(mx));
  }
}

// ---------------- 896->128 conv + global pool via MFMA split-bf16 ----------------
__global__ __launch_bounds__(512) void k_dglm(const float* __restrict__ f1, const float* __restrict__ f2,
    const float* __restrict__ f3, const u16* __restrict__ Wh, const u16* __restrict__ Wl,
    float* __restrict__ g128){
  __shared__ __align__(16) u16 ahh[16*896];
  __shared__ __align__(16) u16 ahl[16*896];
  int b = blockIdx.x, i0 = blockIdx.y*16;
  int t = threadIdx.x;
  for (int i = t; i < 16*112; i += 512){
    int r = i / 112, kb = i - r*112;
    int k0 = kb*8;
    const float* src;
    if (k0 < 128)      src = f1 + ((size_t)b*NPp + i0 + r)*128 + k0;
    else if (k0 < 384) src = f2 + ((size_t)b*NPp + i0 + r)*256 + (k0-128);
    else               src = f3 + ((size_t)b*NPp + i0 + r)*512 + (k0-384);
    unsigned hu[8], lu[8];
#pragma unroll
    for (int e = 0; e < 8; ++e) bf16_split(src[e], hu[e], lu[e]);
    i32x4 H, L;
#pragma unroll
    for (int j2 = 0; j2 < 4; ++j2){
      H[j2] = (int)(hu[2*j2] | (hu[2*j2+1] << 16));
      L[j2] = (int)(lu[2*j2] | (lu[2*j2+1] << 16));
    }
    int idx = r*896 + ((kb ^ (r & 7)) << 3);
    *(bf16x8*)(ahh + idx) = __builtin_bit_cast(bf16x8, H);
    *(bf16x8*)(ahl + idx) = __builtin_bit_cast(bf16x8, L);
  }
  __syncthreads();
  int lane = t & 63, wid = t >> 6;
  int col = lane & 15, g = lane >> 4;
  int aswz = col & 7;
  f32x4 acc = {0.f,0.f,0.f,0.f};
#pragma unroll
  for (int kt = 0; kt < 28; ++kt){
    int kb = kt*4 + g;
    int aidx = col*896 + ((kb ^ aswz) << 3);
    bf16x8 Ah = *(const bf16x8*)(ahh + aidx);
    bf16x8 Al = *(const bf16x8*)(ahl + aidx);
    size_t wo = ((size_t)(wid*28 + kt)*64 + lane)*8;
    bf16x8 Bh = *(const bf16x8*)(Wh + wo);
    bf16x8 Bl = *(const bf16x8*)(Wl + wo);
    acc = __builtin_amdgcn_mfma_f32_16x16x32_bf16(Ah, Bh, acc, 0, 0, 0);
    acc = __builtin_amdgcn_mfma_f32_16x16x32_bf16(Ah, Bl, acc, 0, 0, 0);
    acc = __builtin_amdgcn_mfma_f32_16x16x32_bf16(Al, Bh, acc, 0, 0, 0);
  }
  float mx = fmaxf(fmaxf(acc[0], acc[1]), fmaxf(acc[2], acc[3]));
  mx = fmaxf(mx, 0.0f);
  mx = fmaxf(mx, __shfl_xor(mx, 16));
  mx = fmaxf(mx, __shfl_xor(mx, 32));
  if (lane < 16) atomicMax((int*)(g128 + (size_t)b*128 + wid*16 + lane), __float_as_int(mx));
}

// ---------------- T-Net edge via MFMA: h0=relu(A0+B0[j_k]) -> [20x64]@[64x128] -> col-max ----------------
__global__ __launch_bounds__(128) void k_tedge3m(const float* __restrict__ A0, const float* __restrict__ B0,
    const int* __restrict__ idx, const u16* __restrict__ Wh, const u16* __restrict__ Wl,
    float* __restrict__ out){
  __shared__ __align__(16) u16 hh[32*64];
  __shared__ __align__(16) u16 hl[32*64];
  __shared__ int js[KC];
  int bi = blockIdx.x, t = threadIdx.x;
  int rb = (bi >> 8) << 8;
  if (t < KC) js[t] = idx[(size_t)bi*KC + t];
  __syncthreads();
  for (int i = t; i < 256; i += 128){
    int r = i >> 3, kb = i & 7;
    i32x4 H = {0,0,0,0}, L = {0,0,0,0};
    if (r < KC){
      const float* a = A0 + (size_t)bi*64 + kb*8;
      const float* bm = B0 + (size_t)(rb + js[r])*64 + kb*8;
      unsigned hu[8], lu[8];
#pragma unroll
      for (int e = 0; e < 8; ++e){
        float v = fmaxf(a[e] + bm[e], 0.0f);
        bf16_split(v, hu[e], lu[e]);
      }
#pragma unroll
      for (int j2 = 0; j2 < 4; ++j2){
        H[j2] = (int)(hu[2*j2] | (hu[2*j2+1] << 16));
        L[j2] = (int)(lu[2*j2] | (lu[2*j2+1] << 16));
      }
    }
    int idx2 = r*64 + ((kb ^ (r & 7)) << 3);
    *(bf16x8*)(hh + idx2) = __builtin_bit_cast(bf16x8, H);
    *(bf16x8*)(hl + idx2) = __builtin_bit_cast(bf16x8, L);
  }
  __syncthreads();
  int lane = t & 63, wv = t >> 6;
  int col = lane & 15, g = lane >> 4;
  int aswz = col & 7;
#pragma unroll
  for (int tt = 0; tt < 4; ++tt){
    int ct = wv*4 + tt;
    float mx = 0.0f;
#pragma unroll
    for (int m = 0; m < 2; ++m){
      f32x4 acc = {0.f,0.f,0.f,0.f};
#pragma unroll
      for (int kt = 0; kt < 2; ++kt){
        int kb = kt*4 + g;
        int aidx = (m*16 + col)*64 + ((kb ^ aswz) << 3);
        bf16x8 Ah = *(const bf16x8*)(hh + aidx);
        bf16x8 Al = *(const bf16x8*)(hl + aidx);
        size_t wo = ((size_t)(ct*2 + kt)*64 + lane)*8;
        bf16x8 Bh = *(const bf16x8*)(Wh + wo);
        bf16x8 Bl = *(const bf16x8*)(Wl + wo);
        acc = __builtin_amdgcn_mfma_f32_16x16x32_bf16(Ah, Bh, acc, 0, 0, 0);
        acc = __builtin_amdgcn_mfma_f32_16x16x32_bf16(Ah, Bl, acc, 0, 0, 0);
        acc = __builtin_amdgcn_mfma_f32_16x16x32_bf16(Al, Bh, acc, 0, 0, 0);
      }
      mx = fmaxf(mx, fmaxf(fmaxf(acc[0], acc[1]), fmaxf(acc[2], acc[3])));
    }
    mx = fmaxf(mx, __shfl_xor(mx, 16));
    mx = fmaxf(mx, __shfl_xor(mx, 32));
    if (lane < 16) out[(size_t)bi*128 + ct*16 + col] = mx;
  }
}

// ---------------- edge epilogue: out[i][c] = max_k relu(A[i][c] + B[j_ik][c]) ----------------
template<int COUT>
__global__ __launch_bounds__(256) void k_emax(const float* __restrict__ A, const float* __restrict__ Bm,
    const int* __restrict__ idx, float* __restrict__ out){
  constexpr int GT = COUT/4;
  constexpr int NC = 256/GT;
  __shared__ int js[NC*KC];
  int bi = blockIdx.x, t = threadIdx.x;
  int li = t / GT, c4 = (t % GT)*4;
  int ci = bi*NC + li;
  int rb = (ci >> 8) << 8;
  if (t < NC*KC) js[t] = idx[(size_t)bi*NC*KC + t];
  __syncthreads();
  float4 a = *(const float4*)(A + (size_t)ci*COUT + c4);
  float4 p = make_float4(0.f,0.f,0.f,0.f);
#pragma unroll
  for (int k = 0; k < KC; ++k){
    int j = js[li*KC + k];
    float4 b = *(const float4*)(Bm + (size_t)(rb + j)*COUT + c4);
    p = max4(p, add4(a, b));
  }
  *(float4*)(out + (size_t)ci*COUT + c4) = p;
}

// ---------------- T-Net MLP + 3x3 transform applied to new_xyz ----------------
__global__ __launch_bounds__(256) void k_trest(const float* __restrict__ g1024,
    const float* __restrict__ Wg0, const float* __restrict__ Wg1,
    const float* __restrict__ Wl, const float* __restrict__ bl,
    const float* __restrict__ new_xyz, float* __restrict__ x131){
  __shared__ __align__(16) float g1[1024];
  __shared__ __align__(16) float g5[512];
  __shared__ __align__(16) float g2[256];
  __shared__ float tm[12];
  int b = blockIdx.x, t = threadIdx.x;
  for (int m = t; m < 1024; m += 256) g1[m] = g1024[(size_t)b*1024 + m];
  __syncthreads();
#pragma unroll
  for (int cc = 0; cc < 2; ++cc){
    int c = t + cc*256;
    const float4* wr = (const float4*)(Wg0 + (size_t)c*1024);
    const float4* gv = (const float4*)g1;
    float a = 0.0f;
    for (int qq = 0; qq < 256; ++qq) a = fma4(wr[qq], gv[qq], a);
    g5[c] = fmaxf(a, 0.0f);
  }
  __syncthreads();
  {
    const float4* wr = (const float4*)(Wg1 + (size_t)t*512);
    const float4* gv = (const float4*)g5;
    float a = 0.0f;
    for (int qq = 0; qq < 128; ++qq) a = fma4(wr[qq], gv[qq], a);
    g2[t] = fmaxf(a, 0.0f);
  }
  __syncthreads();
  if (t < 9){
    const float4* wr = (const float4*)(Wl + (size_t)t*256);
    const float4* gv = (const float4*)g2;
    float a = 0.0f;
#pragma unroll
    for (int qq = 0; qq < 64; ++qq) a = fma4(wr[qq], gv[qq], a);
    a += bl[t];
    if (t == 0 || t == 4 || t == 8) a += 1.0f;
    tm[t] = a;
  }
  __syncthreads();
  {
    const float* nx = new_xyz + ((size_t)b*NPp + t)*3;
    float X = nx[0], Y = nx[1], Z = nx[2];
#pragma unroll
    for (int i = 0; i < 3; ++i){
      float v = __fadd_rn(__fadd_rn(__fmul_rn(tm[i*3+0], X), __fmul_rn(tm[i*3+1], Y)), __fmul_rn(tm[i*3+2], Z));
      x131[((size_t)b*NPp + t)*132 + 128 + i] = v;
    }
  }
}

// ---------------- classifier head ----------------
__global__ __launch_bounds__(256) void k_final(const float* __restrict__ g128,
    const float* __restrict__ W0, const float* __restrict__ W1,
    const float* __restrict__ Wc, const float* __restrict__ bc, float* __restrict__ out){
  __shared__ __align__(16) float g0[128];
  __shared__ __align__(16) float g5[512];
  __shared__ __align__(16) float g2[256];
  int b = blockIdx.x, t = threadIdx.x;
  if (t < 128) g0[t] = g128[(size_t)b*128 + t];
  __syncthreads();
#pragma unroll
  for (int cc = 0; cc < 2; ++cc){
    int c = t + cc*256;
    const float4* wr = (const float4*)(W0 + (size_t)c*128);
    const float4* gv = (const float4*)g0;
    float a = 0.0f;
#pragma unroll
    for (int qq = 0; qq < 32; ++qq) a = fma4(wr[qq], gv[qq], a);
    g5[c] = fmaxf(a, 0.0f);
  }
  __syncthreads();
  {
    const float4* wr = (const float4*)(W1 + (size_t)t*512);
    const float4* gv = (const float4*)g5;
    float a = 0.0f;
    for (int qq = 0; qq < 128; ++qq) a = fma4(wr[qq], gv[qq], a);
    g2[t] = fmaxf(a, 0.0f);
  }
  __syncthreads();
  if (t < 40){
    const float4* wr = (const float4*)(Wc + (size_t)t*256);
    const float4* gv = (const float4*)g2;
    float a = 0.0f;
#pragma unroll
    for (int qq = 0; qq < 64; ++qq) a = fma4(wr[qq], gv[qq], a);
    out[(size_t)b*40 + t] = a + bc[t];
  }
}

extern "C" void kernel_launch(void* const* d_in, const int* in_sizes, int n_in,
                              void* d_out, int out_size, void* d_ws, size_t ws_size,
                              hipStream_t stream){
  (void)in_sizes; (void)n_in; (void)out_size; (void)ws_size;
  const float* points     = (const float*)d_in[0];
  const float* sa_w0      = (const float*)d_in[1];
  const float* sa_w1      = (const float*)d_in[2];
  const float* sa_w2      = (const float*)d_in[3];
  const float* t_ec_w0    = (const float*)d_in[4];
  const float* t_ec_w1    = (const float*)d_in[5];
  const float* t_local_w  = (const float*)d_in[6];
  const float* t_g_w0     = (const float*)d_in[7];
  const float* t_g_w1     = (const float*)d_in[8];
  const float* t_lin_w    = (const float*)d_in[9];
  const float* t_lin_b    = (const float*)d_in[10];
  const float* dg_ec_w0   = (const float*)d_in[11];
  const float* dg_ec_w1   = (const float*)d_in[12];
  const float* dg_ec_w2   = (const float*)d_in[13];
  const float* dg_local_w = (const float*)d_in[14];
  const float* dg_g_w0    = (const float*)d_in[15];
  const float* dg_g_w1    = (const float*)d_in[16];
  const float* cls_w      = (const float*)d_in[17];
  const float* cls_b      = (const float*)d_in[18];
  float* out = (float*)d_out;

  float* ws     = (float*)d_ws;
  float* xyz    = ws;                    // 393216
  float* xnrm   = xyz    + 393216;       // 131072
  float* nxyz   = xnrm   + 131072;       // 24576
  float* feat   = nxyz   + 24576;        // 1048576 (dead output buffer -> MFMA weight frags)
  float* x131   = feat   + 1048576;      // 1081344
  float* nrm    = x131   + 1081344;      // 8192
  int*   idx    = (int*)(nrm + 8192);    // 163840
  float* ht     = (float*)(idx + 163840);// 1048576 (reused as f1)
  float* g1024v = ht     + 1048576;      // 32768
  float* f2     = g1024v + 32768;        // 2097152
  float* f3     = f2     + 2097152;      // 4194304
  float* g128v  = f3     + 4194304;      // 4096
  float* wt_t1  = g128v  + 4096;         // 8192   (legacy)
  float* waT0   = wt_t1  + 8192;         // 8384   (legacy)
  float* wbT0   = waT0   + 8384;         // 8384
  float* waD0   = wbT0   + 8384;         // 16768  (legacy)
  float* wbD0   = waD0   + 16768;        // 16768
  float* waD1   = wbD0   + 16768;        // 32768  (legacy)
  float* wbD1   = waD1   + 32768;        // 32768
  float* waD2   = wbD1   + 32768;        // 131072 (legacy)
  float* wbD2   = waD2   + 131072;       // 131072
  float* Ab     = wbD2   + 131072;       // 4194304
  float* Bb     = Ab     + 4194304;      // 4194304
  float* w1Tb   = Bb     + 4194304;      // 4096   (legacy)
  float* f1 = ht;
  float* xT = f3;                        // alias: xT lives in f3 until k_emax<512> writes f3

  // SA MFMA weight fragments alias the HEAD of Ab.
  float* w0f    = Ab;                    // 4096   ([kt][lane][e][4])
  u16*   w1fh   = (u16*)(w0f + 4096);    // 4096 u16
  u16*   w1fl   = w1fh   + 4096;         // 4096 u16
  u16*   w2fh   = w1fl   + 4096;         // 8192 u16
  u16*   w2fl   = w2fh   + 8192;         // 8192 u16

  // All GEMM weight frags live in the DEAD `feat` buffer (4MB; nothing reads it).
  // Total 1286144 u16 = 2.57MB <= 4MB.
  u16* fragu  = (u16*)feat;
  u16* wAD1h  = fragu;                   // 32768
  u16* wAD1l  = wAD1h + 32768;           // 32768
  u16* wBD1h  = wAD1l + 32768;           // 32768
  u16* wBD1l  = wBD1h + 32768;           // 32768
  u16* wAD2h  = wBD1l + 32768;           // 131072
  u16* wAD2l  = wAD2h + 131072;          // 131072
  u16* wBD2h  = wAD2l + 131072;          // 131072
  u16* wBD2l  = wBD2h + 131072;          // 131072
  u16* wTPh   = wBD2l + 131072;          // 131072 (t_local_w frags)
  u16* wTPl   = wTPh  + 131072;          // 131072
  u16* wDGh   = wTPl  + 131072;          // 114688 (dg_local_w frags)
  u16* wDGl   = wDGh  + 114688;          // 114688
  u16* wTEh   = wDGl  + 114688;          // 8192   (t_ec_w1 tedge frags)
  u16* wTEl   = wTEh  + 8192;            // 8192
  u16* wAT0h  = wTEl  + 8192;            // 10240  (padded t_ec_w0 A)
  u16* wAT0l  = wAT0h + 10240;           // 10240
  u16* wBT0h  = wAT0l + 10240;           // 10240
  u16* wBT0l  = wBT0h + 10240;           // 10240
  u16* wAD0h  = wBT0l + 10240;           // 20480  (padded dg_ec_w0 A)
  u16* wAD0l  = wAD0h + 20480;           // 20480
  u16* wBD0h  = wAD0l + 20480;           // 20480
  u16* wBD0l  = wBD0h + 20480;           // 20480

  k_prep_all<<<3875, 256, 0, stream>>>(points, xyz, xnrm,
                                       t_ec_w0, t_ec_w1, dg_ec_w0, dg_ec_w1, dg_ec_w2, sa_w1,
                                       waT0, wbT0, wt_t1, waD0, wbD0, waD1, wbD1, waD2, wbD2, w1Tb,
                                       sa_w0, sa_w1, sa_w2, t_local_w, dg_local_w,
                                       w0f, w1fh, w1fl, w2fh, w2fl,
                                       wAD1h, wAD1l, wBD1h, wBD1l, wAD2h, wAD2l, wBD2h, wBD2l,
                                       wTPh, wTPl, wDGh, wDGl, wTEh, wTEl,
                                       wAT0h, wAT0l, wBT0h, wBT0l, wAD0h, wAD0l, wBD0h, wBD0l);
  k_fps<<<BB, 128, 0, stream>>>(xyz, nxyz);
  k_sa<<<BB*NPp, 64, 0, stream>>>(points, xyz, xnrm, nxyz, w0f, w1fh, w1fl, w2fh, w2fl, x131);

  // T-Net branch (x = [feat, new_xyz]) -- MFMA with zero-padded K
  k_gabp<131,160,64><<<512, 512, 0, stream>>>(x131, 132, wAT0h, wAT0l, wBT0h, wBT0l, Ab, Bb, xT, nrm);
  k_knn3<131><<<1024, 512, 0, stream>>>(xT, nrm, idx);
  k_tedge3m<<<BB*NPp, 128, 0, stream>>>(Ab, Bb, idx, wTEh, wTEl, ht);
  k_tpoolm<<<dim3(BB, 16), 512, 0, stream>>>(ht, wTPh, wTPl, g1024v);
  k_trest<<<BB, 256, 0, stream>>>(g1024v, t_g_w0, t_g_w1, t_lin_w, t_lin_b, nxyz, x131);

  // DGCNN layer 1 -- MFMA with zero-padded K
  k_gabp<131,160,128><<<512, 512, 0, stream>>>(x131, 132, wAD0h, wAD0l, wBD0h, wBD0l, Ab, Bb, xT, nrm);
  k_knn3<131><<<1024, 512, 0, stream>>>(xT, nrm, idx);
  k_emax<128><<<1024, 256, 0, stream>>>(Ab, Bb, idx, f1);
  // layer 2 -- MFMA
  k_gabm<128,256><<<512, 512, 0, stream>>>(f1, 128, wAD1h, wAD1l, wBD1h, wBD1l, Ab, Bb, xT, nrm);
  k_knn3<128><<<1024, 512, 0, stream>>>(xT, nrm, idx);
  k_emax<256><<<2048, 256, 0, stream>>>(Ab, Bb, idx, f2);
  // layer 3 -- MFMA
  k_gabm<256,512><<<512, 512, 0, stream>>>(f2, 256, wAD2h, wAD2l, wBD2h, wBD2l, Ab, Bb, xT, nrm);
  k_knn3<256><<<1024, 512, 0, stream>>>(xT, nrm, idx);
  k_emax<512><<<4096, 256, 0, stream>>>(Ab, Bb, idx, f3);

  // local conv (MFMA) + global pool + head
  k_dglm<<<dim3(BB, 16), 512, 0, stream>>>(f1, f2, f3, wDGh, wDGl, g128v);
  k_final<<<BB, 256, 0, stream>>>(g128v, dg_g_w0, dg_g_w1, cls_w, cls_b, out);
}

// Round 14
// 809.617 us; speedup vs baseline: 1.7238x; 1.0414x over previous
//
#include <hip/hip_runtime.h>
#include <math.h>

#define BB 32
#define NN 4096
#define NPp 256
#define NSs 64
#define KC 20

typedef unsigned long long ull;
typedef unsigned short u16;
typedef short bf16x8 __attribute__((ext_vector_type(8)));
typedef float f32x4 __attribute__((ext_vector_type(4)));
typedef int i32x4 __attribute__((ext_vector_type(4)));

__device__ __forceinline__ float fma4(const float4 w, const float4 v, float a){
  a = fmaf(w.x, v.x, a); a = fmaf(w.y, v.y, a);
  a = fmaf(w.z, v.z, a); a = fmaf(w.w, v.w, a); return a;
}
__device__ __forceinline__ float4 fma4s(const float4 w, float s, float4 a){
  a.x = fmaf(w.x, s, a.x); a.y = fmaf(w.y, s, a.y);
  a.z = fmaf(w.z, s, a.z); a.w = fmaf(w.w, s, a.w); return a;
}
__device__ __forceinline__ float4 max4(float4 a, float4 b){
  a.x = fmaxf(a.x, b.x); a.y = fmaxf(a.y, b.y);
  a.z = fmaxf(a.z, b.z); a.w = fmaxf(a.w, b.w); return a;
}
__device__ __forceinline__ float4 add4(float4 a, float4 b){
  a.x += b.x; a.y += b.y; a.z += b.z; a.w += b.w; return a;
}

template<int C>
__device__ __forceinline__ int dpp_i(int x){
  return __builtin_amdgcn_update_dpp(x, x, C, 0xf, 0xf, false);
}

// split fp32 -> bf16 hi + bf16 lo (truncating; v - hi is exact in fp32)
__device__ __host__ __forceinline__ void bf16_split(float v, unsigned& h16, unsigned& l16){
  unsigned bits = __float_as_uint(v);
  h16 = bits >> 16;
  float hf = __uint_as_float(h16 << 16);
  l16 = __float_as_uint(v - hf) >> 16;
}

// ---------------- fused prep: transpose/norms + ALL MFMA weight frags ----------------
// Round-14: legacy scalar weight-prep section DELETED (787 blocks of dead traffic --
// nothing read waT0/wbT0/wt_t1/waD0/wbD0/waD1/wbD1/waD2/wbD2/w1T since the MFMA ports).
// blocks [0,512): k_prep; [512,576): SA frags; [576,1856): layer-2/3 GEMM frags;
// [1856,2368): t_local_w frags; [2368,2816): dg_local_w frags; [2816,2848): tedge frags;
// [2848,3088): PADDED t_ec_w0 / dg_ec_w0 frags (CINP=160, k>=131 zeroed -> exact no-ops).
// Frag layout everywhere (k_sa-verified): [ct][kt][lane][e], value W[k][c],
// k = kt*32 + 8*(lane>>4) + e, c = ct*16 + (lane&15).
__global__ void k_prep_all(const float* __restrict__ pts, float* __restrict__ xyz, float* __restrict__ xnrm,
                           const float* __restrict__ t0, const float* __restrict__ t1,
                           const float* __restrict__ d0, const float* __restrict__ d1,
                           const float* __restrict__ d2,
                           const float* __restrict__ w0, const float* __restrict__ w1,
                           const float* __restrict__ w2,
                           const float* __restrict__ tl, const float* __restrict__ dgw,
                           float* __restrict__ w0f, u16* __restrict__ w1fh, u16* __restrict__ w1fl,
                           u16* __restrict__ w2fh, u16* __restrict__ w2fl,
                           u16* __restrict__ wAD1h, u16* __restrict__ wAD1l,
                           u16* __restrict__ wBD1h, u16* __restrict__ wBD1l,
                           u16* __restrict__ wAD2h, u16* __restrict__ wAD2l,
                           u16* __restrict__ wBD2h, u16* __restrict__ wBD2l,
                           u16* __restrict__ wTPh, u16* __restrict__ wTPl,
                           u16* __restrict__ wDGh, u16* __restrict__ wDGl,
                           u16* __restrict__ wTEh, u16* __restrict__ wTEl,
                           u16* __restrict__ wAT0h, u16* __restrict__ wAT0l,
                           u16* __restrict__ wBT0h, u16* __restrict__ wBT0l,
                           u16* __restrict__ wAD0h, u16* __restrict__ wAD0l,
                           u16* __restrict__ wBD0h, u16* __restrict__ wBD0l){
  int bid = blockIdx.x;
  if (bid < 512){                        // ---- k_prep ----
    int i = bid*256 + threadIdx.x;
    if (i >= BB*NN) return;
    int b = i >> 12, n = i & (NN-1);
    float X = pts[(b*3+0)*NN + n];
    float Y = pts[(b*3+1)*NN + n];
    float Z = pts[(b*3+2)*NN + n];
    xyz[i*3+0]=X; xyz[i*3+1]=Y; xyz[i*3+2]=Z;
    xnrm[i] = __fadd_rn(__fadd_rn(__fmul_rn(X,X), __fmul_rn(Y,Y)), __fmul_rn(Z,Z));
    return;
  }
  if (bid < 576){                        // ---- SA frags ----
    int i = (bid-512)*256 + threadIdx.x;
    if (i < 4096){                       // w0f: [kt][lane][e][4] (xyz + pad)
      int kt = i >> 11, r = i & 2047;
      int ln = r >> 5, ee = r & 31;
      int e = ee >> 2, j = ee & 3;
      int k = kt*32 + 8*(ln>>4) + e;
      w0f[i] = (j < 3) ? w0[k*3 + j] : 0.0f;
      return;
    }
    i -= 4096;
    if (i < 4096){                       // w1 frags
      int e = i & 7, ln = (i >> 3) & 63, q = i >> 9;
      int kt = q & 1, ct = q >> 1;
      int k = kt*32 + 8*(ln>>4) + e;
      int c = ct*16 + (ln & 15);
      unsigned h16, l16; bf16_split(w1[(size_t)c*64 + k], h16, l16);
      w1fh[i] = (u16)h16; w1fl[i] = (u16)l16;
      return;
    }
    i -= 4096;
    if (i < 8192){                       // w2 frags
      int e = i & 7, ln = (i >> 3) & 63, q = i >> 9;
      int kt = q & 1, c2t = q >> 1;
      int k = kt*32 + 8*(ln>>4) + e;
      int c2 = c2t*16 + (ln & 15);
      unsigned h16, l16; bf16_split(w2[(size_t)c2*64 + k], h16, l16);
      w2fh[i] = (u16)h16; w2fl[i] = (u16)l16;
    }
    return;
  }
  if (bid < 1856){                       // ---- layer-2/3 GEMM weight frags ----
    int i = (bid-576)*256 + threadIdx.x;
    if (i < 32768){                      // D1 wA: [ct(16)][kt(4)][lane][e]
      int e = i & 7, ln = (i >> 3) & 63, q = i >> 9;
      int kt = q & 3, ct = q >> 2;
      int k = kt*32 + 8*(ln>>4) + e;
      int c = ct*16 + (ln & 15);
      float bb = d1[(size_t)c*256 + k], dd = d1[(size_t)c*256 + 128 + k];
      unsigned h, l; bf16_split(__fsub_rn(bb, dd), h, l);
      wAD1h[i] = (u16)h; wAD1l[i] = (u16)l;
      return;
    }
    i -= 32768;
    if (i < 32768){                      // D1 wB
      int e = i & 7, ln = (i >> 3) & 63, q = i >> 9;
      int kt = q & 3, ct = q >> 2;
      int k = kt*32 + 8*(ln>>4) + e;
      int c = ct*16 + (ln & 15);
      float dd = d1[(size_t)c*256 + 128 + k];
      unsigned h, l; bf16_split(dd, h, l);
      wBD1h[i] = (u16)h; wBD1l[i] = (u16)l;
      return;
    }
    i -= 32768;
    if (i < 131072){                     // D2 wA: [ct(32)][kt(8)][lane][e]
      int e = i & 7, ln = (i >> 3) & 63, q = i >> 9;
      int kt = q & 7, ct = q >> 3;
      int k = kt*32 + 8*(ln>>4) + e;
      int c = ct*16 + (ln & 15);
      float bb = d2[(size_t)c*512 + k], dd = d2[(size_t)c*512 + 256 + k];
      unsigned h, l; bf16_split(__fsub_rn(bb, dd), h, l);
      wAD2h[i] = (u16)h; wAD2l[i] = (u16)l;
      return;
    }
    i -= 131072;
    if (i < 131072){                     // D2 wB
      int e = i & 7, ln = (i >> 3) & 63, q = i >> 9;
      int kt = q & 7, ct = q >> 3;
      int k = kt*32 + 8*(ln>>4) + e;
      int c = ct*16 + (ln & 15);
      float dd = d2[(size_t)c*512 + 256 + k];
      unsigned h, l; bf16_split(dd, h, l);
      wBD2h[i] = (u16)h; wBD2l[i] = (u16)l;
    }
    return;
  }
  if (bid < 2368){                       // ---- t_local_w frags: [ct(64)][kt(4)][lane][e] ----
    int i = (bid-1856)*256 + threadIdx.x;
    int e = i & 7, ln = (i >> 3) & 63, q = i >> 9;
    int kt = q & 3, ct = q >> 2;
    int k = kt*32 + 8*(ln>>4) + e;
    int c = ct*16 + (ln & 15);
    unsigned h, l; bf16_split(tl[(size_t)c*128 + k], h, l);
    wTPh[i] = (u16)h; wTPl[i] = (u16)l;
    return;
  }
  if (bid < 2816){                       // ---- dg_local_w frags: [ct(8)][kt(28)][lane][e] ----
    int i = (bid-2368)*256 + threadIdx.x;
    if (i >= 114688) return;
    int e = i & 7, ln = (i >> 3) & 63, q = i >> 9;
    int kt = q % 28, ct = q / 28;
    int k = kt*32 + 8*(ln>>4) + e;
    int c = ct*16 + (ln & 15);
    unsigned h, l; bf16_split(dgw[(size_t)c*896 + k], h, l);
    wDGh[i] = (u16)h; wDGl[i] = (u16)l;
    return;
  }
  if (bid < 2848){                       // ---- t_ec_w1 (tedge) frags: [ct(8)][kt(2)][lane][e] ----
    int i = (bid-2816)*256 + threadIdx.x;
    int e = i & 7, ln = (i >> 3) & 63, q = i >> 9;
    int kt = q & 1, ct = q >> 1;
    int k = kt*32 + 8*(ln>>4) + e;
    int c = ct*16 + (ln & 15);
    unsigned h, l; bf16_split(t1[(size_t)c*64 + k], h, l);
    wTEh[i] = (u16)h; wTEl[i] = (u16)l;
    return;
  }
  {                                      // ---- PADDED t_ec_w0 / dg_ec_w0 frags (CINP=160) ----
    int i = (bid-2848)*256 + threadIdx.x;
    if (i < 10240){                      // T0 wA: [ct(4)][kt(5)][lane][e]
      int e = i & 7, ln = (i >> 3) & 63, q = i >> 9;   // q in [0,20)
      int kt = q % 5, ct = q / 5;
      int k = kt*32 + 8*(ln>>4) + e;
      int c = ct*16 + (ln & 15);
      float v = 0.0f;
      if (k < 131) v = __fsub_rn(t0[(size_t)c*262 + k], t0[(size_t)c*262 + 131 + k]);
      unsigned h, l; bf16_split(v, h, l);
      wAT0h[i] = (u16)h; wAT0l[i] = (u16)l;
      return;
    }
    i -= 10240;
    if (i < 10240){                      // T0 wB
      int e = i & 7, ln = (i >> 3) & 63, q = i >> 9;
      int kt = q % 5, ct = q / 5;
      int k = kt*32 + 8*(ln>>4) + e;
      int c = ct*16 + (ln & 15);
      float v = (k < 131) ? t0[(size_t)c*262 + 131 + k] : 0.0f;
      unsigned h, l; bf16_split(v, h, l);
      wBT0h[i] = (u16)h; wBT0l[i] = (u16)l;
      return;
    }
    i -= 10240;
    if (i < 20480){                      // D0 wA: [ct(8)][kt(5)][lane][e]
      int e = i & 7, ln = (i >> 3) & 63, q = i >> 9;   // q in [0,40)
      int kt = q % 5, ct = q / 5;
      int k = kt*32 + 8*(ln>>4) + e;
      int c = ct*16 + (ln & 15);
      float v = 0.0f;
      if (k < 131) v = __fsub_rn(d0[(size_t)c*262 + k], d0[(size_t)c*262 + 131 + k]);
      unsigned h, l; bf16_split(v, h, l);
      wAD0h[i] = (u16)h; wAD0l[i] = (u16)l;
      return;
    }
    i -= 20480;
    if (i < 20480){                      // D0 wB
      int e = i & 7, ln = (i >> 3) & 63, q = i >> 9;
      int kt = q % 5, ct = q / 5;
      int k = kt*32 + 8*(ln>>4) + e;
      int c = ct*16 + (ln & 15);
      float v = (k < 131) ? d0[(size_t)c*262 + 131 + k] : 0.0f;
      unsigned h, l; bf16_split(v, h, l);
      wBD0h[i] = (u16)h; wBD0l[i] = (u16)l;
    }
  }
}

// ---------------- farthest point sampling: 2 waves, key-only reduce (parked at floor) ----------------
__global__ __launch_bounds__(128, 1) void k_fps(const float* __restrict__ xyz, float* __restrict__ new_xyz){
  __shared__ __align__(16) float lx[NN], ly[NN], lz[NN];
  __shared__ __align__(16) ull wkey[2][2];
  int b = blockIdx.x, t = threadIdx.x;
  int w = t >> 6, lane = t & 63;
  float nx[32], ny[32], nz[32], dist[32];
#pragma unroll
  for (int q = 0; q < 32; ++q){
    int j = q*128 + t;
    const float* p = xyz + ((size_t)b*NN + j)*3;
    float X = p[0], Y = p[1], Z = p[2];
    lx[j] = X; ly[j] = Y; lz[j] = Z;
    nx[q] = -X; ny[q] = -Y; nz[q] = -Z;
    dist[q] = __builtin_inff();
  }
  const float* p0 = xyz + (size_t)b*NN*3;
  float Px = p0[0], Py = p0[1], Pz = p0[2];
  __syncthreads();
  for (int it = 0; it < NPp; ++it){
    if (t == 0){
      float* o = new_xyz + ((size_t)b*NPp + it)*3;
      o[0] = Px; o[1] = Py; o[2] = Pz;
    }
    ull ka0 = 0, ka1 = 0, ka2 = 0, ka3 = 0;
#pragma unroll
    for (int q = 0; q < 32; ++q){
      float dx = __fadd_rn(nx[q], Px);
      float dy = __fadd_rn(ny[q], Py);
      float dz = __fadd_rn(nz[q], Pz);
      float dd = __fadd_rn(__fadd_rn(__fmul_rn(dx,dx), __fmul_rn(dy,dy)), __fmul_rn(dz,dz));
      float dm = fminf(dist[q], dd);
      dist[q] = dm;
      ull key = ((ull)__float_as_uint(dm) << 32) | (unsigned)(4095 - (q*128 + t));
      if      ((q & 3) == 0){ if (key > ka0) ka0 = key; }
      else if ((q & 3) == 1){ if (key > ka1) ka1 = key; }
      else if ((q & 3) == 2){ if (key > ka2) ka2 = key; }
      else                  { if (key > ka3) ka3 = key; }
    }
    ull kb0 = (ka0 > ka1) ? ka0 : ka1;
    ull kb1 = (ka2 > ka3) ? ka2 : ka3;
    ull bk  = (kb0 > kb1) ? kb0 : kb1;
#define FPS_STAGE(C) { \
    unsigned ol = (unsigned)dpp_i<C>((int)(unsigned)bk); \
    unsigned oh = (unsigned)dpp_i<C>((int)(unsigned)(bk >> 32)); \
    ull ok = ((ull)oh << 32) | ol; \
    if (ok > bk) bk = ok; }
    FPS_STAGE(0x111) FPS_STAGE(0x112) FPS_STAGE(0x114) FPS_STAGE(0x118)
    FPS_STAGE(0x142) FPS_STAGE(0x143)
#undef FPS_STAGE
    int par = it & 1;
    if (lane == 63) wkey[par][w] = bk;
    __syncthreads();
    ull k0 = wkey[par][0], k1 = wkey[par][1];
    ull kw = (k0 > k1) ? k0 : k1;
    int idx = 4095 - (int)(unsigned)(kw & 0xFFFFFFFFu);
    Px = lx[idx]; Py = ly[idx]; Pz = lz[idx];
  }
}

// ---------------- ball query + SA convs + maxpool: MFMA split-bf16 ----------------
// Round-14: ball-query early exit restored (bit-exact: once cnt>=64 no gw entry can be
// written, so later chunks are pure dead loads; ~60-80% of scan skipped on average).
__global__ __launch_bounds__(64) void k_sa(const float* __restrict__ pts,
    const float* __restrict__ xyz, const float* __restrict__ xnrm,
    const float* __restrict__ new_xyz, const float* __restrict__ w0f,
    const u16* __restrict__ w1fh, const u16* __restrict__ w1fl,
    const u16* __restrict__ w2fh, const u16* __restrict__ w2fl,
    float* __restrict__ x131){
  __shared__ __align__(16) u16 hh[64*64];
  __shared__ __align__(16) u16 hl[64*64];
  __shared__ int gw[64];
  int bi = blockIdx.x;
  int lane = threadIdx.x;
  int b = bi >> 8;
  const float* q = new_xyz + (size_t)bi*3;
  float qx=q[0], qy=q[1], qz=q[2];
  float nq = __fadd_rn(__fadd_rn(__fmul_rn(qx,qx), __fmul_rn(qy,qy)), __fmul_rn(qz,qz));
  const float* pX = pts + (size_t)(b*3+0)*NN;
  const float* pY = pts + (size_t)(b*3+1)*NN;
  const float* pZ = pts + (size_t)(b*3+2)*NN;
  int cnt = 0;
  for (int base = 0; base < NN && cnt < NSs; base += 256){
#pragma unroll
    for (int u = 0; u < 4; ++u){
      int j = base + u*64 + lane;
      float X = pX[j], Y = pY[j], Z = pZ[j];
      float dot = __fadd_rn(__fadd_rn(__fmul_rn(qx,X), __fmul_rn(qy,Y)), __fmul_rn(qz,Z));
      float d2 = __fsub_rn(__fadd_rn(nq, xnrm[b*NN + j]), __fmul_rn(2.0f, dot));
      bool inb = d2 < 0.04f;
      unsigned long long m = __ballot(inb);
      int pos = cnt + (int)__popcll(m & ((1ull << lane) - 1ull));
      if (inb && pos < NSs) gw[pos] = j;
      cnt += (int)__popcll(m);
    }
  }
  int g0 = gw[0];
  if (lane >= cnt) gw[lane] = g0;
  int gj = gw[lane];
  const float* pp = xyz + ((size_t)b*NN + gj)*3;
  float px = pp[0]-qx, py = pp[1]-qy, pz = pp[2]-qz;
  int col = lane & 15, g = lane >> 4;
  float sxv[4], syv[4], szv[4];
#pragma unroll
  for (int t2 = 0; t2 < 4; ++t2){
    int src = col + 16*t2;
    sxv[t2] = __shfl(px, src);
    syv[t2] = __shfl(py, src);
    szv[t2] = __shfl(pz, src);
  }
  i32x4 ah0[4][2], al0[4][2];
#pragma unroll
  for (int kt = 0; kt < 2; ++kt){
    float4 wrow[8];
    const float4* wp = (const float4*)(w0f + (size_t)(kt*64 + lane)*32);
#pragma unroll
    for (int e = 0; e < 8; ++e) wrow[e] = wp[e];
#pragma unroll
    for (int t2 = 0; t2 < 4; ++t2){
      unsigned hu[8], lu[8];
#pragma unroll
      for (int e = 0; e < 8; ++e){
        float a = fmaf(wrow[e].z, szv[t2], fmaf(wrow[e].y, syv[t2], wrow[e].x*sxv[t2]));
        a = fmaxf(a, 0.0f);
        bf16_split(a, hu[e], lu[e]);
      }
      i32x4 H, L;
#pragma unroll
      for (int j2 = 0; j2 < 4; ++j2){
        H[j2] = (int)(hu[2*j2] | (hu[2*j2+1] << 16));
        L[j2] = (int)(lu[2*j2] | (lu[2*j2+1] << 16));
      }
      ah0[t2][kt] = H; al0[t2][kt] = L;
    }
  }
#pragma unroll
  for (int ct = 0; ct < 4; ++ct){
    bf16x8 bh[2], bl[2];
#pragma unroll
    for (int kt = 0; kt < 2; ++kt){
      bh[kt] = *(const bf16x8*)(w1fh + (size_t)((ct*2+kt)*64 + lane)*8);
      bl[kt] = *(const bf16x8*)(w1fl + (size_t)((ct*2+kt)*64 + lane)*8);
    }
#pragma unroll
    for (int t2 = 0; t2 < 4; ++t2){
      f32x4 acc = {0.f,0.f,0.f,0.f};
#pragma unroll
      for (int kt = 0; kt < 2; ++kt){
        bf16x8 Ah = __builtin_bit_cast(bf16x8, ah0[t2][kt]);
        bf16x8 Al = __builtin_bit_cast(bf16x8, al0[t2][kt]);
        acc = __builtin_amdgcn_mfma_f32_16x16x32_bf16(Ah, bh[kt], acc, 0, 0, 0);
        acc = __builtin_amdgcn_mfma_f32_16x16x32_bf16(Ah, bl[kt], acc, 0, 0, 0);
        acc = __builtin_amdgcn_mfma_f32_16x16x32_bf16(Al, bh[kt], acc, 0, 0, 0);
      }
#pragma unroll
      for (int r = 0; r < 4; ++r){
        float v = fmaxf(acc[r], 0.0f);
        int s = 16*t2 + 4*g + r;
        int cc = ct*16 + col;
        int idx = s*64 + (cc ^ ((s & 7) << 3));
        unsigned h16, l16; bf16_split(v, h16, l16);
        hh[idx] = (u16)h16; hl[idx] = (u16)l16;
      }
    }
  }
  bf16x8 a1h[4][2], a1l[4][2];
#pragma unroll
  for (int t2 = 0; t2 < 4; ++t2){
    int s = col + 16*t2;
    int sw = (s & 7) << 3;
#pragma unroll
    for (int kt = 0; kt < 2; ++kt){
      int k0 = kt*32 + 8*g;
      int idx = s*64 + (k0 ^ sw);
      a1h[t2][kt] = *(const bf16x8*)(hh + idx);
      a1l[t2][kt] = *(const bf16x8*)(hl + idx);
    }
  }
#pragma unroll
  for (int c2t = 0; c2t < 8; ++c2t){
    bf16x8 bh2[2], bl2[2];
#pragma unroll
    for (int kt = 0; kt < 2; ++kt){
      bh2[kt] = *(const bf16x8*)(w2fh + (size_t)((c2t*2+kt)*64 + lane)*8);
      bl2[kt] = *(const bf16x8*)(w2fl + (size_t)((c2t*2+kt)*64 + lane)*8);
    }
    float mx = 0.0f;
#pragma unroll
    for (int t2 = 0; t2 < 4; ++t2){
      f32x4 acc = {0.f,0.f,0.f,0.f};
#pragma unroll
      for (int kt = 0; kt < 2; ++kt){
        acc = __builtin_amdgcn_mfma_f32_16x16x32_bf16(a1h[t2][kt], bh2[kt], acc, 0, 0, 0);
        acc = __builtin_amdgcn_mfma_f32_16x16x32_bf16(a1h[t2][kt], bl2[kt], acc, 0, 0, 0);
        acc = __builtin_amdgcn_mfma_f32_16x16x32_bf16(a1l[t2][kt], bh2[kt], acc, 0, 0, 0);
      }
      mx = fmaxf(mx, fmaxf(fmaxf(acc[0], acc[1]), fmaxf(acc[2], acc[3])));
    }
    mx = fmaxf(mx, __shfl_xor(mx, 16));
    mx = fmaxf(mx, __shfl_xor(mx, 32));
    if (lane < 16){
      int c = c2t*16 + lane;
      x131[(size_t)bi*132 + c] = mx;
    }
  }
  if (lane < 3) x131[(size_t)bi*132 + 128 + lane] = (lane==0)?qx:((lane==1)?qy:qz);
}

// ---------------- kNN: distances in registers, u64-DPP selection, no selection LDS ----------------
template<int CIN>
__global__ __launch_bounds__(512) void k_knn3(const float* __restrict__ xT,
    const float* __restrict__ nrm, int* __restrict__ idxo){
  __shared__ __align__(16) float sch[16*256];
  int bi = blockIdx.x, t = threadIdx.x;
  int w = t >> 6, lane = t & 63;
  int b = bi >> 5;
  int coli = (bi & 31)*8 + w;
  const float* xb = xT + (size_t)b*CIN*256;
  float d0=0.f, d1=0.f, d2=0.f, d3=0.f;
  for (int m0 = 0; m0 < CIN; m0 += 16){
    int mc = (CIN - m0 < 16) ? (CIN - m0) : 16;
    for (int i = t; i < mc*64; i += 512){
      int mm = i >> 6, c4 = i & 63;
      *(float4*)(sch + mm*256 + c4*4) = *(const float4*)(xb + (size_t)(m0+mm)*256 + c4*4);
    }
    __syncthreads();
    for (int mm = 0; mm < mc; ++mm){
      float xm = sch[mm*256 + coli];
      float4 v = *(const float4*)(sch + mm*256 + 4*lane);
      d0 = fmaf(v.x, xm, d0); d1 = fmaf(v.y, xm, d1);
      d2 = fmaf(v.z, xm, d2); d3 = fmaf(v.w, xm, d3);
    }
    __syncthreads();
  }
  float ni = nrm[b*256 + coli];
  float4 dv;
  {
    int j0 = 4*lane;
    dv.x = __fsub_rn(__fadd_rn(ni, nrm[b*256 + j0+0]), __fmul_rn(2.0f, d0));
    dv.y = __fsub_rn(__fadd_rn(ni, nrm[b*256 + j0+1]), __fmul_rn(2.0f, d1));
    dv.z = __fsub_rn(__fadd_rn(ni, nrm[b*256 + j0+2]), __fmul_rn(2.0f, d2));
    dv.w = __fsub_rn(__fadd_rn(ni, nrm[b*256 + j0+3]), __fmul_rn(2.0f, d3));
  }
  for (int r = 0; r < KC; ++r){
    float bv = 3.4e38f; int bj = NPp;
    if (dv.x < bv){ bv = dv.x; bj = 4*lane+0; }
    if (dv.y < bv){ bv = dv.y; bj = 4*lane+1; }
    if (dv.z < bv){ bv = dv.z; bj = 4*lane+2; }
    if (dv.w < bv){ bv = dv.w; bj = 4*lane+3; }
    unsigned xf = __float_as_uint(bv);
    xf = (xf & 0x80000000u) ? ~xf : (xf | 0x80000000u);
    ull key = ((ull)xf << 32) | (unsigned)bj;
#define KN_STAGE(C) { \
    unsigned ol = (unsigned)dpp_i<C>((int)(unsigned)key); \
    unsigned oh = (unsigned)dpp_i<C>((int)(unsigned)(key >> 32)); \
    ull ok = ((ull)oh << 32) | ol; \
    if (ok < key) key = ok; }
    KN_STAGE(0x111) KN_STAGE(0x112) KN_STAGE(0x114) KN_STAGE(0x118)
    KN_STAGE(0x142) KN_STAGE(0x143)
#undef KN_STAGE
    int bjw = __builtin_amdgcn_readlane((int)(unsigned)key, 63);
    if (lane == 0) idxo[((size_t)b*256 + coli)*KC + r] = bjw;
    if ((bjw >> 2) == lane){
      int e = bjw & 3;
      if      (e == 0) dv.x = 3.0e38f;
      else if (e == 1) dv.y = 3.0e38f;
      else if (e == 2) dv.z = 3.0e38f;
      else             dv.w = 3.0e38f;
    }
  }
}

// ---------------- per-point dual GEMM via MFMA split-bf16 (CIN multiple of 32) ----------------
template<int CIN, int COUT>
__global__ __launch_bounds__(512) void k_gabm(const float* __restrict__ x, int xstride,
    const u16* __restrict__ wAh, const u16* __restrict__ wAl,
    const u16* __restrict__ wBh, const u16* __restrict__ wBl,
    float* __restrict__ A, float* __restrict__ B, float* __restrict__ xT,
    float* __restrict__ nrm){
  constexpr int PC  = CIN + 1;
  constexpr int KT  = CIN / 32;
  constexpr int CT  = COUT / 16;
  constexpr int TPW = 2*CT/8;
  constexpr int KB  = CIN / 8;
  __shared__ float xsh[16*PC];
  __shared__ __align__(16) u16 axh[16*CIN];
  __shared__ __align__(16) u16 axl[16*CIN];
  int bi = blockIdx.x, t = threadIdx.x;
  int i0 = bi*16;
  for (int i = t; i < 16*CIN; i += 512){
    int r = i / CIN, m = i - r*CIN;
    xsh[r*PC + m] = x[(size_t)(i0+r)*xstride + m];
  }
  __syncthreads();
  {
    int bb = i0 >> 8, col0 = i0 & 255;
    float* xTb = xT + (size_t)bb*CIN*256 + col0;
    for (int i = t; i < 16*CIN; i += 512){
      int m = i >> 4, r = i & 15;
      xTb[m*256 + r] = xsh[r*PC + m];
    }
  }
  if (t < 16){
    const float* xr = xsh + t*PC;
    float a = 0.0f;
    for (int m = 0; m < CIN; ++m) a = __fadd_rn(a, __fmul_rn(xr[m], xr[m]));
    nrm[i0 + t] = a;
  }
  if (t < 16*KB){
    int r = t / KB, kb = t - r*KB;
    unsigned hu[8], lu[8];
#pragma unroll
    for (int e = 0; e < 8; ++e) bf16_split(xsh[r*PC + kb*8 + e], hu[e], lu[e]);
    i32x4 H, L;
#pragma unroll
    for (int j2 = 0; j2 < 4; ++j2){
      H[j2] = (int)(hu[2*j2] | (hu[2*j2+1] << 16));
      L[j2] = (int)(lu[2*j2] | (lu[2*j2+1] << 16));
    }
    int idx = r*CIN + ((kb ^ (r & 7)) << 3);
    *(bf16x8*)(axh + idx) = __builtin_bit_cast(bf16x8, H);
    *(bf16x8*)(axl + idx) = __builtin_bit_cast(bf16x8, L);
  }
  __syncthreads();
  int lane = t & 63, wid = t >> 6;
  int col = lane & 15, g = lane >> 4;
  int aswz = col & 7;
#pragma unroll
  for (int tt = 0; tt < TPW; ++tt){
    int tile = wid*TPW + tt;
    bool isB = tile >= CT;
    int ct = isB ? tile - CT : tile;
    const u16* Wh = isB ? wBh : wAh;
    const u16* Wl = isB ? wBl : wAl;
    float* Out = isB ? B : A;
    f32x4 acc = {0.f,0.f,0.f,0.f};
#pragma unroll
    for (int kt = 0; kt < KT; ++kt){
      int kb = kt*4 + g;
      int aidx = col*CIN + ((kb ^ aswz) << 3);
      bf16x8 Ah = *(const bf16x8*)(axh + aidx);
      bf16x8 Al = *(const bf16x8*)(axl + aidx);
      size_t wo = ((size_t)(ct*KT + kt)*64 + lane)*8;
      bf16x8 Bh = *(const bf16x8*)(Wh + wo);
      bf16x8 Bl = *(const bf16x8*)(Wl + wo);
      acc = __builtin_amdgcn_mfma_f32_16x16x32_bf16(Ah, Bh, acc, 0, 0, 0);
      acc = __builtin_amdgcn_mfma_f32_16x16x32_bf16(Ah, Bl, acc, 0, 0, 0);
      acc = __builtin_amdgcn_mfma_f32_16x16x32_bf16(Al, Bh, acc, 0, 0, 0);
    }
#pragma unroll
    for (int r = 0; r < 4; ++r){
      Out[(size_t)(i0 + 4*g + r)*COUT + ct*16 + col] = acc[r];
    }
  }
}

// ---------------- per-point dual GEMM via MFMA, K zero-padded (CIN=131 -> CINP=160) ----------------
template<int CIN, int CINP, int COUT>
__global__ __launch_bounds__(512) void k_gabp(const float* __restrict__ x, int xstride,
    const u16* __restrict__ wAh, const u16* __restrict__ wAl,
    const u16* __restrict__ wBh, const u16* __restrict__ wBl,
    float* __restrict__ A, float* __restrict__ B, float* __restrict__ xT,
    float* __restrict__ nrm){
  constexpr int PC  = CIN + 1;
  constexpr int KT  = CINP / 32;       // 5
  constexpr int CT  = COUT / 16;
  constexpr int TPW = 2*CT/8;          // 1 (COUT=64) or 2 (COUT=128)
  constexpr int KB  = CINP / 8;        // 20
  __shared__ float xsh[16*PC];
  __shared__ __align__(16) u16 axh[16*CINP];
  __shared__ __align__(16) u16 axl[16*CINP];
  int bi = blockIdx.x, t = threadIdx.x;
  int i0 = bi*16;
  for (int i = t; i < 16*CIN; i += 512){
    int r = i / CIN, m = i - r*CIN;
    xsh[r*PC + m] = x[(size_t)(i0+r)*xstride + m];
  }
  __syncthreads();
  {
    int bb = i0 >> 8, col0 = i0 & 255;
    float* xTb = xT + (size_t)bb*CIN*256 + col0;
    for (int i = t; i < 16*CIN; i += 512){
      int m = i >> 4, r = i & 15;
      xTb[m*256 + r] = xsh[r*PC + m];
    }
  }
  if (t < 16){
    const float* xr = xsh + t*PC;
    float a = 0.0f;
    for (int m = 0; m < CIN; ++m) a = __fadd_rn(a, __fmul_rn(xr[m], xr[m]));
    nrm[i0 + t] = a;
  }
  if (t < 16*KB){
    int r = t / KB, kb = t - r*KB;
    unsigned hu[8], lu[8];
#pragma unroll
    for (int e = 0; e < 8; ++e){
      int m = kb*8 + e;
      float v = (m < CIN) ? xsh[r*PC + m] : 0.0f;
      bf16_split(v, hu[e], lu[e]);
    }
    i32x4 H, L;
#pragma unroll
    for (int j2 = 0; j2 < 4; ++j2){
      H[j2] = (int)(hu[2*j2] | (hu[2*j2+1] << 16));
      L[j2] = (int)(lu[2*j2] | (lu[2*j2+1] << 16));
    }
    int idx = r*CINP + ((kb ^ (r & 3)) << 3);
    *(bf16x8*)(axh + idx) = __builtin_bit_cast(bf16x8, H);
    *(bf16x8*)(axl + idx) = __builtin_bit_cast(bf16x8, L);
  }
  __syncthreads();
  int lane = t & 63, wid = t >> 6;
  int col = lane & 15, g = lane >> 4;
  int aswz = col & 3;
#pragma unroll
  for (int tt = 0; tt < TPW; ++tt){
    int tile = wid*TPW + tt;
    bool isB = tile >= CT;
    int ct = isB ? tile - CT : tile;
    const u16* Wh = isB ? wBh : wAh;
    const u16* Wl = isB ? wBl : wAl;
    float* Out = isB ? B : A;
    f32x4 acc = {0.f,0.f,0.f,0.f};
#pragma unroll
    for (int kt = 0; kt < KT; ++kt){
      int kb = kt*4 + g;
      int aidx = col*CINP + ((kb ^ aswz) << 3);
      bf16x8 Ah = *(const bf16x8*)(axh + aidx);
      bf16x8 Al = *(const bf16x8*)(axl + aidx);
      size_t wo = ((size_t)(ct*KT + kt)*64 + lane)*8;
      bf16x8 Bh = *(const bf16x8*)(Wh + wo);
      bf16x8 Bl = *(const bf16x8*)(Wl + wo);
      acc = __builtin_amdgcn_mfma_f32_16x16x32_bf16(Ah, Bh, acc, 0, 0, 0);
      acc = __builtin_amdgcn_mfma_f32_16x16x32_bf16(Ah, Bl, acc, 0, 0, 0);
      acc = __builtin_amdgcn_mfma_f32_16x16x32_bf16(Al, Bh, acc, 0, 0, 0);
    }
#pragma unroll
    for (int r = 0; r < 4; ++r){
      Out[(size_t)(i0 + 4*g + r)*COUT + ct*16 + col] = acc[r];
    }
  }
}

// ---------------- T-Net 128->1024 GEMM + pool via MFMA split-bf16 ----------------
__global__ __launch_bounds__(512) void k_tpoolm(const float* __restrict__ h,
    const u16* __restrict__ Wh, const u16* __restrict__ Wl, float* __restrict__ g1024){
  __shared__ __align__(16) u16 ahh[16*128];
  __shared__ __align__(16) u16 ahl[16*128];
  int b = blockIdx.x, i0 = blockIdx.y*16;
  int t = threadIdx.x;
  if (t < 256){
    int r = t >> 4, kb = t & 15;
    const float* hr = h + ((size_t)b*NPp + i0 + r)*128 + kb*8;
    unsigned hu[8], lu[8];
#pragma unroll
    for (int e = 0; e < 8; ++e) bf16_split(hr[e], hu[e], lu[e]);
    i32x4 H, L;
#pragma unroll
    for (int j2 = 0; j2 < 4; ++j2){
      H[j2] = (int)(hu[2*j2] | (hu[2*j2+1] << 16));
      L[j2] = (int)(lu[2*j2] | (lu[2*j2+1] << 16));
    }
    int idx = r*128 + ((kb ^ (r & 7)) << 3);
    *(bf16x8*)(ahh + idx) = __builtin_bit_cast(bf16x8, H);
    *(bf16x8*)(ahl + idx) = __builtin_bit_cast(bf16x8, L);
  }
  __syncthreads();
  int lane = t & 63, wid = t >> 6;
  int col = lane & 15, g = lane >> 4;
  int aswz = col & 7;
#pragma unroll
  for (int tt = 0; tt < 8; ++tt){
    int ct = wid*8 + tt;
    f32x4 acc = {0.f,0.f,0.f,0.f};
#pragma unroll
    for (int kt = 0; kt < 4; ++kt){
      int kb = kt*4 + g;
      int aidx = col*128 + ((kb ^ aswz) << 3);
      bf16x8 Ah = *(const bf16x8*)(ahh + aidx);
      bf16x8 Al = *(const bf16x8*)(ahl + aidx);
      size_t wo = ((size_t)(ct*4 + kt)*64 + lane)*8;
      bf16x8 Bh = *(const bf16x8*)(Wh + wo);
      bf16x8 Bl = *(const bf16x8*)(Wl + wo);
      acc = __builtin_amdgcn_mfma_f32_16x16x32_bf16(Ah, Bh, acc, 0, 0, 0);
      acc = __builtin_amdgcn_mfma_f32_16x16x32_bf16(Ah, Bl, acc, 0, 0, 0);
      acc = __builtin_amdgcn_mfma_f32_16x16x32_bf16(Al, Bh, acc, 0, 0, 0);
    }
    float mx = fmaxf(fmaxf(acc[0], acc[1]), fmaxf(acc[2], acc[3]));
    mx = fmaxf(mx, 0.0f);
    mx = fmaxf(mx, __shfl_xor(mx, 16));
    mx = fmaxf(mx, __shfl_xor(mx, 32));
    if (lane < 16) atomicMax((int*)(g1024 + (size_t)b*1024 + ct*16 + lane), __float_as_int(mx));
  }
}

// ---------------- 896->128 conv + global pool via MFMA split-bf16 ----------------
__global__ __launch_bounds__(512) void k_dglm(const float* __restrict__ f1, const float* __restrict__ f2,
    const float* __restrict__ f3, const u16* __restrict__ Wh, const u16* __restrict__ Wl,
    float* __restrict__ g128){
  __shared__ __align__(16) u16 ahh[16*896];
  __shared__ __align__(16) u16 ahl[16*896];
  int b = blockIdx.x, i0 = blockIdx.y*16;
  int t = threadIdx.x;
  for (int i = t; i < 16*112; i += 512){
    int r = i / 112, kb = i - r*112;
    int k0 = kb*8;
    const float* src;
    if (k0 < 128)      src = f1 + ((size_t)b*NPp + i0 + r)*128 + k0;
    else if (k0 < 384) src = f2 + ((size_t)b*NPp + i0 + r)*256 + (k0-128);
    else               src = f3 + ((size_t)b*NPp + i0 + r)*512 + (k0-384);
    unsigned hu[8], lu[8];
#pragma unroll
    for (int e = 0; e < 8; ++e) bf16_split(src[e], hu[e], lu[e]);
    i32x4 H, L;
#pragma unroll
    for (int j2 = 0; j2 < 4; ++j2){
      H[j2] = (int)(hu[2*j2] | (hu[2*j2+1] << 16));
      L[j2] = (int)(lu[2*j2] | (lu[2*j2+1] << 16));
    }
    int idx = r*896 + ((kb ^ (r & 7)) << 3);
    *(bf16x8*)(ahh + idx) = __builtin_bit_cast(bf16x8, H);
    *(bf16x8*)(ahl + idx) = __builtin_bit_cast(bf16x8, L);
  }
  __syncthreads();
  int lane = t & 63, wid = t >> 6;
  int col = lane & 15, g = lane >> 4;
  int aswz = col & 7;
  f32x4 acc = {0.f,0.f,0.f,0.f};
#pragma unroll
  for (int kt = 0; kt < 28; ++kt){
    int kb = kt*4 + g;
    int aidx = col*896 + ((kb ^ aswz) << 3);
    bf16x8 Ah = *(const bf16x8*)(ahh + aidx);
    bf16x8 Al = *(const bf16x8*)(ahl + aidx);
    size_t wo = ((size_t)(wid*28 + kt)*64 + lane)*8;
    bf16x8 Bh = *(const bf16x8*)(Wh + wo);
    bf16x8 Bl = *(const bf16x8*)(Wl + wo);
    acc = __builtin_amdgcn_mfma_f32_16x16x32_bf16(Ah, Bh, acc, 0, 0, 0);
    acc = __builtin_amdgcn_mfma_f32_16x16x32_bf16(Ah, Bl, acc, 0, 0, 0);
    acc = __builtin_amdgcn_mfma_f32_16x16x32_bf16(Al, Bh, acc, 0, 0, 0);
  }
  float mx = fmaxf(fmaxf(acc[0], acc[1]), fmaxf(acc[2], acc[3]));
  mx = fmaxf(mx, 0.0f);
  mx = fmaxf(mx, __shfl_xor(mx, 16));
  mx = fmaxf(mx, __shfl_xor(mx, 32));
  if (lane < 16) atomicMax((int*)(g128 + (size_t)b*128 + wid*16 + lane), __float_as_int(mx));
}

// ---------------- T-Net edge via MFMA: h0=relu(A0+B0[j_k]) -> [20x64]@[64x128] -> col-max ----------------
__global__ __launch_bounds__(128) void k_tedge3m(const float* __restrict__ A0, const float* __restrict__ B0,
    const int* __restrict__ idx, const u16* __restrict__ Wh, const u16* __restrict__ Wl,
    float* __restrict__ out){
  __shared__ __align__(16) u16 hh[32*64];
  __shared__ __align__(16) u16 hl[32*64];
  __shared__ int js[KC];
  int bi = blockIdx.x, t = threadIdx.x;
  int rb = (bi >> 8) << 8;
  if (t < KC) js[t] = idx[(size_t)bi*KC + t];
  __syncthreads();
  for (int i = t; i < 256; i += 128){
    int r = i >> 3, kb = i & 7;
    i32x4 H = {0,0,0,0}, L = {0,0,0,0};
    if (r < KC){
      const float* a = A0 + (size_t)bi*64 + kb*8;
      const float* bm = B0 + (size_t)(rb + js[r])*64 + kb*8;
      unsigned hu[8], lu[8];
#pragma unroll
      for (int e = 0; e < 8; ++e){
        float v = fmaxf(a[e] + bm[e], 0.0f);
        bf16_split(v, hu[e], lu[e]);
      }
#pragma unroll
      for (int j2 = 0; j2 < 4; ++j2){
        H[j2] = (int)(hu[2*j2] | (hu[2*j2+1] << 16));
        L[j2] = (int)(lu[2*j2] | (lu[2*j2+1] << 16));
      }
    }
    int idx2 = r*64 + ((kb ^ (r & 7)) << 3);
    *(bf16x8*)(hh + idx2) = __builtin_bit_cast(bf16x8, H);
    *(bf16x8*)(hl + idx2) = __builtin_bit_cast(bf16x8, L);
  }
  __syncthreads();
  int lane = t & 63, wv = t >> 6;
  int col = lane & 15, g = lane >> 4;
  int aswz = col & 7;
#pragma unroll
  for (int tt = 0; tt < 4; ++tt){
    int ct = wv*4 + tt;
    float mx = 0.0f;
#pragma unroll
    for (int m = 0; m < 2; ++m){
      f32x4 acc = {0.f,0.f,0.f,0.f};
#pragma unroll
      for (int kt = 0; kt < 2; ++kt){
        int kb = kt*4 + g;
        int aidx = (m*16 + col)*64 + ((kb ^ aswz) << 3);
        bf16x8 Ah = *(const bf16x8*)(hh + aidx);
        bf16x8 Al = *(const bf16x8*)(hl + aidx);
        size_t wo = ((size_t)(ct*2 + kt)*64 + lane)*8;
        bf16x8 Bh = *(const bf16x8*)(Wh + wo);
        bf16x8 Bl = *(const bf16x8*)(Wl + wo);
        acc = __builtin_amdgcn_mfma_f32_16x16x32_bf16(Ah, Bh, acc, 0, 0, 0);
        acc = __builtin_amdgcn_mfma_f32_16x16x32_bf16(Ah, Bl, acc, 0, 0, 0);
        acc = __builtin_amdgcn_mfma_f32_16x16x32_bf16(Al, Bh, acc, 0, 0, 0);
      }
      mx = fmaxf(mx, fmaxf(fmaxf(acc[0], acc[1]), fmaxf(acc[2], acc[3])));
    }
    mx = fmaxf(mx, __shfl_xor(mx, 16));
    mx = fmaxf(mx, __shfl_xor(mx, 32));
    if (lane < 16) out[(size_t)bi*128 + ct*16 + col] = mx;
  }
}

// ---------------- edge epilogue: out[i][c] = max_k relu(A[i][c] + B[j_ik][c]) ----------------
template<int COUT>
__global__ __launch_bounds__(256) void k_emax(const float* __restrict__ A, const float* __restrict__ Bm,
    const int* __restrict__ idx, float* __restrict__ out){
  constexpr int GT = COUT/4;
  constexpr int NC = 256/GT;
  __shared__ int js[NC*KC];
  int bi = blockIdx.x, t = threadIdx.x;
  int li = t / GT, c4 = (t % GT)*4;
  int ci = bi*NC + li;
  int rb = (ci >> 8) << 8;
  if (t < NC*KC) js[t] = idx[(size_t)bi*NC*KC + t];
  __syncthreads();
  float4 a = *(const float4*)(A + (size_t)ci*COUT + c4);
  float4 p = make_float4(0.f,0.f,0.f,0.f);
#pragma unroll
  for (int k = 0; k < KC; ++k){
    int j = js[li*KC + k];
    float4 b = *(const float4*)(Bm + (size_t)(rb + j)*COUT + c4);
    p = max4(p, add4(a, b));
  }
  *(float4*)(out + (size_t)ci*COUT + c4) = p;
}

// ---------------- T-Net MLP + 3x3 transform applied to new_xyz ----------------
__global__ __launch_bounds__(256) void k_trest(const float* __restrict__ g1024,
    const float* __restrict__ Wg0, const float* __restrict__ Wg1,
    const float* __restrict__ Wl, const float* __restrict__ bl,
    const float* __restrict__ new_xyz, float* __restrict__ x131){
  __shared__ __align__(16) float g1[1024];
  __shared__ __align__(16) float g5[512];
  __shared__ __align__(16) float g2[256];
  __shared__ float tm[12];
  int b = blockIdx.x, t = threadIdx.x;
  for (int m = t; m < 1024; m += 256) g1[m] = g1024[(size_t)b*1024 + m];
  __syncthreads();
#pragma unroll
  for (int cc = 0; cc < 2; ++cc){
    int c = t + cc*256;
    const float4* wr = (const float4*)(Wg0 + (size_t)c*1024);
    const float4* gv = (const float4*)g1;
    float a = 0.0f;
    for (int qq = 0; qq < 256; ++qq) a = fma4(wr[qq], gv[qq], a);
    g5[c] = fmaxf(a, 0.0f);
  }
  __syncthreads();
  {
    const float4* wr = (const float4*)(Wg1 + (size_t)t*512);
    const float4* gv = (const float4*)g5;
    float a = 0.0f;
    for (int qq = 0; qq < 128; ++qq) a = fma4(wr[qq], gv[qq], a);
    g2[t] = fmaxf(a, 0.0f);
  }
  __syncthreads();
  if (t < 9){
    const float4* wr = (const float4*)(Wl + (size_t)t*256);
    const float4* gv = (const float4*)g2;
    float a = 0.0f;
#pragma unroll
    for (int qq = 0; qq < 64; ++qq) a = fma4(wr[qq], gv[qq], a);
    a += bl[t];
    if (t == 0 || t == 4 || t == 8) a += 1.0f;
    tm[t] = a;
  }
  __syncthreads();
  {
    const float* nx = new_xyz + ((size_t)b*NPp + t)*3;
    float X = nx[0], Y = nx[1], Z = nx[2];
#pragma unroll
    for (int i = 0; i < 3; ++i){
      float v = __fadd_rn(__fadd_rn(__fmul_rn(tm[i*3+0], X), __fmul_rn(tm[i*3+1], Y)), __fmul_rn(tm[i*3+2], Z));
      x131[((size_t)b*NPp + t)*132 + 128 + i] = v;
    }
  }
}

// ---------------- classifier head ----------------
__global__ __launch_bounds__(256) void k_final(const float* __restrict__ g128,
    const float* __restrict__ W0, const float* __restrict__ W1,
    const float* __restrict__ Wc, const float* __restrict__ bc, float* __restrict__ out){
  __shared__ __align__(16) float g0[128];
  __shared__ __align__(16) float g5[512];
  __shared__ __align__(16) float g2[256];
  int b = blockIdx.x, t = threadIdx.x;
  if (t < 128) g0[t] = g128[(size_t)b*128 + t];
  __syncthreads();
#pragma unroll
  for (int cc = 0; cc < 2; ++cc){
    int c = t + cc*256;
    const float4* wr = (const float4*)(W0 + (size_t)c*128);
    const float4* gv = (const float4*)g0;
    float a = 0.0f;
#pragma unroll
    for (int qq = 0; qq < 32; ++qq) a = fma4(wr[qq], gv[qq], a);
    g5[c] = fmaxf(a, 0.0f);
  }
  __syncthreads();
  {
    const float4* wr = (const float4*)(W1 + (size_t)t*512);
    const float4* gv = (const float4*)g5;
    float a = 0.0f;
    for (int qq = 0; qq < 128; ++qq) a = fma4(wr[qq], gv[qq], a);
    g2[t] = fmaxf(a, 0.0f);
  }
  __syncthreads();
  if (t < 40){
    const float4* wr = (const float4*)(Wc + (size_t)t*256);
    const float4* gv = (const float4*)g2;
    float a = 0.0f;
#pragma unroll
    for (int qq = 0; qq < 64; ++qq) a = fma4(wr[qq], gv[qq], a);
    out[(size_t)b*40 + t] = a + bc[t];
  }
}

extern "C" void kernel_launch(void* const* d_in, const int* in_sizes, int n_in,
                              void* d_out, int out_size, void* d_ws, size_t ws_size,
                              hipStream_t stream){
  (void)in_sizes; (void)n_in; (void)out_size; (void)ws_size;
  const float* points     = (const float*)d_in[0];
  const float* sa_w0      = (const float*)d_in[1];
  const float* sa_w1      = (const float*)d_in[2];
  const float* sa_w2      = (const float*)d_in[3];
  const float* t_ec_w0    = (const float*)d_in[4];
  const float* t_ec_w1    = (const float*)d_in[5];
  const float* t_local_w  = (const float*)d_in[6];
  const float* t_g_w0     = (const float*)d_in[7];
  const float* t_g_w1     = (const float*)d_in[8];
  const float* t_lin_w    = (const float*)d_in[9];
  const float* t_lin_b    = (const float*)d_in[10];
  const float* dg_ec_w0   = (const float*)d_in[11];
  const float* dg_ec_w1   = (const float*)d_in[12];
  const float* dg_ec_w2   = (const float*)d_in[13];
  const float* dg_local_w = (const float*)d_in[14];
  const float* dg_g_w0    = (const float*)d_in[15];
  const float* dg_g_w1    = (const float*)d_in[16];
  const float* cls_w      = (const float*)d_in[17];
  const float* cls_b      = (const float*)d_in[18];
  float* out = (float*)d_out;

  float* ws     = (float*)d_ws;
  float* xyz    = ws;                    // 393216
  float* xnrm   = xyz    + 393216;       // 131072
  float* nxyz   = xnrm   + 131072;       // 24576
  float* feat   = nxyz   + 24576;        // 1048576 (dead output buffer -> MFMA weight frags)
  float* x131   = feat   + 1048576;      // 1081344
  float* nrm    = x131   + 1081344;      // 8192
  int*   idx    = (int*)(nrm + 8192);    // 163840
  float* ht     = (float*)(idx + 163840);// 1048576 (reused as f1)
  float* g1024v = ht     + 1048576;      // 32768
  float* f2     = g1024v + 32768;        // 2097152
  float* f3     = f2     + 2097152;      // 4194304
  float* g128v  = f3     + 4194304;      // 4096
  float* wt_t1  = g128v  + 4096;         // 8192   (legacy, unwritten)
  float* waT0   = wt_t1  + 8192;         // 8384   (legacy, unwritten)
  float* wbT0   = waT0   + 8384;         // 8384
  float* waD0   = wbT0   + 8384;         // 16768
  float* wbD0   = waD0   + 16768;        // 16768
  float* waD1   = wbD0   + 16768;        // 32768
  float* wbD1   = waD1   + 32768;        // 32768
  float* waD2   = wbD1   + 32768;        // 131072
  float* wbD2   = waD2   + 131072;       // 131072
  float* Ab     = wbD2   + 131072;       // 4194304
  float* Bb     = Ab     + 4194304;      // 4194304
  float* w1Tb   = Bb     + 4194304;      // 4096   (legacy)
  float* f1 = ht;
  float* xT = f3;                        // alias: xT lives in f3 until k_emax<512> writes f3

  // SA MFMA weight fragments alias the HEAD of Ab.
  float* w0f    = Ab;                    // 4096   ([kt][lane][e][4])
  u16*   w1fh   = (u16*)(w0f + 4096);    // 4096 u16
  u16*   w1fl   = w1fh   + 4096;         // 4096 u16
  u16*   w2fh   = w1fl   + 4096;         // 8192 u16
  u16*   w2fl   = w2fh   + 8192;         // 8192 u16

  // All GEMM weight frags live in the DEAD `feat` buffer (4MB; nothing reads it).
  u16* fragu  = (u16*)feat;
  u16* wAD1h  = fragu;                   // 32768
  u16* wAD1l  = wAD1h + 32768;           // 32768
  u16* wBD1h  = wAD1l + 32768;           // 32768
  u16* wBD1l  = wBD1h + 32768;           // 32768
  u16* wAD2h  = wBD1l + 32768;           // 131072
  u16* wAD2l  = wAD2h + 131072;          // 131072
  u16* wBD2h  = wAD2l + 131072;          // 131072
  u16* wBD2l  = wBD2h + 131072;          // 131072
  u16* wTPh   = wBD2l + 131072;          // 131072 (t_local_w frags)
  u16* wTPl   = wTPh  + 131072;          // 131072
  u16* wDGh   = wTPl  + 131072;          // 114688 (dg_local_w frags)
  u16* wDGl   = wDGh  + 114688;          // 114688
  u16* wTEh   = wDGl  + 114688;          // 8192   (t_ec_w1 tedge frags)
  u16* wTEl   = wTEh  + 8192;            // 8192
  u16* wAT0h  = wTEl  + 8192;            // 10240  (padded t_ec_w0 A)
  u16* wAT0l  = wAT0h + 10240;           // 10240
  u16* wBT0h  = wAT0l + 10240;           // 10240
  u16* wBT0l  = wBT0h + 10240;           // 10240
  u16* wAD0h  = wBT0l + 10240;           // 20480  (padded dg_ec_w0 A)
  u16* wAD0l  = wAD0h + 20480;           // 20480
  u16* wBD0h  = wAD0l + 20480;           // 20480
  u16* wBD0l  = wBD0h + 20480;           // 20480

  k_prep_all<<<3088, 256, 0, stream>>>(points, xyz, xnrm,
                                       t_ec_w0, t_ec_w1, dg_ec_w0, dg_ec_w1, dg_ec_w2,
                                       sa_w0, sa_w1, sa_w2, t_local_w, dg_local_w,
                                       w0f, w1fh, w1fl, w2fh, w2fl,
                                       wAD1h, wAD1l, wBD1h, wBD1l, wAD2h, wAD2l, wBD2h, wBD2l,
                                       wTPh, wTPl, wDGh, wDGl, wTEh, wTEl,
                                       wAT0h, wAT0l, wBT0h, wBT0l, wAD0h, wAD0l, wBD0h, wBD0l);
  k_fps<<<BB, 128, 0, stream>>>(xyz, nxyz);
  k_sa<<<BB*NPp, 64, 0, stream>>>(points, xyz, xnrm, nxyz, w0f, w1fh, w1fl, w2fh, w2fl, x131);

  // T-Net branch (x = [feat, new_xyz]) -- MFMA with zero-padded K
  k_gabp<131,160,64><<<512, 512, 0, stream>>>(x131, 132, wAT0h, wAT0l, wBT0h, wBT0l, Ab, Bb, xT, nrm);
  k_knn3<131><<<1024, 512, 0, stream>>>(xT, nrm, idx);
  k_tedge3m<<<BB*NPp, 128, 0, stream>>>(Ab, Bb, idx, wTEh, wTEl, ht);
  k_tpoolm<<<dim3(BB, 16), 512, 0, stream>>>(ht, wTPh, wTPl, g1024v);
  k_trest<<<BB, 256, 0, stream>>>(g1024v, t_g_w0, t_g_w1, t_lin_w, t_lin_b, nxyz, x131);

  // DGCNN layer 1 -- MFMA with zero-padded K
  k_gabp<131,160,128><<<512, 512, 0, stream>>>(x131, 132, wAD0h, wAD0l, wBD0h, wBD0l, Ab, Bb, xT, nrm);
  k_knn3<131><<<1024, 512, 0, stream>>>(xT, nrm, idx);
  k_emax<128><<<1024, 256, 0, stream>>>(Ab, Bb, idx, f1);
  // layer 2 -- MFMA
  k_gabm<128,256><<<512, 512, 0, stream>>>(f1, 128, wAD1h, wAD1l, wBD1h, wBD1l, Ab, Bb, xT, nrm);
  k_knn3<128><<<1024, 512, 0, stream>>>(xT, nrm, idx);
  k_emax<256><<<2048, 256, 0, stream>>>(Ab, Bb, idx, f2);
  // layer 3 -- MFMA
  k_gabm<256,512><<<512, 512, 0, stream>>>(f2, 256, wAD2h, wAD2l, wBD2h, wBD2l, Ab, Bb, xT, nrm);
  k_knn3<256><<<1024, 512, 0, stream>>>(xT, nrm, idx);
  k_emax<512><<<4096, 256, 0, stream>>>(Ab, Bb, idx, f3);

  // local conv (MFMA) + global pool + head
  k_dglm<<<dim3(BB, 16), 512, 0, stream>>>(f1, f2, f3, wDGh, wDGl, g128v);
  k_final<<<BB, 256, 0, stream>>>(g128v, dg_g_w0, dg_g_w1, cls_w, cls_b, out);
}

// Round 15
// 809.260 us; speedup vs baseline: 1.7246x; 1.0004x over previous
//
#include <hip/hip_runtime.h>
#include <math.h>

#define BB 32
#define NN 4096
#define NPp 256
#define NSs 64
#define KC 20

typedef unsigned long long ull;
typedef unsigned short u16;
typedef short bf16x8 __attribute__((ext_vector_type(8)));
typedef float f32x4 __attribute__((ext_vector_type(4)));
typedef int i32x4 __attribute__((ext_vector_type(4)));

__device__ __forceinline__ float fma4(const float4 w, const float4 v, float a){
  a = fmaf(w.x, v.x, a); a = fmaf(w.y, v.y, a);
  a = fmaf(w.z, v.z, a); a = fmaf(w.w, v.w, a); return a;
}
__device__ __forceinline__ float4 fma4s(const float4 w, float s, float4 a){
  a.x = fmaf(w.x, s, a.x); a.y = fmaf(w.y, s, a.y);
  a.z = fmaf(w.z, s, a.z); a.w = fmaf(w.w, s, a.w); return a;
}
__device__ __forceinline__ float4 max4(float4 a, float4 b){
  a.x = fmaxf(a.x, b.x); a.y = fmaxf(a.y, b.y);
  a.z = fmaxf(a.z, b.z); a.w = fmaxf(a.w, b.w); return a;
}
__device__ __forceinline__ float4 add4(float4 a, float4 b){
  a.x += b.x; a.y += b.y; a.z += b.z; a.w += b.w; return a;
}

template<int C>
__device__ __forceinline__ int dpp_i(int x){
  return __builtin_amdgcn_update_dpp(x, x, C, 0xf, 0xf, false);
}

// split fp32 -> bf16 hi + bf16 lo (truncating; v - hi is exact in fp32)
__device__ __host__ __forceinline__ void bf16_split(float v, unsigned& h16, unsigned& l16){
  unsigned bits = __float_as_uint(v);
  h16 = bits >> 16;
  float hf = __uint_as_float(h16 << 16);
  l16 = __float_as_uint(v - hf) >> 16;
}

// ---------------- points transpose + norms (must complete BEFORE fps reads xyz) ----------------
__global__ void k_prep_pts(const float* __restrict__ pts, float* __restrict__ xyz, float* __restrict__ xnrm){
  int i = blockIdx.x*256 + threadIdx.x;
  if (i >= BB*NN) return;
  int b = i >> 12, n = i & (NN-1);
  float X = pts[(b*3+0)*NN + n];
  float Y = pts[(b*3+1)*NN + n];
  float Z = pts[(b*3+2)*NN + n];
  xyz[i*3+0]=X; xyz[i*3+1]=Y; xyz[i*3+2]=Z;
  xnrm[i] = __fadd_rn(__fadd_rn(__fmul_rn(X,X), __fmul_rn(Y,Y)), __fmul_rn(Z,Z));
}

// ---------------- MEGA: FPS (blocks [0,32)) + ALL weight-frag prep (blocks [32,5184)) ----------------
// FPS occupies only 32 blocks x 2 waves, idling 224/256 CUs for ~218us. Frag prep depends
// ONLY on weight inputs (not xyz), so its 5152 x 128-thread blocks co-schedule in the fps
// shadow -- the only graph-capture-legal overlap (streams/events banned). All frag section
// bodies are byte-identical to round-14, re-indexed at 128-thread granularity (every
// section size is a multiple of 128). fps body verbatim (all 128 threads -> syncthreads OK).
// Frag block map (bid-32): [0,128) SA; [128,2688) L2/3; [2688,3712) t_local;
// [3712,4608) dg_local; [4608,4672) tedge; [4672,5152) padded T0/D0.
__global__ __launch_bounds__(128, 1) void k_fpsprep(const float* __restrict__ xyz, float* __restrict__ new_xyz,
                           const float* __restrict__ t0, const float* __restrict__ t1,
                           const float* __restrict__ d0, const float* __restrict__ d1,
                           const float* __restrict__ d2,
                           const float* __restrict__ w0, const float* __restrict__ w1,
                           const float* __restrict__ w2,
                           const float* __restrict__ tl, const float* __restrict__ dgw,
                           float* __restrict__ w0f, u16* __restrict__ w1fh, u16* __restrict__ w1fl,
                           u16* __restrict__ w2fh, u16* __restrict__ w2fl,
                           u16* __restrict__ wAD1h, u16* __restrict__ wAD1l,
                           u16* __restrict__ wBD1h, u16* __restrict__ wBD1l,
                           u16* __restrict__ wAD2h, u16* __restrict__ wAD2l,
                           u16* __restrict__ wBD2h, u16* __restrict__ wBD2l,
                           u16* __restrict__ wTPh, u16* __restrict__ wTPl,
                           u16* __restrict__ wDGh, u16* __restrict__ wDGl,
                           u16* __restrict__ wTEh, u16* __restrict__ wTEl,
                           u16* __restrict__ wAT0h, u16* __restrict__ wAT0l,
                           u16* __restrict__ wBT0h, u16* __restrict__ wBT0l,
                           u16* __restrict__ wAD0h, u16* __restrict__ wAD0l,
                           u16* __restrict__ wBD0h, u16* __restrict__ wBD0l){
  if (blockIdx.x < 32){
    // ---------------- FPS body (verbatim; parked at its structural floor) ----------------
    __shared__ __align__(16) float lx[NN], ly[NN], lz[NN];
    __shared__ __align__(16) ull wkey[2][2];
    int b = blockIdx.x, t = threadIdx.x;
    int w = t >> 6, lane = t & 63;
    float nx[32], ny[32], nz[32], dist[32];
#pragma unroll
    for (int q = 0; q < 32; ++q){
      int j = q*128 + t;
      const float* p = xyz + ((size_t)b*NN + j)*3;
      float X = p[0], Y = p[1], Z = p[2];
      lx[j] = X; ly[j] = Y; lz[j] = Z;
      nx[q] = -X; ny[q] = -Y; nz[q] = -Z;
      dist[q] = __builtin_inff();
    }
    const float* p0 = xyz + (size_t)b*NN*3;
    float Px = p0[0], Py = p0[1], Pz = p0[2];
    __syncthreads();
    for (int it = 0; it < NPp; ++it){
      if (t == 0){
        float* o = new_xyz + ((size_t)b*NPp + it)*3;
        o[0] = Px; o[1] = Py; o[2] = Pz;
      }
      ull ka0 = 0, ka1 = 0, ka2 = 0, ka3 = 0;
#pragma unroll
      for (int q = 0; q < 32; ++q){
        float dx = __fadd_rn(nx[q], Px);
        float dy = __fadd_rn(ny[q], Py);
        float dz = __fadd_rn(nz[q], Pz);
        float dd = __fadd_rn(__fadd_rn(__fmul_rn(dx,dx), __fmul_rn(dy,dy)), __fmul_rn(dz,dz));
        float dm = fminf(dist[q], dd);
        dist[q] = dm;
        ull key = ((ull)__float_as_uint(dm) << 32) | (unsigned)(4095 - (q*128 + t));
        if      ((q & 3) == 0){ if (key > ka0) ka0 = key; }
        else if ((q & 3) == 1){ if (key > ka1) ka1 = key; }
        else if ((q & 3) == 2){ if (key > ka2) ka2 = key; }
        else                  { if (key > ka3) ka3 = key; }
      }
      ull kb0 = (ka0 > ka1) ? ka0 : ka1;
      ull kb1 = (ka2 > ka3) ? ka2 : ka3;
      ull bk  = (kb0 > kb1) ? kb0 : kb1;
#define FPS_STAGE(C) { \
      unsigned ol = (unsigned)dpp_i<C>((int)(unsigned)bk); \
      unsigned oh = (unsigned)dpp_i<C>((int)(unsigned)(bk >> 32)); \
      ull ok = ((ull)oh << 32) | ol; \
      if (ok > bk) bk = ok; }
      FPS_STAGE(0x111) FPS_STAGE(0x112) FPS_STAGE(0x114) FPS_STAGE(0x118)
      FPS_STAGE(0x142) FPS_STAGE(0x143)
#undef FPS_STAGE
      int par = it & 1;
      if (lane == 63) wkey[par][w] = bk;
      __syncthreads();
      ull k0 = wkey[par][0], k1 = wkey[par][1];
      ull kw = (k0 > k1) ? k0 : k1;
      int idx = 4095 - (int)(unsigned)(kw & 0xFFFFFFFFu);
      Px = lx[idx]; Py = ly[idx]; Pz = lz[idx];
    }
    return;
  }
  // ---------------- frag prep (independent of xyz; fills idle CUs during FPS) ----------------
  int bid = blockIdx.x - 32;
  if (bid < 128){                        // ---- SA frags (16384 elems) ----
    int i = bid*128 + threadIdx.x;
    if (i < 4096){                       // w0f: [kt][lane][e][4] (xyz + pad)
      int kt = i >> 11, r = i & 2047;
      int ln = r >> 5, ee = r & 31;
      int e = ee >> 2, j = ee & 3;
      int k = kt*32 + 8*(ln>>4) + e;
      w0f[i] = (j < 3) ? w0[k*3 + j] : 0.0f;
      return;
    }
    i -= 4096;
    if (i < 4096){                       // w1 frags
      int e = i & 7, ln = (i >> 3) & 63, q = i >> 9;
      int kt = q & 1, ct = q >> 1;
      int k = kt*32 + 8*(ln>>4) + e;
      int c = ct*16 + (ln & 15);
      unsigned h16, l16; bf16_split(w1[(size_t)c*64 + k], h16, l16);
      w1fh[i] = (u16)h16; w1fl[i] = (u16)l16;
      return;
    }
    i -= 4096;
    if (i < 8192){                       // w2 frags
      int e = i & 7, ln = (i >> 3) & 63, q = i >> 9;
      int kt = q & 1, c2t = q >> 1;
      int k = kt*32 + 8*(ln>>4) + e;
      int c2 = c2t*16 + (ln & 15);
      unsigned h16, l16; bf16_split(w2[(size_t)c2*64 + k], h16, l16);
      w2fh[i] = (u16)h16; w2fl[i] = (u16)l16;
    }
    return;
  }
  if (bid < 2688){                       // ---- layer-2/3 GEMM weight frags (327680 elems) ----
    int i = (bid-128)*128 + threadIdx.x;
    if (i < 32768){                      // D1 wA: [ct(16)][kt(4)][lane][e]
      int e = i & 7, ln = (i >> 3) & 63, q = i >> 9;
      int kt = q & 3, ct = q >> 2;
      int k = kt*32 + 8*(ln>>4) + e;
      int c = ct*16 + (ln & 15);
      float bb = d1[(size_t)c*256 + k], dd = d1[(size_t)c*256 + 128 + k];
      unsigned h, l; bf16_split(__fsub_rn(bb, dd), h, l);
      wAD1h[i] = (u16)h; wAD1l[i] = (u16)l;
      return;
    }
    i -= 32768;
    if (i < 32768){                      // D1 wB
      int e = i & 7, ln = (i >> 3) & 63, q = i >> 9;
      int kt = q & 3, ct = q >> 2;
      int k = kt*32 + 8*(ln>>4) + e;
      int c = ct*16 + (ln & 15);
      float dd = d1[(size_t)c*256 + 128 + k];
      unsigned h, l; bf16_split(dd, h, l);
      wBD1h[i] = (u16)h; wBD1l[i] = (u16)l;
      return;
    }
    i -= 32768;
    if (i < 131072){                     // D2 wA: [ct(32)][kt(8)][lane][e]
      int e = i & 7, ln = (i >> 3) & 63, q = i >> 9;
      int kt = q & 7, ct = q >> 3;
      int k = kt*32 + 8*(ln>>4) + e;
      int c = ct*16 + (ln & 15);
      float bb = d2[(size_t)c*512 + k], dd = d2[(size_t)c*512 + 256 + k];
      unsigned h, l; bf16_split(__fsub_rn(bb, dd), h, l);
      wAD2h[i] = (u16)h; wAD2l[i] = (u16)l;
      return;
    }
    i -= 131072;
    if (i < 131072){                     // D2 wB
      int e = i & 7, ln = (i >> 3) & 63, q = i >> 9;
      int kt = q & 7, ct = q >> 3;
      int k = kt*32 + 8*(ln>>4) + e;
      int c = ct*16 + (ln & 15);
      float dd = d2[(size_t)c*512 + 256 + k];
      unsigned h, l; bf16_split(dd, h, l);
      wBD2h[i] = (u16)h; wBD2l[i] = (u16)l;
    }
    return;
  }
  if (bid < 3712){                       // ---- t_local_w frags (131072 elems) ----
    int i = (bid-2688)*128 + threadIdx.x;
    int e = i & 7, ln = (i >> 3) & 63, q = i >> 9;
    int kt = q & 3, ct = q >> 2;
    int k = kt*32 + 8*(ln>>4) + e;
    int c = ct*16 + (ln & 15);
    unsigned h, l; bf16_split(tl[(size_t)c*128 + k], h, l);
    wTPh[i] = (u16)h; wTPl[i] = (u16)l;
    return;
  }
  if (bid < 4608){                       // ---- dg_local_w frags (114688 elems) ----
    int i = (bid-3712)*128 + threadIdx.x;
    if (i >= 114688) return;
    int e = i & 7, ln = (i >> 3) & 63, q = i >> 9;
    int kt = q % 28, ct = q / 28;
    int k = kt*32 + 8*(ln>>4) + e;
    int c = ct*16 + (ln & 15);
    unsigned h, l; bf16_split(dgw[(size_t)c*896 + k], h, l);
    wDGh[i] = (u16)h; wDGl[i] = (u16)l;
    return;
  }
  if (bid < 4672){                       // ---- t_ec_w1 (tedge) frags (8192 elems) ----
    int i = (bid-4608)*128 + threadIdx.x;
    int e = i & 7, ln = (i >> 3) & 63, q = i >> 9;
    int kt = q & 1, ct = q >> 1;
    int k = kt*32 + 8*(ln>>4) + e;
    int c = ct*16 + (ln & 15);
    unsigned h, l; bf16_split(t1[(size_t)c*64 + k], h, l);
    wTEh[i] = (u16)h; wTEl[i] = (u16)l;
    return;
  }
  {                                      // ---- PADDED t_ec_w0 / dg_ec_w0 frags (61440 elems) ----
    int i = (bid-4672)*128 + threadIdx.x;
    if (i < 10240){                      // T0 wA: [ct(4)][kt(5)][lane][e]
      int e = i & 7, ln = (i >> 3) & 63, q = i >> 9;
      int kt = q % 5, ct = q / 5;
      int k = kt*32 + 8*(ln>>4) + e;
      int c = ct*16 + (ln & 15);
      float v = 0.0f;
      if (k < 131) v = __fsub_rn(t0[(size_t)c*262 + k], t0[(size_t)c*262 + 131 + k]);
      unsigned h, l; bf16_split(v, h, l);
      wAT0h[i] = (u16)h; wAT0l[i] = (u16)l;
      return;
    }
    i -= 10240;
    if (i < 10240){                      // T0 wB
      int e = i & 7, ln = (i >> 3) & 63, q = i >> 9;
      int kt = q % 5, ct = q / 5;
      int k = kt*32 + 8*(ln>>4) + e;
      int c = ct*16 + (ln & 15);
      float v = (k < 131) ? t0[(size_t)c*262 + 131 + k] : 0.0f;
      unsigned h, l; bf16_split(v, h, l);
      wBT0h[i] = (u16)h; wBT0l[i] = (u16)l;
      return;
    }
    i -= 10240;
    if (i < 20480){                      // D0 wA: [ct(8)][kt(5)][lane][e]
      int e = i & 7, ln = (i >> 3) & 63, q = i >> 9;
      int kt = q % 5, ct = q / 5;
      int k = kt*32 + 8*(ln>>4) + e;
      int c = ct*16 + (ln & 15);
      float v = 0.0f;
      if (k < 131) v = __fsub_rn(d0[(size_t)c*262 + k], d0[(size_t)c*262 + 131 + k]);
      unsigned h, l; bf16_split(v, h, l);
      wAD0h[i] = (u16)h; wAD0l[i] = (u16)l;
      return;
    }
    i -= 20480;
    if (i < 20480){                      // D0 wB
      int e = i & 7, ln = (i >> 3) & 63, q = i >> 9;
      int kt = q % 5, ct = q / 5;
      int k = kt*32 + 8*(ln>>4) + e;
      int c = ct*16 + (ln & 15);
      float v = (k < 131) ? d0[(size_t)c*262 + 131 + k] : 0.0f;
      unsigned h, l; bf16_split(v, h, l);
      wBD0h[i] = (u16)h; wBD0l[i] = (u16)l;
    }
  }
}

// ---------------- ball query + SA convs + maxpool: MFMA split-bf16 ----------------
__global__ __launch_bounds__(64) void k_sa(const float* __restrict__ pts,
    const float* __restrict__ xyz, const float* __restrict__ xnrm,
    const float* __restrict__ new_xyz, const float* __restrict__ w0f,
    const u16* __restrict__ w1fh, const u16* __restrict__ w1fl,
    const u16* __restrict__ w2fh, const u16* __restrict__ w2fl,
    float* __restrict__ x131){
  __shared__ __align__(16) u16 hh[64*64];
  __shared__ __align__(16) u16 hl[64*64];
  __shared__ int gw[64];
  int bi = blockIdx.x;
  int lane = threadIdx.x;
  int b = bi >> 8;
  const float* q = new_xyz + (size_t)bi*3;
  float qx=q[0], qy=q[1], qz=q[2];
  float nq = __fadd_rn(__fadd_rn(__fmul_rn(qx,qx), __fmul_rn(qy,qy)), __fmul_rn(qz,qz));
  const float* pX = pts + (size_t)(b*3+0)*NN;
  const float* pY = pts + (size_t)(b*3+1)*NN;
  const float* pZ = pts + (size_t)(b*3+2)*NN;
  int cnt = 0;
  for (int base = 0; base < NN && cnt < NSs; base += 256){
#pragma unroll
    for (int u = 0; u < 4; ++u){
      int j = base + u*64 + lane;
      float X = pX[j], Y = pY[j], Z = pZ[j];
      float dot = __fadd_rn(__fadd_rn(__fmul_rn(qx,X), __fmul_rn(qy,Y)), __fmul_rn(qz,Z));
      float d2 = __fsub_rn(__fadd_rn(nq, xnrm[b*NN + j]), __fmul_rn(2.0f, dot));
      bool inb = d2 < 0.04f;
      unsigned long long m = __ballot(inb);
      int pos = cnt + (int)__popcll(m & ((1ull << lane) - 1ull));
      if (inb && pos < NSs) gw[pos] = j;
      cnt += (int)__popcll(m);
    }
  }
  int g0 = gw[0];
  if (lane >= cnt) gw[lane] = g0;
  int gj = gw[lane];
  const float* pp = xyz + ((size_t)b*NN + gj)*3;
  float px = pp[0]-qx, py = pp[1]-qy, pz = pp[2]-qz;
  int col = lane & 15, g = lane >> 4;
  float sxv[4], syv[4], szv[4];
#pragma unroll
  for (int t2 = 0; t2 < 4; ++t2){
    int src = col + 16*t2;
    sxv[t2] = __shfl(px, src);
    syv[t2] = __shfl(py, src);
    szv[t2] = __shfl(pz, src);
  }
  i32x4 ah0[4][2], al0[4][2];
#pragma unroll
  for (int kt = 0; kt < 2; ++kt){
    float4 wrow[8];
    const float4* wp = (const float4*)(w0f + (size_t)(kt*64 + lane)*32);
#pragma unroll
    for (int e = 0; e < 8; ++e) wrow[e] = wp[e];
#pragma unroll
    for (int t2 = 0; t2 < 4; ++t2){
      unsigned hu[8], lu[8];
#pragma unroll
      for (int e = 0; e < 8; ++e){
        float a = fmaf(wrow[e].z, szv[t2], fmaf(wrow[e].y, syv[t2], wrow[e].x*sxv[t2]));
        a = fmaxf(a, 0.0f);
        bf16_split(a, hu[e], lu[e]);
      }
      i32x4 H, L;
#pragma unroll
      for (int j2 = 0; j2 < 4; ++j2){
        H[j2] = (int)(hu[2*j2] | (hu[2*j2+1] << 16));
        L[j2] = (int)(lu[2*j2] | (lu[2*j2+1] << 16));
      }
      ah0[t2][kt] = H; al0[t2][kt] = L;
    }
  }
#pragma unroll
  for (int ct = 0; ct < 4; ++ct){
    bf16x8 bh[2], bl[2];
#pragma unroll
    for (int kt = 0; kt < 2; ++kt){
      bh[kt] = *(const bf16x8*)(w1fh + (size_t)((ct*2+kt)*64 + lane)*8);
      bl[kt] = *(const bf16x8*)(w1fl + (size_t)((ct*2+kt)*64 + lane)*8);
    }
#pragma unroll
    for (int t2 = 0; t2 < 4; ++t2){
      f32x4 acc = {0.f,0.f,0.f,0.f};
#pragma unroll
      for (int kt = 0; kt < 2; ++kt){
        bf16x8 Ah = __builtin_bit_cast(bf16x8, ah0[t2][kt]);
        bf16x8 Al = __builtin_bit_cast(bf16x8, al0[t2][kt]);
        acc = __builtin_amdgcn_mfma_f32_16x16x32_bf16(Ah, bh[kt], acc, 0, 0, 0);
        acc = __builtin_amdgcn_mfma_f32_16x16x32_bf16(Ah, bl[kt], acc, 0, 0, 0);
        acc = __builtin_amdgcn_mfma_f32_16x16x32_bf16(Al, bh[kt], acc, 0, 0, 0);
      }
#pragma unroll
      for (int r = 0; r < 4; ++r){
        float v = fmaxf(acc[r], 0.0f);
        int s = 16*t2 + 4*g + r;
        int cc = ct*16 + col;
        int idx = s*64 + (cc ^ ((s & 7) << 3));
        unsigned h16, l16; bf16_split(v, h16, l16);
        hh[idx] = (u16)h16; hl[idx] = (u16)l16;
      }
    }
  }
  bf16x8 a1h[4][2], a1l[4][2];
#pragma unroll
  for (int t2 = 0; t2 < 4; ++t2){
    int s = col + 16*t2;
    int sw = (s & 7) << 3;
#pragma unroll
    for (int kt = 0; kt < 2; ++kt){
      int k0 = kt*32 + 8*g;
      int idx = s*64 + (k0 ^ sw);
      a1h[t2][kt] = *(const bf16x8*)(hh + idx);
      a1l[t2][kt] = *(const bf16x8*)(hl + idx);
    }
  }
#pragma unroll
  for (int c2t = 0; c2t < 8; ++c2t){
    bf16x8 bh2[2], bl2[2];
#pragma unroll
    for (int kt = 0; kt < 2; ++kt){
      bh2[kt] = *(const bf16x8*)(w2fh + (size_t)((c2t*2+kt)*64 + lane)*8);
      bl2[kt] = *(const bf16x8*)(w2fl + (size_t)((c2t*2+kt)*64 + lane)*8);
    }
    float mx = 0.0f;
#pragma unroll
    for (int t2 = 0; t2 < 4; ++t2){
      f32x4 acc = {0.f,0.f,0.f,0.f};
#pragma unroll
      for (int kt = 0; kt < 2; ++kt){
        acc = __builtin_amdgcn_mfma_f32_16x16x32_bf16(a1h[t2][kt], bh2[kt], acc, 0, 0, 0);
        acc = __builtin_amdgcn_mfma_f32_16x16x32_bf16(a1h[t2][kt], bl2[kt], acc, 0, 0, 0);
        acc = __builtin_amdgcn_mfma_f32_16x16x32_bf16(a1l[t2][kt], bh2[kt], acc, 0, 0, 0);
      }
      mx = fmaxf(mx, fmaxf(fmaxf(acc[0], acc[1]), fmaxf(acc[2], acc[3])));
    }
    mx = fmaxf(mx, __shfl_xor(mx, 16));
    mx = fmaxf(mx, __shfl_xor(mx, 32));
    if (lane < 16){
      int c = c2t*16 + lane;
      x131[(size_t)bi*132 + c] = mx;
    }
  }
  if (lane < 3) x131[(size_t)bi*132 + 128 + lane] = (lane==0)?qx:((lane==1)?qy:qz);
}

// ---------------- kNN: distances in registers, u64-DPP selection, no selection LDS ----------------
template<int CIN>
__global__ __launch_bounds__(512) void k_knn3(const float* __restrict__ xT,
    const float* __restrict__ nrm, int* __restrict__ idxo){
  __shared__ __align__(16) float sch[16*256];
  int bi = blockIdx.x, t = threadIdx.x;
  int w = t >> 6, lane = t & 63;
  int b = bi >> 5;
  int coli = (bi & 31)*8 + w;
  const float* xb = xT + (size_t)b*CIN*256;
  float d0=0.f, d1=0.f, d2=0.f, d3=0.f;
  for (int m0 = 0; m0 < CIN; m0 += 16){
    int mc = (CIN - m0 < 16) ? (CIN - m0) : 16;
    for (int i = t; i < mc*64; i += 512){
      int mm = i >> 6, c4 = i & 63;
      *(float4*)(sch + mm*256 + c4*4) = *(const float4*)(xb + (size_t)(m0+mm)*256 + c4*4);
    }
    __syncthreads();
    for (int mm = 0; mm < mc; ++mm){
      float xm = sch[mm*256 + coli];
      float4 v = *(const float4*)(sch + mm*256 + 4*lane);
      d0 = fmaf(v.x, xm, d0); d1 = fmaf(v.y, xm, d1);
      d2 = fmaf(v.z, xm, d2); d3 = fmaf(v.w, xm, d3);
    }
    __syncthreads();
  }
  float ni = nrm[b*256 + coli];
  float4 dv;
  {
    int j0 = 4*lane;
    dv.x = __fsub_rn(__fadd_rn(ni, nrm[b*256 + j0+0]), __fmul_rn(2.0f, d0));
    dv.y = __fsub_rn(__fadd_rn(ni, nrm[b*256 + j0+1]), __fmul_rn(2.0f, d1));
    dv.z = __fsub_rn(__fadd_rn(ni, nrm[b*256 + j0+2]), __fmul_rn(2.0f, d2));
    dv.w = __fsub_rn(__fadd_rn(ni, nrm[b*256 + j0+3]), __fmul_rn(2.0f, d3));
  }
  for (int r = 0; r < KC; ++r){
    float bv = 3.4e38f; int bj = NPp;
    if (dv.x < bv){ bv = dv.x; bj = 4*lane+0; }
    if (dv.y < bv){ bv = dv.y; bj = 4*lane+1; }
    if (dv.z < bv){ bv = dv.z; bj = 4*lane+2; }
    if (dv.w < bv){ bv = dv.w; bj = 4*lane+3; }
    unsigned xf = __float_as_uint(bv);
    xf = (xf & 0x80000000u) ? ~xf : (xf | 0x80000000u);
    ull key = ((ull)xf << 32) | (unsigned)bj;
#define KN_STAGE(C) { \
    unsigned ol = (unsigned)dpp_i<C>((int)(unsigned)key); \
    unsigned oh = (unsigned)dpp_i<C>((int)(unsigned)(key >> 32)); \
    ull ok = ((ull)oh << 32) | ol; \
    if (ok < key) key = ok; }
    KN_STAGE(0x111) KN_STAGE(0x112) KN_STAGE(0x114) KN_STAGE(0x118)
    KN_STAGE(0x142) KN_STAGE(0x143)
#undef KN_STAGE
    int bjw = __builtin_amdgcn_readlane((int)(unsigned)key, 63);
    if (lane == 0) idxo[((size_t)b*256 + coli)*KC + r] = bjw;
    if ((bjw >> 2) == lane){
      int e = bjw & 3;
      if      (e == 0) dv.x = 3.0e38f;
      else if (e == 1) dv.y = 3.0e38f;
      else if (e == 2) dv.z = 3.0e38f;
      else             dv.w = 3.0e38f;
    }
  }
}

// ---------------- per-point dual GEMM via MFMA split-bf16 (CIN multiple of 32) ----------------
template<int CIN, int COUT>
__global__ __launch_bounds__(512) void k_gabm(const float* __restrict__ x, int xstride,
    const u16* __restrict__ wAh, const u16* __restrict__ wAl,
    const u16* __restrict__ wBh, const u16* __restrict__ wBl,
    float* __restrict__ A, float* __restrict__ B, float* __restrict__ xT,
    float* __restrict__ nrm){
  constexpr int PC  = CIN + 1;
  constexpr int KT  = CIN / 32;
  constexpr int CT  = COUT / 16;
  constexpr int TPW = 2*CT/8;
  constexpr int KB  = CIN / 8;
  __shared__ float xsh[16*PC];
  __shared__ __align__(16) u16 axh[16*CIN];
  __shared__ __align__(16) u16 axl[16*CIN];
  int bi = blockIdx.x, t = threadIdx.x;
  int i0 = bi*16;
  for (int i = t; i < 16*CIN; i += 512){
    int r = i / CIN, m = i - r*CIN;
    xsh[r*PC + m] = x[(size_t)(i0+r)*xstride + m];
  }
  __syncthreads();
  {
    int bb = i0 >> 8, col0 = i0 & 255;
    float* xTb = xT + (size_t)bb*CIN*256 + col0;
    for (int i = t; i < 16*CIN; i += 512){
      int m = i >> 4, r = i & 15;
      xTb[m*256 + r] = xsh[r*PC + m];
    }
  }
  if (t < 16){
    const float* xr = xsh + t*PC;
    float a = 0.0f;
    for (int m = 0; m < CIN; ++m) a = __fadd_rn(a, __fmul_rn(xr[m], xr[m]));
    nrm[i0 + t] = a;
  }
  if (t < 16*KB){
    int r = t / KB, kb = t - r*KB;
    unsigned hu[8], lu[8];
#pragma unroll
    for (int e = 0; e < 8; ++e) bf16_split(xsh[r*PC + kb*8 + e], hu[e], lu[e]);
    i32x4 H, L;
#pragma unroll
    for (int j2 = 0; j2 < 4; ++j2){
      H[j2] = (int)(hu[2*j2] | (hu[2*j2+1] << 16));
      L[j2] = (int)(lu[2*j2] | (lu[2*j2+1] << 16));
    }
    int idx = r*CIN + ((kb ^ (r & 7)) << 3);
    *(bf16x8*)(axh + idx) = __builtin_bit_cast(bf16x8, H);
    *(bf16x8*)(axl + idx) = __builtin_bit_cast(bf16x8, L);
  }
  __syncthreads();
  int lane = t & 63, wid = t >> 6;
  int col = lane & 15, g = lane >> 4;
  int aswz = col & 7;
#pragma unroll
  for (int tt = 0; tt < TPW; ++tt){
    int tile = wid*TPW + tt;
    bool isB = tile >= CT;
    int ct = isB ? tile - CT : tile;
    const u16* Wh = isB ? wBh : wAh;
    const u16* Wl = isB ? wBl : wAl;
    float* Out = isB ? B : A;
    f32x4 acc = {0.f,0.f,0.f,0.f};
#pragma unroll
    for (int kt = 0; kt < KT; ++kt){
      int kb = kt*4 + g;
      int aidx = col*CIN + ((kb ^ aswz) << 3);
      bf16x8 Ah = *(const bf16x8*)(axh + aidx);
      bf16x8 Al = *(const bf16x8*)(axl + aidx);
      size_t wo = ((size_t)(ct*KT + kt)*64 + lane)*8;
      bf16x8 Bh = *(const bf16x8*)(Wh + wo);
      bf16x8 Bl = *(const bf16x8*)(Wl + wo);
      acc = __builtin_amdgcn_mfma_f32_16x16x32_bf16(Ah, Bh, acc, 0, 0, 0);
      acc = __builtin_amdgcn_mfma_f32_16x16x32_bf16(Ah, Bl, acc, 0, 0, 0);
      acc = __builtin_amdgcn_mfma_f32_16x16x32_bf16(Al, Bh, acc, 0, 0, 0);
    }
#pragma unroll
    for (int r = 0; r < 4; ++r){
      Out[(size_t)(i0 + 4*g + r)*COUT + ct*16 + col] = acc[r];
    }
  }
}

// ---------------- per-point dual GEMM via MFMA, K zero-padded (CIN=131 -> CINP=160) ----------------
template<int CIN, int CINP, int COUT>
__global__ __launch_bounds__(512) void k_gabp(const float* __restrict__ x, int xstride,
    const u16* __restrict__ wAh, const u16* __restrict__ wAl,
    const u16* __restrict__ wBh, const u16* __restrict__ wBl,
    float* __restrict__ A, float* __restrict__ B, float* __restrict__ xT,
    float* __restrict__ nrm){
  constexpr int PC  = CIN + 1;
  constexpr int KT  = CINP / 32;       // 5
  constexpr int CT  = COUT / 16;
  constexpr int TPW = 2*CT/8;          // 1 (COUT=64) or 2 (COUT=128)
  constexpr int KB  = CINP / 8;        // 20
  __shared__ float xsh[16*PC];
  __shared__ __align__(16) u16 axh[16*CINP];
  __shared__ __align__(16) u16 axl[16*CINP];
  int bi = blockIdx.x, t = threadIdx.x;
  int i0 = bi*16;
  for (int i = t; i < 16*CIN; i += 512){
    int r = i / CIN, m = i - r*CIN;
    xsh[r*PC + m] = x[(size_t)(i0+r)*xstride + m];
  }
  __syncthreads();
  {
    int bb = i0 >> 8, col0 = i0 & 255;
    float* xTb = xT + (size_t)bb*CIN*256 + col0;
    for (int i = t; i < 16*CIN; i += 512){
      int m = i >> 4, r = i & 15;
      xTb[m*256 + r] = xsh[r*PC + m];
    }
  }
  if (t < 16){
    const float* xr = xsh + t*PC;
    float a = 0.0f;
    for (int m = 0; m < CIN; ++m) a = __fadd_rn(a, __fmul_rn(xr[m], xr[m]));
    nrm[i0 + t] = a;
  }
  if (t < 16*KB){
    int r = t / KB, kb = t - r*KB;
    unsigned hu[8], lu[8];
#pragma unroll
    for (int e = 0; e < 8; ++e){
      int m = kb*8 + e;
      float v = (m < CIN) ? xsh[r*PC + m] : 0.0f;
      bf16_split(v, hu[e], lu[e]);
    }
    i32x4 H, L;
#pragma unroll
    for (int j2 = 0; j2 < 4; ++j2){
      H[j2] = (int)(hu[2*j2] | (hu[2*j2+1] << 16));
      L[j2] = (int)(lu[2*j2] | (lu[2*j2+1] << 16));
    }
    int idx = r*CINP + ((kb ^ (r & 3)) << 3);
    *(bf16x8*)(axh + idx) = __builtin_bit_cast(bf16x8, H);
    *(bf16x8*)(axl + idx) = __builtin_bit_cast(bf16x8, L);
  }
  __syncthreads();
  int lane = t & 63, wid = t >> 6;
  int col = lane & 15, g = lane >> 4;
  int aswz = col & 3;
#pragma unroll
  for (int tt = 0; tt < TPW; ++tt){
    int tile = wid*TPW + tt;
    bool isB = tile >= CT;
    int ct = isB ? tile - CT : tile;
    const u16* Wh = isB ? wBh : wAh;
    const u16* Wl = isB ? wBl : wAl;
    float* Out = isB ? B : A;
    f32x4 acc = {0.f,0.f,0.f,0.f};
#pragma unroll
    for (int kt = 0; kt < KT; ++kt){
      int kb = kt*4 + g;
      int aidx = col*CINP + ((kb ^ aswz) << 3);
      bf16x8 Ah = *(const bf16x8*)(axh + aidx);
      bf16x8 Al = *(const bf16x8*)(axl + aidx);
      size_t wo = ((size_t)(ct*KT + kt)*64 + lane)*8;
      bf16x8 Bh = *(const bf16x8*)(Wh + wo);
      bf16x8 Bl = *(const bf16x8*)(Wl + wo);
      acc = __builtin_amdgcn_mfma_f32_16x16x32_bf16(Ah, Bh, acc, 0, 0, 0);
      acc = __builtin_amdgcn_mfma_f32_16x16x32_bf16(Ah, Bl, acc, 0, 0, 0);
      acc = __builtin_amdgcn_mfma_f32_16x16x32_bf16(Al, Bh, acc, 0, 0, 0);
    }
#pragma unroll
    for (int r = 0; r < 4; ++r){
      Out[(size_t)(i0 + 4*g + r)*COUT + ct*16 + col] = acc[r];
    }
  }
}

// ---------------- T-Net 128->1024 GEMM + pool via MFMA split-bf16 ----------------
__global__ __launch_bounds__(512) void k_tpoolm(const float* __restrict__ h,
    const u16* __restrict__ Wh, const u16* __restrict__ Wl, float* __restrict__ g1024){
  __shared__ __align__(16) u16 ahh[16*128];
  __shared__ __align__(16) u16 ahl[16*128];
  int b = blockIdx.x, i0 = blockIdx.y*16;
  int t = threadIdx.x;
  if (t < 256){
    int r = t >> 4, kb = t & 15;
    const float* hr = h + ((size_t)b*NPp + i0 + r)*128 + kb*8;
    unsigned hu[8], lu[8];
#pragma unroll
    for (int e = 0; e < 8; ++e) bf16_split(hr[e], hu[e], lu[e]);
    i32x4 H, L;
#pragma unroll
    for (int j2 = 0; j2 < 4; ++j2){
      H[j2] = (int)(hu[2*j2] | (hu[2*j2+1] << 16));
      L[j2] = (int)(lu[2*j2] | (lu[2*j2+1] << 16));
    }
    int idx = r*128 + ((kb ^ (r & 7)) << 3);
    *(bf16x8*)(ahh + idx) = __builtin_bit_cast(bf16x8, H);
    *(bf16x8*)(ahl + idx) = __builtin_bit_cast(bf16x8, L);
  }
  __syncthreads();
  int lane = t & 63, wid = t >> 6;
  int col = lane & 15, g = lane >> 4;
  int aswz = col & 7;
#pragma unroll
  for (int tt = 0; tt < 8; ++tt){
    int ct = wid*8 + tt;
    f32x4 acc = {0.f,0.f,0.f,0.f};
#pragma unroll
    for (int kt = 0; kt < 4; ++kt){
      int kb = kt*4 + g;
      int aidx = col*128 + ((kb ^ aswz) << 3);
      bf16x8 Ah = *(const bf16x8*)(ahh + aidx);
      bf16x8 Al = *(const bf16x8*)(ahl + aidx);
      size_t wo = ((size_t)(ct*4 + kt)*64 + lane)*8;
      bf16x8 Bh = *(const bf16x8*)(Wh + wo);
      bf16x8 Bl = *(const bf16x8*)(Wl + wo);
      acc = __builtin_amdgcn_mfma_f32_16x16x32_bf16(Ah, Bh, acc, 0, 0, 0);
      acc = __builtin_amdgcn_mfma_f32_16x16x32_bf16(Ah, Bl, acc, 0, 0, 0);
      acc = __builtin_amdgcn_mfma_f32_16x16x32_bf16(Al, Bh, acc, 0, 0, 0);
    }
    float mx = fmaxf(fmaxf(acc[0], acc[1]), fmaxf(acc[2], acc[3]));
    mx = fmaxf(mx, 0.0f);
    mx = fmaxf(mx, __shfl_xor(mx, 16));
    mx = fmaxf(mx, __shfl_xor(mx, 32));
    if (lane < 16) atomicMax((int*)(g1024 + (size_t)b*1024 + ct*16 + lane), __float_as_int(mx));
  }
}

// ---------------- 896->128 conv + global pool via MFMA split-bf16 ----------------
__global__ __launch_bounds__(512) void k_dglm(const float* __restrict__ f1, const float* __restrict__ f2,
    const float* __restrict__ f3, const u16* __restrict__ Wh, const u16* __restrict__ Wl,
    float* __restrict__ g128){
  __shared__ __align__(16) u16 ahh[16*896];
  __shared__ __align__(16) u16 ahl[16*896];
  int b = blockIdx.x, i0 = blockIdx.y*16;
  int t = threadIdx.x;
  for (int i = t; i < 16*112; i += 512){
    int r = i / 112, kb = i - r*112;
    int k0 = kb*8;
    const float* src;
    if (k0 < 128)      src = f1 + ((size_t)b*NPp + i0 + r)*128 + k0;
    else if (k0 < 384) src = f2 + ((size_t)b*NPp + i0 + r)*256 + (k0-128);
    else               src = f3 + ((size_t)b*NPp + i0 + r)*512 + (k0-384);
    unsigned hu[8], lu[8];
#pragma unroll
    for (int e = 0; e < 8; ++e) bf16_split(src[e], hu[e], lu[e]);
    i32x4 H, L;
#pragma unroll
    for (int j2 = 0; j2 < 4; ++j2){
      H[j2] = (int)(hu[2*j2] | (hu[2*j2+1] << 16));
      L[j2] = (int)(lu[2*j2] | (lu[2*j2+1] << 16));
    }
    int idx = r*896 + ((kb ^ (r & 7)) << 3);
    *(bf16x8*)(ahh + idx) = __builtin_bit_cast(bf16x8, H);
    *(bf16x8*)(ahl + idx) = __builtin_bit_cast(bf16x8, L);
  }
  __syncthreads();
  int lane = t & 63, wid = t >> 6;
  int col = lane & 15, g = lane >> 4;
  int aswz = col & 7;
  f32x4 acc = {0.f,0.f,0.f,0.f};
#pragma unroll
  for (int kt = 0; kt < 28; ++kt){
    int kb = kt*4 + g;
    int aidx = col*896 + ((kb ^ aswz) << 3);
    bf16x8 Ah = *(const bf16x8*)(ahh + aidx);
    bf16x8 Al = *(const bf16x8*)(ahl + aidx);
    size_t wo = ((size_t)(wid*28 + kt)*64 + lane)*8;
    bf16x8 Bh = *(const bf16x8*)(Wh + wo);
    bf16x8 Bl = *(const bf16x8*)(Wl + wo);
    acc = __builtin_amdgcn_mfma_f32_16x16x32_bf16(Ah, Bh, acc, 0, 0, 0);
    acc = __builtin_amdgcn_mfma_f32_16x16x32_bf16(Ah, Bl, acc, 0, 0, 0);
    acc = __builtin_amdgcn_mfma_f32_16x16x32_bf16(Al, Bh, acc, 0, 0, 0);
  }
  float mx = fmaxf(fmaxf(acc[0], acc[1]), fmaxf(acc[2], acc[3]));
  mx = fmaxf(mx, 0.0f);
  mx = fmaxf(mx, __shfl_xor(mx, 16));
  mx = fmaxf(mx, __shfl_xor(mx, 32));
  if (lane < 16) atomicMax((int*)(g128 + (size_t)b*128 + wid*16 + lane), __float_as_int(mx));
}

// ---------------- T-Net edge via MFMA: h0=relu(A0+B0[j_k]) -> [20x64]@[64x128] -> col-max ----------------
__global__ __launch_bounds__(128) void k_tedge3m(const float* __restrict__ A0, const float* __restrict__ B0,
    const int* __restrict__ idx, const u16* __restrict__ Wh, const u16* __restrict__ Wl,
    float* __restrict__ out){
  __shared__ __align__(16) u16 hh[32*64];
  __shared__ __align__(16) u16 hl[32*64];
  __shared__ int js[KC];
  int bi = blockIdx.x, t = threadIdx.x;
  int rb = (bi >> 8) << 8;
  if (t < KC) js[t] = idx[(size_t)bi*KC + t];
  __syncthreads();
  for (int i = t; i < 256; i += 128){
    int r = i >> 3, kb = i & 7;
    i32x4 H = {0,0,0,0}, L = {0,0,0,0};
    if (r < KC){
      const float* a = A0 + (size_t)bi*64 + kb*8;
      const float* bm = B0 + (size_t)(rb + js[r])*64 + kb*8;
      unsigned hu[8], lu[8];
#pragma unroll
      for (int e = 0; e < 8; ++e){
        float v = fmaxf(a[e] + bm[e], 0.0f);
        bf16_split(v, hu[e], lu[e]);
      }
#pragma unroll
      for (int j2 = 0; j2 < 4; ++j2){
        H[j2] = (int)(hu[2*j2] | (hu[2*j2+1] << 16));
        L[j2] = (int)(lu[2*j2] | (lu[2*j2+1] << 16));
      }
    }
    int idx2 = r*64 + ((kb ^ (r & 7)) << 3);
    *(bf16x8*)(hh + idx2) = __builtin_bit_cast(bf16x8, H);
    *(bf16x8*)(hl + idx2) = __builtin_bit_cast(bf16x8, L);
  }
  __syncthreads();
  int lane = t & 63, wv = t >> 6;
  int col = lane & 15, g = lane >> 4;
  int aswz = col & 7;
#pragma unroll
  for (int tt = 0; tt < 4; ++tt){
    int ct = wv*4 + tt;
    float mx = 0.0f;
#pragma unroll
    for (int m = 0; m < 2; ++m){
      f32x4 acc = {0.f,0.f,0.f,0.f};
#pragma unroll
      for (int kt = 0; kt < 2; ++kt){
        int kb = kt*4 + g;
        int aidx = (m*16 + col)*64 + ((kb ^ aswz) << 3);
        bf16x8 Ah = *(const bf16x8*)(hh + aidx);
        bf16x8 Al = *(const bf16x8*)(hl + aidx);
        size_t wo = ((size_t)(ct*2 + kt)*64 + lane)*8;
        bf16x8 Bh = *(const bf16x8*)(Wh + wo);
        bf16x8 Bl = *(const bf16x8*)(Wl + wo);
        acc = __builtin_amdgcn_mfma_f32_16x16x32_bf16(Ah, Bh, acc, 0, 0, 0);
        acc = __builtin_amdgcn_mfma_f32_16x16x32_bf16(Ah, Bl, acc, 0, 0, 0);
        acc = __builtin_amdgcn_mfma_f32_16x16x32_bf16(Al, Bh, acc, 0, 0, 0);
      }
      mx = fmaxf(mx, fmaxf(fmaxf(acc[0], acc[1]), fmaxf(acc[2], acc[3])));
    }
    mx = fmaxf(mx, __shfl_xor(mx, 16));
    mx = fmaxf(mx, __shfl_xor(mx, 32));
    if (lane < 16) out[(size_t)bi*128 + ct*16 + col] = mx;
  }
}

// ---------------- edge epilogue: out[i][c] = max_k relu(A[i][c] + B[j_ik][c]) ----------------
template<int COUT>
__global__ __launch_bounds__(256) void k_emax(const float* __restrict__ A, const float* __restrict__ Bm,
    const int* __restrict__ idx, float* __restrict__ out){
  constexpr int GT = COUT/4;
  constexpr int NC = 256/GT;
  __shared__ int js[NC*KC];
  int bi = blockIdx.x, t = threadIdx.x;
  int li = t / GT, c4 = (t % GT)*4;
  int ci = bi*NC + li;
  int rb = (ci >> 8) << 8;
  if (t < NC*KC) js[t] = idx[(size_t)bi*NC*KC + t];
  __syncthreads();
  float4 a = *(const float4*)(A + (size_t)ci*COUT + c4);
  float4 p = make_float4(0.f,0.f,0.f,0.f);
#pragma unroll
  for (int k = 0; k < KC; ++k){
    int j = js[li*KC + k];
    float4 b = *(const float4*)(Bm + (size_t)(rb + j)*COUT + c4);
    p = max4(p, add4(a, b));
  }
  *(float4*)(out + (size_t)ci*COUT + c4) = p;
}

// ---------------- T-Net MLP + 3x3 transform applied to new_xyz ----------------
__global__ __launch_bounds__(256) void k_trest(const float* __restrict__ g1024,
    const float* __restrict__ Wg0, const float* __restrict__ Wg1,
    const float* __restrict__ Wl, const float* __restrict__ bl,
    const float* __restrict__ new_xyz, float* __restrict__ x131){
  __shared__ __align__(16) float g1[1024];
  __shared__ __align__(16) float g5[512];
  __shared__ __align__(16) float g2[256];
  __shared__ float tm[12];
  int b = blockIdx.x, t = threadIdx.x;
  for (int m = t; m < 1024; m += 256) g1[m] = g1024[(size_t)b*1024 + m];
  __syncthreads();
#pragma unroll
  for (int cc = 0; cc < 2; ++cc){
    int c = t + cc*256;
    const float4* wr = (const float4*)(Wg0 + (size_t)c*1024);
    const float4* gv = (const float4*)g1;
    float a = 0.0f;
    for (int qq = 0; qq < 256; ++qq) a = fma4(wr[qq], gv[qq], a);
    g5[c] = fmaxf(a, 0.0f);
  }
  __syncthreads();
  {
    const float4* wr = (const float4*)(Wg1 + (size_t)t*512);
    const float4* gv = (const float4*)g5;
    float a = 0.0f;
    for (int qq = 0; qq < 128; ++qq) a = fma4(wr[qq], gv[qq], a);
    g2[t] = fmaxf(a, 0.0f);
  }
  __syncthreads();
  if (t < 9){
    const float4* wr = (const float4*)(Wl + (size_t)t*256);
    const float4* gv = (const float4*)g2;
    float a = 0.0f;
#pragma unroll
    for (int qq = 0; qq < 64; ++qq) a = fma4(wr[qq], gv[qq], a);
    a += bl[t];
    if (t == 0 || t == 4 || t == 8) a += 1.0f;
    tm[t] = a;
  }
  __syncthreads();
  {
    const float* nx = new_xyz + ((size_t)b*NPp + t)*3;
    float X = nx[0], Y = nx[1], Z = nx[2];
#pragma unroll
    for (int i = 0; i < 3; ++i){
      float v = __fadd_rn(__fadd_rn(__fmul_rn(tm[i*3+0], X), __fmul_rn(tm[i*3+1], Y)), __fmul_rn(tm[i*3+2], Z));
      x131[((size_t)b*NPp + t)*132 + 128 + i] = v;
    }
  }
}

// ---------------- classifier head ----------------
__global__ __launch_bounds__(256) void k_final(const float* __restrict__ g128,
    const float* __restrict__ W0, const float* __restrict__ W1,
    const float* __restrict__ Wc, const float* __restrict__ bc, float* __restrict__ out){
  __shared__ __align__(16) float g0[128];
  __shared__ __align__(16) float g5[512];
  __shared__ __align__(16) float g2[256];
  int b = blockIdx.x, t = threadIdx.x;
  if (t < 128) g0[t] = g128[(size_t)b*128 + t];
  __syncthreads();
#pragma unroll
  for (int cc = 0; cc < 2; ++cc){
    int c = t + cc*256;
    const float4* wr = (const float4*)(W0 + (size_t)c*128);
    const float4* gv = (const float4*)g0;
    float a = 0.0f;
#pragma unroll
    for (int qq = 0; qq < 32; ++qq) a = fma4(wr[qq], gv[qq], a);
    g5[c] = fmaxf(a, 0.0f);
  }
  __syncthreads();
  {
    const float4* wr = (const float4*)(W1 + (size_t)t*512);
    const float4* gv = (const float4*)g5;
    float a = 0.0f;
    for (int qq = 0; qq < 128; ++qq) a = fma4(wr[qq], gv[qq], a);
    g2[t] = fmaxf(a, 0.0f);
  }
  __syncthreads();
  if (t < 40){
    const float4* wr = (const float4*)(Wc + (size_t)t*256);
    const float4* gv = (const float4*)g2;
    float a = 0.0f;
#pragma unroll
    for (int qq = 0; qq < 64; ++qq) a = fma4(wr[qq], gv[qq], a);
    out[(size_t)b*40 + t] = a + bc[t];
  }
}

extern "C" void kernel_launch(void* const* d_in, const int* in_sizes, int n_in,
                              void* d_out, int out_size, void* d_ws, size_t ws_size,
                              hipStream_t stream){
  (void)in_sizes; (void)n_in; (void)out_size; (void)ws_size;
  const float* points     = (const float*)d_in[0];
  const float* sa_w0      = (const float*)d_in[1];
  const float* sa_w1      = (const float*)d_in[2];
  const float* sa_w2      = (const float*)d_in[3];
  const float* t_ec_w0    = (const float*)d_in[4];
  const float* t_ec_w1    = (const float*)d_in[5];
  const float* t_local_w  = (const float*)d_in[6];
  const float* t_g_w0     = (const float*)d_in[7];
  const float* t_g_w1     = (const float*)d_in[8];
  const float* t_lin_w    = (const float*)d_in[9];
  const float* t_lin_b    = (const float*)d_in[10];
  const float* dg_ec_w0   = (const float*)d_in[11];
  const float* dg_ec_w1   = (const float*)d_in[12];
  const float* dg_ec_w2   = (const float*)d_in[13];
  const float* dg_local_w = (const float*)d_in[14];
  const float* dg_g_w0    = (const float*)d_in[15];
  const float* dg_g_w1    = (const float*)d_in[16];
  const float* cls_w      = (const float*)d_in[17];
  const float* cls_b      = (const float*)d_in[18];
  float* out = (float*)d_out;

  float* ws     = (float*)d_ws;
  float* xyz    = ws;                    // 393216
  float* xnrm   = xyz    + 393216;       // 131072
  float* nxyz   = xnrm   + 131072;       // 24576
  float* feat   = nxyz   + 24576;        // 1048576 (dead output buffer -> MFMA weight frags)
  float* x131   = feat   + 1048576;      // 1081344
  float* nrm    = x131   + 1081344;      // 8192
  int*   idx    = (int*)(nrm + 8192);    // 163840
  float* ht     = (float*)(idx + 163840);// 1048576 (reused as f1)
  float* g1024v = ht     + 1048576;      // 32768
  float* f2     = g1024v + 32768;        // 2097152
  float* f3     = f2     + 2097152;      // 4194304
  float* g128v  = f3     + 4194304;      // 4096
  float* wt_t1  = g128v  + 4096;         // 8192   (legacy, unwritten)
  float* waT0   = wt_t1  + 8192;         // 8384   (legacy, unwritten)
  float* wbT0   = waT0   + 8384;         // 8384
  float* waD0   = wbT0   + 8384;         // 16768
  float* wbD0   = waD0   + 16768;        // 16768
  float* waD1   = wbD0   + 16768;        // 32768
  float* wbD1   = waD1   + 32768;        // 32768
  float* waD2   = wbD1   + 32768;        // 131072
  float* wbD2   = waD2   + 131072;       // 131072
  float* Ab     = wbD2   + 131072;       // 4194304
  float* Bb     = Ab     + 4194304;      // 4194304
  float* w1Tb   = Bb     + 4194304;      // 4096   (legacy)
  (void)wt_t1; (void)waT0; (void)wbT0; (void)waD0; (void)wbD0;
  (void)waD1; (void)wbD1; (void)waD2; (void)wbD2; (void)w1Tb;
  float* f1 = ht;
  float* xT = f3;                        // alias: xT lives in f3 until k_emax<512> writes f3

  // SA MFMA weight fragments alias the HEAD of Ab.
  float* w0f    = Ab;                    // 4096   ([kt][lane][e][4])
  u16*   w1fh   = (u16*)(w0f + 4096);    // 4096 u16
  u16*   w1fl   = w1fh   + 4096;         // 4096 u16
  u16*   w2fh   = w1fl   + 4096;         // 8192 u16
  u16*   w2fl   = w2fh   + 8192;         // 8192 u16

  // All GEMM weight frags live in the DEAD `feat` buffer (4MB; nothing reads it).
  u16* fragu  = (u16*)feat;
  u16* wAD1h  = fragu;                   // 32768
  u16* wAD1l  = wAD1h + 32768;           // 32768
  u16* wBD1h  = wAD1l + 32768;           // 32768
  u16* wBD1l  = wBD1h + 32768;           // 32768
  u16* wAD2h  = wBD1l + 32768;           // 131072
  u16* wAD2l  = wAD2h + 131072;          // 131072
  u16* wBD2h  = wAD2l + 131072;          // 131072
  u16* wBD2l  = wBD2h + 131072;          // 131072
  u16* wTPh   = wBD2l + 131072;          // 131072 (t_local_w frags)
  u16* wTPl   = wTPh  + 131072;          // 131072
  u16* wDGh   = wTPl  + 131072;          // 114688 (dg_local_w frags)
  u16* wDGl   = wDGh  + 114688;          // 114688
  u16* wTEh   = wDGl  + 114688;          // 8192   (t_ec_w1 tedge frags)
  u16* wTEl   = wTEh  + 8192;            // 8192
  u16* wAT0h  = wTEl  + 8192;            // 10240  (padded t_ec_w0 A)
  u16* wAT0l  = wAT0h + 10240;           // 10240
  u16* wBT0h  = wAT0l + 10240;           // 10240
  u16* wBT0l  = wBT0h + 10240;           // 10240
  u16* wAD0h  = wBT0l + 10240;           // 20480  (padded dg_ec_w0 A)
  u16* wAD0l  = wAD0h + 20480;           // 20480
  u16* wBD0h  = wAD0l + 20480;           // 20480
  u16* wBD0l  = wBD0h + 20480;           // 20480

  // Part 1 (xyz/xnrm) must complete before fps reads xyz.
  k_prep_pts<<<512, 256, 0, stream>>>(points, xyz, xnrm);
  // FPS (blocks 0-31) + all frag prep (blocks 32-5183) overlapped in ONE kernel.
  k_fpsprep<<<5184, 128, 0, stream>>>(xyz, nxyz,
                                      t_ec_w0, t_ec_w1, dg_ec_w0, dg_ec_w1, dg_ec_w2,
                                      sa_w0, sa_w1, sa_w2, t_local_w, dg_local_w,
                                      w0f, w1fh, w1fl, w2fh, w2fl,
                                      wAD1h, wAD1l, wBD1h, wBD1l, wAD2h, wAD2l, wBD2h, wBD2l,
                                      wTPh, wTPl, wDGh, wDGl, wTEh, wTEl,
                                      wAT0h, wAT0l, wBT0h, wBT0l, wAD0h, wAD0l, wBD0h, wBD0l);
  k_sa<<<BB*NPp, 64, 0, stream>>>(points, xyz, xnrm, nxyz, w0f, w1fh, w1fl, w2fh, w2fl, x131);

  // T-Net branch (x = [feat, new_xyz]) -- MFMA with zero-padded K
  k_gabp<131,160,64><<<512, 512, 0, stream>>>(x131, 132, wAT0h, wAT0l, wBT0h, wBT0l, Ab, Bb, xT, nrm);
  k_knn3<131><<<1024, 512, 0, stream>>>(xT, nrm, idx);
  k_tedge3m<<<BB*NPp, 128, 0, stream>>>(Ab, Bb, idx, wTEh, wTEl, ht);
  k_tpoolm<<<dim3(BB, 16), 512, 0, stream>>>(ht, wTPh, wTPl, g1024v);
  k_trest<<<BB, 256, 0, stream>>>(g1024v, t_g_w0, t_g_w1, t_lin_w, t_lin_b, nxyz, x131);

  // DGCNN layer 1 -- MFMA with zero-padded K
  k_gabp<131,160,128><<<512, 512, 0, stream>>>(x131, 132, wAD0h, wAD0l, wBD0h, wBD0l, Ab, Bb, xT, nrm);
  k_knn3<131><<<1024, 512, 0, stream>>>(xT, nrm, idx);
  k_emax<128><<<1024, 256, 0, stream>>>(Ab, Bb, idx, f1);
  // layer 2 -- MFMA
  k_gabm<128,256><<<512, 512, 0, stream>>>(f1, 128, wAD1h, wAD1l, wBD1h, wBD1l, Ab, Bb, xT, nrm);
  k_knn3<128><<<1024, 512, 0, stream>>>(xT, nrm, idx);
  k_emax<256><<<2048, 256, 0, stream>>>(Ab, Bb, idx, f2);
  // layer 3 -- MFMA
  k_gabm<256,512><<<512, 512, 0, stream>>>(f2, 256, wAD2h, wAD2l, wBD2h, wBD2l, Ab, Bb, xT, nrm);
  k_knn3<256><<<1024, 512, 0, stream>>>(xT, nrm, idx);
  k_emax<512><<<4096, 256, 0, stream>>>(Ab, Bb, idx, f3);

  // local conv (MFMA) + global pool + head
  k_dglm<<<dim3(BB, 16), 512, 0, stream>>>(f1, f2, f3, wDGh, wDGl, g128v);
  k_final<<<BB, 256, 0, stream>>>(g128v, dg_g_w0, dg_g_w1, cls_w, cls_b, out);
}